// Round 7
// baseline (288.341 us; speedup 1.0000x reference)
//
#include <hip/hip_runtime.h>
#include <hip/hip_bf16.h>

// ---------------- constants ----------------
#define EPS 1e-6f
#define NBH 32      // B*H
#define LSEQ 1024
#define DHD 64

typedef unsigned short u16;
typedef __bf16 bf16x8 __attribute__((ext_vector_type(8)));
typedef float f32x4 __attribute__((ext_vector_type(4)));

__device__ inline u16 f2bf(float f){
  union { float f; unsigned u; } un; un.f = f;
  unsigned u = un.u;
  u += 0x7fffu + ((u >> 16) & 1u);
  return (u16)(u >> 16);
}

__device__ inline float wred64(float v){
#pragma unroll
  for (int off = 32; off > 0; off >>= 1) v += __shfl_xor(v, off, 64);
  return v;
}

__device__ inline float wscan64(float v, int lane){
  float run = v;
#pragma unroll
  for (int off = 1; off < 64; off <<= 1){
    float t = __shfl_up(run, off, 64);
    if (lane >= off) run += t;
  }
  return run;   // inclusive
}

__device__ inline void gload_lds16(const u16* g, u16* l){
  __builtin_amdgcn_global_load_lds(
      (const __attribute__((address_space(1))) unsigned int*)g,
      (__attribute__((address_space(3))) unsigned int*)l, 16, 0, 0);
}

// ---------------- converts ----------------
__global__ __launch_bounds__(256) void f2bf_kernel(const float* __restrict__ in,
                                                   u16* __restrict__ out, int n4){
  int i = blockIdx.x * 256 + threadIdx.x;
  if (i < n4){
    float4 v = reinterpret_cast<const float4*>(in)[i];
    ushort4 o; o.x = f2bf(v.x); o.y = f2bf(v.y); o.z = f2bf(v.z); o.w = f2bf(v.w);
    reinterpret_cast<ushort4*>(out)[i] = o;
  }
}

// generic 32x32-tile transpose+convert: out[c][r] = bf16(in[r][c])
__device__ inline void tr_tile(const float* in, u16* out, int R, int C){
  __shared__ float tile[32][33];
  int x = threadIdx.x & 31, y = threadIdx.x >> 5;
  int r0 = blockIdx.y * 32, c0 = blockIdx.x * 32;
#pragma unroll
  for (int j = 0; j < 4; j++)
    tile[y + j*8][x] = in[(size_t)(r0 + y + j*8) * C + c0 + x];
  __syncthreads();
#pragma unroll
  for (int j = 0; j < 4; j++)
    out[(size_t)(c0 + y + j*8) * R + r0 + x] = f2bf(tile[x][y + j*8]);
}

__global__ __launch_bounds__(256) void transpose_f2bf(const float* __restrict__ in,
                                                      u16* __restrict__ out, int R, int C){
  tr_tile(in, out, R, C);
}

// 4x 1024x1024 transposes in one launch (z selects matrix)
__global__ __launch_bounds__(256) void transpose4_f2bf(
    const float* __restrict__ w0, const float* __restrict__ w1,
    const float* __restrict__ w2, const float* __restrict__ w3,
    u16* __restrict__ dqkv, u16* __restrict__ dwo){
  int z = blockIdx.z;
  const float* in = (z == 0) ? w0 : (z == 1) ? w1 : (z == 2) ? w2 : w3;
  u16* out = (z < 3) ? (dqkv + (size_t)z * 1024 * 1024) : dwo;
  tr_tile(in, out, 1024, 1024);
}

// gather q/k/v biases into one 3072 vector
__global__ __launch_bounds__(256) void bias_gather(const float* __restrict__ bq,
                                                   const float* __restrict__ bk,
                                                   const float* __restrict__ bv,
                                                   float* __restrict__ dst){
  int i = blockIdx.x * 256 + threadIdx.x;
  if (i < 3072){
    float v = (i < 1024) ? bq[i] : (i < 2048) ? bk[i - 1024] : bv[i - 2048];
    dst[i] = v;
  }
}

// ---------------- bf16 MFMA GEMM (single-buffer m97, small tiles, opt split-K) --------
// C[M,N] = act(A[M,K] @ Bt[N,K]^T + bias)
// ACT: 0 none, 2 gelu(exact)  (OM==1 applies sigmoid for col<2048 internally)
// OM: 1 fused-QKV remap to 3x[B,H,L,DH]; 3 bf16 [M][N];
//     4 raw f32 partial (split-K slice z at outF + z*M*N, no bias)
// blockIdx: x = m-tile, y = n-tile, z = k-slice (gridDim.z slices)
template<int BM, int BN, int ACT, int OM>
__global__ __launch_bounds__(256) void gemm_mfma(
    const u16* __restrict__ A, const u16* __restrict__ Bt,
    const float* __restrict__ bias, const float* __restrict__ resid,
    float* __restrict__ outF, u16* __restrict__ outB,
    int M, int N, int K)
{
  constexpr int BK = 64;
  constexpr int MI = BM / 32;
  constexpr int NJ = BN / 32;
  constexpr int RA = BM / 32;           // A staging rounds (256 thr x 16B)
  constexpr int RB = BN / 32;
  __shared__ u16 As[BM * BK];
  __shared__ u16 Bs[BN * BK];
  const int tid = threadIdx.x;
  const int lane = tid & 63, wave = tid >> 6;
  const int lrow = lane & 15, lg = lane >> 4;
  const int m0 = blockIdx.x * BM, n0 = blockIdx.y * BN;
  const int wm = (wave >> 1) * (BM / 2), wn = (wave & 1) * (BN / 2);

  const int ksz = K / gridDim.z;
  const int k_begin = blockIdx.z * ksz;
  const int k_end = k_begin + ksz;

  f32x4 acc[MI][NJ];
#pragma unroll
  for (int i = 0; i < MI; i++)
#pragma unroll
    for (int j = 0; j < NJ; j++) acc[i][j] = (f32x4){0.f, 0.f, 0.f, 0.f};

  const u16* Ab = A + (size_t)m0 * K;
  const u16* Bb = Bt + (size_t)n0 * K;

  for (int k0 = k_begin; k0 < k_end; k0 += BK){
    __syncthreads();                    // previous compute done with LDS
#pragma unroll
    for (int r = 0; r < RA; ++r){
      int c = r * 256 + tid;
      int row = c >> 3, kk = (c & 7) << 3;
      gload_lds16(Ab + (size_t)row * K + k0 + kk, &As[(r * 256 + wave * 64) * 8]);
    }
#pragma unroll
    for (int r = 0; r < RB; ++r){
      int c = r * 256 + tid;
      int row = c >> 3, kk = (c & 7) << 3;
      gload_lds16(Bb + (size_t)row * K + k0 + kk, &Bs[(r * 256 + wave * 64) * 8]);
    }
    __syncthreads();                    // staging complete (compiler drains vmcnt)
#pragma unroll
    for (int kh = 0; kh < 2; ++kh){
      bf16x8 af[MI], bfv[NJ];
#pragma unroll
      for (int i = 0; i < MI; ++i)
        af[i] = *reinterpret_cast<const bf16x8*>(&As[(wm + i * 16 + lrow) * BK + kh * 32 + lg * 8]);
#pragma unroll
      for (int j = 0; j < NJ; ++j)
        bfv[j] = *reinterpret_cast<const bf16x8*>(&Bs[(wn + j * 16 + lrow) * BK + kh * 32 + lg * 8]);
#pragma unroll
      for (int i = 0; i < MI; ++i)
#pragma unroll
        for (int j = 0; j < NJ; ++j)
          acc[i][j] = __builtin_amdgcn_mfma_f32_16x16x32_bf16(af[i], bfv[j], acc[i][j], 0, 0, 0);
    }
  }

#pragma unroll
  for (int i = 0; i < MI; ++i){
#pragma unroll
    for (int j = 0; j < NJ; ++j){
      int col = n0 + wn + j * 16 + lrow;
      float bv = (OM != 4 && bias) ? bias[col] : 0.f;
#pragma unroll
      for (int r = 0; r < 4; ++r){
        int row = m0 + wm + i * 16 + lg * 4 + r;
        float x = acc[i][j][r] + bv;
        if (OM == 1){
          if (col < 2048) x = 1.f / (1.f + expf(-x));
          int which = col >> 10, cc = col & 1023, h = cc >> 6, d = cc & 63;
          int b = row >> 10, l = row & 1023;
          outF[(size_t)which * (2048ull * 1024) +
               (((size_t)(b * 16 + h)) * 1024 + l) * 64 + d] = x;
        } else if (OM == 4){
          outF[((size_t)blockIdx.z * M + row) * N + col] = x;
        } else {
          if (ACT == 2) x = 0.5f * x * (1.f + erff(x * 0.70710678118654752f));
          outB[(size_t)row * N + col] = f2bf(x);
        }
      }
    }
  }
}

// ---------------- attention scalar pipeline (chunked Gram-tile form) ----------------
__global__ __launch_bounds__(256) void chunk_sums(const float* __restrict__ k, const float* __restrict__ q,
                                                  float* __restrict__ ck, float* __restrict__ cq){
  int blk = blockIdx.x;
  int lane = threadIdx.x & 63, wave = threadIdx.x >> 6;
  size_t base = (size_t)blk * 64 * DHD;
  float sk = 0.f, sq = 0.f;
  for (int l = wave * 16; l < wave * 16 + 16; l++){
    sk += k[base + l * 64 + lane];
    sq += q[base + l * 64 + lane];
  }
  __shared__ float rd[2][4][64];
  rd[0][wave][lane] = sk; rd[1][wave][lane] = sq;
  __syncthreads();
  if (wave == 0){
    ck[(size_t)blk * 64 + lane] = rd[0][0][lane] + rd[0][1][lane] + rd[0][2][lane] + rd[0][3][lane];
    cq[(size_t)blk * 64 + lane] = rd[1][0][lane] + rd[1][1][lane] + rd[1][2][lane] + rd[1][3][lane];
  }
}

// sink_in/src_out via G = Q K^T tile; also emits weighted chunk sums cso=sum so*k, cqsi=sum si*q
__global__ __launch_bounds__(256) void sink_tile(
    const float* __restrict__ q, const float* __restrict__ k,
    const float* __restrict__ ck, const float* __restrict__ cq,
    float* __restrict__ sink_in, float* __restrict__ src_out,
    float* __restrict__ cso, float* __restrict__ cqsi)
{
  int blk = blockIdx.x, bh = blk >> 4, c = blk & 15;
  int tid = threadIdx.x, lane = tid & 63, wave = tid >> 6;
  __shared__ float qT[64][65], kT[64][65], G[64][66];
  __shared__ float PK[64], PQ[64];
  __shared__ float rk[64], rq[64], crk[64], crq[64], siv[64], sov[64];
  __shared__ float rd[2][4][64];
  size_t base = ((size_t)bh * LSEQ + c * 64) * DHD;
  const float* qb = q + base; const float* kb = k + base;
  for (int c4 = tid; c4 < 1024; c4 += 256){
    int l = c4 >> 4, d0 = (c4 & 15) * 4;
    float4 qv = *reinterpret_cast<const float4*>(qb + c4 * 4);
    qT[d0+0][l] = qv.x; qT[d0+1][l] = qv.y; qT[d0+2][l] = qv.z; qT[d0+3][l] = qv.w;
    float4 kv = *reinterpret_cast<const float4*>(kb + c4 * 4);
    kT[d0+0][l] = kv.x; kT[d0+1][l] = kv.y; kT[d0+2][l] = kv.z; kT[d0+3][l] = kv.w;
  }
  if (tid < 64){
    float pk = 0.f, pq = 0.f;
    for (int cc = 0; cc < c; cc++){
      pk += ck[((size_t)bh * 16 + cc) * 64 + tid];
      pq += cq[((size_t)bh * 16 + cc) * 64 + tid];
    }
    PK[tid] = pk; PQ[tid] = pq;
  }
  __syncthreads();
  for (int j = wave * 16; j < wave * 16 + 16; j++){
    float s = wred64(kT[lane][j]);  if (lane == 0) rk[j] = s;
    float s2 = wred64(qT[lane][j]); if (lane == 0) rq[j] = s2;
  }
  float sumPK = wred64(PK[lane]);
  float sumPQ = wred64(PQ[lane]);
  {
    int l = lane, g = wave;
    float qrow[64];
#pragma unroll
    for (int d = 0; d < 64; d++) qrow[d] = qT[d][l];
    float p[16] = {};
    for (int d = 0; d < 64; d++){
      float qv = qrow[d];
#pragma unroll
      for (int j4 = 0; j4 < 4; j4++){
        float4 kk = *reinterpret_cast<const float4*>(&kT[d][g * 16 + j4 * 4]);
        p[j4*4+0] += qv * kk.x; p[j4*4+1] += qv * kk.y;
        p[j4*4+2] += qv * kk.z; p[j4*4+3] += qv * kk.w;
      }
    }
#pragma unroll
    for (int jj = 0; jj < 16; jj++) G[l][g * 16 + jj] = p[jj];
  }
  __syncthreads();
  if (wave == 0)      crk[lane] = wscan64(rk[lane], lane);
  else if (wave == 1) crq[lane] = wscan64(rq[lane], lane);
  __syncthreads();
  const float EPS2 = 64.f * EPS * EPS;
  for (int l = wave * 16; l < wave * 16 + 16; l++){
    float t1 = ((lane <= l) ? G[l][lane] : 0.f) + qT[lane][l] * PK[lane];
    float s1 = wred64(t1);
    float t2 = ((lane <= l) ? G[lane][l] : 0.f) + kT[lane][l] * PQ[lane];
    float s2 = wred64(t2);
    if (lane == 0){
      int L = c * 64 + l; float nrm = (float)(L + 1);
      float den1 = s1 + EPS * rq[l] + EPS * (sumPK + crk[l]) + EPS2;
      float den2 = s2 + EPS * rk[l] + EPS * (sumPQ + crq[l]) + EPS2;
      float si_ = nrm / den1, so_ = nrm / den2;
      sink_in[(size_t)bh * LSEQ + L] = si_;
      src_out[(size_t)bh * LSEQ + L] = so_;
      siv[l] = si_; sov[l] = so_;
    }
  }
  __syncthreads();
  float s1 = 0.f, s2 = 0.f;
  for (int l = wave * 16; l < wave * 16 + 16; l++){
    s1 += sov[l] * kT[lane][l];
    s2 += siv[l] * qT[lane][l];
  }
  rd[0][wave][lane] = s1; rd[1][wave][lane] = s2;
  __syncthreads();
  if (wave == 0){
    cso [(size_t)blk * 64 + lane] = rd[0][0][lane] + rd[0][1][lane] + rd[0][2][lane] + rd[0][3][lane];
    cqsi[(size_t)blk * 64 + lane] = rd[1][0][lane] + rd[1][1][lane] + rd[1][2][lane] + rd[1][3][lane];
  }
}

// cons_sink -> sa = sigmoid; cons_src -> clip -> ebuf = exp
__global__ __launch_bounds__(256) void cons_tile(
    const float* __restrict__ q, const float* __restrict__ k,
    const float* __restrict__ cso, const float* __restrict__ cqsi,
    const float* __restrict__ sink_in, const float* __restrict__ src_out,
    float* __restrict__ sa, float* __restrict__ ebuf)
{
  int blk = blockIdx.x, bh = blk >> 4, c = blk & 15;
  int tid = threadIdx.x, lane = tid & 63, wave = tid >> 6;
  __shared__ float qT[64][65], kT[64][65], G[64][66];
  __shared__ float PKso[64], PQsi[64];
  __shared__ float rk[64], rq[64], cwrk[64], cwrq[64], siv[64], sov[64];
  size_t base = ((size_t)bh * LSEQ + c * 64) * DHD;
  const float* qb = q + base; const float* kb = k + base;
  for (int c4 = tid; c4 < 1024; c4 += 256){
    int l = c4 >> 4, d0 = (c4 & 15) * 4;
    float4 qv = *reinterpret_cast<const float4*>(qb + c4 * 4);
    qT[d0+0][l] = qv.x; qT[d0+1][l] = qv.y; qT[d0+2][l] = qv.z; qT[d0+3][l] = qv.w;
    float4 kv = *reinterpret_cast<const float4*>(kb + c4 * 4);
    kT[d0+0][l] = kv.x; kT[d0+1][l] = kv.y; kT[d0+2][l] = kv.z; kT[d0+3][l] = kv.w;
  }
  if (tid < 64){
    float pk = 0.f, pq = 0.f;
    for (int cc = 0; cc < c; cc++){
      pk += cso [((size_t)bh * 16 + cc) * 64 + tid];
      pq += cqsi[((size_t)bh * 16 + cc) * 64 + tid];
    }
    PKso[tid] = pk; PQsi[tid] = pq;
  } else if (tid < 128){
    int l = tid - 64;
    sov[l] = src_out[(size_t)bh * LSEQ + c * 64 + l];
    siv[l] = sink_in[(size_t)bh * LSEQ + c * 64 + l];
  }
  __syncthreads();
  for (int j = wave * 16; j < wave * 16 + 16; j++){
    float s = wred64(kT[lane][j]);  if (lane == 0) rk[j] = s;
    float s2 = wred64(qT[lane][j]); if (lane == 0) rq[j] = s2;
  }
  float sumPKso = wred64(PKso[lane]);
  float sumPQsi = wred64(PQsi[lane]);
  {
    int l = lane, g = wave;
    float qrow[64];
#pragma unroll
    for (int d = 0; d < 64; d++) qrow[d] = qT[d][l];
    float p[16] = {};
    for (int d = 0; d < 64; d++){
      float qv = qrow[d];
#pragma unroll
      for (int j4 = 0; j4 < 4; j4++){
        float4 kk = *reinterpret_cast<const float4*>(&kT[d][g * 16 + j4 * 4]);
        p[j4*4+0] += qv * kk.x; p[j4*4+1] += qv * kk.y;
        p[j4*4+2] += qv * kk.z; p[j4*4+3] += qv * kk.w;
      }
    }
#pragma unroll
    for (int jj = 0; jj < 16; jj++) G[l][g * 16 + jj] = p[jj];
  }
  __syncthreads();
  if (wave == 0)      cwrk[lane] = wscan64(sov[lane] * rk[lane], lane);
  else if (wave == 1) cwrq[lane] = wscan64(siv[lane] * rq[lane], lane);
  __syncthreads();
  const float EPS2 = 64.f * EPS * EPS;
  for (int l = wave * 16; l < wave * 16 + 16; l++){
    float t3 = ((lane <= l) ? sov[lane] * G[l][lane] : 0.f) + qT[lane][l] * PKso[lane];
    float s3 = wred64(t3);
    float t4 = ((lane <= l) ? siv[lane] * G[lane][l] : 0.f) + kT[lane][l] * PQsi[lane];
    float s4 = wred64(t4);
    if (lane == 0){
      int L = c * 64 + l; float nrm = (float)(L + 1);
      float cs = (s3 + EPS * rq[l] + EPS * (sumPKso + cwrk[l]) + EPS2) / nrm;
      sa[(size_t)bh * LSEQ + L] = 1.f / (1.f + expf(-cs));
      float c2 = (s4 + EPS * rk[l] + EPS * (sumPQsi + cwrq[l]) + EPS2) / nrm;
      c2 = fminf(1.f, fmaxf(-1.f, c2));
      ebuf[(size_t)bh * LSEQ + L] = expf(c2);
    }
  }
}

// src_comp = e / cumsum(e) * (l+1)
__global__ __launch_bounds__(64) void srccomp_kernel(const float* __restrict__ ebuf, float* __restrict__ sc){
  int bh = blockIdx.x; int lane = threadIdx.x;
  const float* eb = ebuf + (size_t)bh * LSEQ;
  float loc[16]; float s = 0.f;
#pragma unroll
  for (int i = 0; i < 16; i++){ loc[i] = eb[lane * 16 + i]; s += loc[i]; }
  float run = wscan64(s, lane);
  float acc = run - s;
  float* scb = sc + (size_t)bh * LSEQ;
#pragma unroll
  for (int i = 0; i < 16; i++){
    acc += loc[i];
    scb[lane * 16 + i] = loc[i] / acc * (float)(lane * 16 + i + 1);
  }
}

// qs = q*sink_in/(l+1);  vs = v*src_comp
__global__ __launch_bounds__(256) void scale_kernel(const float* __restrict__ q, const float* __restrict__ v,
                                                    const float* __restrict__ si, const float* __restrict__ sc,
                                                    float* __restrict__ qs, float* __restrict__ vs){
  int i0 = (blockIdx.x * 256 + threadIdx.x) * 8;
  int r = i0 >> 6; int l = r & (LSEQ - 1);
  float qcoef = si[r] / (float)(l + 1);
  float vcoef = sc[r];
#pragma unroll
  for (int t = 0; t < 8; t += 4){
    float4 qv = *reinterpret_cast<const float4*>(q + i0 + t);
    float4 vv = *reinterpret_cast<const float4*>(v + i0 + t);
    *reinterpret_cast<float4*>(qs + i0 + t) = make_float4(qv.x*qcoef, qv.y*qcoef, qv.z*qcoef, qv.w*qcoef);
    *reinterpret_cast<float4*>(vs + i0 + t) = make_float4(vv.x*vcoef, vv.y*vcoef, vv.z*vcoef, vv.w*vcoef);
  }
}

// ---------------- chunked causal linear attention ----------------
__global__ __launch_bounds__(256) void phaseA(const float* __restrict__ k, const float* __restrict__ vs,
                                              float* __restrict__ S){
  int blk = blockIdx.x; int bh = blk >> 4, c = blk & 15;
  __shared__ float ks[64][68], vss[64][68];
  int tid = threadIdx.x;
  size_t base = ((size_t)bh * LSEQ + c * 64) * DHD;
  const float* kb = k + base; const float* vb = vs + base;
  for (int c4 = tid; c4 < 1024; c4 += 256){
    int l = c4 >> 4, d0 = (c4 & 15) * 4;
    *reinterpret_cast<float4*>(&ks[l][d0])  = *reinterpret_cast<const float4*>(kb + c4 * 4);
    *reinterpret_cast<float4*>(&vss[l][d0]) = *reinterpret_cast<const float4*>(vb + c4 * 4);
  }
  __syncthreads();
  int m = tid >> 2, dg = tid & 3;
  float acc[16] = {};
  for (int l = 0; l < 64; l++){
    float vm = vss[l][m];
#pragma unroll
    for (int d4 = 0; d4 < 4; d4++){
      float4 kk = *reinterpret_cast<const float4*>(&ks[l][dg * 16 + d4 * 4]);
      acc[d4*4+0] += vm * kk.x; acc[d4*4+1] += vm * kk.y;
      acc[d4*4+2] += vm * kk.z; acc[d4*4+3] += vm * kk.w;
    }
  }
  float* Sb = S + (size_t)blk * 4096 + m * 64 + dg * 16;
#pragma unroll
  for (int d4 = 0; d4 < 4; d4++)
    *reinterpret_cast<float4*>(Sb + d4 * 4) =
        make_float4(acc[d4*4], acc[d4*4+1], acc[d4*4+2], acc[d4*4+3]);
}

__global__ __launch_bounds__(256) void phaseB(const float* __restrict__ S, float* __restrict__ KVp){
  int bh = blockIdx.x; int tid = threadIdx.x;
  int off = tid * 16;
  float acc[16] = {};
  for (int c = 0; c < 16; c++){
    size_t idx = ((size_t)bh * 16 + c) * 4096 + off;
#pragma unroll
    for (int t = 0; t < 4; t++)
      *reinterpret_cast<float4*>(KVp + idx + t * 4) =
          make_float4(acc[t*4], acc[t*4+1], acc[t*4+2], acc[t*4+3]);
#pragma unroll
    for (int t = 0; t < 4; t++){
      float4 sv = *reinterpret_cast<const float4*>(S + idx + t * 4);
      acc[t*4] += sv.x; acc[t*4+1] += sv.y; acc[t*4+2] += sv.z; acc[t*4+3] += sv.w;
    }
  }
}

__global__ __launch_bounds__(256) void phaseC(const float* __restrict__ qs, const float* __restrict__ k,
                                              const float* __restrict__ vs, const float* __restrict__ KVp,
                                              const float* __restrict__ sa, u16* __restrict__ x){
  int blk = blockIdx.x; int bh = blk >> 4, c = blk & 15;
  int b = bh >> 4, h = bh & 15;
  __shared__ float qsT[64][65];
  __shared__ float kT[64][68];
  __shared__ float vss[64][68];
  __shared__ float kvs[64][68];
  __shared__ float Ps[64][66];
  int tid = threadIdx.x;
  size_t base = ((size_t)bh * LSEQ + c * 64) * DHD;
  const float* qb = qs + base; const float* kb = k + base; const float* vb = vs + base;
  const float* kvb = KVp + (size_t)blk * 4096;
  for (int c4 = tid; c4 < 1024; c4 += 256){
    int l = c4 >> 4, d0 = (c4 & 15) * 4;
    float4 qv = *reinterpret_cast<const float4*>(qb + c4 * 4);
    qsT[d0+0][l] = qv.x; qsT[d0+1][l] = qv.y; qsT[d0+2][l] = qv.z; qsT[d0+3][l] = qv.w;
    float4 kv4 = *reinterpret_cast<const float4*>(kb + c4 * 4);
    kT[d0+0][l] = kv4.x; kT[d0+1][l] = kv4.y; kT[d0+2][l] = kv4.z; kT[d0+3][l] = kv4.w;
    *reinterpret_cast<float4*>(&vss[l][d0]) = *reinterpret_cast<const float4*>(vb + c4 * 4);
    *reinterpret_cast<float4*>(&kvs[l][d0]) = *reinterpret_cast<const float4*>(kvb + c4 * 4);
  }
  __syncthreads();
  int l = tid & 63, g = tid >> 6;
  float qrow[64];
#pragma unroll
  for (int d = 0; d < 64; d++) qrow[d] = qsT[d][l];

  float p[16] = {};
  for (int d = 0; d < 64; d++){
    float qv = qrow[d];
#pragma unroll
    for (int j4 = 0; j4 < 4; j4++){
      float4 kk = *reinterpret_cast<const float4*>(&kT[d][g * 16 + j4 * 4]);
      p[j4*4+0] += qv * kk.x; p[j4*4+1] += qv * kk.y;
      p[j4*4+2] += qv * kk.z; p[j4*4+3] += qv * kk.w;
    }
  }
#pragma unroll
  for (int jj = 0; jj < 16; jj++){
    int j = g * 16 + jj;
    Ps[l][j] = (j <= l) ? p[jj] : 0.f;
  }
  __syncthreads();

  float acc[16];
#pragma unroll
  for (int mm = 0; mm < 16; mm++){
    float a = 0.f;
#pragma unroll
    for (int d4 = 0; d4 < 16; d4++){
      float4 kv4 = *reinterpret_cast<const float4*>(&kvs[g * 16 + mm][d4 * 4]);
      a += qrow[d4*4+0]*kv4.x + qrow[d4*4+1]*kv4.y + qrow[d4*4+2]*kv4.z + qrow[d4*4+3]*kv4.w;
    }
    acc[mm] = a;
  }
  for (int j = 0; j < 64; j++){
    float pv = Ps[l][j];
#pragma unroll
    for (int m4 = 0; m4 < 4; m4++){
      float4 vv = *reinterpret_cast<const float4*>(&vss[j][g * 16 + m4 * 4]);
      acc[m4*4+0] += pv * vv.x; acc[m4*4+1] += pv * vv.y;
      acc[m4*4+2] += pv * vv.z; acc[m4*4+3] += pv * vv.w;
    }
  }
  float sav = sa[(size_t)bh * LSEQ + c * 64 + l];
  u16* xo = x + ((size_t)(b * 1024 + c * 64 + l)) * 1024 + h * 64 + g * 16;
#pragma unroll
  for (int mm = 0; mm < 16; mm++) xo[mm] = f2bf(acc[mm] * sav);
}

// ---------------- fused layernorms ----------------
// LN over (p0 + p1 + bias + resid); emits f32 + bf16 (Wo split-K combine + LN1)
__global__ __launch_bounds__(256) void ln_fused2b(
    const float* __restrict__ p0, const float* __restrict__ p1,
    const float* __restrict__ resid, const float* __restrict__ bias,
    const float* __restrict__ g, const float* __restrict__ b,
    float* __restrict__ out, u16* __restrict__ outbf){
  int row = blockIdx.x; int tid = threadIdx.x;
  int lane = tid & 63, wave = tid >> 6;
  size_t off = (size_t)row * 1024 + tid * 4;
  float4 a0 = *reinterpret_cast<const float4*>(p0 + off);
  float4 a1 = *reinterpret_cast<const float4*>(p1 + off);
  float4 rr = *reinterpret_cast<const float4*>(resid + off);
  float4 bb = *reinterpret_cast<const float4*>(bias + tid * 4);
  float4 v = make_float4(a0.x + a1.x + rr.x + bb.x, a0.y + a1.y + rr.y + bb.y,
                         a0.z + a1.z + rr.z + bb.z, a0.w + a1.w + rr.w + bb.w);
  float s = v.x + v.y + v.z + v.w;
  float s2 = v.x*v.x + v.y*v.y + v.z*v.z + v.w*v.w;
  s = wred64(s); s2 = wred64(s2);
  __shared__ float red[2][4];
  if (lane == 0){ red[0][wave] = s; red[1][wave] = s2; }
  __syncthreads();
  float S = red[0][0] + red[0][1] + red[0][2] + red[0][3];
  float S2 = red[1][0] + red[1][1] + red[1][2] + red[1][3];
  float mean = S * (1.f / 1024.f);
  float var = S2 * (1.f / 1024.f) - mean * mean;
  float inv = rsqrtf(var + 1e-5f);
  float4 gv = *reinterpret_cast<const float4*>(g + tid * 4);
  float4 bv = *reinterpret_cast<const float4*>(b + tid * 4);
  float y0 = (v.x - mean) * inv * gv.x + bv.x;
  float y1 = (v.y - mean) * inv * gv.y + bv.y;
  float y2 = (v.z - mean) * inv * gv.z + bv.z;
  float y3 = (v.w - mean) * inv * gv.w + bv.w;
  *reinterpret_cast<float4*>(out + off) = make_float4(y0, y1, y2, y3);
  ushort4 o; o.x = f2bf(y0); o.y = f2bf(y1); o.z = f2bf(y2); o.w = f2bf(y3);
  *reinterpret_cast<ushort4*>(outbf + off) = o;
}

// LN over (p0+p1+p2+p3 + bias + resid) -> f32 out (FFN2 split-K4 combine + LN2)
__global__ __launch_bounds__(256) void ln_fused4(
    const float* __restrict__ p0, const float* __restrict__ p1,
    const float* __restrict__ p2, const float* __restrict__ p3,
    const float* __restrict__ resid, const float* __restrict__ bias,
    const float* __restrict__ g, const float* __restrict__ b,
    float* __restrict__ out){
  int row = blockIdx.x; int tid = threadIdx.x;
  int lane = tid & 63, wave = tid >> 6;
  size_t off = (size_t)row * 1024 + tid * 4;
  float4 a0 = *reinterpret_cast<const float4*>(p0 + off);
  float4 a1 = *reinterpret_cast<const float4*>(p1 + off);
  float4 a2 = *reinterpret_cast<const float4*>(p2 + off);
  float4 a3 = *reinterpret_cast<const float4*>(p3 + off);
  float4 rr = *reinterpret_cast<const float4*>(resid + off);
  float4 bb = *reinterpret_cast<const float4*>(bias + tid * 4);
  float4 v = make_float4(a0.x + a1.x + a2.x + a3.x + rr.x + bb.x,
                         a0.y + a1.y + a2.y + a3.y + rr.y + bb.y,
                         a0.z + a1.z + a2.z + a3.z + rr.z + bb.z,
                         a0.w + a1.w + a2.w + a3.w + rr.w + bb.w);
  float s = v.x + v.y + v.z + v.w;
  float s2 = v.x*v.x + v.y*v.y + v.z*v.z + v.w*v.w;
  s = wred64(s); s2 = wred64(s2);
  __shared__ float red[2][4];
  if (lane == 0){ red[0][wave] = s; red[1][wave] = s2; }
  __syncthreads();
  float S = red[0][0] + red[0][1] + red[0][2] + red[0][3];
  float S2 = red[1][0] + red[1][1] + red[1][2] + red[1][3];
  float mean = S * (1.f / 1024.f);
  float var = S2 * (1.f / 1024.f) - mean * mean;
  float inv = rsqrtf(var + 1e-5f);
  float4 gv = *reinterpret_cast<const float4*>(g + tid * 4);
  float4 bv = *reinterpret_cast<const float4*>(b + tid * 4);
  float y0 = (v.x - mean) * inv * gv.x + bv.x;
  float y1 = (v.y - mean) * inv * gv.y + bv.y;
  float y2 = (v.z - mean) * inv * gv.z + bv.z;
  float y3 = (v.w - mean) * inv * gv.w + bv.w;
  *reinterpret_cast<float4*>(out + off) = make_float4(y0, y1, y2, y3);
}

// ---------------- launch ----------------
extern "C" void kernel_launch(void* const* d_in, const int* in_sizes, int n_in,
                              void* d_out, int out_size, void* d_ws, size_t ws_size,
                              hipStream_t stream){
  (void)in_sizes; (void)n_in; (void)out_size; (void)ws_size;
  const float* inputs = (const float*)d_in[0];
  const float* Wq = (const float*)d_in[2];  const float* bq = (const float*)d_in[3];
  const float* Wk = (const float*)d_in[4];  const float* bk = (const float*)d_in[5];
  const float* Wv = (const float*)d_in[6];  const float* bv = (const float*)d_in[7];
  const float* Wo = (const float*)d_in[8];  const float* bo = (const float*)d_in[9];
  const float* ln1g = (const float*)d_in[10]; const float* ln1b = (const float*)d_in[11];
  const float* W1 = (const float*)d_in[12]; const float* b1 = (const float*)d_in[13];
  const float* W2 = (const float*)d_in[14]; const float* b2 = (const float*)d_in[15];
  const float* ln2g = (const float*)d_in[16]; const float* ln2b = (const float*)d_in[17];
  float* out = (float*)d_out;

  char* wsp = (char*)d_ws; size_t off = 0;
  auto alloc = [&](size_t bytes) -> void* {
    off = (off + 255) & ~(size_t)255;
    void* p = wsp + off; off += bytes; return p;
  };
  const size_t MD = (size_t)2048 * 1024;
  u16* Xbf    = (u16*)alloc(MD * 2);
  u16* WqkvT  = (u16*)alloc((size_t)3 * 1024 * 1024 * 2);
  u16* WoT    = (u16*)alloc((size_t)1024 * 1024 * 2);
  u16* W1T    = (u16*)alloc((size_t)4096 * 1024 * 2);
  u16* W2T    = (u16*)alloc((size_t)4096 * 1024 * 2);
  float* bqkv = (float*)alloc(3072 * 4);
  float* qkvb = (float*)alloc(3 * MD * 4);
  float* qb = qkvb; float* kb = qkvb + MD; float* vb = qkvb + 2 * MD;
  // contiguous 32MB quad: attention {S, KVp, qs, vs}; later split-K partial store
  float* quad = (float*)alloc(4 * MD * 4);
  float* Sbuf = quad;            // S
  float* KVp  = quad + MD;       // KV prefix
  float* c1   = quad + 2 * MD;   // qs
  float* c2   = quad + 3 * MD;   // vs
  float* ckb  = (float*)alloc((size_t)512 * 64 * 4);
  float* cqb  = (float*)alloc((size_t)512 * 64 * 4);
  float* csob = (float*)alloc((size_t)512 * 64 * 4);
  float* cqsib= (float*)alloc((size_t)512 * 64 * 4);
  float* sink_in = (float*)alloc(NBH * LSEQ * 4);
  float* src_out = (float*)alloc(NBH * LSEQ * 4);
  float* sabuf   = (float*)alloc(NBH * LSEQ * 4);
  float* ebuf    = (float*)alloc(NBH * LSEQ * 4);
  float* scbuf   = (float*)alloc(NBH * LSEQ * 4);
  u16* xatt   = (u16*)alloc(MD * 2);
  u16* g1     = (u16*)alloc((size_t)2048 * 4096 * 2);
  // reuse after attention: Wo partials = quad[0..1]; FFN2 partials = quad[0..3]
  float* part = quad;
  float* hbuf = vb;              // LN1 f32 out (vb dead after scale_kernel)
  u16* hbf = (u16*)qb;           // LN1 bf16 out (qb dead after scale_kernel)

  // converts + weight prep
  f2bf_kernel<<<2048, 256, 0, stream>>>(inputs, Xbf, (int)(MD / 4));
  transpose4_f2bf<<<dim3(32, 32, 4), 256, 0, stream>>>(Wq, Wk, Wv, Wo, WqkvT, WoT);
  transpose_f2bf<<<dim3(128, 32), 256, 0, stream>>>(W1, W1T, 1024, 4096);
  transpose_f2bf<<<dim3(32, 128), 256, 0, stream>>>(W2, W2T, 4096, 1024);
  bias_gather<<<12, 256, 0, stream>>>(bq, bk, bv, bqkv);

  // fused QKV projection: BM=64,BN=64, grid 32x48 = 1536 blocks (6/CU)
  gemm_mfma<64, 64, 0, 1><<<dim3(32, 48), 256, 0, stream>>>(
      Xbf, WqkvT, bqkv, nullptr, qkvb, nullptr, 2048, 3072, 1024);

  // attention scalars (chunked Gram-tile pipeline)
  chunk_sums<<<512, 256, 0, stream>>>(kb, qb, ckb, cqb);
  sink_tile<<<512, 256, 0, stream>>>(qb, kb, ckb, cqb, sink_in, src_out, csob, cqsib);
  cons_tile<<<512, 256, 0, stream>>>(qb, kb, csob, cqsib, sink_in, src_out, sabuf, ebuf);
  srccomp_kernel<<<32, 64, 0, stream>>>(ebuf, scbuf);
  scale_kernel<<<1024, 256, 0, stream>>>(qb, vb, sink_in, scbuf, c1, c2);

  // chunked causal linear attention
  phaseA<<<512, 256, 0, stream>>>(kb, c2, Sbuf);
  phaseB<<<32, 256, 0, stream>>>(Sbuf, KVp);
  phaseC<<<512, 256, 0, stream>>>(c1, kb, c2, KVp, sabuf, xatt);

  // output projection: BM=64,BN=64, split-K=2 -> partials; combine fused into LN1
  gemm_mfma<64, 64, 0, 4><<<dim3(32, 16, 2), 256, 0, stream>>>(
      xatt, WoT, nullptr, nullptr, part, nullptr, 2048, 1024, 1024);
  ln_fused2b<<<2048, 256, 0, stream>>>(part, part + MD, inputs, bo, ln1g, ln1b, hbuf, hbf);

  // FFN1: BM=64,BN=128, grid 32x32 = 1024 blocks (4/CU)
  gemm_mfma<64, 128, 2, 3><<<dim3(32, 32), 256, 0, stream>>>(
      hbf, W1T, b1, nullptr, nullptr, g1, 2048, 4096, 1024);
  // FFN2: BM=64,BN=64, split-K=4, grid 32x16x4 = 2048 blocks (8/CU), raw partials
  gemm_mfma<64, 64, 0, 4><<<dim3(32, 16, 4), 256, 0, stream>>>(
      g1, W2T, nullptr, nullptr, part, nullptr, 2048, 1024, 4096);
  // LN2 fused with split-K4 reduce + bias + residual
  ln_fused4<<<2048, 256, 0, stream>>>(part, part + MD, part + 2 * MD, part + 3 * MD,
                                      hbuf, b2, ln2g, ln2b, out);
}

// Round 8
// 266.867 us; speedup vs baseline: 1.0805x; 1.0805x over previous
//
#include <hip/hip_runtime.h>
#include <hip/hip_bf16.h>

// ---------------- constants ----------------
#define EPS 1e-6f
#define NBH 32      // B*H
#define LSEQ 1024
#define DHD 64

typedef unsigned short u16;
typedef __bf16 bf16x8 __attribute__((ext_vector_type(8)));
typedef float f32x4 __attribute__((ext_vector_type(4)));

__device__ inline u16 f2bf(float f){
  union { float f; unsigned u; } un; un.f = f;
  unsigned u = un.u;
  u += 0x7fffu + ((u >> 16) & 1u);
  return (u16)(u >> 16);
}

__device__ inline float wred64(float v){
#pragma unroll
  for (int off = 32; off > 0; off >>= 1) v += __shfl_xor(v, off, 64);
  return v;
}

__device__ inline float wscan64(float v, int lane){
  float run = v;
#pragma unroll
  for (int off = 1; off < 64; off <<= 1){
    float t = __shfl_up(run, off, 64);
    if (lane >= off) run += t;
  }
  return run;   // inclusive
}

__device__ inline void gload_lds16(const u16* g, u16* l){
  __builtin_amdgcn_global_load_lds(
      (const __attribute__((address_space(1))) unsigned int*)g,
      (__attribute__((address_space(3))) unsigned int*)l, 16, 0, 0);
}

// ---------------- converts ----------------
__global__ __launch_bounds__(256) void f2bf_kernel(const float* __restrict__ in,
                                                   u16* __restrict__ out, int n4){
  int i = blockIdx.x * 256 + threadIdx.x;
  if (i < n4){
    float4 v = reinterpret_cast<const float4*>(in)[i];
    ushort4 o; o.x = f2bf(v.x); o.y = f2bf(v.y); o.z = f2bf(v.z); o.w = f2bf(v.w);
    reinterpret_cast<ushort4*>(out)[i] = o;
  }
}

// generic 32x32-tile transpose+convert: out[c][r] = bf16(in[r][c])
__device__ inline void tr_tile(const float* in, u16* out, int R, int C){
  __shared__ float tile[32][33];
  int x = threadIdx.x & 31, y = threadIdx.x >> 5;
  int r0 = blockIdx.y * 32, c0 = blockIdx.x * 32;
#pragma unroll
  for (int j = 0; j < 4; j++)
    tile[y + j*8][x] = in[(size_t)(r0 + y + j*8) * C + c0 + x];
  __syncthreads();
#pragma unroll
  for (int j = 0; j < 4; j++)
    out[(size_t)(c0 + y + j*8) * R + r0 + x] = f2bf(tile[x][y + j*8]);
}

__global__ __launch_bounds__(256) void transpose_f2bf(const float* __restrict__ in,
                                                      u16* __restrict__ out, int R, int C){
  tr_tile(in, out, R, C);
}

// 4x 1024x1024 transposes in one launch (z selects matrix)
__global__ __launch_bounds__(256) void transpose4_f2bf(
    const float* __restrict__ w0, const float* __restrict__ w1,
    const float* __restrict__ w2, const float* __restrict__ w3,
    u16* __restrict__ dqkv, u16* __restrict__ dwo){
  int z = blockIdx.z;
  const float* in = (z == 0) ? w0 : (z == 1) ? w1 : (z == 2) ? w2 : w3;
  u16* out = (z < 3) ? (dqkv + (size_t)z * 1024 * 1024) : dwo;
  tr_tile(in, out, 1024, 1024);
}

// gather q/k/v biases into one 3072 vector
__global__ __launch_bounds__(256) void bias_gather(const float* __restrict__ bq,
                                                   const float* __restrict__ bk,
                                                   const float* __restrict__ bv,
                                                   float* __restrict__ dst){
  int i = blockIdx.x * 256 + threadIdx.x;
  if (i < 3072){
    float v = (i < 1024) ? bq[i] : (i < 2048) ? bk[i - 1024] : bv[i - 2048];
    dst[i] = v;
  }
}

// ---------------- bf16 MFMA GEMM (single-buffer, T2 XOR-swizzled LDS) --------
// C[M,N] = act(A[M,K] @ Bt[N,K]^T + bias)
// LDS layout: BK=64 bf16 rows = 128B = 8 x 16B slots. Logical slot s of row r is
// stored at physical slot s^(r&7) (rule #21: global_load_lds writes linearly, so
// the SOURCE address is pre-swizzled and the READ applies the same involution).
// Kills the 16-way ds_read_b128 bank conflict of the naive stride-128B layout.
// ACT: 0 none, 2 gelu(exact)  (OM==1 applies sigmoid for col<2048 internally)
// OM: 1 fused-QKV remap to 3x[B,H,L,DH]; 3 bf16 [M][N];
//     4 raw f32 partial (split-K slice z at outF + z*M*N, no bias)
template<int BM, int BN, int ACT, int OM>
__global__ __launch_bounds__(256) void gemm_mfma(
    const u16* __restrict__ A, const u16* __restrict__ Bt,
    const float* __restrict__ bias, const float* __restrict__ resid,
    float* __restrict__ outF, u16* __restrict__ outB,
    int M, int N, int K)
{
  constexpr int BK = 64;
  constexpr int MI = BM / 32;
  constexpr int NJ = BN / 32;
  constexpr int RA = BM / 32;           // A staging rounds (256 thr x 16B)
  constexpr int RB = BN / 32;
  __shared__ u16 As[BM * BK];
  __shared__ u16 Bs[BN * BK];
  const int tid = threadIdx.x;
  const int lane = tid & 63, wave = tid >> 6;
  const int lrow = lane & 15, lg = lane >> 4;
  const int m0 = blockIdx.x * BM, n0 = blockIdx.y * BN;
  const int wm = (wave >> 1) * (BM / 2), wn = (wave & 1) * (BN / 2);

  const int ksz = K / gridDim.z;
  const int k_begin = blockIdx.z * ksz;
  const int k_end = k_begin + ksz;

  f32x4 acc[MI][NJ];
#pragma unroll
  for (int i = 0; i < MI; i++)
#pragma unroll
    for (int j = 0; j < NJ; j++) acc[i][j] = (f32x4){0.f, 0.f, 0.f, 0.f};

  const u16* Ab = A + (size_t)m0 * K;
  const u16* Bb = Bt + (size_t)n0 * K;

  // swizzled fragment slot per (kh, lane): physical slot = (kh*4+lg) ^ (lrow&7)
  const int s0 = ((0 * 4 + lg) ^ (lrow & 7)) * 8;
  const int s1 = ((1 * 4 + lg) ^ (lrow & 7)) * 8;

  for (int k0 = k_begin; k0 < k_end; k0 += BK){
    __syncthreads();                    // previous compute done with LDS
#pragma unroll
    for (int r = 0; r < RA; ++r){
      int c = r * 256 + tid;            // 16B chunk id: row = c>>3, phys slot = c&7
      int row = c >> 3;
      int kk = ((c ^ row) & 7) << 3;    // logical slot = phys ^ (row&7)
      gload_lds16(Ab + (size_t)row * K + k0 + kk, &As[(r * 256 + wave * 64) * 8]);
    }
#pragma unroll
    for (int r = 0; r < RB; ++r){
      int c = r * 256 + tid;
      int row = c >> 3;
      int kk = ((c ^ row) & 7) << 3;
      gload_lds16(Bb + (size_t)row * K + k0 + kk, &Bs[(r * 256 + wave * 64) * 8]);
    }
    __syncthreads();                    // staging complete (compiler drains vmcnt)
#pragma unroll
    for (int kh = 0; kh < 2; ++kh){
      const int ss = (kh == 0) ? s0 : s1;
      bf16x8 af[MI], bfv[NJ];
#pragma unroll
      for (int i = 0; i < MI; ++i)
        af[i] = *reinterpret_cast<const bf16x8*>(&As[(wm + i * 16 + lrow) * BK + ss]);
#pragma unroll
      for (int j = 0; j < NJ; ++j)
        bfv[j] = *reinterpret_cast<const bf16x8*>(&Bs[(wn + j * 16 + lrow) * BK + ss]);
#pragma unroll
      for (int i = 0; i < MI; ++i)
#pragma unroll
        for (int j = 0; j < NJ; ++j)
          acc[i][j] = __builtin_amdgcn_mfma_f32_16x16x32_bf16(af[i], bfv[j], acc[i][j], 0, 0, 0);
    }
  }

#pragma unroll
  for (int i = 0; i < MI; ++i){
#pragma unroll
    for (int j = 0; j < NJ; ++j){
      int col = n0 + wn + j * 16 + lrow;
      float bv = (OM != 4 && bias) ? bias[col] : 0.f;
#pragma unroll
      for (int r = 0; r < 4; ++r){
        int row = m0 + wm + i * 16 + lg * 4 + r;
        float x = acc[i][j][r] + bv;
        if (OM == 1){
          if (col < 2048) x = 1.f / (1.f + expf(-x));
          int which = col >> 10, cc = col & 1023, h = cc >> 6, d = cc & 63;
          int b = row >> 10, l = row & 1023;
          outF[(size_t)which * (2048ull * 1024) +
               (((size_t)(b * 16 + h)) * 1024 + l) * 64 + d] = x;
        } else if (OM == 4){
          outF[((size_t)blockIdx.z * M + row) * N + col] = x;
        } else {
          if (ACT == 2) x = 0.5f * x * (1.f + erff(x * 0.70710678118654752f));
          outB[(size_t)row * N + col] = f2bf(x);
        }
      }
    }
  }
}

// ---------------- attention scalar pipeline (chunked Gram-tile form) ----------------
__global__ __launch_bounds__(256) void chunk_sums(const float* __restrict__ k, const float* __restrict__ q,
                                                  float* __restrict__ ck, float* __restrict__ cq){
  int blk = blockIdx.x;
  int lane = threadIdx.x & 63, wave = threadIdx.x >> 6;
  size_t base = (size_t)blk * 64 * DHD;
  float sk = 0.f, sq = 0.f;
  for (int l = wave * 16; l < wave * 16 + 16; l++){
    sk += k[base + l * 64 + lane];
    sq += q[base + l * 64 + lane];
  }
  __shared__ float rd[2][4][64];
  rd[0][wave][lane] = sk; rd[1][wave][lane] = sq;
  __syncthreads();
  if (wave == 0){
    ck[(size_t)blk * 64 + lane] = rd[0][0][lane] + rd[0][1][lane] + rd[0][2][lane] + rd[0][3][lane];
    cq[(size_t)blk * 64 + lane] = rd[1][0][lane] + rd[1][1][lane] + rd[1][2][lane] + rd[1][3][lane];
  }
}

// sink_in/src_out via G = Q K^T tile; also emits weighted chunk sums cso=sum so*k, cqsi=sum si*q
__global__ __launch_bounds__(256) void sink_tile(
    const float* __restrict__ q, const float* __restrict__ k,
    const float* __restrict__ ck, const float* __restrict__ cq,
    float* __restrict__ sink_in, float* __restrict__ src_out,
    float* __restrict__ cso, float* __restrict__ cqsi)
{
  int blk = blockIdx.x, bh = blk >> 4, c = blk & 15;
  int tid = threadIdx.x, lane = tid & 63, wave = tid >> 6;
  __shared__ float qT[64][65], kT[64][65], G[64][66];
  __shared__ float PK[64], PQ[64];
  __shared__ float rk[64], rq[64], crk[64], crq[64], siv[64], sov[64];
  __shared__ float rd[2][4][64];
  size_t base = ((size_t)bh * LSEQ + c * 64) * DHD;
  const float* qb = q + base; const float* kb = k + base;
  for (int c4 = tid; c4 < 1024; c4 += 256){
    int l = c4 >> 4, d0 = (c4 & 15) * 4;
    float4 qv = *reinterpret_cast<const float4*>(qb + c4 * 4);
    qT[d0+0][l] = qv.x; qT[d0+1][l] = qv.y; qT[d0+2][l] = qv.z; qT[d0+3][l] = qv.w;
    float4 kv = *reinterpret_cast<const float4*>(kb + c4 * 4);
    kT[d0+0][l] = kv.x; kT[d0+1][l] = kv.y; kT[d0+2][l] = kv.z; kT[d0+3][l] = kv.w;
  }
  if (tid < 64){
    float pk = 0.f, pq = 0.f;
    for (int cc = 0; cc < c; cc++){
      pk += ck[((size_t)bh * 16 + cc) * 64 + tid];
      pq += cq[((size_t)bh * 16 + cc) * 64 + tid];
    }
    PK[tid] = pk; PQ[tid] = pq;
  }
  __syncthreads();
  for (int j = wave * 16; j < wave * 16 + 16; j++){
    float s = wred64(kT[lane][j]);  if (lane == 0) rk[j] = s;
    float s2 = wred64(qT[lane][j]); if (lane == 0) rq[j] = s2;
  }
  float sumPK = wred64(PK[lane]);
  float sumPQ = wred64(PQ[lane]);
  {
    int l = lane, g = wave;
    float qrow[64];
#pragma unroll
    for (int d = 0; d < 64; d++) qrow[d] = qT[d][l];
    float p[16] = {};
    for (int d = 0; d < 64; d++){
      float qv = qrow[d];
#pragma unroll
      for (int j4 = 0; j4 < 4; j4++){
        float4 kk = *reinterpret_cast<const float4*>(&kT[d][g * 16 + j4 * 4]);
        p[j4*4+0] += qv * kk.x; p[j4*4+1] += qv * kk.y;
        p[j4*4+2] += qv * kk.z; p[j4*4+3] += qv * kk.w;
      }
    }
#pragma unroll
    for (int jj = 0; jj < 16; jj++) G[l][g * 16 + jj] = p[jj];
  }
  __syncthreads();
  if (wave == 0)      crk[lane] = wscan64(rk[lane], lane);
  else if (wave == 1) crq[lane] = wscan64(rq[lane], lane);
  __syncthreads();
  const float EPS2 = 64.f * EPS * EPS;
  for (int l = wave * 16; l < wave * 16 + 16; l++){
    float t1 = ((lane <= l) ? G[l][lane] : 0.f) + qT[lane][l] * PK[lane];
    float s1 = wred64(t1);
    float t2 = ((lane <= l) ? G[lane][l] : 0.f) + kT[lane][l] * PQ[lane];
    float s2 = wred64(t2);
    if (lane == 0){
      int L = c * 64 + l; float nrm = (float)(L + 1);
      float den1 = s1 + EPS * rq[l] + EPS * (sumPK + crk[l]) + EPS2;
      float den2 = s2 + EPS * rk[l] + EPS * (sumPQ + crq[l]) + EPS2;
      float si_ = nrm / den1, so_ = nrm / den2;
      sink_in[(size_t)bh * LSEQ + L] = si_;
      src_out[(size_t)bh * LSEQ + L] = so_;
      siv[l] = si_; sov[l] = so_;
    }
  }
  __syncthreads();
  float s1 = 0.f, s2 = 0.f;
  for (int l = wave * 16; l < wave * 16 + 16; l++){
    s1 += sov[l] * kT[lane][l];
    s2 += siv[l] * qT[lane][l];
  }
  rd[0][wave][lane] = s1; rd[1][wave][lane] = s2;
  __syncthreads();
  if (wave == 0){
    cso [(size_t)blk * 64 + lane] = rd[0][0][lane] + rd[0][1][lane] + rd[0][2][lane] + rd[0][3][lane];
    cqsi[(size_t)blk * 64 + lane] = rd[1][0][lane] + rd[1][1][lane] + rd[1][2][lane] + rd[1][3][lane];
  }
}

// cons_sink -> sa = sigmoid; cons_src -> clip -> ebuf = exp
__global__ __launch_bounds__(256) void cons_tile(
    const float* __restrict__ q, const float* __restrict__ k,
    const float* __restrict__ cso, const float* __restrict__ cqsi,
    const float* __restrict__ sink_in, const float* __restrict__ src_out,
    float* __restrict__ sa, float* __restrict__ ebuf)
{
  int blk = blockIdx.x, bh = blk >> 4, c = blk & 15;
  int tid = threadIdx.x, lane = tid & 63, wave = tid >> 6;
  __shared__ float qT[64][65], kT[64][65], G[64][66];
  __shared__ float PKso[64], PQsi[64];
  __shared__ float rk[64], rq[64], cwrk[64], cwrq[64], siv[64], sov[64];
  size_t base = ((size_t)bh * LSEQ + c * 64) * DHD;
  const float* qb = q + base; const float* kb = k + base;
  for (int c4 = tid; c4 < 1024; c4 += 256){
    int l = c4 >> 4, d0 = (c4 & 15) * 4;
    float4 qv = *reinterpret_cast<const float4*>(qb + c4 * 4);
    qT[d0+0][l] = qv.x; qT[d0+1][l] = qv.y; qT[d0+2][l] = qv.z; qT[d0+3][l] = qv.w;
    float4 kv = *reinterpret_cast<const float4*>(kb + c4 * 4);
    kT[d0+0][l] = kv.x; kT[d0+1][l] = kv.y; kT[d0+2][l] = kv.z; kT[d0+3][l] = kv.w;
  }
  if (tid < 64){
    float pk = 0.f, pq = 0.f;
    for (int cc = 0; cc < c; cc++){
      pk += cso [((size_t)bh * 16 + cc) * 64 + tid];
      pq += cqsi[((size_t)bh * 16 + cc) * 64 + tid];
    }
    PKso[tid] = pk; PQsi[tid] = pq;
  } else if (tid < 128){
    int l = tid - 64;
    sov[l] = src_out[(size_t)bh * LSEQ + c * 64 + l];
    siv[l] = sink_in[(size_t)bh * LSEQ + c * 64 + l];
  }
  __syncthreads();
  for (int j = wave * 16; j < wave * 16 + 16; j++){
    float s = wred64(kT[lane][j]);  if (lane == 0) rk[j] = s;
    float s2 = wred64(qT[lane][j]); if (lane == 0) rq[j] = s2;
  }
  float sumPKso = wred64(PKso[lane]);
  float sumPQsi = wred64(PQsi[lane]);
  {
    int l = lane, g = wave;
    float qrow[64];
#pragma unroll
    for (int d = 0; d < 64; d++) qrow[d] = qT[d][l];
    float p[16] = {};
    for (int d = 0; d < 64; d++){
      float qv = qrow[d];
#pragma unroll
      for (int j4 = 0; j4 < 4; j4++){
        float4 kk = *reinterpret_cast<const float4*>(&kT[d][g * 16 + j4 * 4]);
        p[j4*4+0] += qv * kk.x; p[j4*4+1] += qv * kk.y;
        p[j4*4+2] += qv * kk.z; p[j4*4+3] += qv * kk.w;
      }
    }
#pragma unroll
    for (int jj = 0; jj < 16; jj++) G[l][g * 16 + jj] = p[jj];
  }
  __syncthreads();
  if (wave == 0)      cwrk[lane] = wscan64(sov[lane] * rk[lane], lane);
  else if (wave == 1) cwrq[lane] = wscan64(siv[lane] * rq[lane], lane);
  __syncthreads();
  const float EPS2 = 64.f * EPS * EPS;
  for (int l = wave * 16; l < wave * 16 + 16; l++){
    float t3 = ((lane <= l) ? sov[lane] * G[l][lane] : 0.f) + qT[lane][l] * PKso[lane];
    float s3 = wred64(t3);
    float t4 = ((lane <= l) ? siv[lane] * G[lane][l] : 0.f) + kT[lane][l] * PQsi[lane];
    float s4 = wred64(t4);
    if (lane == 0){
      int L = c * 64 + l; float nrm = (float)(L + 1);
      float cs = (s3 + EPS * rq[l] + EPS * (sumPKso + cwrk[l]) + EPS2) / nrm;
      sa[(size_t)bh * LSEQ + L] = 1.f / (1.f + expf(-cs));
      float c2 = (s4 + EPS * rk[l] + EPS * (sumPQsi + cwrq[l]) + EPS2) / nrm;
      c2 = fminf(1.f, fmaxf(-1.f, c2));
      ebuf[(size_t)bh * LSEQ + L] = expf(c2);
    }
  }
}

// src_comp = e / cumsum(e) * (l+1)
__global__ __launch_bounds__(64) void srccomp_kernel(const float* __restrict__ ebuf, float* __restrict__ sc){
  int bh = blockIdx.x; int lane = threadIdx.x;
  const float* eb = ebuf + (size_t)bh * LSEQ;
  float loc[16]; float s = 0.f;
#pragma unroll
  for (int i = 0; i < 16; i++){ loc[i] = eb[lane * 16 + i]; s += loc[i]; }
  float run = wscan64(s, lane);
  float acc = run - s;
  float* scb = sc + (size_t)bh * LSEQ;
#pragma unroll
  for (int i = 0; i < 16; i++){
    acc += loc[i];
    scb[lane * 16 + i] = loc[i] / acc * (float)(lane * 16 + i + 1);
  }
}

// qs = q*sink_in/(l+1);  vs = v*src_comp
__global__ __launch_bounds__(256) void scale_kernel(const float* __restrict__ q, const float* __restrict__ v,
                                                    const float* __restrict__ si, const float* __restrict__ sc,
                                                    float* __restrict__ qs, float* __restrict__ vs){
  int i0 = (blockIdx.x * 256 + threadIdx.x) * 8;
  int r = i0 >> 6; int l = r & (LSEQ - 1);
  float qcoef = si[r] / (float)(l + 1);
  float vcoef = sc[r];
#pragma unroll
  for (int t = 0; t < 8; t += 4){
    float4 qv = *reinterpret_cast<const float4*>(q + i0 + t);
    float4 vv = *reinterpret_cast<const float4*>(v + i0 + t);
    *reinterpret_cast<float4*>(qs + i0 + t) = make_float4(qv.x*qcoef, qv.y*qcoef, qv.z*qcoef, qv.w*qcoef);
    *reinterpret_cast<float4*>(vs + i0 + t) = make_float4(vv.x*vcoef, vv.y*vcoef, vv.z*vcoef, vv.w*vcoef);
  }
}

// ---------------- chunked causal linear attention ----------------
__global__ __launch_bounds__(256) void phaseA(const float* __restrict__ k, const float* __restrict__ vs,
                                              float* __restrict__ S){
  int blk = blockIdx.x; int bh = blk >> 4, c = blk & 15;
  __shared__ float ks[64][68], vss[64][68];
  int tid = threadIdx.x;
  size_t base = ((size_t)bh * LSEQ + c * 64) * DHD;
  const float* kb = k + base; const float* vb = vs + base;
  for (int c4 = tid; c4 < 1024; c4 += 256){
    int l = c4 >> 4, d0 = (c4 & 15) * 4;
    *reinterpret_cast<float4*>(&ks[l][d0])  = *reinterpret_cast<const float4*>(kb + c4 * 4);
    *reinterpret_cast<float4*>(&vss[l][d0]) = *reinterpret_cast<const float4*>(vb + c4 * 4);
  }
  __syncthreads();
  int m = tid >> 2, dg = tid & 3;
  float acc[16] = {};
  for (int l = 0; l < 64; l++){
    float vm = vss[l][m];
#pragma unroll
    for (int d4 = 0; d4 < 4; d4++){
      float4 kk = *reinterpret_cast<const float4*>(&ks[l][dg * 16 + d4 * 4]);
      acc[d4*4+0] += vm * kk.x; acc[d4*4+1] += vm * kk.y;
      acc[d4*4+2] += vm * kk.z; acc[d4*4+3] += vm * kk.w;
    }
  }
  float* Sb = S + (size_t)blk * 4096 + m * 64 + dg * 16;
#pragma unroll
  for (int d4 = 0; d4 < 4; d4++)
    *reinterpret_cast<float4*>(Sb + d4 * 4) =
        make_float4(acc[d4*4], acc[d4*4+1], acc[d4*4+2], acc[d4*4+3]);
}

__global__ __launch_bounds__(256) void phaseB(const float* __restrict__ S, float* __restrict__ KVp){
  int bh = blockIdx.x; int tid = threadIdx.x;
  int off = tid * 16;
  float acc[16] = {};
  for (int c = 0; c < 16; c++){
    size_t idx = ((size_t)bh * 16 + c) * 4096 + off;
#pragma unroll
    for (int t = 0; t < 4; t++)
      *reinterpret_cast<float4*>(KVp + idx + t * 4) =
          make_float4(acc[t*4], acc[t*4+1], acc[t*4+2], acc[t*4+3]);
#pragma unroll
    for (int t = 0; t < 4; t++){
      float4 sv = *reinterpret_cast<const float4*>(S + idx + t * 4);
      acc[t*4] += sv.x; acc[t*4+1] += sv.y; acc[t*4+2] += sv.z; acc[t*4+3] += sv.w;
    }
  }
}

__global__ __launch_bounds__(256) void phaseC(const float* __restrict__ qs, const float* __restrict__ k,
                                              const float* __restrict__ vs, const float* __restrict__ KVp,
                                              const float* __restrict__ sa, u16* __restrict__ x){
  int blk = blockIdx.x; int bh = blk >> 4, c = blk & 15;
  int b = bh >> 4, h = bh & 15;
  __shared__ float qsT[64][65];
  __shared__ float kT[64][68];
  __shared__ float vss[64][68];
  __shared__ float kvs[64][68];
  __shared__ float Ps[64][66];
  int tid = threadIdx.x;
  size_t base = ((size_t)bh * LSEQ + c * 64) * DHD;
  const float* qb = qs + base; const float* kb = k + base; const float* vb = vs + base;
  const float* kvb = KVp + (size_t)blk * 4096;
  for (int c4 = tid; c4 < 1024; c4 += 256){
    int l = c4 >> 4, d0 = (c4 & 15) * 4;
    float4 qv = *reinterpret_cast<const float4*>(qb + c4 * 4);
    qsT[d0+0][l] = qv.x; qsT[d0+1][l] = qv.y; qsT[d0+2][l] = qv.z; qsT[d0+3][l] = qv.w;
    float4 kv4 = *reinterpret_cast<const float4*>(kb + c4 * 4);
    kT[d0+0][l] = kv4.x; kT[d0+1][l] = kv4.y; kT[d0+2][l] = kv4.z; kT[d0+3][l] = kv4.w;
    *reinterpret_cast<float4*>(&vss[l][d0]) = *reinterpret_cast<const float4*>(vb + c4 * 4);
    *reinterpret_cast<float4*>(&kvs[l][d0]) = *reinterpret_cast<const float4*>(kvb + c4 * 4);
  }
  __syncthreads();
  int l = tid & 63, g = tid >> 6;
  float qrow[64];
#pragma unroll
  for (int d = 0; d < 64; d++) qrow[d] = qsT[d][l];

  float p[16] = {};
  for (int d = 0; d < 64; d++){
    float qv = qrow[d];
#pragma unroll
    for (int j4 = 0; j4 < 4; j4++){
      float4 kk = *reinterpret_cast<const float4*>(&kT[d][g * 16 + j4 * 4]);
      p[j4*4+0] += qv * kk.x; p[j4*4+1] += qv * kk.y;
      p[j4*4+2] += qv * kk.z; p[j4*4+3] += qv * kk.w;
    }
  }
#pragma unroll
  for (int jj = 0; jj < 16; jj++){
    int j = g * 16 + jj;
    Ps[l][j] = (j <= l) ? p[jj] : 0.f;
  }
  __syncthreads();

  float acc[16];
#pragma unroll
  for (int mm = 0; mm < 16; mm++){
    float a = 0.f;
#pragma unroll
    for (int d4 = 0; d4 < 16; d4++){
      float4 kv4 = *reinterpret_cast<const float4*>(&kvs[g * 16 + mm][d4 * 4]);
      a += qrow[d4*4+0]*kv4.x + qrow[d4*4+1]*kv4.y + qrow[d4*4+2]*kv4.z + qrow[d4*4+3]*kv4.w;
    }
    acc[mm] = a;
  }
  for (int j = 0; j < 64; j++){
    float pv = Ps[l][j];
#pragma unroll
    for (int m4 = 0; m4 < 4; m4++){
      float4 vv = *reinterpret_cast<const float4*>(&vss[j][g * 16 + m4 * 4]);
      acc[m4*4+0] += pv * vv.x; acc[m4*4+1] += pv * vv.y;
      acc[m4*4+2] += pv * vv.z; acc[m4*4+3] += pv * vv.w;
    }
  }
  float sav = sa[(size_t)bh * LSEQ + c * 64 + l];
  u16* xo = x + ((size_t)(b * 1024 + c * 64 + l)) * 1024 + h * 64 + g * 16;
#pragma unroll
  for (int mm = 0; mm < 16; mm++) xo[mm] = f2bf(acc[mm] * sav);
}

// ---------------- fused layernorms ----------------
// LN over (p0 + p1 + bias + resid); emits f32 + bf16 (Wo split-K combine + LN1)
__global__ __launch_bounds__(256) void ln_fused2b(
    const float* __restrict__ p0, const float* __restrict__ p1,
    const float* __restrict__ resid, const float* __restrict__ bias,
    const float* __restrict__ g, const float* __restrict__ b,
    float* __restrict__ out, u16* __restrict__ outbf){
  int row = blockIdx.x; int tid = threadIdx.x;
  int lane = tid & 63, wave = tid >> 6;
  size_t off = (size_t)row * 1024 + tid * 4;
  float4 a0 = *reinterpret_cast<const float4*>(p0 + off);
  float4 a1 = *reinterpret_cast<const float4*>(p1 + off);
  float4 rr = *reinterpret_cast<const float4*>(resid + off);
  float4 bb = *reinterpret_cast<const float4*>(bias + tid * 4);
  float4 v = make_float4(a0.x + a1.x + rr.x + bb.x, a0.y + a1.y + rr.y + bb.y,
                         a0.z + a1.z + rr.z + bb.z, a0.w + a1.w + rr.w + bb.w);
  float s = v.x + v.y + v.z + v.w;
  float s2 = v.x*v.x + v.y*v.y + v.z*v.z + v.w*v.w;
  s = wred64(s); s2 = wred64(s2);
  __shared__ float red[2][4];
  if (lane == 0){ red[0][wave] = s; red[1][wave] = s2; }
  __syncthreads();
  float S = red[0][0] + red[0][1] + red[0][2] + red[0][3];
  float S2 = red[1][0] + red[1][1] + red[1][2] + red[1][3];
  float mean = S * (1.f / 1024.f);
  float var = S2 * (1.f / 1024.f) - mean * mean;
  float inv = rsqrtf(var + 1e-5f);
  float4 gv = *reinterpret_cast<const float4*>(g + tid * 4);
  float4 bv = *reinterpret_cast<const float4*>(b + tid * 4);
  float y0 = (v.x - mean) * inv * gv.x + bv.x;
  float y1 = (v.y - mean) * inv * gv.y + bv.y;
  float y2 = (v.z - mean) * inv * gv.z + bv.z;
  float y3 = (v.w - mean) * inv * gv.w + bv.w;
  *reinterpret_cast<float4*>(out + off) = make_float4(y0, y1, y2, y3);
  ushort4 o; o.x = f2bf(y0); o.y = f2bf(y1); o.z = f2bf(y2); o.w = f2bf(y3);
  *reinterpret_cast<ushort4*>(outbf + off) = o;
}

// LN over (p0+p1+p2+p3 + bias + resid) -> f32 out (FFN2 split-K4 combine + LN2)
__global__ __launch_bounds__(256) void ln_fused4(
    const float* __restrict__ p0, const float* __restrict__ p1,
    const float* __restrict__ p2, const float* __restrict__ p3,
    const float* __restrict__ resid, const float* __restrict__ bias,
    const float* __restrict__ g, const float* __restrict__ b,
    float* __restrict__ out){
  int row = blockIdx.x; int tid = threadIdx.x;
  int lane = tid & 63, wave = tid >> 6;
  size_t off = (size_t)row * 1024 + tid * 4;
  float4 a0 = *reinterpret_cast<const float4*>(p0 + off);
  float4 a1 = *reinterpret_cast<const float4*>(p1 + off);
  float4 a2 = *reinterpret_cast<const float4*>(p2 + off);
  float4 a3 = *reinterpret_cast<const float4*>(p3 + off);
  float4 rr = *reinterpret_cast<const float4*>(resid + off);
  float4 bb = *reinterpret_cast<const float4*>(bias + tid * 4);
  float4 v = make_float4(a0.x + a1.x + a2.x + a3.x + rr.x + bb.x,
                         a0.y + a1.y + a2.y + a3.y + rr.y + bb.y,
                         a0.z + a1.z + a2.z + a3.z + rr.z + bb.z,
                         a0.w + a1.w + a2.w + a3.w + rr.w + bb.w);
  float s = v.x + v.y + v.z + v.w;
  float s2 = v.x*v.x + v.y*v.y + v.z*v.z + v.w*v.w;
  s = wred64(s); s2 = wred64(s2);
  __shared__ float red[2][4];
  if (lane == 0){ red[0][wave] = s; red[1][wave] = s2; }
  __syncthreads();
  float S = red[0][0] + red[0][1] + red[0][2] + red[0][3];
  float S2 = red[1][0] + red[1][1] + red[1][2] + red[1][3];
  float mean = S * (1.f / 1024.f);
  float var = S2 * (1.f / 1024.f) - mean * mean;
  float inv = rsqrtf(var + 1e-5f);
  float4 gv = *reinterpret_cast<const float4*>(g + tid * 4);
  float4 bv = *reinterpret_cast<const float4*>(b + tid * 4);
  float y0 = (v.x - mean) * inv * gv.x + bv.x;
  float y1 = (v.y - mean) * inv * gv.y + bv.y;
  float y2 = (v.z - mean) * inv * gv.z + bv.z;
  float y3 = (v.w - mean) * inv * gv.w + bv.w;
  *reinterpret_cast<float4*>(out + off) = make_float4(y0, y1, y2, y3);
}

// ---------------- launch ----------------
extern "C" void kernel_launch(void* const* d_in, const int* in_sizes, int n_in,
                              void* d_out, int out_size, void* d_ws, size_t ws_size,
                              hipStream_t stream){
  (void)in_sizes; (void)n_in; (void)out_size; (void)ws_size;
  const float* inputs = (const float*)d_in[0];
  const float* Wq = (const float*)d_in[2];  const float* bq = (const float*)d_in[3];
  const float* Wk = (const float*)d_in[4];  const float* bk = (const float*)d_in[5];
  const float* Wv = (const float*)d_in[6];  const float* bv = (const float*)d_in[7];
  const float* Wo = (const float*)d_in[8];  const float* bo = (const float*)d_in[9];
  const float* ln1g = (const float*)d_in[10]; const float* ln1b = (const float*)d_in[11];
  const float* W1 = (const float*)d_in[12]; const float* b1 = (const float*)d_in[13];
  const float* W2 = (const float*)d_in[14]; const float* b2 = (const float*)d_in[15];
  const float* ln2g = (const float*)d_in[16]; const float* ln2b = (const float*)d_in[17];
  float* out = (float*)d_out;

  char* wsp = (char*)d_ws; size_t off = 0;
  auto alloc = [&](size_t bytes) -> void* {
    off = (off + 255) & ~(size_t)255;
    void* p = wsp + off; off += bytes; return p;
  };
  const size_t MD = (size_t)2048 * 1024;
  u16* Xbf    = (u16*)alloc(MD * 2);
  u16* WqkvT  = (u16*)alloc((size_t)3 * 1024 * 1024 * 2);
  u16* WoT    = (u16*)alloc((size_t)1024 * 1024 * 2);
  u16* W1T    = (u16*)alloc((size_t)4096 * 1024 * 2);
  u16* W2T    = (u16*)alloc((size_t)4096 * 1024 * 2);
  float* bqkv = (float*)alloc(3072 * 4);
  float* qkvb = (float*)alloc(3 * MD * 4);
  float* qb = qkvb; float* kb = qkvb + MD; float* vb = qkvb + 2 * MD;
  // contiguous 32MB quad: attention {S, KVp, qs, vs}; later split-K partial store
  float* quad = (float*)alloc(4 * MD * 4);
  float* Sbuf = quad;            // S
  float* KVp  = quad + MD;       // KV prefix
  float* c1   = quad + 2 * MD;   // qs
  float* c2   = quad + 3 * MD;   // vs
  float* ckb  = (float*)alloc((size_t)512 * 64 * 4);
  float* cqb  = (float*)alloc((size_t)512 * 64 * 4);
  float* csob = (float*)alloc((size_t)512 * 64 * 4);
  float* cqsib= (float*)alloc((size_t)512 * 64 * 4);
  float* sink_in = (float*)alloc(NBH * LSEQ * 4);
  float* src_out = (float*)alloc(NBH * LSEQ * 4);
  float* sabuf   = (float*)alloc(NBH * LSEQ * 4);
  float* ebuf    = (float*)alloc(NBH * LSEQ * 4);
  float* scbuf   = (float*)alloc(NBH * LSEQ * 4);
  u16* xatt   = (u16*)alloc(MD * 2);
  u16* g1     = (u16*)alloc((size_t)2048 * 4096 * 2);
  // reuse after attention: Wo partials = quad[0..1]; FFN2 partials = quad[0..3]
  float* part = quad;
  float* hbuf = vb;              // LN1 f32 out (vb dead after scale_kernel)
  u16* hbf = (u16*)qb;           // LN1 bf16 out (qb dead after scale_kernel)

  // converts + weight prep
  f2bf_kernel<<<2048, 256, 0, stream>>>(inputs, Xbf, (int)(MD / 4));
  transpose4_f2bf<<<dim3(32, 32, 4), 256, 0, stream>>>(Wq, Wk, Wv, Wo, WqkvT, WoT);
  transpose_f2bf<<<dim3(128, 32), 256, 0, stream>>>(W1, W1T, 1024, 4096);
  transpose_f2bf<<<dim3(32, 128), 256, 0, stream>>>(W2, W2T, 4096, 1024);
  bias_gather<<<12, 256, 0, stream>>>(bq, bk, bv, bqkv);

  // fused QKV projection: BM=64,BN=64, grid 32x48 = 1536 blocks (6/CU)
  gemm_mfma<64, 64, 0, 1><<<dim3(32, 48), 256, 0, stream>>>(
      Xbf, WqkvT, bqkv, nullptr, qkvb, nullptr, 2048, 3072, 1024);

  // attention scalars (chunked Gram-tile pipeline)
  chunk_sums<<<512, 256, 0, stream>>>(kb, qb, ckb, cqb);
  sink_tile<<<512, 256, 0, stream>>>(qb, kb, ckb, cqb, sink_in, src_out, csob, cqsib);
  cons_tile<<<512, 256, 0, stream>>>(qb, kb, csob, cqsib, sink_in, src_out, sabuf, ebuf);
  srccomp_kernel<<<32, 64, 0, stream>>>(ebuf, scbuf);
  scale_kernel<<<1024, 256, 0, stream>>>(qb, vb, sink_in, scbuf, c1, c2);

  // chunked causal linear attention
  phaseA<<<512, 256, 0, stream>>>(kb, c2, Sbuf);
  phaseB<<<32, 256, 0, stream>>>(Sbuf, KVp);
  phaseC<<<512, 256, 0, stream>>>(c1, kb, c2, KVp, sabuf, xatt);

  // output projection: BM=64,BN=64, split-K=2 -> partials; combine fused into LN1
  gemm_mfma<64, 64, 0, 4><<<dim3(32, 16, 2), 256, 0, stream>>>(
      xatt, WoT, nullptr, nullptr, part, nullptr, 2048, 1024, 1024);
  ln_fused2b<<<2048, 256, 0, stream>>>(part, part + MD, inputs, bo, ln1g, ln1b, hbuf, hbf);

  // FFN1: BM=64,BN=128, grid 32x32 = 1024 blocks (4/CU)
  gemm_mfma<64, 128, 2, 3><<<dim3(32, 32), 256, 0, stream>>>(
      hbf, W1T, b1, nullptr, nullptr, g1, 2048, 4096, 1024);
  // FFN2: BM=64,BN=64, split-K=4, grid 32x16x4 = 2048 blocks (8/CU), raw partials
  gemm_mfma<64, 64, 0, 4><<<dim3(32, 16, 4), 256, 0, stream>>>(
      g1, W2T, nullptr, nullptr, part, nullptr, 2048, 1024, 4096);
  // LN2 fused with split-K4 reduce + bias + residual
  ln_fused4<<<2048, 256, 0, stream>>>(part, part + MD, part + 2 * MD, part + 3 * MD,
                                      hbuf, b2, ln2g, ln2b, out);
}

// Round 9
// 264.332 us; speedup vs baseline: 1.0908x; 1.0096x over previous
//
#include <hip/hip_runtime.h>
#include <hip/hip_bf16.h>

// ---------------- constants ----------------
#define EPS 1e-6f
#define NBH 32      // B*H
#define LSEQ 1024
#define DHD 64

typedef unsigned short u16;
typedef __bf16 bf16x8 __attribute__((ext_vector_type(8)));
typedef float f32x4 __attribute__((ext_vector_type(4)));

__device__ inline u16 f2bf(float f){
  union { float f; unsigned u; } un; un.f = f;
  unsigned u = un.u;
  u += 0x7fffu + ((u >> 16) & 1u);
  return (u16)(u >> 16);
}

__device__ inline float wred64(float v){
#pragma unroll
  for (int off = 32; off > 0; off >>= 1) v += __shfl_xor(v, off, 64);
  return v;
}

__device__ inline float wscan64(float v, int lane){
  float run = v;
#pragma unroll
  for (int off = 1; off < 64; off <<= 1){
    float t = __shfl_up(run, off, 64);
    if (lane >= off) run += t;
  }
  return run;   // inclusive
}

__device__ inline void gload_lds16(const u16* g, u16* l){
  __builtin_amdgcn_global_load_lds(
      (const __attribute__((address_space(1))) unsigned int*)g,
      (__attribute__((address_space(3))) unsigned int*)l, 16, 0, 0);
}

// ---------------- converts ----------------
__global__ __launch_bounds__(256) void f2bf_kernel(const float* __restrict__ in,
                                                   u16* __restrict__ out, int n4){
  int i = blockIdx.x * 256 + threadIdx.x;
  if (i < n4){
    float4 v = reinterpret_cast<const float4*>(in)[i];
    ushort4 o; o.x = f2bf(v.x); o.y = f2bf(v.y); o.z = f2bf(v.z); o.w = f2bf(v.w);
    reinterpret_cast<ushort4*>(out)[i] = o;
  }
}

// generic 32x32-tile transpose+convert: out[c][r] = bf16(in[r][c])
__device__ inline void tr_tile(const float* in, u16* out, int R, int C){
  __shared__ float tile[32][33];
  int x = threadIdx.x & 31, y = threadIdx.x >> 5;
  int r0 = blockIdx.y * 32, c0 = blockIdx.x * 32;
#pragma unroll
  for (int j = 0; j < 4; j++)
    tile[y + j*8][x] = in[(size_t)(r0 + y + j*8) * C + c0 + x];
  __syncthreads();
#pragma unroll
  for (int j = 0; j < 4; j++)
    out[(size_t)(c0 + y + j*8) * R + r0 + x] = f2bf(tile[x][y + j*8]);
}

__global__ __launch_bounds__(256) void transpose_f2bf(const float* __restrict__ in,
                                                      u16* __restrict__ out, int R, int C){
  tr_tile(in, out, R, C);
}

// 4x 1024x1024 transposes in one launch (z selects matrix)
__global__ __launch_bounds__(256) void transpose4_f2bf(
    const float* __restrict__ w0, const float* __restrict__ w1,
    const float* __restrict__ w2, const float* __restrict__ w3,
    u16* __restrict__ dqkv, u16* __restrict__ dwo){
  int z = blockIdx.z;
  const float* in = (z == 0) ? w0 : (z == 1) ? w1 : (z == 2) ? w2 : w3;
  u16* out = (z < 3) ? (dqkv + (size_t)z * 1024 * 1024) : dwo;
  tr_tile(in, out, 1024, 1024);
}

// gather q/k/v biases into one 3072 vector
__global__ __launch_bounds__(256) void bias_gather(const float* __restrict__ bq,
                                                   const float* __restrict__ bk,
                                                   const float* __restrict__ bv,
                                                   float* __restrict__ dst){
  int i = blockIdx.x * 256 + threadIdx.x;
  if (i < 3072){
    float v = (i < 1024) ? bq[i] : (i < 2048) ? bk[i - 1024] : bv[i - 2048];
    dst[i] = v;
  }
}

// ---------------- bf16 MFMA GEMM (single-buffer, T2 XOR-swizzled LDS) --------
// C[M,N] = act(A[M,K] @ Bt[N,K]^T + bias)
// LDS layout: BK=64 bf16 rows = 128B = 8 x 16B slots. Logical slot s of row r is
// stored at physical slot s^(r&7) (rule #21: global_load_lds writes linearly, so
// the SOURCE address is pre-swizzled and the READ applies the same involution).
// ACT: 0 none, 2 gelu(exact)  (OM==1 applies sigmoid for col<2048 internally)
// OM: 1 fused-QKV remap to 3x[B,H,L,DH]; 3 bf16 [M][N];
//     4 raw f32 partial (split-K slice z at outF + z*M*N, no bias)
template<int BM, int BN, int ACT, int OM>
__global__ __launch_bounds__(256) void gemm_mfma(
    const u16* __restrict__ A, const u16* __restrict__ Bt,
    const float* __restrict__ bias, const float* __restrict__ resid,
    float* __restrict__ outF, u16* __restrict__ outB,
    int M, int N, int K)
{
  constexpr int BK = 64;
  constexpr int MI = BM / 32;
  constexpr int NJ = BN / 32;
  constexpr int RA = BM / 32;           // A staging rounds (256 thr x 16B)
  constexpr int RB = BN / 32;
  __shared__ u16 As[BM * BK];
  __shared__ u16 Bs[BN * BK];
  const int tid = threadIdx.x;
  const int lane = tid & 63, wave = tid >> 6;
  const int lrow = lane & 15, lg = lane >> 4;
  const int m0 = blockIdx.x * BM, n0 = blockIdx.y * BN;
  const int wm = (wave >> 1) * (BM / 2), wn = (wave & 1) * (BN / 2);

  const int ksz = K / gridDim.z;
  const int k_begin = blockIdx.z * ksz;
  const int k_end = k_begin + ksz;

  f32x4 acc[MI][NJ];
#pragma unroll
  for (int i = 0; i < MI; i++)
#pragma unroll
    for (int j = 0; j < NJ; j++) acc[i][j] = (f32x4){0.f, 0.f, 0.f, 0.f};

  const u16* Ab = A + (size_t)m0 * K;
  const u16* Bb = Bt + (size_t)n0 * K;

  // swizzled fragment slot per (kh, lane): physical slot = (kh*4+lg) ^ (lrow&7)
  const int s0 = ((0 * 4 + lg) ^ (lrow & 7)) * 8;
  const int s1 = ((1 * 4 + lg) ^ (lrow & 7)) * 8;

  for (int k0 = k_begin; k0 < k_end; k0 += BK){
    __syncthreads();                    // previous compute done with LDS
#pragma unroll
    for (int r = 0; r < RA; ++r){
      int c = r * 256 + tid;            // 16B chunk id: row = c>>3, phys slot = c&7
      int row = c >> 3;
      int kk = ((c ^ row) & 7) << 3;    // logical slot = phys ^ (row&7)
      gload_lds16(Ab + (size_t)row * K + k0 + kk, &As[(r * 256 + wave * 64) * 8]);
    }
#pragma unroll
    for (int r = 0; r < RB; ++r){
      int c = r * 256 + tid;
      int row = c >> 3;
      int kk = ((c ^ row) & 7) << 3;
      gload_lds16(Bb + (size_t)row * K + k0 + kk, &Bs[(r * 256 + wave * 64) * 8]);
    }
    __syncthreads();                    // staging complete (compiler drains vmcnt)
#pragma unroll
    for (int kh = 0; kh < 2; ++kh){
      const int ss = (kh == 0) ? s0 : s1;
      bf16x8 af[MI], bfv[NJ];
#pragma unroll
      for (int i = 0; i < MI; ++i)
        af[i] = *reinterpret_cast<const bf16x8*>(&As[(wm + i * 16 + lrow) * BK + ss]);
#pragma unroll
      for (int j = 0; j < NJ; ++j)
        bfv[j] = *reinterpret_cast<const bf16x8*>(&Bs[(wn + j * 16 + lrow) * BK + ss]);
#pragma unroll
      for (int i = 0; i < MI; ++i)
#pragma unroll
        for (int j = 0; j < NJ; ++j)
          acc[i][j] = __builtin_amdgcn_mfma_f32_16x16x32_bf16(af[i], bfv[j], acc[i][j], 0, 0, 0);
    }
  }

#pragma unroll
  for (int i = 0; i < MI; ++i){
#pragma unroll
    for (int j = 0; j < NJ; ++j){
      int col = n0 + wn + j * 16 + lrow;
      float bv = (OM != 4 && bias) ? bias[col] : 0.f;
#pragma unroll
      for (int r = 0; r < 4; ++r){
        int row = m0 + wm + i * 16 + lg * 4 + r;
        float x = acc[i][j][r] + bv;
        if (OM == 1){
          if (col < 2048) x = 1.f / (1.f + expf(-x));
          int which = col >> 10, cc = col & 1023, h = cc >> 6, d = cc & 63;
          int b = row >> 10, l = row & 1023;
          outF[(size_t)which * (2048ull * 1024) +
               (((size_t)(b * 16 + h)) * 1024 + l) * 64 + d] = x;
        } else if (OM == 4){
          outF[((size_t)blockIdx.z * M + row) * N + col] = x;
        } else {
          if (ACT == 2) x = 0.5f * x * (1.f + erff(x * 0.70710678118654752f));
          outB[(size_t)row * N + col] = f2bf(x);
        }
      }
    }
  }
}

// ---------------- attention scalar pipeline (chunked Gram-tile form) ----------------
__global__ __launch_bounds__(256) void chunk_sums(const float* __restrict__ k, const float* __restrict__ q,
                                                  float* __restrict__ ck, float* __restrict__ cq){
  int blk = blockIdx.x;
  int lane = threadIdx.x & 63, wave = threadIdx.x >> 6;
  size_t base = (size_t)blk * 64 * DHD;
  float sk = 0.f, sq = 0.f;
  for (int l = wave * 16; l < wave * 16 + 16; l++){
    sk += k[base + l * 64 + lane];
    sq += q[base + l * 64 + lane];
  }
  __shared__ float rd[2][4][64];
  rd[0][wave][lane] = sk; rd[1][wave][lane] = sq;
  __syncthreads();
  if (wave == 0){
    ck[(size_t)blk * 64 + lane] = rd[0][0][lane] + rd[0][1][lane] + rd[0][2][lane] + rd[0][3][lane];
    cq[(size_t)blk * 64 + lane] = rd[1][0][lane] + rd[1][1][lane] + rd[1][2][lane] + rd[1][3][lane];
  }
}

// sink_in/src_out via G = Q K^T tile; also emits weighted chunk sums cso=sum so*k, cqsi=sum si*q
__global__ __launch_bounds__(256) void sink_tile(
    const float* __restrict__ q, const float* __restrict__ k,
    const float* __restrict__ ck, const float* __restrict__ cq,
    float* __restrict__ sink_in, float* __restrict__ src_out,
    float* __restrict__ cso, float* __restrict__ cqsi)
{
  int blk = blockIdx.x, bh = blk >> 4, c = blk & 15;
  int tid = threadIdx.x, lane = tid & 63, wave = tid >> 6;
  __shared__ float qT[64][65], kT[64][65], G[64][66];
  __shared__ float PK[64], PQ[64];
  __shared__ float rk[64], rq[64], crk[64], crq[64], siv[64], sov[64];
  __shared__ float rd[2][4][64];
  size_t base = ((size_t)bh * LSEQ + c * 64) * DHD;
  const float* qb = q + base; const float* kb = k + base;
  for (int c4 = tid; c4 < 1024; c4 += 256){
    int l = c4 >> 4, d0 = (c4 & 15) * 4;
    float4 qv = *reinterpret_cast<const float4*>(qb + c4 * 4);
    qT[d0+0][l] = qv.x; qT[d0+1][l] = qv.y; qT[d0+2][l] = qv.z; qT[d0+3][l] = qv.w;
    float4 kv = *reinterpret_cast<const float4*>(kb + c4 * 4);
    kT[d0+0][l] = kv.x; kT[d0+1][l] = kv.y; kT[d0+2][l] = kv.z; kT[d0+3][l] = kv.w;
  }
  if (tid < 64){
    float pk = 0.f, pq = 0.f;
    for (int cc = 0; cc < c; cc++){
      pk += ck[((size_t)bh * 16 + cc) * 64 + tid];
      pq += cq[((size_t)bh * 16 + cc) * 64 + tid];
    }
    PK[tid] = pk; PQ[tid] = pq;
  }
  __syncthreads();
  for (int j = wave * 16; j < wave * 16 + 16; j++){
    float s = wred64(kT[lane][j]);  if (lane == 0) rk[j] = s;
    float s2 = wred64(qT[lane][j]); if (lane == 0) rq[j] = s2;
  }
  float sumPK = wred64(PK[lane]);
  float sumPQ = wred64(PQ[lane]);
  {
    int l = lane, g = wave;
    float qrow[64];
#pragma unroll
    for (int d = 0; d < 64; d++) qrow[d] = qT[d][l];
    float p[16] = {};
    for (int d = 0; d < 64; d++){
      float qv = qrow[d];
#pragma unroll
      for (int j4 = 0; j4 < 4; j4++){
        float4 kk = *reinterpret_cast<const float4*>(&kT[d][g * 16 + j4 * 4]);
        p[j4*4+0] += qv * kk.x; p[j4*4+1] += qv * kk.y;
        p[j4*4+2] += qv * kk.z; p[j4*4+3] += qv * kk.w;
      }
    }
#pragma unroll
    for (int jj = 0; jj < 16; jj++) G[l][g * 16 + jj] = p[jj];
  }
  __syncthreads();
  if (wave == 0)      crk[lane] = wscan64(rk[lane], lane);
  else if (wave == 1) crq[lane] = wscan64(rq[lane], lane);
  __syncthreads();
  const float EPS2 = 64.f * EPS * EPS;
  for (int l = wave * 16; l < wave * 16 + 16; l++){
    float t1 = ((lane <= l) ? G[l][lane] : 0.f) + qT[lane][l] * PK[lane];
    float s1 = wred64(t1);
    float t2 = ((lane <= l) ? G[lane][l] : 0.f) + kT[lane][l] * PQ[lane];
    float s2 = wred64(t2);
    if (lane == 0){
      int L = c * 64 + l; float nrm = (float)(L + 1);
      float den1 = s1 + EPS * rq[l] + EPS * (sumPK + crk[l]) + EPS2;
      float den2 = s2 + EPS * rk[l] + EPS * (sumPQ + crq[l]) + EPS2;
      float si_ = nrm / den1, so_ = nrm / den2;
      sink_in[(size_t)bh * LSEQ + L] = si_;
      src_out[(size_t)bh * LSEQ + L] = so_;
      siv[l] = si_; sov[l] = so_;
    }
  }
  __syncthreads();
  float s1 = 0.f, s2 = 0.f;
  for (int l = wave * 16; l < wave * 16 + 16; l++){
    s1 += sov[l] * kT[lane][l];
    s2 += siv[l] * qT[lane][l];
  }
  rd[0][wave][lane] = s1; rd[1][wave][lane] = s2;
  __syncthreads();
  if (wave == 0){
    cso [(size_t)blk * 64 + lane] = rd[0][0][lane] + rd[0][1][lane] + rd[0][2][lane] + rd[0][3][lane];
    cqsi[(size_t)blk * 64 + lane] = rd[1][0][lane] + rd[1][1][lane] + rd[1][2][lane] + rd[1][3][lane];
  }
}

// cons_sink -> sa = sigmoid; cons_src -> clip -> ebuf = exp
__global__ __launch_bounds__(256) void cons_tile(
    const float* __restrict__ q, const float* __restrict__ k,
    const float* __restrict__ cso, const float* __restrict__ cqsi,
    const float* __restrict__ sink_in, const float* __restrict__ src_out,
    float* __restrict__ sa, float* __restrict__ ebuf)
{
  int blk = blockIdx.x, bh = blk >> 4, c = blk & 15;
  int tid = threadIdx.x, lane = tid & 63, wave = tid >> 6;
  __shared__ float qT[64][65], kT[64][65], G[64][66];
  __shared__ float PKso[64], PQsi[64];
  __shared__ float rk[64], rq[64], cwrk[64], cwrq[64], siv[64], sov[64];
  size_t base = ((size_t)bh * LSEQ + c * 64) * DHD;
  const float* qb = q + base; const float* kb = k + base;
  for (int c4 = tid; c4 < 1024; c4 += 256){
    int l = c4 >> 4, d0 = (c4 & 15) * 4;
    float4 qv = *reinterpret_cast<const float4*>(qb + c4 * 4);
    qT[d0+0][l] = qv.x; qT[d0+1][l] = qv.y; qT[d0+2][l] = qv.z; qT[d0+3][l] = qv.w;
    float4 kv = *reinterpret_cast<const float4*>(kb + c4 * 4);
    kT[d0+0][l] = kv.x; kT[d0+1][l] = kv.y; kT[d0+2][l] = kv.z; kT[d0+3][l] = kv.w;
  }
  if (tid < 64){
    float pk = 0.f, pq = 0.f;
    for (int cc = 0; cc < c; cc++){
      pk += cso [((size_t)bh * 16 + cc) * 64 + tid];
      pq += cqsi[((size_t)bh * 16 + cc) * 64 + tid];
    }
    PKso[tid] = pk; PQsi[tid] = pq;
  } else if (tid < 128){
    int l = tid - 64;
    sov[l] = src_out[(size_t)bh * LSEQ + c * 64 + l];
    siv[l] = sink_in[(size_t)bh * LSEQ + c * 64 + l];
  }
  __syncthreads();
  for (int j = wave * 16; j < wave * 16 + 16; j++){
    float s = wred64(kT[lane][j]);  if (lane == 0) rk[j] = s;
    float s2 = wred64(qT[lane][j]); if (lane == 0) rq[j] = s2;
  }
  float sumPKso = wred64(PKso[lane]);
  float sumPQsi = wred64(PQsi[lane]);
  {
    int l = lane, g = wave;
    float qrow[64];
#pragma unroll
    for (int d = 0; d < 64; d++) qrow[d] = qT[d][l];
    float p[16] = {};
    for (int d = 0; d < 64; d++){
      float qv = qrow[d];
#pragma unroll
      for (int j4 = 0; j4 < 4; j4++){
        float4 kk = *reinterpret_cast<const float4*>(&kT[d][g * 16 + j4 * 4]);
        p[j4*4+0] += qv * kk.x; p[j4*4+1] += qv * kk.y;
        p[j4*4+2] += qv * kk.z; p[j4*4+3] += qv * kk.w;
      }
    }
#pragma unroll
    for (int jj = 0; jj < 16; jj++) G[l][g * 16 + jj] = p[jj];
  }
  __syncthreads();
  if (wave == 0)      cwrk[lane] = wscan64(sov[lane] * rk[lane], lane);
  else if (wave == 1) cwrq[lane] = wscan64(siv[lane] * rq[lane], lane);
  __syncthreads();
  const float EPS2 = 64.f * EPS * EPS;
  for (int l = wave * 16; l < wave * 16 + 16; l++){
    float t3 = ((lane <= l) ? sov[lane] * G[l][lane] : 0.f) + qT[lane][l] * PKso[lane];
    float s3 = wred64(t3);
    float t4 = ((lane <= l) ? siv[lane] * G[lane][l] : 0.f) + kT[lane][l] * PQsi[lane];
    float s4 = wred64(t4);
    if (lane == 0){
      int L = c * 64 + l; float nrm = (float)(L + 1);
      float cs = (s3 + EPS * rq[l] + EPS * (sumPKso + cwrk[l]) + EPS2) / nrm;
      sa[(size_t)bh * LSEQ + L] = 1.f / (1.f + expf(-cs));
      float c2 = (s4 + EPS * rk[l] + EPS * (sumPQsi + cwrq[l]) + EPS2) / nrm;
      c2 = fminf(1.f, fmaxf(-1.f, c2));
      ebuf[(size_t)bh * LSEQ + L] = expf(c2);
    }
  }
}

// src_comp = e / cumsum(e) * (l+1)
__global__ __launch_bounds__(64) void srccomp_kernel(const float* __restrict__ ebuf, float* __restrict__ sc){
  int bh = blockIdx.x; int lane = threadIdx.x;
  const float* eb = ebuf + (size_t)bh * LSEQ;
  float loc[16]; float s = 0.f;
#pragma unroll
  for (int i = 0; i < 16; i++){ loc[i] = eb[lane * 16 + i]; s += loc[i]; }
  float run = wscan64(s, lane);
  float acc = run - s;
  float* scb = sc + (size_t)bh * LSEQ;
#pragma unroll
  for (int i = 0; i < 16; i++){
    acc += loc[i];
    scb[lane * 16 + i] = loc[i] / acc * (float)(lane * 16 + i + 1);
  }
}

// qs = q*sink_in/(l+1);  vs = v*src_comp
__global__ __launch_bounds__(256) void scale_kernel(const float* __restrict__ q, const float* __restrict__ v,
                                                    const float* __restrict__ si, const float* __restrict__ sc,
                                                    float* __restrict__ qs, float* __restrict__ vs){
  int i0 = (blockIdx.x * 256 + threadIdx.x) * 8;
  int r = i0 >> 6; int l = r & (LSEQ - 1);
  float qcoef = si[r] / (float)(l + 1);
  float vcoef = sc[r];
#pragma unroll
  for (int t = 0; t < 8; t += 4){
    float4 qv = *reinterpret_cast<const float4*>(q + i0 + t);
    float4 vv = *reinterpret_cast<const float4*>(v + i0 + t);
    *reinterpret_cast<float4*>(qs + i0 + t) = make_float4(qv.x*qcoef, qv.y*qcoef, qv.z*qcoef, qv.w*qcoef);
    *reinterpret_cast<float4*>(vs + i0 + t) = make_float4(vv.x*vcoef, vv.y*vcoef, vv.z*vcoef, vv.w*vcoef);
  }
}

// ---------------- chunked causal linear attention ----------------
__global__ __launch_bounds__(256) void phaseA(const float* __restrict__ k, const float* __restrict__ vs,
                                              float* __restrict__ S){
  int blk = blockIdx.x; int bh = blk >> 4, c = blk & 15;
  __shared__ float ks[64][68], vss[64][68];
  int tid = threadIdx.x;
  size_t base = ((size_t)bh * LSEQ + c * 64) * DHD;
  const float* kb = k + base; const float* vb = vs + base;
  for (int c4 = tid; c4 < 1024; c4 += 256){
    int l = c4 >> 4, d0 = (c4 & 15) * 4;
    *reinterpret_cast<float4*>(&ks[l][d0])  = *reinterpret_cast<const float4*>(kb + c4 * 4);
    *reinterpret_cast<float4*>(&vss[l][d0]) = *reinterpret_cast<const float4*>(vb + c4 * 4);
  }
  __syncthreads();
  int m = tid >> 2, dg = tid & 3;
  float acc[16] = {};
  for (int l = 0; l < 64; l++){
    float vm = vss[l][m];
#pragma unroll
    for (int d4 = 0; d4 < 4; d4++){
      float4 kk = *reinterpret_cast<const float4*>(&ks[l][dg * 16 + d4 * 4]);
      acc[d4*4+0] += vm * kk.x; acc[d4*4+1] += vm * kk.y;
      acc[d4*4+2] += vm * kk.z; acc[d4*4+3] += vm * kk.w;
    }
  }
  float* Sb = S + (size_t)blk * 4096 + m * 64 + dg * 16;
#pragma unroll
  for (int d4 = 0; d4 < 4; d4++)
    *reinterpret_cast<float4*>(Sb + d4 * 4) =
        make_float4(acc[d4*4], acc[d4*4+1], acc[d4*4+2], acc[d4*4+3]);
}

__global__ __launch_bounds__(256) void phaseB(const float* __restrict__ S, float* __restrict__ KVp){
  int bh = blockIdx.x; int tid = threadIdx.x;
  int off = tid * 16;
  float acc[16] = {};
  for (int c = 0; c < 16; c++){
    size_t idx = ((size_t)bh * 16 + c) * 4096 + off;
#pragma unroll
    for (int t = 0; t < 4; t++)
      *reinterpret_cast<float4*>(KVp + idx + t * 4) =
          make_float4(acc[t*4], acc[t*4+1], acc[t*4+2], acc[t*4+3]);
#pragma unroll
    for (int t = 0; t < 4; t++){
      float4 sv = *reinterpret_cast<const float4*>(S + idx + t * 4);
      acc[t*4] += sv.x; acc[t*4+1] += sv.y; acc[t*4+2] += sv.z; acc[t*4+3] += sv.w;
    }
  }
}

__global__ __launch_bounds__(256) void phaseC(const float* __restrict__ qs, const float* __restrict__ k,
                                              const float* __restrict__ vs, const float* __restrict__ KVp,
                                              const float* __restrict__ sa, u16* __restrict__ x){
  int blk = blockIdx.x; int bh = blk >> 4, c = blk & 15;
  int b = bh >> 4, h = bh & 15;
  __shared__ float qsT[64][65];
  __shared__ float kT[64][68];
  __shared__ float vss[64][68];
  __shared__ float kvs[64][68];
  __shared__ float Ps[64][66];
  int tid = threadIdx.x;
  size_t base = ((size_t)bh * LSEQ + c * 64) * DHD;
  const float* qb = qs + base; const float* kb = k + base; const float* vb = vs + base;
  const float* kvb = KVp + (size_t)blk * 4096;
  for (int c4 = tid; c4 < 1024; c4 += 256){
    int l = c4 >> 4, d0 = (c4 & 15) * 4;
    float4 qv = *reinterpret_cast<const float4*>(qb + c4 * 4);
    qsT[d0+0][l] = qv.x; qsT[d0+1][l] = qv.y; qsT[d0+2][l] = qv.z; qsT[d0+3][l] = qv.w;
    float4 kv4 = *reinterpret_cast<const float4*>(kb + c4 * 4);
    kT[d0+0][l] = kv4.x; kT[d0+1][l] = kv4.y; kT[d0+2][l] = kv4.z; kT[d0+3][l] = kv4.w;
    *reinterpret_cast<float4*>(&vss[l][d0]) = *reinterpret_cast<const float4*>(vb + c4 * 4);
    *reinterpret_cast<float4*>(&kvs[l][d0]) = *reinterpret_cast<const float4*>(kvb + c4 * 4);
  }
  __syncthreads();
  int l = tid & 63, g = tid >> 6;
  float qrow[64];
#pragma unroll
  for (int d = 0; d < 64; d++) qrow[d] = qsT[d][l];

  float p[16] = {};
  for (int d = 0; d < 64; d++){
    float qv = qrow[d];
#pragma unroll
    for (int j4 = 0; j4 < 4; j4++){
      float4 kk = *reinterpret_cast<const float4*>(&kT[d][g * 16 + j4 * 4]);
      p[j4*4+0] += qv * kk.x; p[j4*4+1] += qv * kk.y;
      p[j4*4+2] += qv * kk.z; p[j4*4+3] += qv * kk.w;
    }
  }
#pragma unroll
  for (int jj = 0; jj < 16; jj++){
    int j = g * 16 + jj;
    Ps[l][j] = (j <= l) ? p[jj] : 0.f;
  }
  __syncthreads();

  float acc[16];
#pragma unroll
  for (int mm = 0; mm < 16; mm++){
    float a = 0.f;
#pragma unroll
    for (int d4 = 0; d4 < 16; d4++){
      float4 kv4 = *reinterpret_cast<const float4*>(&kvs[g * 16 + mm][d4 * 4]);
      a += qrow[d4*4+0]*kv4.x + qrow[d4*4+1]*kv4.y + qrow[d4*4+2]*kv4.z + qrow[d4*4+3]*kv4.w;
    }
    acc[mm] = a;
  }
  for (int j = 0; j < 64; j++){
    float pv = Ps[l][j];
#pragma unroll
    for (int m4 = 0; m4 < 4; m4++){
      float4 vv = *reinterpret_cast<const float4*>(&vss[j][g * 16 + m4 * 4]);
      acc[m4*4+0] += pv * vv.x; acc[m4*4+1] += pv * vv.y;
      acc[m4*4+2] += pv * vv.z; acc[m4*4+3] += pv * vv.w;
    }
  }
  float sav = sa[(size_t)bh * LSEQ + c * 64 + l];
  u16* xo = x + ((size_t)(b * 1024 + c * 64 + l)) * 1024 + h * 64 + g * 16;
#pragma unroll
  for (int mm = 0; mm < 16; mm++) xo[mm] = f2bf(acc[mm] * sav);
}

// ---------------- fused layernorms ----------------
// LN over (p0 + p1 + bias + resid); emits f32 + bf16 (Wo split-K combine + LN1)
__global__ __launch_bounds__(256) void ln_fused2b(
    const float* __restrict__ p0, const float* __restrict__ p1,
    const float* __restrict__ resid, const float* __restrict__ bias,
    const float* __restrict__ g, const float* __restrict__ b,
    float* __restrict__ out, u16* __restrict__ outbf){
  int row = blockIdx.x; int tid = threadIdx.x;
  int lane = tid & 63, wave = tid >> 6;
  size_t off = (size_t)row * 1024 + tid * 4;
  float4 a0 = *reinterpret_cast<const float4*>(p0 + off);
  float4 a1 = *reinterpret_cast<const float4*>(p1 + off);
  float4 rr = *reinterpret_cast<const float4*>(resid + off);
  float4 bb = *reinterpret_cast<const float4*>(bias + tid * 4);
  float4 v = make_float4(a0.x + a1.x + rr.x + bb.x, a0.y + a1.y + rr.y + bb.y,
                         a0.z + a1.z + rr.z + bb.z, a0.w + a1.w + rr.w + bb.w);
  float s = v.x + v.y + v.z + v.w;
  float s2 = v.x*v.x + v.y*v.y + v.z*v.z + v.w*v.w;
  s = wred64(s); s2 = wred64(s2);
  __shared__ float red[2][4];
  if (lane == 0){ red[0][wave] = s; red[1][wave] = s2; }
  __syncthreads();
  float S = red[0][0] + red[0][1] + red[0][2] + red[0][3];
  float S2 = red[1][0] + red[1][1] + red[1][2] + red[1][3];
  float mean = S * (1.f / 1024.f);
  float var = S2 * (1.f / 1024.f) - mean * mean;
  float inv = rsqrtf(var + 1e-5f);
  float4 gv = *reinterpret_cast<const float4*>(g + tid * 4);
  float4 bv = *reinterpret_cast<const float4*>(b + tid * 4);
  float y0 = (v.x - mean) * inv * gv.x + bv.x;
  float y1 = (v.y - mean) * inv * gv.y + bv.y;
  float y2 = (v.z - mean) * inv * gv.z + bv.z;
  float y3 = (v.w - mean) * inv * gv.w + bv.w;
  *reinterpret_cast<float4*>(out + off) = make_float4(y0, y1, y2, y3);
  ushort4 o; o.x = f2bf(y0); o.y = f2bf(y1); o.z = f2bf(y2); o.w = f2bf(y3);
  *reinterpret_cast<ushort4*>(outbf + off) = o;
}

// LN over (p0+p1+p2+p3 + bias + resid) -> f32 out (FFN2 split-K4 combine + LN2)
__global__ __launch_bounds__(256) void ln_fused4(
    const float* __restrict__ p0, const float* __restrict__ p1,
    const float* __restrict__ p2, const float* __restrict__ p3,
    const float* __restrict__ resid, const float* __restrict__ bias,
    const float* __restrict__ g, const float* __restrict__ b,
    float* __restrict__ out){
  int row = blockIdx.x; int tid = threadIdx.x;
  int lane = tid & 63, wave = tid >> 6;
  size_t off = (size_t)row * 1024 + tid * 4;
  float4 a0 = *reinterpret_cast<const float4*>(p0 + off);
  float4 a1 = *reinterpret_cast<const float4*>(p1 + off);
  float4 a2 = *reinterpret_cast<const float4*>(p2 + off);
  float4 a3 = *reinterpret_cast<const float4*>(p3 + off);
  float4 rr = *reinterpret_cast<const float4*>(resid + off);
  float4 bb = *reinterpret_cast<const float4*>(bias + tid * 4);
  float4 v = make_float4(a0.x + a1.x + a2.x + a3.x + rr.x + bb.x,
                         a0.y + a1.y + a2.y + a3.y + rr.y + bb.y,
                         a0.z + a1.z + a2.z + a3.z + rr.z + bb.z,
                         a0.w + a1.w + a2.w + a3.w + rr.w + bb.w);
  float s = v.x + v.y + v.z + v.w;
  float s2 = v.x*v.x + v.y*v.y + v.z*v.z + v.w*v.w;
  s = wred64(s); s2 = wred64(s2);
  __shared__ float red[2][4];
  if (lane == 0){ red[0][wave] = s; red[1][wave] = s2; }
  __syncthreads();
  float S = red[0][0] + red[0][1] + red[0][2] + red[0][3];
  float S2 = red[1][0] + red[1][1] + red[1][2] + red[1][3];
  float mean = S * (1.f / 1024.f);
  float var = S2 * (1.f / 1024.f) - mean * mean;
  float inv = rsqrtf(var + 1e-5f);
  float4 gv = *reinterpret_cast<const float4*>(g + tid * 4);
  float4 bv = *reinterpret_cast<const float4*>(b + tid * 4);
  float y0 = (v.x - mean) * inv * gv.x + bv.x;
  float y1 = (v.y - mean) * inv * gv.y + bv.y;
  float y2 = (v.z - mean) * inv * gv.z + bv.z;
  float y3 = (v.w - mean) * inv * gv.w + bv.w;
  *reinterpret_cast<float4*>(out + off) = make_float4(y0, y1, y2, y3);
}

// ---------------- launch ----------------
extern "C" void kernel_launch(void* const* d_in, const int* in_sizes, int n_in,
                              void* d_out, int out_size, void* d_ws, size_t ws_size,
                              hipStream_t stream){
  (void)in_sizes; (void)n_in; (void)out_size; (void)ws_size;
  const float* inputs = (const float*)d_in[0];
  const float* Wq = (const float*)d_in[2];  const float* bq = (const float*)d_in[3];
  const float* Wk = (const float*)d_in[4];  const float* bk = (const float*)d_in[5];
  const float* Wv = (const float*)d_in[6];  const float* bv = (const float*)d_in[7];
  const float* Wo = (const float*)d_in[8];  const float* bo = (const float*)d_in[9];
  const float* ln1g = (const float*)d_in[10]; const float* ln1b = (const float*)d_in[11];
  const float* W1 = (const float*)d_in[12]; const float* b1 = (const float*)d_in[13];
  const float* W2 = (const float*)d_in[14]; const float* b2 = (const float*)d_in[15];
  const float* ln2g = (const float*)d_in[16]; const float* ln2b = (const float*)d_in[17];
  float* out = (float*)d_out;

  char* wsp = (char*)d_ws; size_t off = 0;
  auto alloc = [&](size_t bytes) -> void* {
    off = (off + 255) & ~(size_t)255;
    void* p = wsp + off; off += bytes; return p;
  };
  const size_t MD = (size_t)2048 * 1024;
  u16* Xbf    = (u16*)alloc(MD * 2);
  u16* WqkvT  = (u16*)alloc((size_t)3 * 1024 * 1024 * 2);
  u16* WoT    = (u16*)alloc((size_t)1024 * 1024 * 2);
  u16* W1T    = (u16*)alloc((size_t)4096 * 1024 * 2);
  u16* W2T    = (u16*)alloc((size_t)4096 * 1024 * 2);
  float* bqkv = (float*)alloc(3072 * 4);
  float* qkvb = (float*)alloc(3 * MD * 4);
  float* qb = qkvb; float* kb = qkvb + MD; float* vb = qkvb + 2 * MD;
  // contiguous 32MB quad: attention {S, KVp, qs, vs}; later split-K partial store
  float* quad = (float*)alloc(4 * MD * 4);
  float* Sbuf = quad;            // S
  float* KVp  = quad + MD;       // KV prefix
  float* c1   = quad + 2 * MD;   // qs
  float* c2   = quad + 3 * MD;   // vs
  float* ckb  = (float*)alloc((size_t)512 * 64 * 4);
  float* cqb  = (float*)alloc((size_t)512 * 64 * 4);
  float* csob = (float*)alloc((size_t)512 * 64 * 4);
  float* cqsib= (float*)alloc((size_t)512 * 64 * 4);
  float* sink_in = (float*)alloc(NBH * LSEQ * 4);
  float* src_out = (float*)alloc(NBH * LSEQ * 4);
  float* sabuf   = (float*)alloc(NBH * LSEQ * 4);
  float* ebuf    = (float*)alloc(NBH * LSEQ * 4);
  float* scbuf   = (float*)alloc(NBH * LSEQ * 4);
  u16* xatt   = (u16*)alloc(MD * 2);
  u16* g1     = (u16*)alloc((size_t)2048 * 4096 * 2);
  // reuse after attention: Wo partials = quad[0..1]; FFN2 partials = quad[0..3]
  float* part = quad;
  float* hbuf = vb;              // LN1 f32 out (vb dead after scale_kernel)
  u16* hbf = (u16*)qb;           // LN1 bf16 out (qb dead after scale_kernel)

  // converts + weight prep
  f2bf_kernel<<<2048, 256, 0, stream>>>(inputs, Xbf, (int)(MD / 4));
  transpose4_f2bf<<<dim3(32, 32, 4), 256, 0, stream>>>(Wq, Wk, Wv, Wo, WqkvT, WoT);
  transpose_f2bf<<<dim3(128, 32), 256, 0, stream>>>(W1, W1T, 1024, 4096);
  transpose_f2bf<<<dim3(32, 128), 256, 0, stream>>>(W2, W2T, 4096, 1024);
  bias_gather<<<12, 256, 0, stream>>>(bq, bk, bv, bqkv);

  // fused QKV projection: BM=128,BN=64, grid 16x48 = 768 blocks (3/CU)
  gemm_mfma<128, 64, 0, 1><<<dim3(16, 48), 256, 0, stream>>>(
      Xbf, WqkvT, bqkv, nullptr, qkvb, nullptr, 2048, 3072, 1024);

  // attention scalars (chunked Gram-tile pipeline)
  chunk_sums<<<512, 256, 0, stream>>>(kb, qb, ckb, cqb);
  sink_tile<<<512, 256, 0, stream>>>(qb, kb, ckb, cqb, sink_in, src_out, csob, cqsib);
  cons_tile<<<512, 256, 0, stream>>>(qb, kb, csob, cqsib, sink_in, src_out, sabuf, ebuf);
  srccomp_kernel<<<32, 64, 0, stream>>>(ebuf, scbuf);
  scale_kernel<<<1024, 256, 0, stream>>>(qb, vb, sink_in, scbuf, c1, c2);

  // chunked causal linear attention
  phaseA<<<512, 256, 0, stream>>>(kb, c2, Sbuf);
  phaseB<<<32, 256, 0, stream>>>(Sbuf, KVp);
  phaseC<<<512, 256, 0, stream>>>(c1, kb, c2, KVp, sabuf, xatt);

  // output projection: BM=128,BN=64, split-K=2, grid 16x16x2 = 512 blocks
  gemm_mfma<128, 64, 0, 4><<<dim3(16, 16, 2), 256, 0, stream>>>(
      xatt, WoT, nullptr, nullptr, part, nullptr, 2048, 1024, 1024);
  ln_fused2b<<<2048, 256, 0, stream>>>(part, part + MD, inputs, bo, ln1g, ln1b, hbuf, hbf);

  // FFN1: BM=128,BN=64, grid 16x64 = 1024 blocks (4/CU)
  gemm_mfma<128, 64, 2, 3><<<dim3(16, 64), 256, 0, stream>>>(
      hbf, W1T, b1, nullptr, nullptr, g1, 2048, 4096, 1024);
  // FFN2: BM=128,BN=64, split-K=4, grid 16x16x4 = 1024 blocks (4/CU), raw partials
  gemm_mfma<128, 64, 0, 4><<<dim3(16, 16, 4), 256, 0, stream>>>(
      g1, W2T, nullptr, nullptr, part, nullptr, 2048, 1024, 4096);
  // LN2 fused with split-K4 reduce + bias + residual
  ln_fused4<<<2048, 256, 0, stream>>>(part, part + MD, part + 2 * MD, part + 3 * MD,
                                      hbuf, b2, ln2g, ln2b, out);
}

// Round 10
// 257.219 us; speedup vs baseline: 1.1210x; 1.0277x over previous
//
#include <hip/hip_runtime.h>
#include <hip/hip_bf16.h>

// ---------------- constants ----------------
#define EPS 1e-6f
#define NBH 32      // B*H
#define LSEQ 1024
#define DHD 64

typedef unsigned short u16;
typedef __bf16 bf16x8 __attribute__((ext_vector_type(8)));
typedef float f32x4 __attribute__((ext_vector_type(4)));

__device__ inline u16 f2bf(float f){
  union { float f; unsigned u; } un; un.f = f;
  unsigned u = un.u;
  u += 0x7fffu + ((u >> 16) & 1u);
  return (u16)(u >> 16);
}

__device__ inline float wred64(float v){
#pragma unroll
  for (int off = 32; off > 0; off >>= 1) v += __shfl_xor(v, off, 64);
  return v;
}

__device__ inline float wscan64(float v, int lane){
  float run = v;
#pragma unroll
  for (int off = 1; off < 64; off <<= 1){
    float t = __shfl_up(run, off, 64);
    if (lane >= off) run += t;
  }
  return run;   // inclusive
}

__device__ inline void gload_lds16(const u16* g, u16* l){
  __builtin_amdgcn_global_load_lds(
      (const __attribute__((address_space(1))) unsigned int*)g,
      (__attribute__((address_space(3))) unsigned int*)l, 16, 0, 0);
}

// ---------------- converts ----------------
__global__ __launch_bounds__(256) void f2bf_kernel(const float* __restrict__ in,
                                                   u16* __restrict__ out, int n4){
  int i = blockIdx.x * 256 + threadIdx.x;
  if (i < n4){
    float4 v = reinterpret_cast<const float4*>(in)[i];
    ushort4 o; o.x = f2bf(v.x); o.y = f2bf(v.y); o.z = f2bf(v.z); o.w = f2bf(v.w);
    reinterpret_cast<ushort4*>(out)[i] = o;
  }
}

// generic 32x32-tile transpose+convert: out[c][r] = bf16(in[r][c])
__device__ inline void tr_tile(const float* in, u16* out, int R, int C){
  __shared__ float tile[32][33];
  int x = threadIdx.x & 31, y = threadIdx.x >> 5;
  int r0 = blockIdx.y * 32, c0 = blockIdx.x * 32;
#pragma unroll
  for (int j = 0; j < 4; j++)
    tile[y + j*8][x] = in[(size_t)(r0 + y + j*8) * C + c0 + x];
  __syncthreads();
#pragma unroll
  for (int j = 0; j < 4; j++)
    out[(size_t)(c0 + y + j*8) * R + r0 + x] = f2bf(tile[x][y + j*8]);
}

__global__ __launch_bounds__(256) void transpose_f2bf(const float* __restrict__ in,
                                                      u16* __restrict__ out, int R, int C){
  tr_tile(in, out, R, C);
}

// 4x 1024x1024 transposes in one launch (z selects matrix)
__global__ __launch_bounds__(256) void transpose4_f2bf(
    const float* __restrict__ w0, const float* __restrict__ w1,
    const float* __restrict__ w2, const float* __restrict__ w3,
    u16* __restrict__ dqkv, u16* __restrict__ dwo){
  int z = blockIdx.z;
  const float* in = (z == 0) ? w0 : (z == 1) ? w1 : (z == 2) ? w2 : w3;
  u16* out = (z < 3) ? (dqkv + (size_t)z * 1024 * 1024) : dwo;
  tr_tile(in, out, 1024, 1024);
}

// gather q/k/v biases into one 3072 vector
__global__ __launch_bounds__(256) void bias_gather(const float* __restrict__ bq,
                                                   const float* __restrict__ bk,
                                                   const float* __restrict__ bv,
                                                   float* __restrict__ dst){
  int i = blockIdx.x * 256 + threadIdx.x;
  if (i < 3072){
    float v = (i < 1024) ? bq[i] : (i < 2048) ? bk[i - 1024] : bv[i - 2048];
    dst[i] = v;
  }
}

// ---------------- bf16 MFMA GEMM (single-buffer, T2 XOR-swizzled LDS) --------
// C[M,N] = act(A[M,K] @ Bt[N,K]^T + bias)
// LDS layout: BK=64 bf16 rows = 128B = 8 x 16B slots. Logical slot s of row r is
// stored at physical slot s^(r&7) (rule #21: global_load_lds writes linearly, so
// the SOURCE address is pre-swizzled and the READ applies the same involution).
// ACT: 0 none, 2 gelu(exact)  (OM==1 applies sigmoid for col<2048 internally)
// OM: 1 fused-QKV remap to 3x[B,H,L,DH]; 3 bf16 [M][N];
//     4 raw f32 partial (split-K slice z at outF + z*M*N, no bias)
template<int BM, int BN, int ACT, int OM>
__global__ __launch_bounds__(256) void gemm_mfma(
    const u16* __restrict__ A, const u16* __restrict__ Bt,
    const float* __restrict__ bias, const float* __restrict__ resid,
    float* __restrict__ outF, u16* __restrict__ outB,
    int M, int N, int K)
{
  constexpr int BK = 64;
  constexpr int MI = BM / 32;
  constexpr int NJ = BN / 32;
  constexpr int RA = BM / 32;           // A staging rounds (256 thr x 16B)
  constexpr int RB = BN / 32;
  __shared__ u16 As[BM * BK];
  __shared__ u16 Bs[BN * BK];
  const int tid = threadIdx.x;
  const int lane = tid & 63, wave = tid >> 6;
  const int lrow = lane & 15, lg = lane >> 4;
  const int m0 = blockIdx.x * BM, n0 = blockIdx.y * BN;
  const int wm = (wave >> 1) * (BM / 2), wn = (wave & 1) * (BN / 2);

  const int ksz = K / gridDim.z;
  const int k_begin = blockIdx.z * ksz;
  const int k_end = k_begin + ksz;

  f32x4 acc[MI][NJ];
#pragma unroll
  for (int i = 0; i < MI; i++)
#pragma unroll
    for (int j = 0; j < NJ; j++) acc[i][j] = (f32x4){0.f, 0.f, 0.f, 0.f};

  const u16* Ab = A + (size_t)m0 * K;
  const u16* Bb = Bt + (size_t)n0 * K;

  // swizzled fragment slot per (kh, lane): physical slot = (kh*4+lg) ^ (lrow&7)
  const int s0 = ((0 * 4 + lg) ^ (lrow & 7)) * 8;
  const int s1 = ((1 * 4 + lg) ^ (lrow & 7)) * 8;

  for (int k0 = k_begin; k0 < k_end; k0 += BK){
    __syncthreads();                    // previous compute done with LDS
#pragma unroll
    for (int r = 0; r < RA; ++r){
      int c = r * 256 + tid;            // 16B chunk id: row = c>>3, phys slot = c&7
      int row = c >> 3;
      int kk = ((c ^ row) & 7) << 3;    // logical slot = phys ^ (row&7)
      gload_lds16(Ab + (size_t)row * K + k0 + kk, &As[(r * 256 + wave * 64) * 8]);
    }
#pragma unroll
    for (int r = 0; r < RB; ++r){
      int c = r * 256 + tid;
      int row = c >> 3;
      int kk = ((c ^ row) & 7) << 3;
      gload_lds16(Bb + (size_t)row * K + k0 + kk, &Bs[(r * 256 + wave * 64) * 8]);
    }
    __syncthreads();                    // staging complete (compiler drains vmcnt)
#pragma unroll
    for (int kh = 0; kh < 2; ++kh){
      const int ss = (kh == 0) ? s0 : s1;
      bf16x8 af[MI], bfv[NJ];
#pragma unroll
      for (int i = 0; i < MI; ++i)
        af[i] = *reinterpret_cast<const bf16x8*>(&As[(wm + i * 16 + lrow) * BK + ss]);
#pragma unroll
      for (int j = 0; j < NJ; ++j)
        bfv[j] = *reinterpret_cast<const bf16x8*>(&Bs[(wn + j * 16 + lrow) * BK + ss]);
#pragma unroll
      for (int i = 0; i < MI; ++i)
#pragma unroll
        for (int j = 0; j < NJ; ++j)
          acc[i][j] = __builtin_amdgcn_mfma_f32_16x16x32_bf16(af[i], bfv[j], acc[i][j], 0, 0, 0);
    }
  }

#pragma unroll
  for (int i = 0; i < MI; ++i){
#pragma unroll
    for (int j = 0; j < NJ; ++j){
      int col = n0 + wn + j * 16 + lrow;
      float bv = (OM != 4 && bias) ? bias[col] : 0.f;
#pragma unroll
      for (int r = 0; r < 4; ++r){
        int row = m0 + wm + i * 16 + lg * 4 + r;
        float x = acc[i][j][r] + bv;
        if (OM == 1){
          if (col < 2048) x = 1.f / (1.f + expf(-x));
          int which = col >> 10, cc = col & 1023, h = cc >> 6, d = cc & 63;
          int b = row >> 10, l = row & 1023;
          outF[(size_t)which * (2048ull * 1024) +
               (((size_t)(b * 16 + h)) * 1024 + l) * 64 + d] = x;
        } else if (OM == 4){
          outF[((size_t)blockIdx.z * M + row) * N + col] = x;
        } else {
          if (ACT == 2) x = 0.5f * x * (1.f + erff(x * 0.70710678118654752f));
          outB[(size_t)row * N + col] = f2bf(x);
        }
      }
    }
  }
}

// ---------------- attention scalar pipeline (chunked Gram-tile form) ----------------
__global__ __launch_bounds__(256) void chunk_sums(const float* __restrict__ k, const float* __restrict__ q,
                                                  float* __restrict__ ck, float* __restrict__ cq){
  int blk = blockIdx.x;
  int lane = threadIdx.x & 63, wave = threadIdx.x >> 6;
  size_t base = (size_t)blk * 64 * DHD;
  float sk = 0.f, sq = 0.f;
  for (int l = wave * 16; l < wave * 16 + 16; l++){
    sk += k[base + l * 64 + lane];
    sq += q[base + l * 64 + lane];
  }
  __shared__ float rd[2][4][64];
  rd[0][wave][lane] = sk; rd[1][wave][lane] = sq;
  __syncthreads();
  if (wave == 0){
    ck[(size_t)blk * 64 + lane] = rd[0][0][lane] + rd[0][1][lane] + rd[0][2][lane] + rd[0][3][lane];
    cq[(size_t)blk * 64 + lane] = rd[1][0][lane] + rd[1][1][lane] + rd[1][2][lane] + rd[1][3][lane];
  }
}

// sink_in/src_out via G = Q K^T tile; also emits weighted chunk sums cso=sum so*k, cqsi=sum si*q
__global__ __launch_bounds__(256) void sink_tile(
    const float* __restrict__ q, const float* __restrict__ k,
    const float* __restrict__ ck, const float* __restrict__ cq,
    float* __restrict__ sink_in, float* __restrict__ src_out,
    float* __restrict__ cso, float* __restrict__ cqsi)
{
  int blk = blockIdx.x, bh = blk >> 4, c = blk & 15;
  int tid = threadIdx.x, lane = tid & 63, wave = tid >> 6;
  __shared__ float qT[64][65], kT[64][65], G[64][66];
  __shared__ float PK[64], PQ[64];
  __shared__ float rk[64], rq[64], crk[64], crq[64], siv[64], sov[64];
  __shared__ float rd[2][4][64];
  size_t base = ((size_t)bh * LSEQ + c * 64) * DHD;
  const float* qb = q + base; const float* kb = k + base;
  for (int c4 = tid; c4 < 1024; c4 += 256){
    int l = c4 >> 4, d0 = (c4 & 15) * 4;
    float4 qv = *reinterpret_cast<const float4*>(qb + c4 * 4);
    qT[d0+0][l] = qv.x; qT[d0+1][l] = qv.y; qT[d0+2][l] = qv.z; qT[d0+3][l] = qv.w;
    float4 kv = *reinterpret_cast<const float4*>(kb + c4 * 4);
    kT[d0+0][l] = kv.x; kT[d0+1][l] = kv.y; kT[d0+2][l] = kv.z; kT[d0+3][l] = kv.w;
  }
  if (tid < 64){
    float pk = 0.f, pq = 0.f;
    for (int cc = 0; cc < c; cc++){
      pk += ck[((size_t)bh * 16 + cc) * 64 + tid];
      pq += cq[((size_t)bh * 16 + cc) * 64 + tid];
    }
    PK[tid] = pk; PQ[tid] = pq;
  }
  __syncthreads();
  for (int j = wave * 16; j < wave * 16 + 16; j++){
    float s = wred64(kT[lane][j]);  if (lane == 0) rk[j] = s;
    float s2 = wred64(qT[lane][j]); if (lane == 0) rq[j] = s2;
  }
  float sumPK = wred64(PK[lane]);
  float sumPQ = wred64(PQ[lane]);
  {
    int l = lane, g = wave;
    float qrow[64];
#pragma unroll
    for (int d = 0; d < 64; d++) qrow[d] = qT[d][l];
    float p[16] = {};
    for (int d = 0; d < 64; d++){
      float qv = qrow[d];
#pragma unroll
      for (int j4 = 0; j4 < 4; j4++){
        float4 kk = *reinterpret_cast<const float4*>(&kT[d][g * 16 + j4 * 4]);
        p[j4*4+0] += qv * kk.x; p[j4*4+1] += qv * kk.y;
        p[j4*4+2] += qv * kk.z; p[j4*4+3] += qv * kk.w;
      }
    }
#pragma unroll
    for (int jj = 0; jj < 16; jj++) G[l][g * 16 + jj] = p[jj];
  }
  __syncthreads();
  if (wave == 0)      crk[lane] = wscan64(rk[lane], lane);
  else if (wave == 1) crq[lane] = wscan64(rq[lane], lane);
  __syncthreads();
  const float EPS2 = 64.f * EPS * EPS;
  for (int l = wave * 16; l < wave * 16 + 16; l++){
    float t1 = ((lane <= l) ? G[l][lane] : 0.f) + qT[lane][l] * PK[lane];
    float s1 = wred64(t1);
    float t2 = ((lane <= l) ? G[lane][l] : 0.f) + kT[lane][l] * PQ[lane];
    float s2 = wred64(t2);
    if (lane == 0){
      int L = c * 64 + l; float nrm = (float)(L + 1);
      float den1 = s1 + EPS * rq[l] + EPS * (sumPK + crk[l]) + EPS2;
      float den2 = s2 + EPS * rk[l] + EPS * (sumPQ + crq[l]) + EPS2;
      float si_ = nrm / den1, so_ = nrm / den2;
      sink_in[(size_t)bh * LSEQ + L] = si_;
      src_out[(size_t)bh * LSEQ + L] = so_;
      siv[l] = si_; sov[l] = so_;
    }
  }
  __syncthreads();
  float s1 = 0.f, s2 = 0.f;
  for (int l = wave * 16; l < wave * 16 + 16; l++){
    s1 += sov[l] * kT[lane][l];
    s2 += siv[l] * qT[lane][l];
  }
  rd[0][wave][lane] = s1; rd[1][wave][lane] = s2;
  __syncthreads();
  if (wave == 0){
    cso [(size_t)blk * 64 + lane] = rd[0][0][lane] + rd[0][1][lane] + rd[0][2][lane] + rd[0][3][lane];
    cqsi[(size_t)blk * 64 + lane] = rd[1][0][lane] + rd[1][1][lane] + rd[1][2][lane] + rd[1][3][lane];
  }
}

// cons_sink -> sa = sigmoid; cons_src -> clip -> ebuf = exp
__global__ __launch_bounds__(256) void cons_tile(
    const float* __restrict__ q, const float* __restrict__ k,
    const float* __restrict__ cso, const float* __restrict__ cqsi,
    const float* __restrict__ sink_in, const float* __restrict__ src_out,
    float* __restrict__ sa, float* __restrict__ ebuf)
{
  int blk = blockIdx.x, bh = blk >> 4, c = blk & 15;
  int tid = threadIdx.x, lane = tid & 63, wave = tid >> 6;
  __shared__ float qT[64][65], kT[64][65], G[64][66];
  __shared__ float PKso[64], PQsi[64];
  __shared__ float rk[64], rq[64], cwrk[64], cwrq[64], siv[64], sov[64];
  size_t base = ((size_t)bh * LSEQ + c * 64) * DHD;
  const float* qb = q + base; const float* kb = k + base;
  for (int c4 = tid; c4 < 1024; c4 += 256){
    int l = c4 >> 4, d0 = (c4 & 15) * 4;
    float4 qv = *reinterpret_cast<const float4*>(qb + c4 * 4);
    qT[d0+0][l] = qv.x; qT[d0+1][l] = qv.y; qT[d0+2][l] = qv.z; qT[d0+3][l] = qv.w;
    float4 kv = *reinterpret_cast<const float4*>(kb + c4 * 4);
    kT[d0+0][l] = kv.x; kT[d0+1][l] = kv.y; kT[d0+2][l] = kv.z; kT[d0+3][l] = kv.w;
  }
  if (tid < 64){
    float pk = 0.f, pq = 0.f;
    for (int cc = 0; cc < c; cc++){
      pk += cso [((size_t)bh * 16 + cc) * 64 + tid];
      pq += cqsi[((size_t)bh * 16 + cc) * 64 + tid];
    }
    PKso[tid] = pk; PQsi[tid] = pq;
  } else if (tid < 128){
    int l = tid - 64;
    sov[l] = src_out[(size_t)bh * LSEQ + c * 64 + l];
    siv[l] = sink_in[(size_t)bh * LSEQ + c * 64 + l];
  }
  __syncthreads();
  for (int j = wave * 16; j < wave * 16 + 16; j++){
    float s = wred64(kT[lane][j]);  if (lane == 0) rk[j] = s;
    float s2 = wred64(qT[lane][j]); if (lane == 0) rq[j] = s2;
  }
  float sumPKso = wred64(PKso[lane]);
  float sumPQsi = wred64(PQsi[lane]);
  {
    int l = lane, g = wave;
    float qrow[64];
#pragma unroll
    for (int d = 0; d < 64; d++) qrow[d] = qT[d][l];
    float p[16] = {};
    for (int d = 0; d < 64; d++){
      float qv = qrow[d];
#pragma unroll
      for (int j4 = 0; j4 < 4; j4++){
        float4 kk = *reinterpret_cast<const float4*>(&kT[d][g * 16 + j4 * 4]);
        p[j4*4+0] += qv * kk.x; p[j4*4+1] += qv * kk.y;
        p[j4*4+2] += qv * kk.z; p[j4*4+3] += qv * kk.w;
      }
    }
#pragma unroll
    for (int jj = 0; jj < 16; jj++) G[l][g * 16 + jj] = p[jj];
  }
  __syncthreads();
  if (wave == 0)      cwrk[lane] = wscan64(sov[lane] * rk[lane], lane);
  else if (wave == 1) cwrq[lane] = wscan64(siv[lane] * rq[lane], lane);
  __syncthreads();
  const float EPS2 = 64.f * EPS * EPS;
  for (int l = wave * 16; l < wave * 16 + 16; l++){
    float t3 = ((lane <= l) ? sov[lane] * G[l][lane] : 0.f) + qT[lane][l] * PKso[lane];
    float s3 = wred64(t3);
    float t4 = ((lane <= l) ? siv[lane] * G[lane][l] : 0.f) + kT[lane][l] * PQsi[lane];
    float s4 = wred64(t4);
    if (lane == 0){
      int L = c * 64 + l; float nrm = (float)(L + 1);
      float cs = (s3 + EPS * rq[l] + EPS * (sumPKso + cwrk[l]) + EPS2) / nrm;
      sa[(size_t)bh * LSEQ + L] = 1.f / (1.f + expf(-cs));
      float c2 = (s4 + EPS * rk[l] + EPS * (sumPQsi + cwrq[l]) + EPS2) / nrm;
      c2 = fminf(1.f, fmaxf(-1.f, c2));
      ebuf[(size_t)bh * LSEQ + L] = expf(c2);
    }
  }
}

// src_comp = e / cumsum(e) * (l+1)
__global__ __launch_bounds__(64) void srccomp_kernel(const float* __restrict__ ebuf, float* __restrict__ sc){
  int bh = blockIdx.x; int lane = threadIdx.x;
  const float* eb = ebuf + (size_t)bh * LSEQ;
  float loc[16]; float s = 0.f;
#pragma unroll
  for (int i = 0; i < 16; i++){ loc[i] = eb[lane * 16 + i]; s += loc[i]; }
  float run = wscan64(s, lane);
  float acc = run - s;
  float* scb = sc + (size_t)bh * LSEQ;
#pragma unroll
  for (int i = 0; i < 16; i++){
    acc += loc[i];
    scb[lane * 16 + i] = loc[i] / acc * (float)(lane * 16 + i + 1);
  }
}

// ---------------- chunked causal linear attention (scale fused in) ----------------
// phase A: S[m][d] = sum_{l in chunk} (v[l,m]*sc[l]) * k[l,d]
__global__ __launch_bounds__(256) void phaseA(const float* __restrict__ k, const float* __restrict__ v,
                                              const float* __restrict__ sc, float* __restrict__ S){
  int blk = blockIdx.x; int bh = blk >> 4, c = blk & 15;
  __shared__ float ks[64][68], vss[64][68];
  __shared__ float vc[64];
  int tid = threadIdx.x;
  size_t base = ((size_t)bh * LSEQ + c * 64) * DHD;
  const float* kb = k + base; const float* vb = v + base;
  if (tid < 64) vc[tid] = sc[(size_t)bh * LSEQ + c * 64 + tid];
  __syncthreads();
  for (int c4 = tid; c4 < 1024; c4 += 256){
    int l = c4 >> 4, d0 = (c4 & 15) * 4;
    *reinterpret_cast<float4*>(&ks[l][d0]) = *reinterpret_cast<const float4*>(kb + c4 * 4);
    float4 vv = *reinterpret_cast<const float4*>(vb + c4 * 4);
    float w = vc[l];
    vss[l][d0+0] = vv.x * w; vss[l][d0+1] = vv.y * w;
    vss[l][d0+2] = vv.z * w; vss[l][d0+3] = vv.w * w;
  }
  __syncthreads();
  int m = tid >> 2, dg = tid & 3;
  float acc[16] = {};
  for (int l = 0; l < 64; l++){
    float vm = vss[l][m];
#pragma unroll
    for (int d4 = 0; d4 < 4; d4++){
      float4 kk = *reinterpret_cast<const float4*>(&ks[l][dg * 16 + d4 * 4]);
      acc[d4*4+0] += vm * kk.x; acc[d4*4+1] += vm * kk.y;
      acc[d4*4+2] += vm * kk.z; acc[d4*4+3] += vm * kk.w;
    }
  }
  float* Sb = S + (size_t)blk * 4096 + m * 64 + dg * 16;
#pragma unroll
  for (int d4 = 0; d4 < 4; d4++)
    *reinterpret_cast<float4*>(Sb + d4 * 4) =
        make_float4(acc[d4*4], acc[d4*4+1], acc[d4*4+2], acc[d4*4+3]);
}

// phase B: exclusive prefix over chunks; one block per (bh, c) = 512 blocks
__global__ __launch_bounds__(256) void phaseB(const float* __restrict__ S, float* __restrict__ KVp){
  int blk = blockIdx.x; int bh = blk >> 4, c = blk & 15;
  int off = threadIdx.x * 16;
  float acc[16] = {};
  for (int cc = 0; cc < c; cc++){
    size_t idx = ((size_t)bh * 16 + cc) * 4096 + off;
#pragma unroll
    for (int t = 0; t < 4; t++){
      float4 sv = *reinterpret_cast<const float4*>(S + idx + t * 4);
      acc[t*4] += sv.x; acc[t*4+1] += sv.y; acc[t*4+2] += sv.z; acc[t*4+3] += sv.w;
    }
  }
  size_t oidx = ((size_t)bh * 16 + c) * 4096 + off;
#pragma unroll
  for (int t = 0; t < 4; t++)
    *reinterpret_cast<float4*>(KVp + oidx + t * 4) =
        make_float4(acc[t*4], acc[t*4+1], acc[t*4+2], acc[t*4+3]);
}

// phase C: x[l,m] = sa[l]*( sum_d (q[l,d]*qc[l])*KVp[m,d] + sum_{j<=l} P[l,j]*(v[j,m]*vc[j]) )
__global__ __launch_bounds__(256) void phaseC(const float* __restrict__ q, const float* __restrict__ k,
                                              const float* __restrict__ v, const float* __restrict__ KVp,
                                              const float* __restrict__ sink_in, const float* __restrict__ sc,
                                              const float* __restrict__ sa, u16* __restrict__ x){
  int blk = blockIdx.x; int bh = blk >> 4, c = blk & 15;
  int b = bh >> 4, h = bh & 15;
  __shared__ float qsT[64][65];
  __shared__ float kT[64][68];
  __shared__ float vss[64][68];
  __shared__ float kvs[64][68];
  __shared__ float Ps[64][66];
  __shared__ float qc[64], vc[64];
  int tid = threadIdx.x;
  size_t base = ((size_t)bh * LSEQ + c * 64) * DHD;
  const float* qb = q + base; const float* kb = k + base; const float* vb = v + base;
  const float* kvb = KVp + (size_t)blk * 4096;
  if (tid < 64){
    int L = c * 64 + tid;
    qc[tid] = sink_in[(size_t)bh * LSEQ + L] / (float)(L + 1);
    vc[tid] = sc[(size_t)bh * LSEQ + L];
  }
  __syncthreads();
  for (int c4 = tid; c4 < 1024; c4 += 256){
    int l = c4 >> 4, d0 = (c4 & 15) * 4;
    float qw = qc[l], vw = vc[l];
    float4 qv = *reinterpret_cast<const float4*>(qb + c4 * 4);
    qsT[d0+0][l] = qv.x * qw; qsT[d0+1][l] = qv.y * qw;
    qsT[d0+2][l] = qv.z * qw; qsT[d0+3][l] = qv.w * qw;
    float4 kv4 = *reinterpret_cast<const float4*>(kb + c4 * 4);
    kT[d0+0][l] = kv4.x; kT[d0+1][l] = kv4.y; kT[d0+2][l] = kv4.z; kT[d0+3][l] = kv4.w;
    float4 vv = *reinterpret_cast<const float4*>(vb + c4 * 4);
    vss[l][d0+0] = vv.x * vw; vss[l][d0+1] = vv.y * vw;
    vss[l][d0+2] = vv.z * vw; vss[l][d0+3] = vv.w * vw;
    *reinterpret_cast<float4*>(&kvs[l][d0]) = *reinterpret_cast<const float4*>(kvb + c4 * 4);
  }
  __syncthreads();
  int l = tid & 63, g = tid >> 6;
  float qrow[64];
#pragma unroll
  for (int d = 0; d < 64; d++) qrow[d] = qsT[d][l];

  float p[16] = {};
  for (int d = 0; d < 64; d++){
    float qv = qrow[d];
#pragma unroll
    for (int j4 = 0; j4 < 4; j4++){
      float4 kk = *reinterpret_cast<const float4*>(&kT[d][g * 16 + j4 * 4]);
      p[j4*4+0] += qv * kk.x; p[j4*4+1] += qv * kk.y;
      p[j4*4+2] += qv * kk.z; p[j4*4+3] += qv * kk.w;
    }
  }
#pragma unroll
  for (int jj = 0; jj < 16; jj++){
    int j = g * 16 + jj;
    Ps[l][j] = (j <= l) ? p[jj] : 0.f;
  }
  __syncthreads();

  float acc[16];
#pragma unroll
  for (int mm = 0; mm < 16; mm++){
    float a = 0.f;
#pragma unroll
    for (int d4 = 0; d4 < 16; d4++){
      float4 kv4 = *reinterpret_cast<const float4*>(&kvs[g * 16 + mm][d4 * 4]);
      a += qrow[d4*4+0]*kv4.x + qrow[d4*4+1]*kv4.y + qrow[d4*4+2]*kv4.z + qrow[d4*4+3]*kv4.w;
    }
    acc[mm] = a;
  }
  for (int j = 0; j < 64; j++){
    float pv = Ps[l][j];
#pragma unroll
    for (int m4 = 0; m4 < 4; m4++){
      float4 vv = *reinterpret_cast<const float4*>(&vss[j][g * 16 + m4 * 4]);
      acc[m4*4+0] += pv * vv.x; acc[m4*4+1] += pv * vv.y;
      acc[m4*4+2] += pv * vv.z; acc[m4*4+3] += pv * vv.w;
    }
  }
  float sav = sa[(size_t)bh * LSEQ + c * 64 + l];
  u16* xo = x + ((size_t)(b * 1024 + c * 64 + l)) * 1024 + h * 64 + g * 16;
#pragma unroll
  for (int mm = 0; mm < 16; mm++) xo[mm] = f2bf(acc[mm] * sav);
}

// ---------------- fused layernorms ----------------
// LN over (p0 + p1 + bias + resid); emits f32 + bf16 (Wo split-K combine + LN1)
__global__ __launch_bounds__(256) void ln_fused2b(
    const float* __restrict__ p0, const float* __restrict__ p1,
    const float* __restrict__ resid, const float* __restrict__ bias,
    const float* __restrict__ g, const float* __restrict__ b,
    float* __restrict__ out, u16* __restrict__ outbf){
  int row = blockIdx.x; int tid = threadIdx.x;
  int lane = tid & 63, wave = tid >> 6;
  size_t off = (size_t)row * 1024 + tid * 4;
  float4 a0 = *reinterpret_cast<const float4*>(p0 + off);
  float4 a1 = *reinterpret_cast<const float4*>(p1 + off);
  float4 rr = *reinterpret_cast<const float4*>(resid + off);
  float4 bb = *reinterpret_cast<const float4*>(bias + tid * 4);
  float4 v = make_float4(a0.x + a1.x + rr.x + bb.x, a0.y + a1.y + rr.y + bb.y,
                         a0.z + a1.z + rr.z + bb.z, a0.w + a1.w + rr.w + bb.w);
  float s = v.x + v.y + v.z + v.w;
  float s2 = v.x*v.x + v.y*v.y + v.z*v.z + v.w*v.w;
  s = wred64(s); s2 = wred64(s2);
  __shared__ float red[2][4];
  if (lane == 0){ red[0][wave] = s; red[1][wave] = s2; }
  __syncthreads();
  float S = red[0][0] + red[0][1] + red[0][2] + red[0][3];
  float S2 = red[1][0] + red[1][1] + red[1][2] + red[1][3];
  float mean = S * (1.f / 1024.f);
  float var = S2 * (1.f / 1024.f) - mean * mean;
  float inv = rsqrtf(var + 1e-5f);
  float4 gv = *reinterpret_cast<const float4*>(g + tid * 4);
  float4 bv = *reinterpret_cast<const float4*>(b + tid * 4);
  float y0 = (v.x - mean) * inv * gv.x + bv.x;
  float y1 = (v.y - mean) * inv * gv.y + bv.y;
  float y2 = (v.z - mean) * inv * gv.z + bv.z;
  float y3 = (v.w - mean) * inv * gv.w + bv.w;
  *reinterpret_cast<float4*>(out + off) = make_float4(y0, y1, y2, y3);
  ushort4 o; o.x = f2bf(y0); o.y = f2bf(y1); o.z = f2bf(y2); o.w = f2bf(y3);
  *reinterpret_cast<ushort4*>(outbf + off) = o;
}

// LN over (p0+p1+p2+p3 + bias + resid) -> f32 out (FFN2 split-K4 combine + LN2)
__global__ __launch_bounds__(256) void ln_fused4(
    const float* __restrict__ p0, const float* __restrict__ p1,
    const float* __restrict__ p2, const float* __restrict__ p3,
    const float* __restrict__ resid, const float* __restrict__ bias,
    const float* __restrict__ g, const float* __restrict__ b,
    float* __restrict__ out){
  int row = blockIdx.x; int tid = threadIdx.x;
  int lane = tid & 63, wave = tid >> 6;
  size_t off = (size_t)row * 1024 + tid * 4;
  float4 a0 = *reinterpret_cast<const float4*>(p0 + off);
  float4 a1 = *reinterpret_cast<const float4*>(p1 + off);
  float4 a2 = *reinterpret_cast<const float4*>(p2 + off);
  float4 a3 = *reinterpret_cast<const float4*>(p3 + off);
  float4 rr = *reinterpret_cast<const float4*>(resid + off);
  float4 bb = *reinterpret_cast<const float4*>(bias + tid * 4);
  float4 v = make_float4(a0.x + a1.x + a2.x + a3.x + rr.x + bb.x,
                         a0.y + a1.y + a2.y + a3.y + rr.y + bb.y,
                         a0.z + a1.z + a2.z + a3.z + rr.z + bb.z,
                         a0.w + a1.w + a2.w + a3.w + rr.w + bb.w);
  float s = v.x + v.y + v.z + v.w;
  float s2 = v.x*v.x + v.y*v.y + v.z*v.z + v.w*v.w;
  s = wred64(s); s2 = wred64(s2);
  __shared__ float red[2][4];
  if (lane == 0){ red[0][wave] = s; red[1][wave] = s2; }
  __syncthreads();
  float S = red[0][0] + red[0][1] + red[0][2] + red[0][3];
  float S2 = red[1][0] + red[1][1] + red[1][2] + red[1][3];
  float mean = S * (1.f / 1024.f);
  float var = S2 * (1.f / 1024.f) - mean * mean;
  float inv = rsqrtf(var + 1e-5f);
  float4 gv = *reinterpret_cast<const float4*>(g + tid * 4);
  float4 bv = *reinterpret_cast<const float4*>(b + tid * 4);
  float y0 = (v.x - mean) * inv * gv.x + bv.x;
  float y1 = (v.y - mean) * inv * gv.y + bv.y;
  float y2 = (v.z - mean) * inv * gv.z + bv.z;
  float y3 = (v.w - mean) * inv * gv.w + bv.w;
  *reinterpret_cast<float4*>(out + off) = make_float4(y0, y1, y2, y3);
}

// ---------------- launch ----------------
extern "C" void kernel_launch(void* const* d_in, const int* in_sizes, int n_in,
                              void* d_out, int out_size, void* d_ws, size_t ws_size,
                              hipStream_t stream){
  (void)in_sizes; (void)n_in; (void)out_size; (void)ws_size;
  const float* inputs = (const float*)d_in[0];
  const float* Wq = (const float*)d_in[2];  const float* bq = (const float*)d_in[3];
  const float* Wk = (const float*)d_in[4];  const float* bk = (const float*)d_in[5];
  const float* Wv = (const float*)d_in[6];  const float* bv = (const float*)d_in[7];
  const float* Wo = (const float*)d_in[8];  const float* bo = (const float*)d_in[9];
  const float* ln1g = (const float*)d_in[10]; const float* ln1b = (const float*)d_in[11];
  const float* W1 = (const float*)d_in[12]; const float* b1 = (const float*)d_in[13];
  const float* W2 = (const float*)d_in[14]; const float* b2 = (const float*)d_in[15];
  const float* ln2g = (const float*)d_in[16]; const float* ln2b = (const float*)d_in[17];
  float* out = (float*)d_out;

  char* wsp = (char*)d_ws; size_t off = 0;
  auto alloc = [&](size_t bytes) -> void* {
    off = (off + 255) & ~(size_t)255;
    void* p = wsp + off; off += bytes; return p;
  };
  const size_t MD = (size_t)2048 * 1024;
  u16* Xbf    = (u16*)alloc(MD * 2);
  u16* WqkvT  = (u16*)alloc((size_t)3 * 1024 * 1024 * 2);
  u16* WoT    = (u16*)alloc((size_t)1024 * 1024 * 2);
  u16* W1T    = (u16*)alloc((size_t)4096 * 1024 * 2);
  u16* W2T    = (u16*)alloc((size_t)4096 * 1024 * 2);
  float* bqkv = (float*)alloc(3072 * 4);
  float* qkvb = (float*)alloc(3 * MD * 4);
  float* qb = qkvb; float* kb = qkvb + MD; float* vb = qkvb + 2 * MD;
  // contiguous 32MB quad: attention {S, KVp}; later split-K partial store
  float* quad = (float*)alloc(4 * MD * 4);
  float* Sbuf = quad;            // S
  float* KVp  = quad + MD;       // KV prefix
  float* ckb  = (float*)alloc((size_t)512 * 64 * 4);
  float* cqb  = (float*)alloc((size_t)512 * 64 * 4);
  float* csob = (float*)alloc((size_t)512 * 64 * 4);
  float* cqsib= (float*)alloc((size_t)512 * 64 * 4);
  float* sink_in = (float*)alloc(NBH * LSEQ * 4);
  float* src_out = (float*)alloc(NBH * LSEQ * 4);
  float* sabuf   = (float*)alloc(NBH * LSEQ * 4);
  float* ebuf    = (float*)alloc(NBH * LSEQ * 4);
  float* scbuf   = (float*)alloc(NBH * LSEQ * 4);
  u16* xatt   = (u16*)alloc(MD * 2);
  u16* g1     = (u16*)alloc((size_t)2048 * 4096 * 2);
  // reuse after attention: Wo partials = quad[0..1]; FFN2 partials = quad[0..3]
  float* part = quad;
  float* hbuf = vb;              // LN1 f32 out (vb dead after phaseC)
  u16* hbf = (u16*)qb;           // LN1 bf16 out (qb dead after phaseC)

  // converts + weight prep
  f2bf_kernel<<<2048, 256, 0, stream>>>(inputs, Xbf, (int)(MD / 4));
  transpose4_f2bf<<<dim3(32, 32, 4), 256, 0, stream>>>(Wq, Wk, Wv, Wo, WqkvT, WoT);
  transpose_f2bf<<<dim3(128, 32), 256, 0, stream>>>(W1, W1T, 1024, 4096);
  transpose_f2bf<<<dim3(32, 128), 256, 0, stream>>>(W2, W2T, 4096, 1024);
  bias_gather<<<12, 256, 0, stream>>>(bq, bk, bv, bqkv);

  // fused QKV projection: BM=128,BN=64, grid 16x48 = 768 blocks (3/CU)
  gemm_mfma<128, 64, 0, 1><<<dim3(16, 48), 256, 0, stream>>>(
      Xbf, WqkvT, bqkv, nullptr, qkvb, nullptr, 2048, 3072, 1024);

  // attention scalars (chunked Gram-tile pipeline)
  chunk_sums<<<512, 256, 0, stream>>>(kb, qb, ckb, cqb);
  sink_tile<<<512, 256, 0, stream>>>(qb, kb, ckb, cqb, sink_in, src_out, csob, cqsib);
  cons_tile<<<512, 256, 0, stream>>>(qb, kb, csob, cqsib, sink_in, src_out, sabuf, ebuf);
  srccomp_kernel<<<32, 64, 0, stream>>>(ebuf, scbuf);

  // chunked causal linear attention (scale fused into A and C)
  phaseA<<<512, 256, 0, stream>>>(kb, vb, scbuf, Sbuf);
  phaseB<<<512, 256, 0, stream>>>(Sbuf, KVp);
  phaseC<<<512, 256, 0, stream>>>(qb, kb, vb, KVp, sink_in, scbuf, sabuf, xatt);

  // output projection: BM=128,BN=64, split-K=2, grid 16x16x2 = 512 blocks
  gemm_mfma<128, 64, 0, 4><<<dim3(16, 16, 2), 256, 0, stream>>>(
      xatt, WoT, nullptr, nullptr, part, nullptr, 2048, 1024, 1024);
  ln_fused2b<<<2048, 256, 0, stream>>>(part, part + MD, inputs, bo, ln1g, ln1b, hbuf, hbf);

  // FFN1: BM=128,BN=128, grid 16x32 = 512 blocks (2/CU), dense 16-MFMA/8-read tiles
  gemm_mfma<128, 128, 2, 3><<<dim3(16, 32), 256, 0, stream>>>(
      hbf, W1T, b1, nullptr, nullptr, g1, 2048, 4096, 1024);
  // FFN2: BM=128,BN=128, split-K=4, grid 16x8x4 = 512 blocks, raw partials
  gemm_mfma<128, 128, 0, 4><<<dim3(16, 8, 4), 256, 0, stream>>>(
      g1, W2T, nullptr, nullptr, part, nullptr, 2048, 1024, 4096);
  // LN2 fused with split-K4 reduce + bias + residual
  ln_fused4<<<2048, 256, 0, stream>>>(part, part + MD, part + 2 * MD, part + 3 * MD,
                                      hbuf, b2, ln2g, ln2b, out);
}

// Round 11
// 221.596 us; speedup vs baseline: 1.3012x; 1.1608x over previous
//
#include <hip/hip_runtime.h>
#include <hip/hip_bf16.h>

// ---------------- constants ----------------
#define EPS 1e-6f
#define NBH 32      // B*H
#define LSEQ 1024
#define DHD 64

typedef unsigned short u16;
typedef __bf16 bf16x8 __attribute__((ext_vector_type(8)));
typedef float f32x4 __attribute__((ext_vector_type(4)));

__device__ inline u16 f2bf(float f){
  union { float f; unsigned u; } un; un.f = f;
  unsigned u = un.u;
  u += 0x7fffu + ((u >> 16) & 1u);
  return (u16)(u >> 16);
}

__device__ inline float wred64(float v){
#pragma unroll
  for (int off = 32; off > 0; off >>= 1) v += __shfl_xor(v, off, 64);
  return v;
}

__device__ inline float wscan64(float v, int lane){
  float run = v;
#pragma unroll
  for (int off = 1; off < 64; off <<= 1){
    float t = __shfl_up(run, off, 64);
    if (lane >= off) run += t;
  }
  return run;   // inclusive
}

__device__ inline float fast_sigmoid(float x){
  return 1.f / (1.f + __expf(-x));
}

__device__ inline void gload_lds16(const u16* g, u16* l){
  __builtin_amdgcn_global_load_lds(
      (const __attribute__((address_space(1))) unsigned int*)g,
      (__attribute__((address_space(3))) unsigned int*)l, 16, 0, 0);
}

// ---------------- converts ----------------
__global__ __launch_bounds__(256) void f2bf_kernel(const float* __restrict__ in,
                                                   u16* __restrict__ out, int n4){
  int i = blockIdx.x * 256 + threadIdx.x;
  if (i < n4){
    float4 v = reinterpret_cast<const float4*>(in)[i];
    ushort4 o; o.x = f2bf(v.x); o.y = f2bf(v.y); o.z = f2bf(v.z); o.w = f2bf(v.w);
    reinterpret_cast<ushort4*>(out)[i] = o;
  }
}

// generic 32x32-tile transpose+convert: out[c][r] = bf16(in[r][c])
__device__ inline void tr_tile2(const float* in, u16* out, int R, int C, int r0, int c0){
  __shared__ float tile[32][33];
  int x = threadIdx.x & 31, y = threadIdx.x >> 5;
#pragma unroll
  for (int j = 0; j < 4; j++)
    tile[y + j*8][x] = in[(size_t)(r0 + y + j*8) * C + c0 + x];
  __syncthreads();
#pragma unroll
  for (int j = 0; j < 4; j++)
    out[(size_t)(c0 + y + j*8) * R + r0 + x] = f2bf(tile[x][y + j*8]);
}

// 4x 1024x1024 transposes in one launch (z selects matrix)
__global__ __launch_bounds__(256) void transpose4_f2bf(
    const float* __restrict__ w0, const float* __restrict__ w1,
    const float* __restrict__ w2, const float* __restrict__ w3,
    u16* __restrict__ dqkv, u16* __restrict__ dwo){
  int z = blockIdx.z;
  const float* in = (z == 0) ? w0 : (z == 1) ? w1 : (z == 2) ? w2 : w3;
  u16* out = (z < 3) ? (dqkv + (size_t)z * 1024 * 1024) : dwo;
  tr_tile2(in, out, 1024, 1024, blockIdx.y * 32, blockIdx.x * 32);
}

// W1 (1024x4096) and W2 (4096x1024) transposes in one launch
__global__ __launch_bounds__(256) void transpose2_f2bf(
    const float* __restrict__ w1, const float* __restrict__ w2,
    u16* __restrict__ d1, u16* __restrict__ d2){
  if (blockIdx.z == 0)
    tr_tile2(w1, d1, 1024, 4096, blockIdx.y * 32, blockIdx.x * 32);   // 128 x-blocks cols
  else
    tr_tile2(w2, d2, 4096, 1024, blockIdx.x * 32, blockIdx.y * 32);   // 128 x-blocks rows
}

// gather q/k/v biases into one 3072 vector
__global__ __launch_bounds__(256) void bias_gather(const float* __restrict__ bq,
                                                   const float* __restrict__ bk,
                                                   const float* __restrict__ bv,
                                                   float* __restrict__ dst){
  int i = blockIdx.x * 256 + threadIdx.x;
  if (i < 3072){
    float v = (i < 1024) ? bq[i] : (i < 2048) ? bk[i - 1024] : bv[i - 2048];
    dst[i] = v;
  }
}

// ---------------- bf16 MFMA GEMM (single-buffer, T2 XOR-swizzled LDS) --------
// C[M,N] = act(A[M,K] @ Bt[N,K]^T + bias)
// LDS: BK=64 bf16 rows = 8 x 16B slots; slot s of row r at phys slot s^(r&7)
// (rule #21: linear gload_lds dest + pre-swizzled SOURCE + swizzled READ).
// ACT: 0 none, 2 gelu  (OM==1 applies fast sigmoid for col<2048 internally)
// OM: 1 fused-QKV remap to 3x[B,H,L,DH]; 3 bf16 [M][N];
//     4 raw f32 partial (split-K slice z at outF + z*M*N, no bias)
template<int BM, int BN, int ACT, int OM>
__global__ __launch_bounds__(256) void gemm_mfma(
    const u16* __restrict__ A, const u16* __restrict__ Bt,
    const float* __restrict__ bias, const float* __restrict__ resid,
    float* __restrict__ outF, u16* __restrict__ outB,
    int M, int N, int K)
{
  constexpr int BK = 64;
  constexpr int MI = BM / 32;
  constexpr int NJ = BN / 32;
  constexpr int RA = BM / 32;
  constexpr int RB = BN / 32;
  __shared__ u16 As[BM * BK];
  __shared__ u16 Bs[BN * BK];
  const int tid = threadIdx.x;
  const int lane = tid & 63, wave = tid >> 6;
  const int lrow = lane & 15, lg = lane >> 4;
  const int m0 = blockIdx.x * BM, n0 = blockIdx.y * BN;
  const int wm = (wave >> 1) * (BM / 2), wn = (wave & 1) * (BN / 2);

  const int ksz = K / gridDim.z;
  const int k_begin = blockIdx.z * ksz;
  const int k_end = k_begin + ksz;

  f32x4 acc[MI][NJ];
#pragma unroll
  for (int i = 0; i < MI; i++)
#pragma unroll
    for (int j = 0; j < NJ; j++) acc[i][j] = (f32x4){0.f, 0.f, 0.f, 0.f};

  const u16* Ab = A + (size_t)m0 * K;
  const u16* Bb = Bt + (size_t)n0 * K;

  const int s0 = ((0 * 4 + lg) ^ (lrow & 7)) * 8;
  const int s1 = ((1 * 4 + lg) ^ (lrow & 7)) * 8;

  for (int k0 = k_begin; k0 < k_end; k0 += BK){
    __syncthreads();
#pragma unroll
    for (int r = 0; r < RA; ++r){
      int c = r * 256 + tid;
      int row = c >> 3;
      int kk = ((c ^ row) & 7) << 3;
      gload_lds16(Ab + (size_t)row * K + k0 + kk, &As[(r * 256 + wave * 64) * 8]);
    }
#pragma unroll
    for (int r = 0; r < RB; ++r){
      int c = r * 256 + tid;
      int row = c >> 3;
      int kk = ((c ^ row) & 7) << 3;
      gload_lds16(Bb + (size_t)row * K + k0 + kk, &Bs[(r * 256 + wave * 64) * 8]);
    }
    __syncthreads();
#pragma unroll
    for (int kh = 0; kh < 2; ++kh){
      const int ss = (kh == 0) ? s0 : s1;
      bf16x8 af[MI], bfv[NJ];
#pragma unroll
      for (int i = 0; i < MI; ++i)
        af[i] = *reinterpret_cast<const bf16x8*>(&As[(wm + i * 16 + lrow) * BK + ss]);
#pragma unroll
      for (int j = 0; j < NJ; ++j)
        bfv[j] = *reinterpret_cast<const bf16x8*>(&Bs[(wn + j * 16 + lrow) * BK + ss]);
#pragma unroll
      for (int i = 0; i < MI; ++i)
#pragma unroll
        for (int j = 0; j < NJ; ++j)
          acc[i][j] = __builtin_amdgcn_mfma_f32_16x16x32_bf16(af[i], bfv[j], acc[i][j], 0, 0, 0);
    }
  }

#pragma unroll
  for (int i = 0; i < MI; ++i){
#pragma unroll
    for (int j = 0; j < NJ; ++j){
      int col = n0 + wn + j * 16 + lrow;
      float bv = (OM != 4 && bias) ? bias[col] : 0.f;
#pragma unroll
      for (int r = 0; r < 4; ++r){
        int row = m0 + wm + i * 16 + lg * 4 + r;
        float x = acc[i][j][r] + bv;
        if (OM == 1){
          if (col < 2048) x = fast_sigmoid(x);
          int which = col >> 10, cc = col & 1023, h = cc >> 6, d = cc & 63;
          int b = row >> 10, l = row & 1023;
          outF[(size_t)which * (2048ull * 1024) +
               (((size_t)(b * 16 + h)) * 1024 + l) * 64 + d] = x;
        } else if (OM == 4){
          outF[((size_t)blockIdx.z * M + row) * N + col] = x;
        } else {
          if (ACT == 2){
            // tanh-form gelu via fast exp: tanh(u) = 1 - 2/(e^{2u}+1)
            float u = 0.7978845608f * (x + 0.044715f * x * x * x);
            float e = __expf(2.f * u);
            x = 0.5f * x * (2.f - 2.f / (e + 1.f));
          }
          outB[(size_t)row * N + col] = f2bf(x);
        }
      }
    }
  }
}

// ---------------- attention scalar pipeline (chunked Gram-tile form) ----------------
__global__ __launch_bounds__(256) void chunk_sums(const float* __restrict__ k, const float* __restrict__ q,
                                                  float* __restrict__ ck, float* __restrict__ cq){
  int blk = blockIdx.x;
  int lane = threadIdx.x & 63, wave = threadIdx.x >> 6;
  size_t base = (size_t)blk * 64 * DHD;
  float sk = 0.f, sq = 0.f;
  for (int l = wave * 16; l < wave * 16 + 16; l++){
    sk += k[base + l * 64 + lane];
    sq += q[base + l * 64 + lane];
  }
  __shared__ float rd[2][4][64];
  rd[0][wave][lane] = sk; rd[1][wave][lane] = sq;
  __syncthreads();
  if (wave == 0){
    ck[(size_t)blk * 64 + lane] = rd[0][0][lane] + rd[0][1][lane] + rd[0][2][lane] + rd[0][3][lane];
    cq[(size_t)blk * 64 + lane] = rd[1][0][lane] + rd[1][1][lane] + rd[1][2][lane] + rd[1][3][lane];
  }
}

// sink_in/src_out via G = Q K^T tile; also emits weighted chunk sums cso, cqsi.
// Reductions use quarter-split LDS partials (no per-row wred64 serialization).
__global__ __launch_bounds__(256) void sink_tile(
    const float* __restrict__ q, const float* __restrict__ k,
    const float* __restrict__ ck, const float* __restrict__ cq,
    float* __restrict__ sink_in, float* __restrict__ src_out,
    float* __restrict__ cso, float* __restrict__ cqsi)
{
  int blk = blockIdx.x, bh = blk >> 4, c = blk & 15;
  int tid = threadIdx.x, lane = tid & 63, wave = tid >> 6;
  __shared__ float qT[64][65], kT[64][65], G[64][66];
  __shared__ float PK[64], PQ[64];
  __shared__ float rk[64], rq[64], crk[64], crq[64], siv[64], sov[64];
  __shared__ float rd[2][4][64];
  size_t base = ((size_t)bh * LSEQ + c * 64) * DHD;
  const float* qb = q + base; const float* kb = k + base;
  for (int c4 = tid; c4 < 1024; c4 += 256){
    int l = c4 >> 4, d0 = (c4 & 15) * 4;
    float4 qv = *reinterpret_cast<const float4*>(qb + c4 * 4);
    qT[d0+0][l] = qv.x; qT[d0+1][l] = qv.y; qT[d0+2][l] = qv.z; qT[d0+3][l] = qv.w;
    float4 kv = *reinterpret_cast<const float4*>(kb + c4 * 4);
    kT[d0+0][l] = kv.x; kT[d0+1][l] = kv.y; kT[d0+2][l] = kv.z; kT[d0+3][l] = kv.w;
  }
  if (tid < 64){
    float pk = 0.f, pq = 0.f;
    for (int cc = 0; cc < c; cc++){
      pk += ck[((size_t)bh * 16 + cc) * 64 + tid];
      pq += cq[((size_t)bh * 16 + cc) * 64 + tid];
    }
    PK[tid] = pk; PQ[tid] = pq;
  }
  __syncthreads();
  float sumPK = wred64(PK[lane]);
  float sumPQ = wred64(PQ[lane]);
  // G tile (unmasked) + row sums via quarter partials
  {
    int l = lane, g = wave;
    float qrow[64];
#pragma unroll
    for (int d = 0; d < 64; d++) qrow[d] = qT[d][l];
    float p[16] = {};
    for (int d = 0; d < 64; d++){
      float qv = qrow[d];
#pragma unroll
      for (int j4 = 0; j4 < 4; j4++){
        float4 kk = *reinterpret_cast<const float4*>(&kT[d][g * 16 + j4 * 4]);
        p[j4*4+0] += qv * kk.x; p[j4*4+1] += qv * kk.y;
        p[j4*4+2] += qv * kk.z; p[j4*4+3] += qv * kk.w;
      }
    }
#pragma unroll
    for (int jj = 0; jj < 16; jj++) G[l][g * 16 + jj] = p[jj];
  }
  {
    float pk_ = 0.f, pq_ = 0.f;
#pragma unroll
    for (int d = wave * 16; d < wave * 16 + 16; d++){
      pk_ += kT[d][lane]; pq_ += qT[d][lane];
    }
    rd[0][wave][lane] = pk_; rd[1][wave][lane] = pq_;
  }
  __syncthreads();
  if (tid < 64){
    rk[tid] = rd[0][0][tid] + rd[0][1][tid] + rd[0][2][tid] + rd[0][3][tid];
    rq[tid] = rd[1][0][tid] + rd[1][1][tid] + rd[1][2][tid] + rd[1][3][tid];
  }
  __syncthreads();
  if (wave == 0)      crk[lane] = wscan64(rk[lane], lane);
  else if (wave == 1) crq[lane] = wscan64(rq[lane], lane);
  __syncthreads();
  // masked Gram-row sums via quarter partials
  {
    int l = lane;
    float p1 = 0.f, p2 = 0.f;
#pragma unroll
    for (int j = wave * 16; j < wave * 16 + 16; j++){
      float g1 = (j <= l) ? G[l][j] : 0.f;
      p1 += g1 + qT[j][l] * PK[j];
      float g2 = (j <= l) ? G[j][l] : 0.f;
      p2 += g2 + kT[j][l] * PQ[j];
    }
    rd[0][wave][l] = p1; rd[1][wave][l] = p2;
  }
  __syncthreads();
  const float EPS2 = 64.f * EPS * EPS;
  if (tid < 64){
    int l = tid;
    float s1 = rd[0][0][l] + rd[0][1][l] + rd[0][2][l] + rd[0][3][l];
    float s2 = rd[1][0][l] + rd[1][1][l] + rd[1][2][l] + rd[1][3][l];
    int L = c * 64 + l; float nrm = (float)(L + 1);
    float den1 = s1 + EPS * rq[l] + EPS * (sumPK + crk[l]) + EPS2;
    float den2 = s2 + EPS * rk[l] + EPS * (sumPQ + crq[l]) + EPS2;
    float si_ = nrm / den1, so_ = nrm / den2;
    sink_in[(size_t)bh * LSEQ + L] = si_;
    src_out[(size_t)bh * LSEQ + L] = so_;
    siv[l] = si_; sov[l] = so_;
  }
  __syncthreads();
  // weighted chunk column sums for the cons pass
  float s1 = 0.f, s2 = 0.f;
  for (int l = wave * 16; l < wave * 16 + 16; l++){
    s1 += sov[l] * kT[lane][l];
    s2 += siv[l] * qT[lane][l];
  }
  rd[0][wave][lane] = s1; rd[1][wave][lane] = s2;
  __syncthreads();
  if (wave == 0){
    cso [(size_t)blk * 64 + lane] = rd[0][0][lane] + rd[0][1][lane] + rd[0][2][lane] + rd[0][3][lane];
    cqsi[(size_t)blk * 64 + lane] = rd[1][0][lane] + rd[1][1][lane] + rd[1][2][lane] + rd[1][3][lane];
  }
}

// cons_sink -> sa = sigmoid; cons_src -> clip -> ebuf = exp
__global__ __launch_bounds__(256) void cons_tile(
    const float* __restrict__ q, const float* __restrict__ k,
    const float* __restrict__ cso, const float* __restrict__ cqsi,
    const float* __restrict__ sink_in, const float* __restrict__ src_out,
    float* __restrict__ sa, float* __restrict__ ebuf)
{
  int blk = blockIdx.x, bh = blk >> 4, c = blk & 15;
  int tid = threadIdx.x, lane = tid & 63, wave = tid >> 6;
  __shared__ float qT[64][65], kT[64][65], G[64][66];
  __shared__ float PKso[64], PQsi[64];
  __shared__ float rk[64], rq[64], cwrk[64], cwrq[64], siv[64], sov[64];
  __shared__ float rd[2][4][64];
  size_t base = ((size_t)bh * LSEQ + c * 64) * DHD;
  const float* qb = q + base; const float* kb = k + base;
  for (int c4 = tid; c4 < 1024; c4 += 256){
    int l = c4 >> 4, d0 = (c4 & 15) * 4;
    float4 qv = *reinterpret_cast<const float4*>(qb + c4 * 4);
    qT[d0+0][l] = qv.x; qT[d0+1][l] = qv.y; qT[d0+2][l] = qv.z; qT[d0+3][l] = qv.w;
    float4 kv = *reinterpret_cast<const float4*>(kb + c4 * 4);
    kT[d0+0][l] = kv.x; kT[d0+1][l] = kv.y; kT[d0+2][l] = kv.z; kT[d0+3][l] = kv.w;
  }
  if (tid < 64){
    float pk = 0.f, pq = 0.f;
    for (int cc = 0; cc < c; cc++){
      pk += cso [((size_t)bh * 16 + cc) * 64 + tid];
      pq += cqsi[((size_t)bh * 16 + cc) * 64 + tid];
    }
    PKso[tid] = pk; PQsi[tid] = pq;
  } else if (tid < 128){
    int l = tid - 64;
    sov[l] = src_out[(size_t)bh * LSEQ + c * 64 + l];
    siv[l] = sink_in[(size_t)bh * LSEQ + c * 64 + l];
  }
  __syncthreads();
  float sumPKso = wred64(PKso[lane]);
  float sumPQsi = wred64(PQsi[lane]);
  {
    int l = lane, g = wave;
    float qrow[64];
#pragma unroll
    for (int d = 0; d < 64; d++) qrow[d] = qT[d][l];
    float p[16] = {};
    for (int d = 0; d < 64; d++){
      float qv = qrow[d];
#pragma unroll
      for (int j4 = 0; j4 < 4; j4++){
        float4 kk = *reinterpret_cast<const float4*>(&kT[d][g * 16 + j4 * 4]);
        p[j4*4+0] += qv * kk.x; p[j4*4+1] += qv * kk.y;
        p[j4*4+2] += qv * kk.z; p[j4*4+3] += qv * kk.w;
      }
    }
#pragma unroll
    for (int jj = 0; jj < 16; jj++) G[l][g * 16 + jj] = p[jj];
  }
  {
    float pk_ = 0.f, pq_ = 0.f;
#pragma unroll
    for (int d = wave * 16; d < wave * 16 + 16; d++){
      pk_ += kT[d][lane]; pq_ += qT[d][lane];
    }
    rd[0][wave][lane] = pk_; rd[1][wave][lane] = pq_;
  }
  __syncthreads();
  if (tid < 64){
    rk[tid] = rd[0][0][tid] + rd[0][1][tid] + rd[0][2][tid] + rd[0][3][tid];
    rq[tid] = rd[1][0][tid] + rd[1][1][tid] + rd[1][2][tid] + rd[1][3][tid];
  }
  __syncthreads();
  if (wave == 0)      cwrk[lane] = wscan64(sov[lane] * rk[lane], lane);
  else if (wave == 1) cwrq[lane] = wscan64(siv[lane] * rq[lane], lane);
  __syncthreads();
  {
    int l = lane;
    float p3 = 0.f, p4 = 0.f;
#pragma unroll
    for (int j = wave * 16; j < wave * 16 + 16; j++){
      float g3 = (j <= l) ? sov[j] * G[l][j] : 0.f;
      p3 += g3 + qT[j][l] * PKso[j];
      float g4 = (j <= l) ? siv[j] * G[j][l] : 0.f;
      p4 += g4 + kT[j][l] * PQsi[j];
    }
    rd[0][wave][l] = p3; rd[1][wave][l] = p4;
  }
  __syncthreads();
  const float EPS2 = 64.f * EPS * EPS;
  if (tid < 64){
    int l = tid;
    float s3 = rd[0][0][l] + rd[0][1][l] + rd[0][2][l] + rd[0][3][l];
    float s4 = rd[1][0][l] + rd[1][1][l] + rd[1][2][l] + rd[1][3][l];
    int L = c * 64 + l; float nrm = (float)(L + 1);
    float cs = (s3 + EPS * rq[l] + EPS * (sumPKso + cwrk[l]) + EPS2) / nrm;
    sa[(size_t)bh * LSEQ + L] = fast_sigmoid(cs);
    float c2 = (s4 + EPS * rk[l] + EPS * (sumPQsi + cwrq[l]) + EPS2) / nrm;
    c2 = fminf(1.f, fmaxf(-1.f, c2));
    ebuf[(size_t)bh * LSEQ + L] = __expf(c2);
  }
}

// src_comp = e / cumsum(e) * (l+1)
__global__ __launch_bounds__(64) void srccomp_kernel(const float* __restrict__ ebuf, float* __restrict__ sc){
  int bh = blockIdx.x; int lane = threadIdx.x;
  const float* eb = ebuf + (size_t)bh * LSEQ;
  float loc[16]; float s = 0.f;
#pragma unroll
  for (int i = 0; i < 16; i++){ loc[i] = eb[lane * 16 + i]; s += loc[i]; }
  float run = wscan64(s, lane);
  float acc = run - s;
  float* scb = sc + (size_t)bh * LSEQ;
#pragma unroll
  for (int i = 0; i < 16; i++){
    acc += loc[i];
    scb[lane * 16 + i] = loc[i] / acc * (float)(lane * 16 + i + 1);
  }
}

// ---------------- chunked causal linear attention (scale fused in) ----------------
__global__ __launch_bounds__(256) void phaseA(const float* __restrict__ k, const float* __restrict__ v,
                                              const float* __restrict__ sc, float* __restrict__ S){
  int blk = blockIdx.x; int bh = blk >> 4, c = blk & 15;
  __shared__ float ks[64][68], vss[64][68];
  __shared__ float vc[64];
  int tid = threadIdx.x;
  size_t base = ((size_t)bh * LSEQ + c * 64) * DHD;
  const float* kb = k + base; const float* vb = v + base;
  if (tid < 64) vc[tid] = sc[(size_t)bh * LSEQ + c * 64 + tid];
  __syncthreads();
  for (int c4 = tid; c4 < 1024; c4 += 256){
    int l = c4 >> 4, d0 = (c4 & 15) * 4;
    *reinterpret_cast<float4*>(&ks[l][d0]) = *reinterpret_cast<const float4*>(kb + c4 * 4);
    float4 vv = *reinterpret_cast<const float4*>(vb + c4 * 4);
    float w = vc[l];
    vss[l][d0+0] = vv.x * w; vss[l][d0+1] = vv.y * w;
    vss[l][d0+2] = vv.z * w; vss[l][d0+3] = vv.w * w;
  }
  __syncthreads();
  int m = tid >> 2, dg = tid & 3;
  float acc[16] = {};
  for (int l = 0; l < 64; l++){
    float vm = vss[l][m];
#pragma unroll
    for (int d4 = 0; d4 < 4; d4++){
      float4 kk = *reinterpret_cast<const float4*>(&ks[l][dg * 16 + d4 * 4]);
      acc[d4*4+0] += vm * kk.x; acc[d4*4+1] += vm * kk.y;
      acc[d4*4+2] += vm * kk.z; acc[d4*4+3] += vm * kk.w;
    }
  }
  float* Sb = S + (size_t)blk * 4096 + m * 64 + dg * 16;
#pragma unroll
  for (int d4 = 0; d4 < 4; d4++)
    *reinterpret_cast<float4*>(Sb + d4 * 4) =
        make_float4(acc[d4*4], acc[d4*4+1], acc[d4*4+2], acc[d4*4+3]);
}

__global__ __launch_bounds__(256) void phaseB(const float* __restrict__ S, float* __restrict__ KVp){
  int blk = blockIdx.x; int bh = blk >> 4, c = blk & 15;
  int off = threadIdx.x * 16;
  float acc[16] = {};
  for (int cc = 0; cc < c; cc++){
    size_t idx = ((size_t)bh * 16 + cc) * 4096 + off;
#pragma unroll
    for (int t = 0; t < 4; t++){
      float4 sv = *reinterpret_cast<const float4*>(S + idx + t * 4);
      acc[t*4] += sv.x; acc[t*4+1] += sv.y; acc[t*4+2] += sv.z; acc[t*4+3] += sv.w;
    }
  }
  size_t oidx = ((size_t)bh * 16 + c) * 4096 + off;
#pragma unroll
  for (int t = 0; t < 4; t++)
    *reinterpret_cast<float4*>(KVp + oidx + t * 4) =
        make_float4(acc[t*4], acc[t*4+1], acc[t*4+2], acc[t*4+3]);
}

__global__ __launch_bounds__(256) void phaseC(const float* __restrict__ q, const float* __restrict__ k,
                                              const float* __restrict__ v, const float* __restrict__ KVp,
                                              const float* __restrict__ sink_in, const float* __restrict__ sc,
                                              const float* __restrict__ sa, u16* __restrict__ x){
  int blk = blockIdx.x; int bh = blk >> 4, c = blk & 15;
  int b = bh >> 4, h = bh & 15;
  __shared__ float qsT[64][65];
  __shared__ float kT[64][68];
  __shared__ float vss[64][68];
  __shared__ float kvs[64][68];
  __shared__ float Ps[64][66];
  __shared__ float qc[64], vc[64];
  int tid = threadIdx.x;
  size_t base = ((size_t)bh * LSEQ + c * 64) * DHD;
  const float* qb = q + base; const float* kb = k + base; const float* vb = v + base;
  const float* kvb = KVp + (size_t)blk * 4096;
  if (tid < 64){
    int L = c * 64 + tid;
    qc[tid] = sink_in[(size_t)bh * LSEQ + L] / (float)(L + 1);
    vc[tid] = sc[(size_t)bh * LSEQ + L];
  }
  __syncthreads();
  for (int c4 = tid; c4 < 1024; c4 += 256){
    int l = c4 >> 4, d0 = (c4 & 15) * 4;
    float qw = qc[l], vw = vc[l];
    float4 qv = *reinterpret_cast<const float4*>(qb + c4 * 4);
    qsT[d0+0][l] = qv.x * qw; qsT[d0+1][l] = qv.y * qw;
    qsT[d0+2][l] = qv.z * qw; qsT[d0+3][l] = qv.w * qw;
    float4 kv4 = *reinterpret_cast<const float4*>(kb + c4 * 4);
    kT[d0+0][l] = kv4.x; kT[d0+1][l] = kv4.y; kT[d0+2][l] = kv4.z; kT[d0+3][l] = kv4.w;
    float4 vv = *reinterpret_cast<const float4*>(vb + c4 * 4);
    vss[l][d0+0] = vv.x * vw; vss[l][d0+1] = vv.y * vw;
    vss[l][d0+2] = vv.z * vw; vss[l][d0+3] = vv.w * vw;
    *reinterpret_cast<float4*>(&kvs[l][d0]) = *reinterpret_cast<const float4*>(kvb + c4 * 4);
  }
  __syncthreads();
  int l = tid & 63, g = tid >> 6;
  float qrow[64];
#pragma unroll
  for (int d = 0; d < 64; d++) qrow[d] = qsT[d][l];

  float p[16] = {};
  for (int d = 0; d < 64; d++){
    float qv = qrow[d];
#pragma unroll
    for (int j4 = 0; j4 < 4; j4++){
      float4 kk = *reinterpret_cast<const float4*>(&kT[d][g * 16 + j4 * 4]);
      p[j4*4+0] += qv * kk.x; p[j4*4+1] += qv * kk.y;
      p[j4*4+2] += qv * kk.z; p[j4*4+3] += qv * kk.w;
    }
  }
#pragma unroll
  for (int jj = 0; jj < 16; jj++){
    int j = g * 16 + jj;
    Ps[l][j] = (j <= l) ? p[jj] : 0.f;
  }
  __syncthreads();

  float acc[16];
#pragma unroll
  for (int mm = 0; mm < 16; mm++){
    float a = 0.f;
#pragma unroll
    for (int d4 = 0; d4 < 16; d4++){
      float4 kv4 = *reinterpret_cast<const float4*>(&kvs[g * 16 + mm][d4 * 4]);
      a += qrow[d4*4+0]*kv4.x + qrow[d4*4+1]*kv4.y + qrow[d4*4+2]*kv4.z + qrow[d4*4+3]*kv4.w;
    }
    acc[mm] = a;
  }
  for (int j = 0; j < 64; j++){
    float pv = Ps[l][j];
#pragma unroll
    for (int m4 = 0; m4 < 4; m4++){
      float4 vv = *reinterpret_cast<const float4*>(&vss[j][g * 16 + m4 * 4]);
      acc[m4*4+0] += pv * vv.x; acc[m4*4+1] += pv * vv.y;
      acc[m4*4+2] += pv * vv.z; acc[m4*4+3] += pv * vv.w;
    }
  }
  float sav = sa[(size_t)bh * LSEQ + c * 64 + l];
  u16* xo = x + ((size_t)(b * 1024 + c * 64 + l)) * 1024 + h * 64 + g * 16;
#pragma unroll
  for (int mm = 0; mm < 16; mm++) xo[mm] = f2bf(acc[mm] * sav);
}

// ---------------- fused layernorms ----------------
__global__ __launch_bounds__(256) void ln_fused2b(
    const float* __restrict__ p0, const float* __restrict__ p1,
    const float* __restrict__ resid, const float* __restrict__ bias,
    const float* __restrict__ g, const float* __restrict__ b,
    float* __restrict__ out, u16* __restrict__ outbf){
  int row = blockIdx.x; int tid = threadIdx.x;
  int lane = tid & 63, wave = tid >> 6;
  size_t off = (size_t)row * 1024 + tid * 4;
  float4 a0 = *reinterpret_cast<const float4*>(p0 + off);
  float4 a1 = *reinterpret_cast<const float4*>(p1 + off);
  float4 rr = *reinterpret_cast<const float4*>(resid + off);
  float4 bb = *reinterpret_cast<const float4*>(bias + tid * 4);
  float4 v = make_float4(a0.x + a1.x + rr.x + bb.x, a0.y + a1.y + rr.y + bb.y,
                         a0.z + a1.z + rr.z + bb.z, a0.w + a1.w + rr.w + bb.w);
  float s = v.x + v.y + v.z + v.w;
  float s2 = v.x*v.x + v.y*v.y + v.z*v.z + v.w*v.w;
  s = wred64(s); s2 = wred64(s2);
  __shared__ float red[2][4];
  if (lane == 0){ red[0][wave] = s; red[1][wave] = s2; }
  __syncthreads();
  float S = red[0][0] + red[0][1] + red[0][2] + red[0][3];
  float S2 = red[1][0] + red[1][1] + red[1][2] + red[1][3];
  float mean = S * (1.f / 1024.f);
  float var = S2 * (1.f / 1024.f) - mean * mean;
  float inv = rsqrtf(var + 1e-5f);
  float4 gv = *reinterpret_cast<const float4*>(g + tid * 4);
  float4 bv = *reinterpret_cast<const float4*>(b + tid * 4);
  float y0 = (v.x - mean) * inv * gv.x + bv.x;
  float y1 = (v.y - mean) * inv * gv.y + bv.y;
  float y2 = (v.z - mean) * inv * gv.z + bv.z;
  float y3 = (v.w - mean) * inv * gv.w + bv.w;
  *reinterpret_cast<float4*>(out + off) = make_float4(y0, y1, y2, y3);
  ushort4 o; o.x = f2bf(y0); o.y = f2bf(y1); o.z = f2bf(y2); o.w = f2bf(y3);
  *reinterpret_cast<ushort4*>(outbf + off) = o;
}

__global__ __launch_bounds__(256) void ln_fused4(
    const float* __restrict__ p0, const float* __restrict__ p1,
    const float* __restrict__ p2, const float* __restrict__ p3,
    const float* __restrict__ resid, const float* __restrict__ bias,
    const float* __restrict__ g, const float* __restrict__ b,
    float* __restrict__ out){
  int row = blockIdx.x; int tid = threadIdx.x;
  int lane = tid & 63, wave = tid >> 6;
  size_t off = (size_t)row * 1024 + tid * 4;
  float4 a0 = *reinterpret_cast<const float4*>(p0 + off);
  float4 a1 = *reinterpret_cast<const float4*>(p1 + off);
  float4 a2 = *reinterpret_cast<const float4*>(p2 + off);
  float4 a3 = *reinterpret_cast<const float4*>(p3 + off);
  float4 rr = *reinterpret_cast<const float4*>(resid + off);
  float4 bb = *reinterpret_cast<const float4*>(bias + tid * 4);
  float4 v = make_float4(a0.x + a1.x + a2.x + a3.x + rr.x + bb.x,
                         a0.y + a1.y + a2.y + a3.y + rr.y + bb.y,
                         a0.z + a1.z + a2.z + a3.z + rr.z + bb.z,
                         a0.w + a1.w + a2.w + a3.w + rr.w + bb.w);
  float s = v.x + v.y + v.z + v.w;
  float s2 = v.x*v.x + v.y*v.y + v.z*v.z + v.w*v.w;
  s = wred64(s); s2 = wred64(s2);
  __shared__ float red[2][4];
  if (lane == 0){ red[0][wave] = s; red[1][wave] = s2; }
  __syncthreads();
  float S = red[0][0] + red[0][1] + red[0][2] + red[0][3];
  float S2 = red[1][0] + red[1][1] + red[1][2] + red[1][3];
  float mean = S * (1.f / 1024.f);
  float var = S2 * (1.f / 1024.f) - mean * mean;
  float inv = rsqrtf(var + 1e-5f);
  float4 gv = *reinterpret_cast<const float4*>(g + tid * 4);
  float4 bv = *reinterpret_cast<const float4*>(b + tid * 4);
  float y0 = (v.x - mean) * inv * gv.x + bv.x;
  float y1 = (v.y - mean) * inv * gv.y + bv.y;
  float y2 = (v.z - mean) * inv * gv.z + bv.z;
  float y3 = (v.w - mean) * inv * gv.w + bv.w;
  *reinterpret_cast<float4*>(out + off) = make_float4(y0, y1, y2, y3);
}

// ---------------- launch ----------------
extern "C" void kernel_launch(void* const* d_in, const int* in_sizes, int n_in,
                              void* d_out, int out_size, void* d_ws, size_t ws_size,
                              hipStream_t stream){
  (void)in_sizes; (void)n_in; (void)out_size; (void)ws_size;
  const float* inputs = (const float*)d_in[0];
  const float* Wq = (const float*)d_in[2];  const float* bq = (const float*)d_in[3];
  const float* Wk = (const float*)d_in[4];  const float* bk = (const float*)d_in[5];
  const float* Wv = (const float*)d_in[6];  const float* bv = (const float*)d_in[7];
  const float* Wo = (const float*)d_in[8];  const float* bo = (const float*)d_in[9];
  const float* ln1g = (const float*)d_in[10]; const float* ln1b = (const float*)d_in[11];
  const float* W1 = (const float*)d_in[12]; const float* b1 = (const float*)d_in[13];
  const float* W2 = (const float*)d_in[14]; const float* b2 = (const float*)d_in[15];
  const float* ln2g = (const float*)d_in[16]; const float* ln2b = (const float*)d_in[17];
  float* out = (float*)d_out;

  char* wsp = (char*)d_ws; size_t off = 0;
  auto alloc = [&](size_t bytes) -> void* {
    off = (off + 255) & ~(size_t)255;
    void* p = wsp + off; off += bytes; return p;
  };
  const size_t MD = (size_t)2048 * 1024;
  u16* Xbf    = (u16*)alloc(MD * 2);
  u16* WqkvT  = (u16*)alloc((size_t)3 * 1024 * 1024 * 2);
  u16* WoT    = (u16*)alloc((size_t)1024 * 1024 * 2);
  u16* W1T    = (u16*)alloc((size_t)4096 * 1024 * 2);
  u16* W2T    = (u16*)alloc((size_t)4096 * 1024 * 2);
  float* bqkv = (float*)alloc(3072 * 4);
  float* qkvb = (float*)alloc(3 * MD * 4);
  float* qb = qkvb; float* kb = qkvb + MD; float* vb = qkvb + 2 * MD;
  float* quad = (float*)alloc(4 * MD * 4);
  float* Sbuf = quad;
  float* KVp  = quad + MD;
  float* ckb  = (float*)alloc((size_t)512 * 64 * 4);
  float* cqb  = (float*)alloc((size_t)512 * 64 * 4);
  float* csob = (float*)alloc((size_t)512 * 64 * 4);
  float* cqsib= (float*)alloc((size_t)512 * 64 * 4);
  float* sink_in = (float*)alloc(NBH * LSEQ * 4);
  float* src_out = (float*)alloc(NBH * LSEQ * 4);
  float* sabuf   = (float*)alloc(NBH * LSEQ * 4);
  float* ebuf    = (float*)alloc(NBH * LSEQ * 4);
  float* scbuf   = (float*)alloc(NBH * LSEQ * 4);
  u16* xatt   = (u16*)alloc(MD * 2);
  u16* g1     = (u16*)alloc((size_t)2048 * 4096 * 2);
  float* part = quad;
  float* hbuf = vb;
  u16* hbf = (u16*)qb;

  // converts + weight prep
  f2bf_kernel<<<2048, 256, 0, stream>>>(inputs, Xbf, (int)(MD / 4));
  transpose4_f2bf<<<dim3(32, 32, 4), 256, 0, stream>>>(Wq, Wk, Wv, Wo, WqkvT, WoT);
  transpose2_f2bf<<<dim3(128, 32, 2), 256, 0, stream>>>(W1, W2, W1T, W2T);
  bias_gather<<<12, 256, 0, stream>>>(bq, bk, bv, bqkv);

  // fused QKV projection: BM=128,BN=64, grid 16x48 = 768 blocks (3/CU)
  gemm_mfma<128, 64, 0, 1><<<dim3(16, 48), 256, 0, stream>>>(
      Xbf, WqkvT, bqkv, nullptr, qkvb, nullptr, 2048, 3072, 1024);

  // attention scalars (chunked Gram-tile pipeline)
  chunk_sums<<<512, 256, 0, stream>>>(kb, qb, ckb, cqb);
  sink_tile<<<512, 256, 0, stream>>>(qb, kb, ckb, cqb, sink_in, src_out, csob, cqsib);
  cons_tile<<<512, 256, 0, stream>>>(qb, kb, csob, cqsib, sink_in, src_out, sabuf, ebuf);
  srccomp_kernel<<<32, 64, 0, stream>>>(ebuf, scbuf);

  // chunked causal linear attention (scale fused into A and C)
  phaseA<<<512, 256, 0, stream>>>(kb, vb, scbuf, Sbuf);
  phaseB<<<512, 256, 0, stream>>>(Sbuf, KVp);
  phaseC<<<512, 256, 0, stream>>>(qb, kb, vb, KVp, sink_in, scbuf, sabuf, xatt);

  // output projection: BM=128,BN=64, split-K=2
  gemm_mfma<128, 64, 0, 4><<<dim3(16, 16, 2), 256, 0, stream>>>(
      xatt, WoT, nullptr, nullptr, part, nullptr, 2048, 1024, 1024);
  ln_fused2b<<<2048, 256, 0, stream>>>(part, part + MD, inputs, bo, ln1g, ln1b, hbuf, hbf);

  // FFN1: BM=128,BN=128 (fast gelu)
  gemm_mfma<128, 128, 2, 3><<<dim3(16, 32), 256, 0, stream>>>(
      hbf, W1T, b1, nullptr, nullptr, g1, 2048, 4096, 1024);
  // FFN2: BM=128,BN=128, split-K=4
  gemm_mfma<128, 128, 0, 4><<<dim3(16, 8, 4), 256, 0, stream>>>(
      g1, W2T, nullptr, nullptr, part, nullptr, 2048, 1024, 4096);
  ln_fused4<<<2048, 256, 0, stream>>>(part, part + MD, part + 2 * MD, part + 3 * MD,
                                      hbuf, b2, ln2g, ln2b, out);
}

// Round 12
// 216.281 us; speedup vs baseline: 1.3332x; 1.0246x over previous
//
#include <hip/hip_runtime.h>
#include <hip/hip_bf16.h>

// ---------------- constants ----------------
#define EPS 1e-6f
#define NBH 32      // B*H
#define LSEQ 1024
#define DHD 64

typedef unsigned short u16;
typedef __bf16 bf16x8 __attribute__((ext_vector_type(8)));
typedef float f32x4 __attribute__((ext_vector_type(4)));

__device__ inline u16 f2bf(float f){
  union { float f; unsigned u; } un; un.f = f;
  unsigned u = un.u;
  u += 0x7fffu + ((u >> 16) & 1u);
  return (u16)(u >> 16);
}

__device__ inline float wred64(float v){
#pragma unroll
  for (int off = 32; off > 0; off >>= 1) v += __shfl_xor(v, off, 64);
  return v;
}

__device__ inline float wscan64(float v, int lane){
  float run = v;
#pragma unroll
  for (int off = 1; off < 64; off <<= 1){
    float t = __shfl_up(run, off, 64);
    if (lane >= off) run += t;
  }
  return run;   // inclusive
}

__device__ inline float fast_sigmoid(float x){
  return 1.f / (1.f + __expf(-x));
}

__device__ inline void gload_lds16(const u16* g, u16* l){
  __builtin_amdgcn_global_load_lds(
      (const __attribute__((address_space(1))) unsigned int*)g,
      (__attribute__((address_space(3))) unsigned int*)l, 16, 0, 0);
}

// ---------------- converts ----------------
__global__ __launch_bounds__(256) void f2bf_kernel(const float* __restrict__ in,
                                                   u16* __restrict__ out, int n4){
  int i = blockIdx.x * 256 + threadIdx.x;
  if (i < n4){
    float4 v = reinterpret_cast<const float4*>(in)[i];
    ushort4 o; o.x = f2bf(v.x); o.y = f2bf(v.y); o.z = f2bf(v.z); o.w = f2bf(v.w);
    reinterpret_cast<ushort4*>(out)[i] = o;
  }
}

// generic 32x32-tile transpose+convert: out[c][r] = bf16(in[r][c])
__device__ inline void tr_tile2(const float* in, u16* out, int R, int C, int r0, int c0){
  __shared__ float tile[32][33];
  int x = threadIdx.x & 31, y = threadIdx.x >> 5;
#pragma unroll
  for (int j = 0; j < 4; j++)
    tile[y + j*8][x] = in[(size_t)(r0 + y + j*8) * C + c0 + x];
  __syncthreads();
#pragma unroll
  for (int j = 0; j < 4; j++)
    out[(size_t)(c0 + y + j*8) * R + r0 + x] = f2bf(tile[x][y + j*8]);
}

// 4x 1024x1024 transposes in one launch (z selects matrix)
__global__ __launch_bounds__(256) void transpose4_f2bf(
    const float* __restrict__ w0, const float* __restrict__ w1,
    const float* __restrict__ w2, const float* __restrict__ w3,
    u16* __restrict__ dqkv, u16* __restrict__ dwo){
  int z = blockIdx.z;
  const float* in = (z == 0) ? w0 : (z == 1) ? w1 : (z == 2) ? w2 : w3;
  u16* out = (z < 3) ? (dqkv + (size_t)z * 1024 * 1024) : dwo;
  tr_tile2(in, out, 1024, 1024, blockIdx.y * 32, blockIdx.x * 32);
}

// W1 (1024x4096) and W2 (4096x1024) transposes in one launch
__global__ __launch_bounds__(256) void transpose2_f2bf(
    const float* __restrict__ w1, const float* __restrict__ w2,
    u16* __restrict__ d1, u16* __restrict__ d2){
  if (blockIdx.z == 0)
    tr_tile2(w1, d1, 1024, 4096, blockIdx.y * 32, blockIdx.x * 32);
  else
    tr_tile2(w2, d2, 4096, 1024, blockIdx.x * 32, blockIdx.y * 32);
}

// gather q/k/v biases into one 3072 vector
__global__ __launch_bounds__(256) void bias_gather(const float* __restrict__ bq,
                                                   const float* __restrict__ bk,
                                                   const float* __restrict__ bv,
                                                   float* __restrict__ dst){
  int i = blockIdx.x * 256 + threadIdx.x;
  if (i < 3072){
    float v = (i < 1024) ? bq[i] : (i < 2048) ? bk[i - 1024] : bv[i - 2048];
    dst[i] = v;
  }
}

// ---------------- bf16 MFMA GEMM (dbuf + counted vmcnt, T2 XOR-swizzled LDS) ----
// C[M,N] = act(A[M,K] @ Bt[N,K]^T + bias)
// LDS: BK=64 bf16 rows = 8 x 16B slots; slot s of row r at phys slot s^(r&7)
// (rule #21: linear gload_lds dest + pre-swizzled SOURCE + swizzled READ).
// Pipeline: STAGE(next) issued before compute(cur); s_waitcnt vmcnt(NS) keeps
// the next tile's NS loads in flight across the barrier (T3 minimum 2-phase).
// ACT: 0 none, 2 gelu  (OM==1 applies fast sigmoid for col<2048 internally)
// OM: 1 fused-QKV remap to 3x[B,H,L,DH]; 3 bf16 [M][N];
//     4 raw f32 partial (split-K slice z at outF + z*M*N, no bias)
template<int BM, int BN, int ACT, int OM>
__global__ __launch_bounds__(256) void gemm_mfma(
    const u16* __restrict__ A, const u16* __restrict__ Bt,
    const float* __restrict__ bias, const float* __restrict__ resid,
    float* __restrict__ outF, u16* __restrict__ outB,
    int M, int N, int K)
{
  constexpr int BK = 64;
  constexpr int MI = BM / 32;
  constexpr int NJ = BN / 32;
  constexpr int RA = BM / 32;
  constexpr int RB = BN / 32;
  constexpr int NS = RA + RB;           // gload_lds per wave per stage
  __shared__ u16 As[2][BM * BK];
  __shared__ u16 Bs[2][BN * BK];
  const int tid = threadIdx.x;
  const int lane = tid & 63, wave = tid >> 6;
  const int lrow = lane & 15, lg = lane >> 4;
  const int m0 = blockIdx.x * BM, n0 = blockIdx.y * BN;
  const int wm = (wave >> 1) * (BM / 2), wn = (wave & 1) * (BN / 2);

  const int ksz = K / gridDim.z;
  const int k_begin = blockIdx.z * ksz;
  const int k_end = k_begin + ksz;

  f32x4 acc[MI][NJ];
#pragma unroll
  for (int i = 0; i < MI; i++)
#pragma unroll
    for (int j = 0; j < NJ; j++) acc[i][j] = (f32x4){0.f, 0.f, 0.f, 0.f};

  const u16* Ab = A + (size_t)m0 * K;
  const u16* Bb = Bt + (size_t)n0 * K;

  const int s0 = ((0 * 4 + lg) ^ (lrow & 7)) * 8;
  const int s1 = ((1 * 4 + lg) ^ (lrow & 7)) * 8;

  auto STAGE = [&](int buf, int k0){
#pragma unroll
    for (int r = 0; r < RA; ++r){
      int c = r * 256 + tid;
      int row = c >> 3;
      int kk = ((c ^ row) & 7) << 3;
      gload_lds16(Ab + (size_t)row * K + k0 + kk, &As[buf][(r * 256 + wave * 64) * 8]);
    }
#pragma unroll
    for (int r = 0; r < RB; ++r){
      int c = r * 256 + tid;
      int row = c >> 3;
      int kk = ((c ^ row) & 7) << 3;
      gload_lds16(Bb + (size_t)row * K + k0 + kk, &Bs[buf][(r * 256 + wave * 64) * 8]);
    }
  };

  STAGE(0, k_begin);
  int cur = 0;
  for (int k0 = k_begin; k0 < k_end; k0 += BK){
    if (k0 + BK < k_end){
      STAGE(cur ^ 1, k0 + BK);          // prefetch next tile into other buffer
      // wait only for CURRENT tile's loads; next tile's NS stay in flight
      if constexpr (NS == 8)      asm volatile("s_waitcnt vmcnt(8)" ::: "memory");
      else if constexpr (NS == 6) asm volatile("s_waitcnt vmcnt(6)" ::: "memory");
      else                        asm volatile("s_waitcnt vmcnt(0)" ::: "memory");
    } else {
      asm volatile("s_waitcnt vmcnt(0)" ::: "memory");
    }
    __builtin_amdgcn_s_barrier();       // current-tile LDS writes visible to all
    __builtin_amdgcn_sched_barrier(0);  // keep ds_reads below the barrier (rule #18)
#pragma unroll
    for (int kh = 0; kh < 2; ++kh){
      const int ss = (kh == 0) ? s0 : s1;
      bf16x8 af[MI], bfv[NJ];
#pragma unroll
      for (int i = 0; i < MI; ++i)
        af[i] = *reinterpret_cast<const bf16x8*>(&As[cur][(wm + i * 16 + lrow) * BK + ss]);
#pragma unroll
      for (int j = 0; j < NJ; ++j)
        bfv[j] = *reinterpret_cast<const bf16x8*>(&Bs[cur][(wn + j * 16 + lrow) * BK + ss]);
#pragma unroll
      for (int i = 0; i < MI; ++i)
#pragma unroll
        for (int j = 0; j < NJ; ++j)
          acc[i][j] = __builtin_amdgcn_mfma_f32_16x16x32_bf16(af[i], bfv[j], acc[i][j], 0, 0, 0);
    }
    __builtin_amdgcn_s_barrier();       // all waves done reading buf[cur] before restage
    cur ^= 1;
  }

#pragma unroll
  for (int i = 0; i < MI; ++i){
#pragma unroll
    for (int j = 0; j < NJ; ++j){
      int col = n0 + wn + j * 16 + lrow;
      float bv = (OM != 4 && bias) ? bias[col] : 0.f;
#pragma unroll
      for (int r = 0; r < 4; ++r){
        int row = m0 + wm + i * 16 + lg * 4 + r;
        float x = acc[i][j][r] + bv;
        if (OM == 1){
          if (col < 2048) x = fast_sigmoid(x);
          int which = col >> 10, cc = col & 1023, h = cc >> 6, d = cc & 63;
          int b = row >> 10, l = row & 1023;
          outF[(size_t)which * (2048ull * 1024) +
               (((size_t)(b * 16 + h)) * 1024 + l) * 64 + d] = x;
        } else if (OM == 4){
          outF[((size_t)blockIdx.z * M + row) * N + col] = x;
        } else {
          if (ACT == 2){
            float u = 0.7978845608f * (x + 0.044715f * x * x * x);
            float e = __expf(2.f * u);
            x = 0.5f * x * (2.f - 2.f / (e + 1.f));
          }
          outB[(size_t)row * N + col] = f2bf(x);
        }
      }
    }
  }
}

// ---------------- attention scalar pipeline (chunked Gram-tile form) ----------------
__global__ __launch_bounds__(256) void chunk_sums(const float* __restrict__ k, const float* __restrict__ q,
                                                  float* __restrict__ ck, float* __restrict__ cq){
  int blk = blockIdx.x;
  int lane = threadIdx.x & 63, wave = threadIdx.x >> 6;
  size_t base = (size_t)blk * 64 * DHD;
  float sk = 0.f, sq = 0.f;
  for (int l = wave * 16; l < wave * 16 + 16; l++){
    sk += k[base + l * 64 + lane];
    sq += q[base + l * 64 + lane];
  }
  __shared__ float rd[2][4][64];
  rd[0][wave][lane] = sk; rd[1][wave][lane] = sq;
  __syncthreads();
  if (wave == 0){
    ck[(size_t)blk * 64 + lane] = rd[0][0][lane] + rd[0][1][lane] + rd[0][2][lane] + rd[0][3][lane];
    cq[(size_t)blk * 64 + lane] = rd[1][0][lane] + rd[1][1][lane] + rd[1][2][lane] + rd[1][3][lane];
  }
}

// sink_in/src_out via G = Q K^T tile; also emits weighted chunk sums cso, cqsi.
__global__ __launch_bounds__(256) void sink_tile(
    const float* __restrict__ q, const float* __restrict__ k,
    const float* __restrict__ ck, const float* __restrict__ cq,
    float* __restrict__ sink_in, float* __restrict__ src_out,
    float* __restrict__ cso, float* __restrict__ cqsi)
{
  int blk = blockIdx.x, bh = blk >> 4, c = blk & 15;
  int tid = threadIdx.x, lane = tid & 63, wave = tid >> 6;
  __shared__ float qT[64][65], kT[64][65], G[64][66];
  __shared__ float PK[64], PQ[64];
  __shared__ float rk[64], rq[64], crk[64], crq[64], siv[64], sov[64];
  __shared__ float rd[2][4][64];
  size_t base = ((size_t)bh * LSEQ + c * 64) * DHD;
  const float* qb = q + base; const float* kb = k + base;
  for (int c4 = tid; c4 < 1024; c4 += 256){
    int l = c4 >> 4, d0 = (c4 & 15) * 4;
    float4 qv = *reinterpret_cast<const float4*>(qb + c4 * 4);
    qT[d0+0][l] = qv.x; qT[d0+1][l] = qv.y; qT[d0+2][l] = qv.z; qT[d0+3][l] = qv.w;
    float4 kv = *reinterpret_cast<const float4*>(kb + c4 * 4);
    kT[d0+0][l] = kv.x; kT[d0+1][l] = kv.y; kT[d0+2][l] = kv.z; kT[d0+3][l] = kv.w;
  }
  if (tid < 64){
    float pk = 0.f, pq = 0.f;
    for (int cc = 0; cc < c; cc++){
      pk += ck[((size_t)bh * 16 + cc) * 64 + tid];
      pq += cq[((size_t)bh * 16 + cc) * 64 + tid];
    }
    PK[tid] = pk; PQ[tid] = pq;
  }
  __syncthreads();
  float sumPK = wred64(PK[lane]);
  float sumPQ = wred64(PQ[lane]);
  {
    int l = lane, g = wave;
    float qrow[64];
#pragma unroll
    for (int d = 0; d < 64; d++) qrow[d] = qT[d][l];
    float p[16] = {};
    for (int d = 0; d < 64; d++){
      float qv = qrow[d];
#pragma unroll
      for (int j4 = 0; j4 < 4; j4++){
        float4 kk = *reinterpret_cast<const float4*>(&kT[d][g * 16 + j4 * 4]);
        p[j4*4+0] += qv * kk.x; p[j4*4+1] += qv * kk.y;
        p[j4*4+2] += qv * kk.z; p[j4*4+3] += qv * kk.w;
      }
    }
#pragma unroll
    for (int jj = 0; jj < 16; jj++) G[l][g * 16 + jj] = p[jj];
  }
  {
    float pk_ = 0.f, pq_ = 0.f;
#pragma unroll
    for (int d = wave * 16; d < wave * 16 + 16; d++){
      pk_ += kT[d][lane]; pq_ += qT[d][lane];
    }
    rd[0][wave][lane] = pk_; rd[1][wave][lane] = pq_;
  }
  __syncthreads();
  if (tid < 64){
    rk[tid] = rd[0][0][tid] + rd[0][1][tid] + rd[0][2][tid] + rd[0][3][tid];
    rq[tid] = rd[1][0][tid] + rd[1][1][tid] + rd[1][2][tid] + rd[1][3][tid];
  }
  __syncthreads();
  if (wave == 0)      crk[lane] = wscan64(rk[lane], lane);
  else if (wave == 1) crq[lane] = wscan64(rq[lane], lane);
  __syncthreads();
  {
    int l = lane;
    float p1 = 0.f, p2 = 0.f;
#pragma unroll
    for (int j = wave * 16; j < wave * 16 + 16; j++){
      float g1 = (j <= l) ? G[l][j] : 0.f;
      p1 += g1 + qT[j][l] * PK[j];
      float g2 = (j <= l) ? G[j][l] : 0.f;
      p2 += g2 + kT[j][l] * PQ[j];
    }
    rd[0][wave][l] = p1; rd[1][wave][l] = p2;
  }
  __syncthreads();
  const float EPS2 = 64.f * EPS * EPS;
  if (tid < 64){
    int l = tid;
    float s1 = rd[0][0][l] + rd[0][1][l] + rd[0][2][l] + rd[0][3][l];
    float s2 = rd[1][0][l] + rd[1][1][l] + rd[1][2][l] + rd[1][3][l];
    int L = c * 64 + l; float nrm = (float)(L + 1);
    float den1 = s1 + EPS * rq[l] + EPS * (sumPK + crk[l]) + EPS2;
    float den2 = s2 + EPS * rk[l] + EPS * (sumPQ + crq[l]) + EPS2;
    float si_ = nrm / den1, so_ = nrm / den2;
    sink_in[(size_t)bh * LSEQ + L] = si_;
    src_out[(size_t)bh * LSEQ + L] = so_;
    siv[l] = si_; sov[l] = so_;
  }
  __syncthreads();
  float s1 = 0.f, s2 = 0.f;
  for (int l = wave * 16; l < wave * 16 + 16; l++){
    s1 += sov[l] * kT[lane][l];
    s2 += siv[l] * qT[lane][l];
  }
  rd[0][wave][lane] = s1; rd[1][wave][lane] = s2;
  __syncthreads();
  if (wave == 0){
    cso [(size_t)blk * 64 + lane] = rd[0][0][lane] + rd[0][1][lane] + rd[0][2][lane] + rd[0][3][lane];
    cqsi[(size_t)blk * 64 + lane] = rd[1][0][lane] + rd[1][1][lane] + rd[1][2][lane] + rd[1][3][lane];
  }
}

// cons_sink -> sa = sigmoid; cons_src -> clip -> ebuf = exp
__global__ __launch_bounds__(256) void cons_tile(
    const float* __restrict__ q, const float* __restrict__ k,
    const float* __restrict__ cso, const float* __restrict__ cqsi,
    const float* __restrict__ sink_in, const float* __restrict__ src_out,
    float* __restrict__ sa, float* __restrict__ ebuf)
{
  int blk = blockIdx.x, bh = blk >> 4, c = blk & 15;
  int tid = threadIdx.x, lane = tid & 63, wave = tid >> 6;
  __shared__ float qT[64][65], kT[64][65], G[64][66];
  __shared__ float PKso[64], PQsi[64];
  __shared__ float rk[64], rq[64], cwrk[64], cwrq[64], siv[64], sov[64];
  __shared__ float rd[2][4][64];
  size_t base = ((size_t)bh * LSEQ + c * 64) * DHD;
  const float* qb = q + base; const float* kb = k + base;
  for (int c4 = tid; c4 < 1024; c4 += 256){
    int l = c4 >> 4, d0 = (c4 & 15) * 4;
    float4 qv = *reinterpret_cast<const float4*>(qb + c4 * 4);
    qT[d0+0][l] = qv.x; qT[d0+1][l] = qv.y; qT[d0+2][l] = qv.z; qT[d0+3][l] = qv.w;
    float4 kv = *reinterpret_cast<const float4*>(kb + c4 * 4);
    kT[d0+0][l] = kv.x; kT[d0+1][l] = kv.y; kT[d0+2][l] = kv.z; kT[d0+3][l] = kv.w;
  }
  if (tid < 64){
    float pk = 0.f, pq = 0.f;
    for (int cc = 0; cc < c; cc++){
      pk += cso [((size_t)bh * 16 + cc) * 64 + tid];
      pq += cqsi[((size_t)bh * 16 + cc) * 64 + tid];
    }
    PKso[tid] = pk; PQsi[tid] = pq;
  } else if (tid < 128){
    int l = tid - 64;
    sov[l] = src_out[(size_t)bh * LSEQ + c * 64 + l];
    siv[l] = sink_in[(size_t)bh * LSEQ + c * 64 + l];
  }
  __syncthreads();
  float sumPKso = wred64(PKso[lane]);
  float sumPQsi = wred64(PQsi[lane]);
  {
    int l = lane, g = wave;
    float qrow[64];
#pragma unroll
    for (int d = 0; d < 64; d++) qrow[d] = qT[d][l];
    float p[16] = {};
    for (int d = 0; d < 64; d++){
      float qv = qrow[d];
#pragma unroll
      for (int j4 = 0; j4 < 4; j4++){
        float4 kk = *reinterpret_cast<const float4*>(&kT[d][g * 16 + j4 * 4]);
        p[j4*4+0] += qv * kk.x; p[j4*4+1] += qv * kk.y;
        p[j4*4+2] += qv * kk.z; p[j4*4+3] += qv * kk.w;
      }
    }
#pragma unroll
    for (int jj = 0; jj < 16; jj++) G[l][g * 16 + jj] = p[jj];
  }
  {
    float pk_ = 0.f, pq_ = 0.f;
#pragma unroll
    for (int d = wave * 16; d < wave * 16 + 16; d++){
      pk_ += kT[d][lane]; pq_ += qT[d][lane];
    }
    rd[0][wave][lane] = pk_; rd[1][wave][lane] = pq_;
  }
  __syncthreads();
  if (tid < 64){
    rk[tid] = rd[0][0][tid] + rd[0][1][tid] + rd[0][2][tid] + rd[0][3][tid];
    rq[tid] = rd[1][0][tid] + rd[1][1][tid] + rd[1][2][tid] + rd[1][3][tid];
  }
  __syncthreads();
  if (wave == 0)      cwrk[lane] = wscan64(sov[lane] * rk[lane], lane);
  else if (wave == 1) cwrq[lane] = wscan64(siv[lane] * rq[lane], lane);
  __syncthreads();
  {
    int l = lane;
    float p3 = 0.f, p4 = 0.f;
#pragma unroll
    for (int j = wave * 16; j < wave * 16 + 16; j++){
      float g3 = (j <= l) ? sov[j] * G[l][j] : 0.f;
      p3 += g3 + qT[j][l] * PKso[j];
      float g4 = (j <= l) ? siv[j] * G[j][l] : 0.f;
      p4 += g4 + kT[j][l] * PQsi[j];
    }
    rd[0][wave][l] = p3; rd[1][wave][l] = p4;
  }
  __syncthreads();
  const float EPS2 = 64.f * EPS * EPS;
  if (tid < 64){
    int l = tid;
    float s3 = rd[0][0][l] + rd[0][1][l] + rd[0][2][l] + rd[0][3][l];
    float s4 = rd[1][0][l] + rd[1][1][l] + rd[1][2][l] + rd[1][3][l];
    int L = c * 64 + l; float nrm = (float)(L + 1);
    float cs = (s3 + EPS * rq[l] + EPS * (sumPKso + cwrk[l]) + EPS2) / nrm;
    sa[(size_t)bh * LSEQ + L] = fast_sigmoid(cs);
    float c2 = (s4 + EPS * rk[l] + EPS * (sumPQsi + cwrq[l]) + EPS2) / nrm;
    c2 = fminf(1.f, fmaxf(-1.f, c2));
    ebuf[(size_t)bh * LSEQ + L] = __expf(c2);
  }
}

// src_comp = e / cumsum(e) * (l+1)
__global__ __launch_bounds__(64) void srccomp_kernel(const float* __restrict__ ebuf, float* __restrict__ sc){
  int bh = blockIdx.x; int lane = threadIdx.x;
  const float* eb = ebuf + (size_t)bh * LSEQ;
  float loc[16]; float s = 0.f;
#pragma unroll
  for (int i = 0; i < 16; i++){ loc[i] = eb[lane * 16 + i]; s += loc[i]; }
  float run = wscan64(s, lane);
  float acc = run - s;
  float* scb = sc + (size_t)bh * LSEQ;
#pragma unroll
  for (int i = 0; i < 16; i++){
    acc += loc[i];
    scb[lane * 16 + i] = loc[i] / acc * (float)(lane * 16 + i + 1);
  }
}

// ---------------- chunked causal linear attention (scale fused in) ----------------
__global__ __launch_bounds__(256) void phaseA(const float* __restrict__ k, const float* __restrict__ v,
                                              const float* __restrict__ sc, float* __restrict__ S){
  int blk = blockIdx.x; int bh = blk >> 4, c = blk & 15;
  __shared__ float ks[64][68], vss[64][68];
  __shared__ float vc[64];
  int tid = threadIdx.x;
  size_t base = ((size_t)bh * LSEQ + c * 64) * DHD;
  const float* kb = k + base; const float* vb = v + base;
  if (tid < 64) vc[tid] = sc[(size_t)bh * LSEQ + c * 64 + tid];
  __syncthreads();
  for (int c4 = tid; c4 < 1024; c4 += 256){
    int l = c4 >> 4, d0 = (c4 & 15) * 4;
    *reinterpret_cast<float4*>(&ks[l][d0]) = *reinterpret_cast<const float4*>(kb + c4 * 4);
    float4 vv = *reinterpret_cast<const float4*>(vb + c4 * 4);
    float w = vc[l];
    vss[l][d0+0] = vv.x * w; vss[l][d0+1] = vv.y * w;
    vss[l][d0+2] = vv.z * w; vss[l][d0+3] = vv.w * w;
  }
  __syncthreads();
  int m = tid >> 2, dg = tid & 3;
  float acc[16] = {};
  for (int l = 0; l < 64; l++){
    float vm = vss[l][m];
#pragma unroll
    for (int d4 = 0; d4 < 4; d4++){
      float4 kk = *reinterpret_cast<const float4*>(&ks[l][dg * 16 + d4 * 4]);
      acc[d4*4+0] += vm * kk.x; acc[d4*4+1] += vm * kk.y;
      acc[d4*4+2] += vm * kk.z; acc[d4*4+3] += vm * kk.w;
    }
  }
  float* Sb = S + (size_t)blk * 4096 + m * 64 + dg * 16;
#pragma unroll
  for (int d4 = 0; d4 < 4; d4++)
    *reinterpret_cast<float4*>(Sb + d4 * 4) =
        make_float4(acc[d4*4], acc[d4*4+1], acc[d4*4+2], acc[d4*4+3]);
}

__global__ __launch_bounds__(256) void phaseB(const float* __restrict__ S, float* __restrict__ KVp){
  int blk = blockIdx.x; int bh = blk >> 4, c = blk & 15;
  int off = threadIdx.x * 16;
  float acc[16] = {};
  for (int cc = 0; cc < c; cc++){
    size_t idx = ((size_t)bh * 16 + cc) * 4096 + off;
#pragma unroll
    for (int t = 0; t < 4; t++){
      float4 sv = *reinterpret_cast<const float4*>(S + idx + t * 4);
      acc[t*4] += sv.x; acc[t*4+1] += sv.y; acc[t*4+2] += sv.z; acc[t*4+3] += sv.w;
    }
  }
  size_t oidx = ((size_t)bh * 16 + c) * 4096 + off;
#pragma unroll
  for (int t = 0; t < 4; t++)
    *reinterpret_cast<float4*>(KVp + oidx + t * 4) =
        make_float4(acc[t*4], acc[t*4+1], acc[t*4+2], acc[t*4+3]);
}

__global__ __launch_bounds__(256) void phaseC(const float* __restrict__ q, const float* __restrict__ k,
                                              const float* __restrict__ v, const float* __restrict__ KVp,
                                              const float* __restrict__ sink_in, const float* __restrict__ sc,
                                              const float* __restrict__ sa, u16* __restrict__ x){
  int blk = blockIdx.x; int bh = blk >> 4, c = blk & 15;
  int b = bh >> 4, h = bh & 15;
  __shared__ float qsT[64][65];
  __shared__ float kT[64][68];
  __shared__ float vss[64][68];
  __shared__ float kvs[64][68];
  __shared__ float Ps[64][66];
  __shared__ float qc[64], vc[64];
  int tid = threadIdx.x;
  size_t base = ((size_t)bh * LSEQ + c * 64) * DHD;
  const float* qb = q + base; const float* kb = k + base; const float* vb = v + base;
  const float* kvb = KVp + (size_t)blk * 4096;
  if (tid < 64){
    int L = c * 64 + tid;
    qc[tid] = sink_in[(size_t)bh * LSEQ + L] / (float)(L + 1);
    vc[tid] = sc[(size_t)bh * LSEQ + L];
  }
  __syncthreads();
  for (int c4 = tid; c4 < 1024; c4 += 256){
    int l = c4 >> 4, d0 = (c4 & 15) * 4;
    float qw = qc[l], vw = vc[l];
    float4 qv = *reinterpret_cast<const float4*>(qb + c4 * 4);
    qsT[d0+0][l] = qv.x * qw; qsT[d0+1][l] = qv.y * qw;
    qsT[d0+2][l] = qv.z * qw; qsT[d0+3][l] = qv.w * qw;
    float4 kv4 = *reinterpret_cast<const float4*>(kb + c4 * 4);
    kT[d0+0][l] = kv4.x; kT[d0+1][l] = kv4.y; kT[d0+2][l] = kv4.z; kT[d0+3][l] = kv4.w;
    float4 vv = *reinterpret_cast<const float4*>(vb + c4 * 4);
    vss[l][d0+0] = vv.x * vw; vss[l][d0+1] = vv.y * vw;
    vss[l][d0+2] = vv.z * vw; vss[l][d0+3] = vv.w * vw;
    *reinterpret_cast<float4*>(&kvs[l][d0]) = *reinterpret_cast<const float4*>(kvb + c4 * 4);
  }
  __syncthreads();
  int l = tid & 63, g = tid >> 6;
  float qrow[64];
#pragma unroll
  for (int d = 0; d < 64; d++) qrow[d] = qsT[d][l];

  float p[16] = {};
  for (int d = 0; d < 64; d++){
    float qv = qrow[d];
#pragma unroll
    for (int j4 = 0; j4 < 4; j4++){
      float4 kk = *reinterpret_cast<const float4*>(&kT[d][g * 16 + j4 * 4]);
      p[j4*4+0] += qv * kk.x; p[j4*4+1] += qv * kk.y;
      p[j4*4+2] += qv * kk.z; p[j4*4+3] += qv * kk.w;
    }
  }
#pragma unroll
  for (int jj = 0; jj < 16; jj++){
    int j = g * 16 + jj;
    Ps[l][j] = (j <= l) ? p[jj] : 0.f;
  }
  __syncthreads();

  float acc[16];
#pragma unroll
  for (int mm = 0; mm < 16; mm++){
    float a = 0.f;
#pragma unroll
    for (int d4 = 0; d4 < 16; d4++){
      float4 kv4 = *reinterpret_cast<const float4*>(&kvs[g * 16 + mm][d4 * 4]);
      a += qrow[d4*4+0]*kv4.x + qrow[d4*4+1]*kv4.y + qrow[d4*4+2]*kv4.z + qrow[d4*4+3]*kv4.w;
    }
    acc[mm] = a;
  }
  for (int j = 0; j < 64; j++){
    float pv = Ps[l][j];
#pragma unroll
    for (int m4 = 0; m4 < 4; m4++){
      float4 vv = *reinterpret_cast<const float4*>(&vss[j][g * 16 + m4 * 4]);
      acc[m4*4+0] += pv * vv.x; acc[m4*4+1] += pv * vv.y;
      acc[m4*4+2] += pv * vv.z; acc[m4*4+3] += pv * vv.w;
    }
  }
  float sav = sa[(size_t)bh * LSEQ + c * 64 + l];
  u16* xo = x + ((size_t)(b * 1024 + c * 64 + l)) * 1024 + h * 64 + g * 16;
#pragma unroll
  for (int mm = 0; mm < 16; mm++) xo[mm] = f2bf(acc[mm] * sav);
}

// ---------------- fused layernorms ----------------
__global__ __launch_bounds__(256) void ln_fused2b(
    const float* __restrict__ p0, const float* __restrict__ p1,
    const float* __restrict__ resid, const float* __restrict__ bias,
    const float* __restrict__ g, const float* __restrict__ b,
    float* __restrict__ out, u16* __restrict__ outbf){
  int row = blockIdx.x; int tid = threadIdx.x;
  int lane = tid & 63, wave = tid >> 6;
  size_t off = (size_t)row * 1024 + tid * 4;
  float4 a0 = *reinterpret_cast<const float4*>(p0 + off);
  float4 a1 = *reinterpret_cast<const float4*>(p1 + off);
  float4 rr = *reinterpret_cast<const float4*>(resid + off);
  float4 bb = *reinterpret_cast<const float4*>(bias + tid * 4);
  float4 v = make_float4(a0.x + a1.x + rr.x + bb.x, a0.y + a1.y + rr.y + bb.y,
                         a0.z + a1.z + rr.z + bb.z, a0.w + a1.w + rr.w + bb.w);
  float s = v.x + v.y + v.z + v.w;
  float s2 = v.x*v.x + v.y*v.y + v.z*v.z + v.w*v.w;
  s = wred64(s); s2 = wred64(s2);
  __shared__ float red[2][4];
  if (lane == 0){ red[0][wave] = s; red[1][wave] = s2; }
  __syncthreads();
  float S = red[0][0] + red[0][1] + red[0][2] + red[0][3];
  float S2 = red[1][0] + red[1][1] + red[1][2] + red[1][3];
  float mean = S * (1.f / 1024.f);
  float var = S2 * (1.f / 1024.f) - mean * mean;
  float inv = rsqrtf(var + 1e-5f);
  float4 gv = *reinterpret_cast<const float4*>(g + tid * 4);
  float4 bv = *reinterpret_cast<const float4*>(b + tid * 4);
  float y0 = (v.x - mean) * inv * gv.x + bv.x;
  float y1 = (v.y - mean) * inv * gv.y + bv.y;
  float y2 = (v.z - mean) * inv * gv.z + bv.z;
  float y3 = (v.w - mean) * inv * gv.w + bv.w;
  *reinterpret_cast<float4*>(out + off) = make_float4(y0, y1, y2, y3);
  ushort4 o; o.x = f2bf(y0); o.y = f2bf(y1); o.z = f2bf(y2); o.w = f2bf(y3);
  *reinterpret_cast<ushort4*>(outbf + off) = o;
}

__global__ __launch_bounds__(256) void ln_fused4(
    const float* __restrict__ p0, const float* __restrict__ p1,
    const float* __restrict__ p2, const float* __restrict__ p3,
    const float* __restrict__ resid, const float* __restrict__ bias,
    const float* __restrict__ g, const float* __restrict__ b,
    float* __restrict__ out){
  int row = blockIdx.x; int tid = threadIdx.x;
  int lane = tid & 63, wave = tid >> 6;
  size_t off = (size_t)row * 1024 + tid * 4;
  float4 a0 = *reinterpret_cast<const float4*>(p0 + off);
  float4 a1 = *reinterpret_cast<const float4*>(p1 + off);
  float4 a2 = *reinterpret_cast<const float4*>(p2 + off);
  float4 a3 = *reinterpret_cast<const float4*>(p3 + off);
  float4 rr = *reinterpret_cast<const float4*>(resid + off);
  float4 bb = *reinterpret_cast<const float4*>(bias + tid * 4);
  float4 v = make_float4(a0.x + a1.x + a2.x + a3.x + rr.x + bb.x,
                         a0.y + a1.y + a2.y + a3.y + rr.y + bb.y,
                         a0.z + a1.z + a2.z + a3.z + rr.z + bb.z,
                         a0.w + a1.w + a2.w + a3.w + rr.w + bb.w);
  float s = v.x + v.y + v.z + v.w;
  float s2 = v.x*v.x + v.y*v.y + v.z*v.z + v.w*v.w;
  s = wred64(s); s2 = wred64(s2);
  __shared__ float red[2][4];
  if (lane == 0){ red[0][wave] = s; red[1][wave] = s2; }
  __syncthreads();
  float S = red[0][0] + red[0][1] + red[0][2] + red[0][3];
  float S2 = red[1][0] + red[1][1] + red[1][2] + red[1][3];
  float mean = S * (1.f / 1024.f);
  float var = S2 * (1.f / 1024.f) - mean * mean;
  float inv = rsqrtf(var + 1e-5f);
  float4 gv = *reinterpret_cast<const float4*>(g + tid * 4);
  float4 bv = *reinterpret_cast<const float4*>(b + tid * 4);
  float y0 = (v.x - mean) * inv * gv.x + bv.x;
  float y1 = (v.y - mean) * inv * gv.y + bv.y;
  float y2 = (v.z - mean) * inv * gv.z + bv.z;
  float y3 = (v.w - mean) * inv * gv.w + bv.w;
  *reinterpret_cast<float4*>(out + off) = make_float4(y0, y1, y2, y3);
}

// ---------------- launch ----------------
extern "C" void kernel_launch(void* const* d_in, const int* in_sizes, int n_in,
                              void* d_out, int out_size, void* d_ws, size_t ws_size,
                              hipStream_t stream){
  (void)in_sizes; (void)n_in; (void)out_size; (void)ws_size;
  const float* inputs = (const float*)d_in[0];
  const float* Wq = (const float*)d_in[2];  const float* bq = (const float*)d_in[3];
  const float* Wk = (const float*)d_in[4];  const float* bk = (const float*)d_in[5];
  const float* Wv = (const float*)d_in[6];  const float* bv = (const float*)d_in[7];
  const float* Wo = (const float*)d_in[8];  const float* bo = (const float*)d_in[9];
  const float* ln1g = (const float*)d_in[10]; const float* ln1b = (const float*)d_in[11];
  const float* W1 = (const float*)d_in[12]; const float* b1 = (const float*)d_in[13];
  const float* W2 = (const float*)d_in[14]; const float* b2 = (const float*)d_in[15];
  const float* ln2g = (const float*)d_in[16]; const float* ln2b = (const float*)d_in[17];
  float* out = (float*)d_out;

  char* wsp = (char*)d_ws; size_t off = 0;
  auto alloc = [&](size_t bytes) -> void* {
    off = (off + 255) & ~(size_t)255;
    void* p = wsp + off; off += bytes; return p;
  };
  const size_t MD = (size_t)2048 * 1024;
  u16* Xbf    = (u16*)alloc(MD * 2);
  u16* WqkvT  = (u16*)alloc((size_t)3 * 1024 * 1024 * 2);
  u16* WoT    = (u16*)alloc((size_t)1024 * 1024 * 2);
  u16* W1T    = (u16*)alloc((size_t)4096 * 1024 * 2);
  u16* W2T    = (u16*)alloc((size_t)4096 * 1024 * 2);
  float* bqkv = (float*)alloc(3072 * 4);
  float* qkvb = (float*)alloc(3 * MD * 4);
  float* qb = qkvb; float* kb = qkvb + MD; float* vb = qkvb + 2 * MD;
  float* quad = (float*)alloc(4 * MD * 4);
  float* Sbuf = quad;
  float* KVp  = quad + MD;
  float* ckb  = (float*)alloc((size_t)512 * 64 * 4);
  float* cqb  = (float*)alloc((size_t)512 * 64 * 4);
  float* csob = (float*)alloc((size_t)512 * 64 * 4);
  float* cqsib= (float*)alloc((size_t)512 * 64 * 4);
  float* sink_in = (float*)alloc(NBH * LSEQ * 4);
  float* src_out = (float*)alloc(NBH * LSEQ * 4);
  float* sabuf   = (float*)alloc(NBH * LSEQ * 4);
  float* ebuf    = (float*)alloc(NBH * LSEQ * 4);
  float* scbuf   = (float*)alloc(NBH * LSEQ * 4);
  u16* xatt   = (u16*)alloc(MD * 2);
  u16* g1     = (u16*)alloc((size_t)2048 * 4096 * 2);
  float* part = quad;
  float* hbuf = vb;
  u16* hbf = (u16*)qb;

  // converts + weight prep
  f2bf_kernel<<<2048, 256, 0, stream>>>(inputs, Xbf, (int)(MD / 4));
  transpose4_f2bf<<<dim3(32, 32, 4), 256, 0, stream>>>(Wq, Wk, Wv, Wo, WqkvT, WoT);
  transpose2_f2bf<<<dim3(128, 32, 2), 256, 0, stream>>>(W1, W2, W1T, W2T);
  bias_gather<<<12, 256, 0, stream>>>(bq, bk, bv, bqkv);

  // fused QKV projection: BM=128,BN=64, grid 16x48 = 768 blocks (3/CU, 48KB LDS)
  gemm_mfma<128, 64, 0, 1><<<dim3(16, 48), 256, 0, stream>>>(
      Xbf, WqkvT, bqkv, nullptr, qkvb, nullptr, 2048, 3072, 1024);

  // attention scalars (chunked Gram-tile pipeline)
  chunk_sums<<<512, 256, 0, stream>>>(kb, qb, ckb, cqb);
  sink_tile<<<512, 256, 0, stream>>>(qb, kb, ckb, cqb, sink_in, src_out, csob, cqsib);
  cons_tile<<<512, 256, 0, stream>>>(qb, kb, csob, cqsib, sink_in, src_out, sabuf, ebuf);
  srccomp_kernel<<<32, 64, 0, stream>>>(ebuf, scbuf);

  // chunked causal linear attention (scale fused into A and C)
  phaseA<<<512, 256, 0, stream>>>(kb, vb, scbuf, Sbuf);
  phaseB<<<512, 256, 0, stream>>>(Sbuf, KVp);
  phaseC<<<512, 256, 0, stream>>>(qb, kb, vb, KVp, sink_in, scbuf, sabuf, xatt);

  // output projection: BM=128,BN=64, split-K=2
  gemm_mfma<128, 64, 0, 4><<<dim3(16, 16, 2), 256, 0, stream>>>(
      xatt, WoT, nullptr, nullptr, part, nullptr, 2048, 1024, 1024);
  ln_fused2b<<<2048, 256, 0, stream>>>(part, part + MD, inputs, bo, ln1g, ln1b, hbuf, hbf);

  // FFN1: BM=128,BN=128 (fast gelu), 64KB LDS dbuf -> 2 blocks/CU = grid
  gemm_mfma<128, 128, 2, 3><<<dim3(16, 32), 256, 0, stream>>>(
      hbf, W1T, b1, nullptr, nullptr, g1, 2048, 4096, 1024);
  // FFN2: BM=128,BN=128, split-K=4
  gemm_mfma<128, 128, 0, 4><<<dim3(16, 8, 4), 256, 0, stream>>>(
      g1, W2T, nullptr, nullptr, part, nullptr, 2048, 1024, 4096);
  ln_fused4<<<2048, 256, 0, stream>>>(part, part + MD, part + 2 * MD, part + 3 * MD,
                                      hbuf, b2, ln2g, ln2b, out);
}

// Round 13
// 206.939 us; speedup vs baseline: 1.3934x; 1.0451x over previous
//
#include <hip/hip_runtime.h>
#include <hip/hip_bf16.h>

// ---------------- constants ----------------
#define EPS 1e-6f
#define NBH 32      // B*H
#define LSEQ 1024
#define DHD 64

typedef unsigned short u16;
typedef __bf16 bf16x8 __attribute__((ext_vector_type(8)));
typedef float f32x4 __attribute__((ext_vector_type(4)));

__device__ inline u16 f2bf(float f){
  union { float f; unsigned u; } un; un.f = f;
  unsigned u = un.u;
  u += 0x7fffu + ((u >> 16) & 1u);
  return (u16)(u >> 16);
}

__device__ inline float wred64(float v){
#pragma unroll
  for (int off = 32; off > 0; off >>= 1) v += __shfl_xor(v, off, 64);
  return v;
}

__device__ inline float wscan64(float v, int lane){
  float run = v;
#pragma unroll
  for (int off = 1; off < 64; off <<= 1){
    float t = __shfl_up(run, off, 64);
    if (lane >= off) run += t;
  }
  return run;   // inclusive
}

__device__ inline float fast_sigmoid(float x){
  return 1.f / (1.f + __expf(-x));
}

__device__ inline void gload_lds16(const u16* g, u16* l){
  __builtin_amdgcn_global_load_lds(
      (const __attribute__((address_space(1))) unsigned int*)g,
      (__attribute__((address_space(3))) unsigned int*)l, 16, 0, 0);
}

// ---------------- mega prep kernel (f2bf + 6 transposes + bias gather) -------
__device__ inline void tr_tile2(const float* in, u16* out, int R, int C, int r0, int c0){
  __shared__ float tile[32][33];
  int x = threadIdx.x & 31, y = threadIdx.x >> 5;
#pragma unroll
  for (int j = 0; j < 4; j++)
    tile[y + j*8][x] = in[(size_t)(r0 + y + j*8) * C + c0 + x];
  __syncthreads();
#pragma unroll
  for (int j = 0; j < 4; j++)
    out[(size_t)(c0 + y + j*8) * R + r0 + x] = f2bf(tile[x][y + j*8]);
}

// blocks: [0,2048) f2bf inputs; [2048,6144) Wq/Wk/Wv/Wo transposes;
// [6144,14336) W1/W2 transposes; [14336,14348) bias gather
__global__ __launch_bounds__(256) void prep_all(
    const float* __restrict__ inputs, u16* __restrict__ Xbf,
    const float* __restrict__ Wq, const float* __restrict__ Wk,
    const float* __restrict__ Wv, const float* __restrict__ Wo,
    u16* __restrict__ dqkv, u16* __restrict__ dwo,
    const float* __restrict__ W1, const float* __restrict__ W2,
    u16* __restrict__ d1, u16* __restrict__ d2,
    const float* __restrict__ bq, const float* __restrict__ bk,
    const float* __restrict__ bv, float* __restrict__ bqkv)
{
  int b = blockIdx.x;
  if (b < 2048){
    int i = b * 256 + threadIdx.x;
    float4 v = reinterpret_cast<const float4*>(inputs)[i];
    ushort4 o; o.x = f2bf(v.x); o.y = f2bf(v.y); o.z = f2bf(v.z); o.w = f2bf(v.w);
    reinterpret_cast<ushort4*>(Xbf)[i] = o;
  } else if (b < 6144){
    int t = b - 2048;
    int z = t >> 10, rem = t & 1023;
    int bx = rem & 31, by = rem >> 5;
    const float* in = (z == 0) ? Wq : (z == 1) ? Wk : (z == 2) ? Wv : Wo;
    u16* out = (z < 3) ? (dqkv + (size_t)z * 1024 * 1024) : dwo;
    tr_tile2(in, out, 1024, 1024, by * 32, bx * 32);
  } else if (b < 14336){
    int t = b - 6144;
    int z = t >> 12, rem = t & 4095;
    int bx = rem & 127, by = rem >> 7;
    if (z == 0) tr_tile2(W1, d1, 1024, 4096, by * 32, bx * 32);
    else        tr_tile2(W2, d2, 4096, 1024, bx * 32, by * 32);
  } else {
    int i = (b - 14336) * 256 + threadIdx.x;
    if (i < 3072){
      float v = (i < 1024) ? bq[i] : (i < 2048) ? bk[i - 1024] : bv[i - 2048];
      bqkv[i] = v;
    }
  }
}

// ---------------- bf16 MFMA GEMM (dbuf + counted vmcnt, T2 XOR-swizzled LDS) ----
// C[M,N] = act(A[M,K] @ Bt[N,K]^T + bias)
// LDS: BK=64 bf16 rows = 8 x 16B slots; slot s of row r at phys slot s^(r&7)
// (rule #21: linear gload_lds dest + pre-swizzled SOURCE + swizzled READ).
// Pipeline: STAGE(next) before compute(cur); s_waitcnt vmcnt(NS) keeps the
// next tile's loads in flight across the barrier (T3 minimum 2-phase).
// ACT: 0 none, 2 gelu  (OM==1 applies fast sigmoid for col<2048 internally)
// OM: 1 fused-QKV remap to 3x[B,H,L,DH]; 3 bf16 [M][N];
//     4 raw f32 partial (split-K slice z at outF + z*M*N, no bias)
template<int BM, int BN, int ACT, int OM>
__global__ __launch_bounds__(256) void gemm_mfma(
    const u16* __restrict__ A, const u16* __restrict__ Bt,
    const float* __restrict__ bias, const float* __restrict__ resid,
    float* __restrict__ outF, u16* __restrict__ outB,
    int M, int N, int K)
{
  constexpr int BK = 64;
  constexpr int MI = BM / 32;
  constexpr int NJ = BN / 32;
  constexpr int RA = BM / 32;
  constexpr int RB = BN / 32;
  constexpr int NS = RA + RB;
  __shared__ u16 As[2][BM * BK];
  __shared__ u16 Bs[2][BN * BK];
  const int tid = threadIdx.x;
  const int lane = tid & 63, wave = tid >> 6;
  const int lrow = lane & 15, lg = lane >> 4;
  const int m0 = blockIdx.x * BM, n0 = blockIdx.y * BN;
  const int wm = (wave >> 1) * (BM / 2), wn = (wave & 1) * (BN / 2);

  const int ksz = K / gridDim.z;
  const int k_begin = blockIdx.z * ksz;
  const int k_end = k_begin + ksz;

  f32x4 acc[MI][NJ];
#pragma unroll
  for (int i = 0; i < MI; i++)
#pragma unroll
    for (int j = 0; j < NJ; j++) acc[i][j] = (f32x4){0.f, 0.f, 0.f, 0.f};

  const u16* Ab = A + (size_t)m0 * K;
  const u16* Bb = Bt + (size_t)n0 * K;

  const int s0 = ((0 * 4 + lg) ^ (lrow & 7)) * 8;
  const int s1 = ((1 * 4 + lg) ^ (lrow & 7)) * 8;

  auto STAGE = [&](int buf, int k0){
#pragma unroll
    for (int r = 0; r < RA; ++r){
      int c = r * 256 + tid;
      int row = c >> 3;
      int kk = ((c ^ row) & 7) << 3;
      gload_lds16(Ab + (size_t)row * K + k0 + kk, &As[buf][(r * 256 + wave * 64) * 8]);
    }
#pragma unroll
    for (int r = 0; r < RB; ++r){
      int c = r * 256 + tid;
      int row = c >> 3;
      int kk = ((c ^ row) & 7) << 3;
      gload_lds16(Bb + (size_t)row * K + k0 + kk, &Bs[buf][(r * 256 + wave * 64) * 8]);
    }
  };

  STAGE(0, k_begin);
  int cur = 0;
  for (int k0 = k_begin; k0 < k_end; k0 += BK){
    if (k0 + BK < k_end){
      STAGE(cur ^ 1, k0 + BK);
      if constexpr (NS == 8)      asm volatile("s_waitcnt vmcnt(8)" ::: "memory");
      else if constexpr (NS == 6) asm volatile("s_waitcnt vmcnt(6)" ::: "memory");
      else                        asm volatile("s_waitcnt vmcnt(0)" ::: "memory");
    } else {
      asm volatile("s_waitcnt vmcnt(0)" ::: "memory");
    }
    __builtin_amdgcn_s_barrier();
    __builtin_amdgcn_sched_barrier(0);
#pragma unroll
    for (int kh = 0; kh < 2; ++kh){
      const int ss = (kh == 0) ? s0 : s1;
      bf16x8 af[MI], bfv[NJ];
#pragma unroll
      for (int i = 0; i < MI; ++i)
        af[i] = *reinterpret_cast<const bf16x8*>(&As[cur][(wm + i * 16 + lrow) * BK + ss]);
#pragma unroll
      for (int j = 0; j < NJ; ++j)
        bfv[j] = *reinterpret_cast<const bf16x8*>(&Bs[cur][(wn + j * 16 + lrow) * BK + ss]);
#pragma unroll
      for (int i = 0; i < MI; ++i)
#pragma unroll
        for (int j = 0; j < NJ; ++j)
          acc[i][j] = __builtin_amdgcn_mfma_f32_16x16x32_bf16(af[i], bfv[j], acc[i][j], 0, 0, 0);
    }
    __builtin_amdgcn_s_barrier();
    cur ^= 1;
  }

#pragma unroll
  for (int i = 0; i < MI; ++i){
#pragma unroll
    for (int j = 0; j < NJ; ++j){
      int col = n0 + wn + j * 16 + lrow;
      float bv = (OM != 4 && bias) ? bias[col] : 0.f;
#pragma unroll
      for (int r = 0; r < 4; ++r){
        int row = m0 + wm + i * 16 + lg * 4 + r;
        float x = acc[i][j][r] + bv;
        if (OM == 1){
          if (col < 2048) x = fast_sigmoid(x);
          int which = col >> 10, cc = col & 1023, h = cc >> 6, d = cc & 63;
          int b = row >> 10, l = row & 1023;
          outF[(size_t)which * (2048ull * 1024) +
               (((size_t)(b * 16 + h)) * 1024 + l) * 64 + d] = x;
        } else if (OM == 4){
          outF[((size_t)blockIdx.z * M + row) * N + col] = x;
        } else {
          if (ACT == 2){
            float u = 0.7978845608f * (x + 0.044715f * x * x * x);
            float e = __expf(2.f * u);
            x = 0.5f * x * (2.f - 2.f / (e + 1.f));
          }
          outB[(size_t)row * N + col] = f2bf(x);
        }
      }
    }
  }
}

// ---------------- attention scalar pipeline (chunked Gram-tile form) ----------------
__global__ __launch_bounds__(256) void chunk_sums(const float* __restrict__ k, const float* __restrict__ q,
                                                  float* __restrict__ ck, float* __restrict__ cq){
  int blk = blockIdx.x;
  int lane = threadIdx.x & 63, wave = threadIdx.x >> 6;
  size_t base = (size_t)blk * 64 * DHD;
  float sk = 0.f, sq = 0.f;
  for (int l = wave * 16; l < wave * 16 + 16; l++){
    sk += k[base + l * 64 + lane];
    sq += q[base + l * 64 + lane];
  }
  __shared__ float rd[2][4][64];
  rd[0][wave][lane] = sk; rd[1][wave][lane] = sq;
  __syncthreads();
  if (wave == 0){
    ck[(size_t)blk * 64 + lane] = rd[0][0][lane] + rd[0][1][lane] + rd[0][2][lane] + rd[0][3][lane];
    cq[(size_t)blk * 64 + lane] = rd[1][0][lane] + rd[1][1][lane] + rd[1][2][lane] + rd[1][3][lane];
  }
}

__global__ __launch_bounds__(256) void sink_tile(
    const float* __restrict__ q, const float* __restrict__ k,
    const float* __restrict__ ck, const float* __restrict__ cq,
    float* __restrict__ sink_in, float* __restrict__ src_out,
    float* __restrict__ cso, float* __restrict__ cqsi)
{
  int blk = blockIdx.x, bh = blk >> 4, c = blk & 15;
  int tid = threadIdx.x, lane = tid & 63, wave = tid >> 6;
  __shared__ float qT[64][65], kT[64][65], G[64][66];
  __shared__ float PK[64], PQ[64];
  __shared__ float rk[64], rq[64], crk[64], crq[64], siv[64], sov[64];
  __shared__ float rd[2][4][64];
  size_t base = ((size_t)bh * LSEQ + c * 64) * DHD;
  const float* qb = q + base; const float* kb = k + base;
  for (int c4 = tid; c4 < 1024; c4 += 256){
    int l = c4 >> 4, d0 = (c4 & 15) * 4;
    float4 qv = *reinterpret_cast<const float4*>(qb + c4 * 4);
    qT[d0+0][l] = qv.x; qT[d0+1][l] = qv.y; qT[d0+2][l] = qv.z; qT[d0+3][l] = qv.w;
    float4 kv = *reinterpret_cast<const float4*>(kb + c4 * 4);
    kT[d0+0][l] = kv.x; kT[d0+1][l] = kv.y; kT[d0+2][l] = kv.z; kT[d0+3][l] = kv.w;
  }
  if (tid < 64){
    float pk = 0.f, pq = 0.f;
    for (int cc = 0; cc < c; cc++){
      pk += ck[((size_t)bh * 16 + cc) * 64 + tid];
      pq += cq[((size_t)bh * 16 + cc) * 64 + tid];
    }
    PK[tid] = pk; PQ[tid] = pq;
  }
  __syncthreads();
  float sumPK = wred64(PK[lane]);
  float sumPQ = wred64(PQ[lane]);
  {
    int l = lane, g = wave;
    float qrow[64];
#pragma unroll
    for (int d = 0; d < 64; d++) qrow[d] = qT[d][l];
    float p[16] = {};
    for (int d = 0; d < 64; d++){
      float qv = qrow[d];
#pragma unroll
      for (int j4 = 0; j4 < 4; j4++){
        float4 kk = *reinterpret_cast<const float4*>(&kT[d][g * 16 + j4 * 4]);
        p[j4*4+0] += qv * kk.x; p[j4*4+1] += qv * kk.y;
        p[j4*4+2] += qv * kk.z; p[j4*4+3] += qv * kk.w;
      }
    }
#pragma unroll
    for (int jj = 0; jj < 16; jj++) G[l][g * 16 + jj] = p[jj];
  }
  {
    float pk_ = 0.f, pq_ = 0.f;
#pragma unroll
    for (int d = wave * 16; d < wave * 16 + 16; d++){
      pk_ += kT[d][lane]; pq_ += qT[d][lane];
    }
    rd[0][wave][lane] = pk_; rd[1][wave][lane] = pq_;
  }
  __syncthreads();
  if (tid < 64){
    rk[tid] = rd[0][0][tid] + rd[0][1][tid] + rd[0][2][tid] + rd[0][3][tid];
    rq[tid] = rd[1][0][tid] + rd[1][1][tid] + rd[1][2][tid] + rd[1][3][tid];
  }
  __syncthreads();
  if (wave == 0)      crk[lane] = wscan64(rk[lane], lane);
  else if (wave == 1) crq[lane] = wscan64(rq[lane], lane);
  __syncthreads();
  {
    int l = lane;
    float p1 = 0.f, p2 = 0.f;
#pragma unroll
    for (int j = wave * 16; j < wave * 16 + 16; j++){
      float g1 = (j <= l) ? G[l][j] : 0.f;
      p1 += g1 + qT[j][l] * PK[j];
      float g2 = (j <= l) ? G[j][l] : 0.f;
      p2 += g2 + kT[j][l] * PQ[j];
    }
    rd[0][wave][l] = p1; rd[1][wave][l] = p2;
  }
  __syncthreads();
  const float EPS2 = 64.f * EPS * EPS;
  if (tid < 64){
    int l = tid;
    float s1 = rd[0][0][l] + rd[0][1][l] + rd[0][2][l] + rd[0][3][l];
    float s2 = rd[1][0][l] + rd[1][1][l] + rd[1][2][l] + rd[1][3][l];
    int L = c * 64 + l; float nrm = (float)(L + 1);
    float den1 = s1 + EPS * rq[l] + EPS * (sumPK + crk[l]) + EPS2;
    float den2 = s2 + EPS * rk[l] + EPS * (sumPQ + crq[l]) + EPS2;
    float si_ = nrm / den1, so_ = nrm / den2;
    sink_in[(size_t)bh * LSEQ + L] = si_;
    src_out[(size_t)bh * LSEQ + L] = so_;
    siv[l] = si_; sov[l] = so_;
  }
  __syncthreads();
  float s1 = 0.f, s2 = 0.f;
  for (int l = wave * 16; l < wave * 16 + 16; l++){
    s1 += sov[l] * kT[lane][l];
    s2 += siv[l] * qT[lane][l];
  }
  rd[0][wave][lane] = s1; rd[1][wave][lane] = s2;
  __syncthreads();
  if (wave == 0){
    cso [(size_t)blk * 64 + lane] = rd[0][0][lane] + rd[0][1][lane] + rd[0][2][lane] + rd[0][3][lane];
    cqsi[(size_t)blk * 64 + lane] = rd[1][0][lane] + rd[1][1][lane] + rd[1][2][lane] + rd[1][3][lane];
  }
}

__global__ __launch_bounds__(256) void cons_tile(
    const float* __restrict__ q, const float* __restrict__ k,
    const float* __restrict__ cso, const float* __restrict__ cqsi,
    const float* __restrict__ sink_in, const float* __restrict__ src_out,
    float* __restrict__ sa, float* __restrict__ ebuf)
{
  int blk = blockIdx.x, bh = blk >> 4, c = blk & 15;
  int tid = threadIdx.x, lane = tid & 63, wave = tid >> 6;
  __shared__ float qT[64][65], kT[64][65], G[64][66];
  __shared__ float PKso[64], PQsi[64];
  __shared__ float rk[64], rq[64], cwrk[64], cwrq[64], siv[64], sov[64];
  __shared__ float rd[2][4][64];
  size_t base = ((size_t)bh * LSEQ + c * 64) * DHD;
  const float* qb = q + base; const float* kb = k + base;
  for (int c4 = tid; c4 < 1024; c4 += 256){
    int l = c4 >> 4, d0 = (c4 & 15) * 4;
    float4 qv = *reinterpret_cast<const float4*>(qb + c4 * 4);
    qT[d0+0][l] = qv.x; qT[d0+1][l] = qv.y; qT[d0+2][l] = qv.z; qT[d0+3][l] = qv.w;
    float4 kv = *reinterpret_cast<const float4*>(kb + c4 * 4);
    kT[d0+0][l] = kv.x; kT[d0+1][l] = kv.y; kT[d0+2][l] = kv.z; kT[d0+3][l] = kv.w;
  }
  if (tid < 64){
    float pk = 0.f, pq = 0.f;
    for (int cc = 0; cc < c; cc++){
      pk += cso [((size_t)bh * 16 + cc) * 64 + tid];
      pq += cqsi[((size_t)bh * 16 + cc) * 64 + tid];
    }
    PKso[tid] = pk; PQsi[tid] = pq;
  } else if (tid < 128){
    int l = tid - 64;
    sov[l] = src_out[(size_t)bh * LSEQ + c * 64 + l];
    siv[l] = sink_in[(size_t)bh * LSEQ + c * 64 + l];
  }
  __syncthreads();
  float sumPKso = wred64(PKso[lane]);
  float sumPQsi = wred64(PQsi[lane]);
  {
    int l = lane, g = wave;
    float qrow[64];
#pragma unroll
    for (int d = 0; d < 64; d++) qrow[d] = qT[d][l];
    float p[16] = {};
    for (int d = 0; d < 64; d++){
      float qv = qrow[d];
#pragma unroll
      for (int j4 = 0; j4 < 4; j4++){
        float4 kk = *reinterpret_cast<const float4*>(&kT[d][g * 16 + j4 * 4]);
        p[j4*4+0] += qv * kk.x; p[j4*4+1] += qv * kk.y;
        p[j4*4+2] += qv * kk.z; p[j4*4+3] += qv * kk.w;
      }
    }
#pragma unroll
    for (int jj = 0; jj < 16; jj++) G[l][g * 16 + jj] = p[jj];
  }
  {
    float pk_ = 0.f, pq_ = 0.f;
#pragma unroll
    for (int d = wave * 16; d < wave * 16 + 16; d++){
      pk_ += kT[d][lane]; pq_ += qT[d][lane];
    }
    rd[0][wave][lane] = pk_; rd[1][wave][lane] = pq_;
  }
  __syncthreads();
  if (tid < 64){
    rk[tid] = rd[0][0][tid] + rd[0][1][tid] + rd[0][2][tid] + rd[0][3][tid];
    rq[tid] = rd[1][0][tid] + rd[1][1][tid] + rd[1][2][tid] + rd[1][3][tid];
  }
  __syncthreads();
  if (wave == 0)      cwrk[lane] = wscan64(sov[lane] * rk[lane], lane);
  else if (wave == 1) cwrq[lane] = wscan64(siv[lane] * rq[lane], lane);
  __syncthreads();
  {
    int l = lane;
    float p3 = 0.f, p4 = 0.f;
#pragma unroll
    for (int j = wave * 16; j < wave * 16 + 16; j++){
      float g3 = (j <= l) ? sov[j] * G[l][j] : 0.f;
      p3 += g3 + qT[j][l] * PKso[j];
      float g4 = (j <= l) ? siv[j] * G[j][l] : 0.f;
      p4 += g4 + kT[j][l] * PQsi[j];
    }
    rd[0][wave][l] = p3; rd[1][wave][l] = p4;
  }
  __syncthreads();
  const float EPS2 = 64.f * EPS * EPS;
  if (tid < 64){
    int l = tid;
    float s3 = rd[0][0][l] + rd[0][1][l] + rd[0][2][l] + rd[0][3][l];
    float s4 = rd[1][0][l] + rd[1][1][l] + rd[1][2][l] + rd[1][3][l];
    int L = c * 64 + l; float nrm = (float)(L + 1);
    float cs = (s3 + EPS * rq[l] + EPS * (sumPKso + cwrk[l]) + EPS2) / nrm;
    sa[(size_t)bh * LSEQ + L] = fast_sigmoid(cs);
    float c2 = (s4 + EPS * rk[l] + EPS * (sumPQsi + cwrq[l]) + EPS2) / nrm;
    c2 = fminf(1.f, fmaxf(-1.f, c2));
    ebuf[(size_t)bh * LSEQ + L] = __expf(c2);
  }
}

// src_comp = e / cumsum(e) * (l+1)
__global__ __launch_bounds__(64) void srccomp_kernel(const float* __restrict__ ebuf, float* __restrict__ sc){
  int bh = blockIdx.x; int lane = threadIdx.x;
  const float* eb = ebuf + (size_t)bh * LSEQ;
  float loc[16]; float s = 0.f;
#pragma unroll
  for (int i = 0; i < 16; i++){ loc[i] = eb[lane * 16 + i]; s += loc[i]; }
  float run = wscan64(s, lane);
  float acc = run - s;
  float* scb = sc + (size_t)bh * LSEQ;
#pragma unroll
  for (int i = 0; i < 16; i++){
    acc += loc[i];
    scb[lane * 16 + i] = loc[i] / acc * (float)(lane * 16 + i + 1);
  }
}

// ---------------- chunked causal linear attention (scale fused in) ----------------
__global__ __launch_bounds__(256) void phaseA(const float* __restrict__ k, const float* __restrict__ v,
                                              const float* __restrict__ sc, float* __restrict__ S){
  int blk = blockIdx.x; int bh = blk >> 4, c = blk & 15;
  __shared__ float ks[64][68], vss[64][68];
  __shared__ float vc[64];
  int tid = threadIdx.x;
  size_t base = ((size_t)bh * LSEQ + c * 64) * DHD;
  const float* kb = k + base; const float* vb = v + base;
  if (tid < 64) vc[tid] = sc[(size_t)bh * LSEQ + c * 64 + tid];
  __syncthreads();
  for (int c4 = tid; c4 < 1024; c4 += 256){
    int l = c4 >> 4, d0 = (c4 & 15) * 4;
    *reinterpret_cast<float4*>(&ks[l][d0]) = *reinterpret_cast<const float4*>(kb + c4 * 4);
    float4 vv = *reinterpret_cast<const float4*>(vb + c4 * 4);
    float w = vc[l];
    vss[l][d0+0] = vv.x * w; vss[l][d0+1] = vv.y * w;
    vss[l][d0+2] = vv.z * w; vss[l][d0+3] = vv.w * w;
  }
  __syncthreads();
  int m = tid >> 2, dg = tid & 3;
  float acc[16] = {};
  for (int l = 0; l < 64; l++){
    float vm = vss[l][m];
#pragma unroll
    for (int d4 = 0; d4 < 4; d4++){
      float4 kk = *reinterpret_cast<const float4*>(&ks[l][dg * 16 + d4 * 4]);
      acc[d4*4+0] += vm * kk.x; acc[d4*4+1] += vm * kk.y;
      acc[d4*4+2] += vm * kk.z; acc[d4*4+3] += vm * kk.w;
    }
  }
  float* Sb = S + (size_t)blk * 4096 + m * 64 + dg * 16;
#pragma unroll
  for (int d4 = 0; d4 < 4; d4++)
    *reinterpret_cast<float4*>(Sb + d4 * 4) =
        make_float4(acc[d4*4], acc[d4*4+1], acc[d4*4+2], acc[d4*4+3]);
}

// phase C with inlined KV-prefix (former phaseB): each thread accumulates its
// 16 owned kvs elements over prior chunks' S directly from global.
__global__ __launch_bounds__(256) void phaseC(const float* __restrict__ q, const float* __restrict__ k,
                                              const float* __restrict__ v, const float* __restrict__ S,
                                              const float* __restrict__ sink_in, const float* __restrict__ sc,
                                              const float* __restrict__ sa, u16* __restrict__ x){
  int blk = blockIdx.x; int bh = blk >> 4, c = blk & 15;
  int b = bh >> 4, h = bh & 15;
  __shared__ float qsT[64][65];
  __shared__ float kT[64][68];
  __shared__ float vss[64][68];
  __shared__ float kvs[64][68];
  __shared__ float Ps[64][66];
  __shared__ float qc[64], vc[64];
  int tid = threadIdx.x;
  size_t base = ((size_t)bh * LSEQ + c * 64) * DHD;
  const float* qb = q + base; const float* kb = k + base; const float* vb = v + base;
  if (tid < 64){
    int L = c * 64 + tid;
    qc[tid] = sink_in[(size_t)bh * LSEQ + L] / (float)(L + 1);
    vc[tid] = sc[(size_t)bh * LSEQ + L];
  }
  // KV prefix: accumulate 16 elements per thread over chunks 0..c-1
  {
    int off16 = tid * 16;
    float accp[16] = {};
    for (int cc = 0; cc < c; cc++){
      size_t idx = ((size_t)bh * 16 + cc) * 4096 + off16;
#pragma unroll
      for (int t4 = 0; t4 < 4; t4++){
        float4 sv = *reinterpret_cast<const float4*>(S + idx + t4 * 4);
        accp[t4*4+0] += sv.x; accp[t4*4+1] += sv.y;
        accp[t4*4+2] += sv.z; accp[t4*4+3] += sv.w;
      }
    }
#pragma unroll
    for (int e = 0; e < 16; e++){
      int j = off16 + e;
      kvs[j >> 6][j & 63] = accp[e];
    }
  }
  __syncthreads();
  for (int c4 = tid; c4 < 1024; c4 += 256){
    int l = c4 >> 4, d0 = (c4 & 15) * 4;
    float qw = qc[l], vw = vc[l];
    float4 qv = *reinterpret_cast<const float4*>(qb + c4 * 4);
    qsT[d0+0][l] = qv.x * qw; qsT[d0+1][l] = qv.y * qw;
    qsT[d0+2][l] = qv.z * qw; qsT[d0+3][l] = qv.w * qw;
    float4 kv4 = *reinterpret_cast<const float4*>(kb + c4 * 4);
    kT[d0+0][l] = kv4.x; kT[d0+1][l] = kv4.y; kT[d0+2][l] = kv4.z; kT[d0+3][l] = kv4.w;
    float4 vv = *reinterpret_cast<const float4*>(vb + c4 * 4);
    vss[l][d0+0] = vv.x * vw; vss[l][d0+1] = vv.y * vw;
    vss[l][d0+2] = vv.z * vw; vss[l][d0+3] = vv.w * vw;
  }
  __syncthreads();
  int l = tid & 63, g = tid >> 6;
  float qrow[64];
#pragma unroll
  for (int d = 0; d < 64; d++) qrow[d] = qsT[d][l];

  float p[16] = {};
  for (int d = 0; d < 64; d++){
    float qv = qrow[d];
#pragma unroll
    for (int j4 = 0; j4 < 4; j4++){
      float4 kk = *reinterpret_cast<const float4*>(&kT[d][g * 16 + j4 * 4]);
      p[j4*4+0] += qv * kk.x; p[j4*4+1] += qv * kk.y;
      p[j4*4+2] += qv * kk.z; p[j4*4+3] += qv * kk.w;
    }
  }
#pragma unroll
  for (int jj = 0; jj < 16; jj++){
    int j = g * 16 + jj;
    Ps[l][j] = (j <= l) ? p[jj] : 0.f;
  }
  __syncthreads();

  float acc[16];
#pragma unroll
  for (int mm = 0; mm < 16; mm++){
    float a = 0.f;
#pragma unroll
    for (int d4 = 0; d4 < 16; d4++){
      float4 kv4 = *reinterpret_cast<const float4*>(&kvs[g * 16 + mm][d4 * 4]);
      a += qrow[d4*4+0]*kv4.x + qrow[d4*4+1]*kv4.y + qrow[d4*4+2]*kv4.z + qrow[d4*4+3]*kv4.w;
    }
    acc[mm] = a;
  }
  for (int j = 0; j < 64; j++){
    float pv = Ps[l][j];
#pragma unroll
    for (int m4 = 0; m4 < 4; m4++){
      float4 vv = *reinterpret_cast<const float4*>(&vss[j][g * 16 + m4 * 4]);
      acc[m4*4+0] += pv * vv.x; acc[m4*4+1] += pv * vv.y;
      acc[m4*4+2] += pv * vv.z; acc[m4*4+3] += pv * vv.w;
    }
  }
  float sav = sa[(size_t)bh * LSEQ + c * 64 + l];
  u16* xo = x + ((size_t)(b * 1024 + c * 64 + l)) * 1024 + h * 64 + g * 16;
#pragma unroll
  for (int mm = 0; mm < 16; mm++) xo[mm] = f2bf(acc[mm] * sav);
}

// ---------------- fused layernorms ----------------
__global__ __launch_bounds__(256) void ln_fused2b(
    const float* __restrict__ p0, const float* __restrict__ p1,
    const float* __restrict__ resid, const float* __restrict__ bias,
    const float* __restrict__ g, const float* __restrict__ b,
    float* __restrict__ out, u16* __restrict__ outbf){
  int row = blockIdx.x; int tid = threadIdx.x;
  int lane = tid & 63, wave = tid >> 6;
  size_t off = (size_t)row * 1024 + tid * 4;
  float4 a0 = *reinterpret_cast<const float4*>(p0 + off);
  float4 a1 = *reinterpret_cast<const float4*>(p1 + off);
  float4 rr = *reinterpret_cast<const float4*>(resid + off);
  float4 bb = *reinterpret_cast<const float4*>(bias + tid * 4);
  float4 v = make_float4(a0.x + a1.x + rr.x + bb.x, a0.y + a1.y + rr.y + bb.y,
                         a0.z + a1.z + rr.z + bb.z, a0.w + a1.w + rr.w + bb.w);
  float s = v.x + v.y + v.z + v.w;
  float s2 = v.x*v.x + v.y*v.y + v.z*v.z + v.w*v.w;
  s = wred64(s); s2 = wred64(s2);
  __shared__ float red[2][4];
  if (lane == 0){ red[0][wave] = s; red[1][wave] = s2; }
  __syncthreads();
  float S = red[0][0] + red[0][1] + red[0][2] + red[0][3];
  float S2 = red[1][0] + red[1][1] + red[1][2] + red[1][3];
  float mean = S * (1.f / 1024.f);
  float var = S2 * (1.f / 1024.f) - mean * mean;
  float inv = rsqrtf(var + 1e-5f);
  float4 gv = *reinterpret_cast<const float4*>(g + tid * 4);
  float4 bv = *reinterpret_cast<const float4*>(b + tid * 4);
  float y0 = (v.x - mean) * inv * gv.x + bv.x;
  float y1 = (v.y - mean) * inv * gv.y + bv.y;
  float y2 = (v.z - mean) * inv * gv.z + bv.z;
  float y3 = (v.w - mean) * inv * gv.w + bv.w;
  *reinterpret_cast<float4*>(out + off) = make_float4(y0, y1, y2, y3);
  ushort4 o; o.x = f2bf(y0); o.y = f2bf(y1); o.z = f2bf(y2); o.w = f2bf(y3);
  *reinterpret_cast<ushort4*>(outbf + off) = o;
}

__global__ __launch_bounds__(256) void ln_fused4(
    const float* __restrict__ p0, const float* __restrict__ p1,
    const float* __restrict__ p2, const float* __restrict__ p3,
    const float* __restrict__ resid, const float* __restrict__ bias,
    const float* __restrict__ g, const float* __restrict__ b,
    float* __restrict__ out){
  int row = blockIdx.x; int tid = threadIdx.x;
  int lane = tid & 63, wave = tid >> 6;
  size_t off = (size_t)row * 1024 + tid * 4;
  float4 a0 = *reinterpret_cast<const float4*>(p0 + off);
  float4 a1 = *reinterpret_cast<const float4*>(p1 + off);
  float4 a2 = *reinterpret_cast<const float4*>(p2 + off);
  float4 a3 = *reinterpret_cast<const float4*>(p3 + off);
  float4 rr = *reinterpret_cast<const float4*>(resid + off);
  float4 bb = *reinterpret_cast<const float4*>(bias + tid * 4);
  float4 v = make_float4(a0.x + a1.x + a2.x + a3.x + rr.x + bb.x,
                         a0.y + a1.y + a2.y + a3.y + rr.y + bb.y,
                         a0.z + a1.z + a2.z + a3.z + rr.z + bb.z,
                         a0.w + a1.w + a2.w + a3.w + rr.w + bb.w);
  float s = v.x + v.y + v.z + v.w;
  float s2 = v.x*v.x + v.y*v.y + v.z*v.z + v.w*v.w;
  s = wred64(s); s2 = wred64(s2);
  __shared__ float red[2][4];
  if (lane == 0){ red[0][wave] = s; red[1][wave] = s2; }
  __syncthreads();
  float S = red[0][0] + red[0][1] + red[0][2] + red[0][3];
  float S2 = red[1][0] + red[1][1] + red[1][2] + red[1][3];
  float mean = S * (1.f / 1024.f);
  float var = S2 * (1.f / 1024.f) - mean * mean;
  float inv = rsqrtf(var + 1e-5f);
  float4 gv = *reinterpret_cast<const float4*>(g + tid * 4);
  float4 bv = *reinterpret_cast<const float4*>(b + tid * 4);
  float y0 = (v.x - mean) * inv * gv.x + bv.x;
  float y1 = (v.y - mean) * inv * gv.y + bv.y;
  float y2 = (v.z - mean) * inv * gv.z + bv.z;
  float y3 = (v.w - mean) * inv * gv.w + bv.w;
  *reinterpret_cast<float4*>(out + off) = make_float4(y0, y1, y2, y3);
}

// ---------------- launch ----------------
extern "C" void kernel_launch(void* const* d_in, const int* in_sizes, int n_in,
                              void* d_out, int out_size, void* d_ws, size_t ws_size,
                              hipStream_t stream){
  (void)in_sizes; (void)n_in; (void)out_size; (void)ws_size;
  const float* inputs = (const float*)d_in[0];
  const float* Wq = (const float*)d_in[2];  const float* bq = (const float*)d_in[3];
  const float* Wk = (const float*)d_in[4];  const float* bk = (const float*)d_in[5];
  const float* Wv = (const float*)d_in[6];  const float* bv = (const float*)d_in[7];
  const float* Wo = (const float*)d_in[8];  const float* bo = (const float*)d_in[9];
  const float* ln1g = (const float*)d_in[10]; const float* ln1b = (const float*)d_in[11];
  const float* W1 = (const float*)d_in[12]; const float* b1 = (const float*)d_in[13];
  const float* W2 = (const float*)d_in[14]; const float* b2 = (const float*)d_in[15];
  const float* ln2g = (const float*)d_in[16]; const float* ln2b = (const float*)d_in[17];
  float* out = (float*)d_out;

  char* wsp = (char*)d_ws; size_t off = 0;
  auto alloc = [&](size_t bytes) -> void* {
    off = (off + 255) & ~(size_t)255;
    void* p = wsp + off; off += bytes; return p;
  };
  const size_t MD = (size_t)2048 * 1024;
  u16* Xbf    = (u16*)alloc(MD * 2);
  u16* WqkvT  = (u16*)alloc((size_t)3 * 1024 * 1024 * 2);
  u16* WoT    = (u16*)alloc((size_t)1024 * 1024 * 2);
  u16* W1T    = (u16*)alloc((size_t)4096 * 1024 * 2);
  u16* W2T    = (u16*)alloc((size_t)4096 * 1024 * 2);
  float* bqkv = (float*)alloc(3072 * 4);
  float* qkvb = (float*)alloc(3 * MD * 4);
  float* qb = qkvb; float* kb = qkvb + MD; float* vb = qkvb + 2 * MD;
  float* quad = (float*)alloc(4 * MD * 4);
  float* Sbuf = quad;
  float* ckb  = (float*)alloc((size_t)512 * 64 * 4);
  float* cqb  = (float*)alloc((size_t)512 * 64 * 4);
  float* csob = (float*)alloc((size_t)512 * 64 * 4);
  float* cqsib= (float*)alloc((size_t)512 * 64 * 4);
  float* sink_in = (float*)alloc(NBH * LSEQ * 4);
  float* src_out = (float*)alloc(NBH * LSEQ * 4);
  float* sabuf   = (float*)alloc(NBH * LSEQ * 4);
  float* ebuf    = (float*)alloc(NBH * LSEQ * 4);
  float* scbuf   = (float*)alloc(NBH * LSEQ * 4);
  u16* xatt   = (u16*)alloc(MD * 2);
  u16* g1     = (u16*)alloc((size_t)2048 * 4096 * 2);
  float* part = quad;
  float* hbuf = vb;
  u16* hbf = (u16*)qb;

  // all prep in one launch: f2bf (2048) + 4x tr1024 (4096) + W1/W2 tr (8192) + bias (12)
  prep_all<<<14348, 256, 0, stream>>>(inputs, Xbf, Wq, Wk, Wv, Wo, WqkvT, WoT,
                                      W1, W2, W1T, W2T, bq, bk, bv, bqkv);

  // fused QKV projection: BM=128,BN=64, grid 16x48 = 768 blocks (3/CU, 48KB LDS)
  gemm_mfma<128, 64, 0, 1><<<dim3(16, 48), 256, 0, stream>>>(
      Xbf, WqkvT, bqkv, nullptr, qkvb, nullptr, 2048, 3072, 1024);

  // attention scalars (chunked Gram-tile pipeline)
  chunk_sums<<<512, 256, 0, stream>>>(kb, qb, ckb, cqb);
  sink_tile<<<512, 256, 0, stream>>>(qb, kb, ckb, cqb, sink_in, src_out, csob, cqsib);
  cons_tile<<<512, 256, 0, stream>>>(qb, kb, csob, cqsib, sink_in, src_out, sabuf, ebuf);
  srccomp_kernel<<<32, 64, 0, stream>>>(ebuf, scbuf);

  // chunked causal linear attention (scale fused; KV-prefix inlined in phaseC)
  phaseA<<<512, 256, 0, stream>>>(kb, vb, scbuf, Sbuf);
  phaseC<<<512, 256, 0, stream>>>(qb, kb, vb, Sbuf, sink_in, scbuf, sabuf, xatt);

  // output projection: BM=128,BN=64, split-K=2 (partials in quad slots 2,3)
  float* wopart = quad + 2 * MD;
  gemm_mfma<128, 64, 0, 4><<<dim3(16, 16, 2), 256, 0, stream>>>(
      xatt, WoT, nullptr, nullptr, wopart, nullptr, 2048, 1024, 1024);
  ln_fused2b<<<2048, 256, 0, stream>>>(wopart, wopart + MD, inputs, bo, ln1g, ln1b, hbuf, hbf);

  // FFN1: BM=128,BN=128 (fast gelu)
  gemm_mfma<128, 128, 2, 3><<<dim3(16, 32), 256, 0, stream>>>(
      hbf, W1T, b1, nullptr, nullptr, g1, 2048, 4096, 1024);
  // FFN2: BM=128,BN=128, split-K=4
  gemm_mfma<128, 128, 0, 4><<<dim3(16, 8, 4), 256, 0, stream>>>(
      g1, W2T, nullptr, nullptr, part, nullptr, 2048, 1024, 4096);
  ln_fused4<<<2048, 256, 0, stream>>>(part, part + MD, part + 2 * MD, part + 3 * MD,
                                      hbuf, b2, ln2g, ln2b, out);
}

// Round 14
// 198.887 us; speedup vs baseline: 1.4498x; 1.0405x over previous
//
#include <hip/hip_runtime.h>
#include <hip/hip_bf16.h>

// ---------------- constants ----------------
#define EPS 1e-6f
#define NBH 32      // B*H
#define LSEQ 1024
#define DHD 64

typedef unsigned short u16;
typedef __bf16 bf16x8 __attribute__((ext_vector_type(8)));
typedef float f32x4 __attribute__((ext_vector_type(4)));

__device__ inline u16 f2bf(float f){
  union { float f; unsigned u; } un; un.f = f;
  unsigned u = un.u;
  u += 0x7fffu + ((u >> 16) & 1u);
  return (u16)(u >> 16);
}

__device__ inline float wred64(float v){
#pragma unroll
  for (int off = 32; off > 0; off >>= 1) v += __shfl_xor(v, off, 64);
  return v;
}

__device__ inline float wscan64(float v, int lane){
  float run = v;
#pragma unroll
  for (int off = 1; off < 64; off <<= 1){
    float t = __shfl_up(run, off, 64);
    if (lane >= off) run += t;
  }
  return run;   // inclusive
}

__device__ inline float fast_sigmoid(float x){
  return 1.f / (1.f + __expf(-x));
}

__device__ inline void gload_lds16(const u16* g, u16* l){
  __builtin_amdgcn_global_load_lds(
      (const __attribute__((address_space(1))) unsigned int*)g,
      (__attribute__((address_space(3))) unsigned int*)l, 16, 0, 0);
}

// ---------------- mega prep kernel (f2bf + 6 transposes + bias gather) -------
__device__ inline void tr_tile2(const float* in, u16* out, int R, int C, int r0, int c0){
  __shared__ float tile[32][33];
  int x = threadIdx.x & 31, y = threadIdx.x >> 5;
#pragma unroll
  for (int j = 0; j < 4; j++)
    tile[y + j*8][x] = in[(size_t)(r0 + y + j*8) * C + c0 + x];
  __syncthreads();
#pragma unroll
  for (int j = 0; j < 4; j++)
    out[(size_t)(c0 + y + j*8) * R + r0 + x] = f2bf(tile[x][y + j*8]);
}

// blocks: [0,2048) f2bf inputs; [2048,6144) Wq/Wk/Wv/Wo transposes;
// [6144,14336) W1/W2 transposes; [14336,14348) bias gather
__global__ __launch_bounds__(256) void prep_all(
    const float* __restrict__ inputs, u16* __restrict__ Xbf,
    const float* __restrict__ Wq, const float* __restrict__ Wk,
    const float* __restrict__ Wv, const float* __restrict__ Wo,
    u16* __restrict__ dqkv, u16* __restrict__ dwo,
    const float* __restrict__ W1, const float* __restrict__ W2,
    u16* __restrict__ d1, u16* __restrict__ d2,
    const float* __restrict__ bq, const float* __restrict__ bk,
    const float* __restrict__ bv, float* __restrict__ bqkv)
{
  int b = blockIdx.x;
  if (b < 2048){
    int i = b * 256 + threadIdx.x;
    float4 v = reinterpret_cast<const float4*>(inputs)[i];
    ushort4 o; o.x = f2bf(v.x); o.y = f2bf(v.y); o.z = f2bf(v.z); o.w = f2bf(v.w);
    reinterpret_cast<ushort4*>(Xbf)[i] = o;
  } else if (b < 6144){
    int t = b - 2048;
    int z = t >> 10, rem = t & 1023;
    int bx = rem & 31, by = rem >> 5;
    const float* in = (z == 0) ? Wq : (z == 1) ? Wk : (z == 2) ? Wv : Wo;
    u16* out = (z < 3) ? (dqkv + (size_t)z * 1024 * 1024) : dwo;
    tr_tile2(in, out, 1024, 1024, by * 32, bx * 32);
  } else if (b < 14336){
    int t = b - 6144;
    int z = t >> 12, rem = t & 4095;
    int bx = rem & 127, by = rem >> 7;
    if (z == 0) tr_tile2(W1, d1, 1024, 4096, by * 32, bx * 32);
    else        tr_tile2(W2, d2, 4096, 1024, bx * 32, by * 32);
  } else {
    int i = (b - 14336) * 256 + threadIdx.x;
    if (i < 3072){
      float v = (i < 1024) ? bq[i] : (i < 2048) ? bk[i - 1024] : bv[i - 2048];
      bqkv[i] = v;
    }
  }
}

// ---------------- bf16 MFMA GEMM (dbuf + counted vmcnt, T2 XOR-swizzled LDS) ----
// C[M,N] = act(A[M,K] @ Bt[N,K]^T + bias)
// LDS: BK=64 bf16 rows = 8 x 16B slots; slot s of row r at phys slot s^(r&7)
// (rule #21: linear gload_lds dest + pre-swizzled SOURCE + swizzled READ).
// Pipeline: STAGE(next) before compute(cur); s_waitcnt vmcnt(NS) keeps the
// next tile's loads in flight across the barrier (T3 minimum 2-phase).
// ACT: 0 none, 2 gelu  (OM==1 applies fast sigmoid for col<2048 internally)
// OM: 1 fused-QKV remap to 3x[B,H,L,DH]; 3 bf16 [M][N];
//     4 raw f32 partial (split-K slice z at outF + z*M*N, no bias)
template<int BM, int BN, int ACT, int OM>
__global__ __launch_bounds__(256) void gemm_mfma(
    const u16* __restrict__ A, const u16* __restrict__ Bt,
    const float* __restrict__ bias, const float* __restrict__ resid,
    float* __restrict__ outF, u16* __restrict__ outB,
    int M, int N, int K)
{
  constexpr int BK = 64;
  constexpr int MI = BM / 32;
  constexpr int NJ = BN / 32;
  constexpr int RA = BM / 32;
  constexpr int RB = BN / 32;
  constexpr int NS = RA + RB;
  __shared__ u16 As[2][BM * BK];
  __shared__ u16 Bs[2][BN * BK];
  const int tid = threadIdx.x;
  const int lane = tid & 63, wave = tid >> 6;
  const int lrow = lane & 15, lg = lane >> 4;
  const int m0 = blockIdx.x * BM, n0 = blockIdx.y * BN;
  const int wm = (wave >> 1) * (BM / 2), wn = (wave & 1) * (BN / 2);

  const int ksz = K / gridDim.z;
  const int k_begin = blockIdx.z * ksz;
  const int k_end = k_begin + ksz;

  f32x4 acc[MI][NJ];
#pragma unroll
  for (int i = 0; i < MI; i++)
#pragma unroll
    for (int j = 0; j < NJ; j++) acc[i][j] = (f32x4){0.f, 0.f, 0.f, 0.f};

  const u16* Ab = A + (size_t)m0 * K;
  const u16* Bb = Bt + (size_t)n0 * K;

  const int s0 = ((0 * 4 + lg) ^ (lrow & 7)) * 8;
  const int s1 = ((1 * 4 + lg) ^ (lrow & 7)) * 8;

  auto STAGE = [&](int buf, int k0){
#pragma unroll
    for (int r = 0; r < RA; ++r){
      int c = r * 256 + tid;
      int row = c >> 3;
      int kk = ((c ^ row) & 7) << 3;
      gload_lds16(Ab + (size_t)row * K + k0 + kk, &As[buf][(r * 256 + wave * 64) * 8]);
    }
#pragma unroll
    for (int r = 0; r < RB; ++r){
      int c = r * 256 + tid;
      int row = c >> 3;
      int kk = ((c ^ row) & 7) << 3;
      gload_lds16(Bb + (size_t)row * K + k0 + kk, &Bs[buf][(r * 256 + wave * 64) * 8]);
    }
  };

  STAGE(0, k_begin);
  int cur = 0;
  for (int k0 = k_begin; k0 < k_end; k0 += BK){
    if (k0 + BK < k_end){
      STAGE(cur ^ 1, k0 + BK);
      if constexpr (NS == 8)      asm volatile("s_waitcnt vmcnt(8)" ::: "memory");
      else if constexpr (NS == 6) asm volatile("s_waitcnt vmcnt(6)" ::: "memory");
      else                        asm volatile("s_waitcnt vmcnt(0)" ::: "memory");
    } else {
      asm volatile("s_waitcnt vmcnt(0)" ::: "memory");
    }
    __builtin_amdgcn_s_barrier();
    __builtin_amdgcn_sched_barrier(0);
#pragma unroll
    for (int kh = 0; kh < 2; ++kh){
      const int ss = (kh == 0) ? s0 : s1;
      bf16x8 af[MI], bfv[NJ];
#pragma unroll
      for (int i = 0; i < MI; ++i)
        af[i] = *reinterpret_cast<const bf16x8*>(&As[cur][(wm + i * 16 + lrow) * BK + ss]);
#pragma unroll
      for (int j = 0; j < NJ; ++j)
        bfv[j] = *reinterpret_cast<const bf16x8*>(&Bs[cur][(wn + j * 16 + lrow) * BK + ss]);
#pragma unroll
      for (int i = 0; i < MI; ++i)
#pragma unroll
        for (int j = 0; j < NJ; ++j)
          acc[i][j] = __builtin_amdgcn_mfma_f32_16x16x32_bf16(af[i], bfv[j], acc[i][j], 0, 0, 0);
    }
    __builtin_amdgcn_s_barrier();
    cur ^= 1;
  }

#pragma unroll
  for (int i = 0; i < MI; ++i){
#pragma unroll
    for (int j = 0; j < NJ; ++j){
      int col = n0 + wn + j * 16 + lrow;
      float bv = (OM != 4 && bias) ? bias[col] : 0.f;
#pragma unroll
      for (int r = 0; r < 4; ++r){
        int row = m0 + wm + i * 16 + lg * 4 + r;
        float x = acc[i][j][r] + bv;
        if (OM == 1){
          if (col < 2048) x = fast_sigmoid(x);
          int which = col >> 10, cc = col & 1023, h = cc >> 6, d = cc & 63;
          int b = row >> 10, l = row & 1023;
          outF[(size_t)which * (2048ull * 1024) +
               (((size_t)(b * 16 + h)) * 1024 + l) * 64 + d] = x;
        } else if (OM == 4){
          outF[((size_t)blockIdx.z * M + row) * N + col] = x;
        } else {
          if (ACT == 2){
            float u = 0.7978845608f * (x + 0.044715f * x * x * x);
            float e = __expf(2.f * u);
            x = 0.5f * x * (2.f - 2.f / (e + 1.f));
          }
          outB[(size_t)row * N + col] = f2bf(x);
        }
      }
    }
  }
}

// ---------------- attention scalar pipeline (chunked Gram-tile form) ----------------
__global__ __launch_bounds__(256) void chunk_sums(const float* __restrict__ k, const float* __restrict__ q,
                                                  float* __restrict__ ck, float* __restrict__ cq){
  int blk = blockIdx.x;
  int lane = threadIdx.x & 63, wave = threadIdx.x >> 6;
  size_t base = (size_t)blk * 64 * DHD;
  float sk = 0.f, sq = 0.f;
  for (int l = wave * 16; l < wave * 16 + 16; l++){
    sk += k[base + l * 64 + lane];
    sq += q[base + l * 64 + lane];
  }
  __shared__ float rd[2][4][64];
  rd[0][wave][lane] = sk; rd[1][wave][lane] = sq;
  __syncthreads();
  if (wave == 0){
    ck[(size_t)blk * 64 + lane] = rd[0][0][lane] + rd[0][1][lane] + rd[0][2][lane] + rd[0][3][lane];
    cq[(size_t)blk * 64 + lane] = rd[1][0][lane] + rd[1][1][lane] + rd[1][2][lane] + rd[1][3][lane];
  }
}

__global__ __launch_bounds__(256) void sink_tile(
    const float* __restrict__ q, const float* __restrict__ k,
    const float* __restrict__ ck, const float* __restrict__ cq,
    float* __restrict__ sink_in, float* __restrict__ src_out,
    float* __restrict__ cso, float* __restrict__ cqsi)
{
  int blk = blockIdx.x, bh = blk >> 4, c = blk & 15;
  int tid = threadIdx.x, lane = tid & 63, wave = tid >> 6;
  __shared__ float qT[64][65], kT[64][65], G[64][66];
  __shared__ float PK[64], PQ[64];
  __shared__ float rk[64], rq[64], crk[64], crq[64], siv[64], sov[64];
  __shared__ float rd[2][4][64];
  size_t base = ((size_t)bh * LSEQ + c * 64) * DHD;
  const float* qb = q + base; const float* kb = k + base;
  for (int c4 = tid; c4 < 1024; c4 += 256){
    int l = c4 >> 4, d0 = (c4 & 15) * 4;
    float4 qv = *reinterpret_cast<const float4*>(qb + c4 * 4);
    qT[d0+0][l] = qv.x; qT[d0+1][l] = qv.y; qT[d0+2][l] = qv.z; qT[d0+3][l] = qv.w;
    float4 kv = *reinterpret_cast<const float4*>(kb + c4 * 4);
    kT[d0+0][l] = kv.x; kT[d0+1][l] = kv.y; kT[d0+2][l] = kv.z; kT[d0+3][l] = kv.w;
  }
  if (tid < 64){
    float pk = 0.f, pq = 0.f;
    for (int cc = 0; cc < c; cc++){
      pk += ck[((size_t)bh * 16 + cc) * 64 + tid];
      pq += cq[((size_t)bh * 16 + cc) * 64 + tid];
    }
    PK[tid] = pk; PQ[tid] = pq;
  }
  __syncthreads();
  float sumPK = wred64(PK[lane]);
  float sumPQ = wred64(PQ[lane]);
  {
    int l = lane, g = wave;
    float qrow[64];
#pragma unroll
    for (int d = 0; d < 64; d++) qrow[d] = qT[d][l];
    float p[16] = {};
    for (int d = 0; d < 64; d++){
      float qv = qrow[d];
#pragma unroll
      for (int j4 = 0; j4 < 4; j4++){
        float4 kk = *reinterpret_cast<const float4*>(&kT[d][g * 16 + j4 * 4]);
        p[j4*4+0] += qv * kk.x; p[j4*4+1] += qv * kk.y;
        p[j4*4+2] += qv * kk.z; p[j4*4+3] += qv * kk.w;
      }
    }
#pragma unroll
    for (int jj = 0; jj < 16; jj++) G[l][g * 16 + jj] = p[jj];
  }
  {
    float pk_ = 0.f, pq_ = 0.f;
#pragma unroll
    for (int d = wave * 16; d < wave * 16 + 16; d++){
      pk_ += kT[d][lane]; pq_ += qT[d][lane];
    }
    rd[0][wave][lane] = pk_; rd[1][wave][lane] = pq_;
  }
  __syncthreads();
  if (tid < 64){
    rk[tid] = rd[0][0][tid] + rd[0][1][tid] + rd[0][2][tid] + rd[0][3][tid];
    rq[tid] = rd[1][0][tid] + rd[1][1][tid] + rd[1][2][tid] + rd[1][3][tid];
  }
  __syncthreads();
  if (wave == 0)      crk[lane] = wscan64(rk[lane], lane);
  else if (wave == 1) crq[lane] = wscan64(rq[lane], lane);
  __syncthreads();
  {
    int l = lane;
    float p1 = 0.f, p2 = 0.f;
#pragma unroll
    for (int j = wave * 16; j < wave * 16 + 16; j++){
      float g1 = (j <= l) ? G[l][j] : 0.f;
      p1 += g1 + qT[j][l] * PK[j];
      float g2 = (j <= l) ? G[j][l] : 0.f;
      p2 += g2 + kT[j][l] * PQ[j];
    }
    rd[0][wave][l] = p1; rd[1][wave][l] = p2;
  }
  __syncthreads();
  const float EPS2 = 64.f * EPS * EPS;
  if (tid < 64){
    int l = tid;
    float s1 = rd[0][0][l] + rd[0][1][l] + rd[0][2][l] + rd[0][3][l];
    float s2 = rd[1][0][l] + rd[1][1][l] + rd[1][2][l] + rd[1][3][l];
    int L = c * 64 + l; float nrm = (float)(L + 1);
    float den1 = s1 + EPS * rq[l] + EPS * (sumPK + crk[l]) + EPS2;
    float den2 = s2 + EPS * rk[l] + EPS * (sumPQ + crq[l]) + EPS2;
    float si_ = nrm / den1, so_ = nrm / den2;
    sink_in[(size_t)bh * LSEQ + L] = si_;
    src_out[(size_t)bh * LSEQ + L] = so_;
    siv[l] = si_; sov[l] = so_;
  }
  __syncthreads();
  float s1 = 0.f, s2 = 0.f;
  for (int l = wave * 16; l < wave * 16 + 16; l++){
    s1 += sov[l] * kT[lane][l];
    s2 += siv[l] * qT[lane][l];
  }
  rd[0][wave][lane] = s1; rd[1][wave][lane] = s2;
  __syncthreads();
  if (wave == 0){
    cso [(size_t)blk * 64 + lane] = rd[0][0][lane] + rd[0][1][lane] + rd[0][2][lane] + rd[0][3][lane];
    cqsi[(size_t)blk * 64 + lane] = rd[1][0][lane] + rd[1][1][lane] + rd[1][2][lane] + rd[1][3][lane];
  }
}

__global__ __launch_bounds__(256) void cons_tile(
    const float* __restrict__ q, const float* __restrict__ k,
    const float* __restrict__ cso, const float* __restrict__ cqsi,
    const float* __restrict__ sink_in, const float* __restrict__ src_out,
    float* __restrict__ sa, float* __restrict__ ebuf)
{
  int blk = blockIdx.x, bh = blk >> 4, c = blk & 15;
  int tid = threadIdx.x, lane = tid & 63, wave = tid >> 6;
  __shared__ float qT[64][65], kT[64][65], G[64][66];
  __shared__ float PKso[64], PQsi[64];
  __shared__ float rk[64], rq[64], cwrk[64], cwrq[64], siv[64], sov[64];
  __shared__ float rd[2][4][64];
  size_t base = ((size_t)bh * LSEQ + c * 64) * DHD;
  const float* qb = q + base; const float* kb = k + base;
  for (int c4 = tid; c4 < 1024; c4 += 256){
    int l = c4 >> 4, d0 = (c4 & 15) * 4;
    float4 qv = *reinterpret_cast<const float4*>(qb + c4 * 4);
    qT[d0+0][l] = qv.x; qT[d0+1][l] = qv.y; qT[d0+2][l] = qv.z; qT[d0+3][l] = qv.w;
    float4 kv = *reinterpret_cast<const float4*>(kb + c4 * 4);
    kT[d0+0][l] = kv.x; kT[d0+1][l] = kv.y; kT[d0+2][l] = kv.z; kT[d0+3][l] = kv.w;
  }
  if (tid < 64){
    float pk = 0.f, pq = 0.f;
    for (int cc = 0; cc < c; cc++){
      pk += cso [((size_t)bh * 16 + cc) * 64 + tid];
      pq += cqsi[((size_t)bh * 16 + cc) * 64 + tid];
    }
    PKso[tid] = pk; PQsi[tid] = pq;
  } else if (tid < 128){
    int l = tid - 64;
    sov[l] = src_out[(size_t)bh * LSEQ + c * 64 + l];
    siv[l] = sink_in[(size_t)bh * LSEQ + c * 64 + l];
  }
  __syncthreads();
  float sumPKso = wred64(PKso[lane]);
  float sumPQsi = wred64(PQsi[lane]);
  {
    int l = lane, g = wave;
    float qrow[64];
#pragma unroll
    for (int d = 0; d < 64; d++) qrow[d] = qT[d][l];
    float p[16] = {};
    for (int d = 0; d < 64; d++){
      float qv = qrow[d];
#pragma unroll
      for (int j4 = 0; j4 < 4; j4++){
        float4 kk = *reinterpret_cast<const float4*>(&kT[d][g * 16 + j4 * 4]);
        p[j4*4+0] += qv * kk.x; p[j4*4+1] += qv * kk.y;
        p[j4*4+2] += qv * kk.z; p[j4*4+3] += qv * kk.w;
      }
    }
#pragma unroll
    for (int jj = 0; jj < 16; jj++) G[l][g * 16 + jj] = p[jj];
  }
  {
    float pk_ = 0.f, pq_ = 0.f;
#pragma unroll
    for (int d = wave * 16; d < wave * 16 + 16; d++){
      pk_ += kT[d][lane]; pq_ += qT[d][lane];
    }
    rd[0][wave][lane] = pk_; rd[1][wave][lane] = pq_;
  }
  __syncthreads();
  if (tid < 64){
    rk[tid] = rd[0][0][tid] + rd[0][1][tid] + rd[0][2][tid] + rd[0][3][tid];
    rq[tid] = rd[1][0][tid] + rd[1][1][tid] + rd[1][2][tid] + rd[1][3][tid];
  }
  __syncthreads();
  if (wave == 0)      cwrk[lane] = wscan64(sov[lane] * rk[lane], lane);
  else if (wave == 1) cwrq[lane] = wscan64(siv[lane] * rq[lane], lane);
  __syncthreads();
  {
    int l = lane;
    float p3 = 0.f, p4 = 0.f;
#pragma unroll
    for (int j = wave * 16; j < wave * 16 + 16; j++){
      float g3 = (j <= l) ? sov[j] * G[l][j] : 0.f;
      p3 += g3 + qT[j][l] * PKso[j];
      float g4 = (j <= l) ? siv[j] * G[j][l] : 0.f;
      p4 += g4 + kT[j][l] * PQsi[j];
    }
    rd[0][wave][l] = p3; rd[1][wave][l] = p4;
  }
  __syncthreads();
  const float EPS2 = 64.f * EPS * EPS;
  if (tid < 64){
    int l = tid;
    float s3 = rd[0][0][l] + rd[0][1][l] + rd[0][2][l] + rd[0][3][l];
    float s4 = rd[1][0][l] + rd[1][1][l] + rd[1][2][l] + rd[1][3][l];
    int L = c * 64 + l; float nrm = (float)(L + 1);
    float cs = (s3 + EPS * rq[l] + EPS * (sumPKso + cwrk[l]) + EPS2) / nrm;
    sa[(size_t)bh * LSEQ + L] = fast_sigmoid(cs);
    float c2 = (s4 + EPS * rk[l] + EPS * (sumPQsi + cwrq[l]) + EPS2) / nrm;
    c2 = fminf(1.f, fmaxf(-1.f, c2));
    ebuf[(size_t)bh * LSEQ + L] = __expf(c2);
  }
}

// src_comp = e / cumsum(e) * (l+1)
__global__ __launch_bounds__(64) void srccomp_kernel(const float* __restrict__ ebuf, float* __restrict__ sc){
  int bh = blockIdx.x; int lane = threadIdx.x;
  const float* eb = ebuf + (size_t)bh * LSEQ;
  float loc[16]; float s = 0.f;
#pragma unroll
  for (int i = 0; i < 16; i++){ loc[i] = eb[lane * 16 + i]; s += loc[i]; }
  float run = wscan64(s, lane);
  float acc = run - s;
  float* scb = sc + (size_t)bh * LSEQ;
#pragma unroll
  for (int i = 0; i < 16; i++){
    acc += loc[i];
    scb[lane * 16 + i] = loc[i] / acc * (float)(lane * 16 + i + 1);
  }
}

// ---------------- chunked causal linear attention (scale fused in) ----------------
__global__ __launch_bounds__(256) void phaseA(const float* __restrict__ k, const float* __restrict__ v,
                                              const float* __restrict__ sc, float* __restrict__ S){
  int blk = blockIdx.x; int bh = blk >> 4, c = blk & 15;
  __shared__ float ks[64][68], vss[64][68];
  __shared__ float vc[64];
  int tid = threadIdx.x;
  size_t base = ((size_t)bh * LSEQ + c * 64) * DHD;
  const float* kb = k + base; const float* vb = v + base;
  if (tid < 64) vc[tid] = sc[(size_t)bh * LSEQ + c * 64 + tid];
  __syncthreads();
  for (int c4 = tid; c4 < 1024; c4 += 256){
    int l = c4 >> 4, d0 = (c4 & 15) * 4;
    *reinterpret_cast<float4*>(&ks[l][d0]) = *reinterpret_cast<const float4*>(kb + c4 * 4);
    float4 vv = *reinterpret_cast<const float4*>(vb + c4 * 4);
    float w = vc[l];
    vss[l][d0+0] = vv.x * w; vss[l][d0+1] = vv.y * w;
    vss[l][d0+2] = vv.z * w; vss[l][d0+3] = vv.w * w;
  }
  __syncthreads();
  int m = tid >> 2, dg = tid & 3;
  float acc[16] = {};
  for (int l = 0; l < 64; l++){
    float vm = vss[l][m];
#pragma unroll
    for (int d4 = 0; d4 < 4; d4++){
      float4 kk = *reinterpret_cast<const float4*>(&ks[l][dg * 16 + d4 * 4]);
      acc[d4*4+0] += vm * kk.x; acc[d4*4+1] += vm * kk.y;
      acc[d4*4+2] += vm * kk.z; acc[d4*4+3] += vm * kk.w;
    }
  }
  float* Sb = S + (size_t)blk * 4096 + m * 64 + dg * 16;
#pragma unroll
  for (int d4 = 0; d4 < 4; d4++)
    *reinterpret_cast<float4*>(Sb + d4 * 4) =
        make_float4(acc[d4*4], acc[d4*4+1], acc[d4*4+2], acc[d4*4+3]);
}

// phase C with inlined KV-prefix; Ps overlays qsT (qrow registers cached first)
// LDS: qp(16.9K) + kT(17.4K) + vss(17.4K) + kvs(17.4K) ~= 70KB -> 2 blocks/CU
__global__ __launch_bounds__(256) void phaseC(const float* __restrict__ q, const float* __restrict__ k,
                                              const float* __restrict__ v, const float* __restrict__ S,
                                              const float* __restrict__ sink_in, const float* __restrict__ sc,
                                              const float* __restrict__ sa, u16* __restrict__ x){
  int blk = blockIdx.x; int bh = blk >> 4, c = blk & 15;
  int b = bh >> 4, h = bh & 15;
  __shared__ float qp[64][66];      // qsT[d][l] first, then Ps[l][j]
  __shared__ float kT[64][68];
  __shared__ float vss[64][68];
  __shared__ float kvs[64][68];
  __shared__ float qc[64], vc[64];
  int tid = threadIdx.x;
  size_t base = ((size_t)bh * LSEQ + c * 64) * DHD;
  const float* qb = q + base; const float* kb = k + base; const float* vb = v + base;
  if (tid < 64){
    int L = c * 64 + tid;
    qc[tid] = sink_in[(size_t)bh * LSEQ + L] / (float)(L + 1);
    vc[tid] = sc[(size_t)bh * LSEQ + L];
  }
  // KV prefix: accumulate 16 elements per thread over chunks 0..c-1
  {
    int off16 = tid * 16;
    float accp[16] = {};
    for (int cc = 0; cc < c; cc++){
      size_t idx = ((size_t)bh * 16 + cc) * 4096 + off16;
#pragma unroll
      for (int t4 = 0; t4 < 4; t4++){
        float4 sv = *reinterpret_cast<const float4*>(S + idx + t4 * 4);
        accp[t4*4+0] += sv.x; accp[t4*4+1] += sv.y;
        accp[t4*4+2] += sv.z; accp[t4*4+3] += sv.w;
      }
    }
#pragma unroll
    for (int e = 0; e < 16; e++){
      int j = off16 + e;
      kvs[j >> 6][j & 63] = accp[e];
    }
  }
  __syncthreads();
  for (int c4 = tid; c4 < 1024; c4 += 256){
    int l = c4 >> 4, d0 = (c4 & 15) * 4;
    float qw = qc[l], vw = vc[l];
    float4 qv = *reinterpret_cast<const float4*>(qb + c4 * 4);
    qp[d0+0][l] = qv.x * qw; qp[d0+1][l] = qv.y * qw;
    qp[d0+2][l] = qv.z * qw; qp[d0+3][l] = qv.w * qw;
    float4 kv4 = *reinterpret_cast<const float4*>(kb + c4 * 4);
    kT[d0+0][l] = kv4.x; kT[d0+1][l] = kv4.y; kT[d0+2][l] = kv4.z; kT[d0+3][l] = kv4.w;
    float4 vv = *reinterpret_cast<const float4*>(vb + c4 * 4);
    vss[l][d0+0] = vv.x * vw; vss[l][d0+1] = vv.y * vw;
    vss[l][d0+2] = vv.z * vw; vss[l][d0+3] = vv.w * vw;
  }
  __syncthreads();
  int l = tid & 63, g = tid >> 6;
  float qrow[64];
#pragma unroll
  for (int d = 0; d < 64; d++) qrow[d] = qp[d][l];   // qsT consumed into registers
  __syncthreads();                                    // all qrow loads done before Ps overwrite

  float p[16] = {};
  for (int d = 0; d < 64; d++){
    float qv = qrow[d];
#pragma unroll
    for (int j4 = 0; j4 < 4; j4++){
      float4 kk = *reinterpret_cast<const float4*>(&kT[d][g * 16 + j4 * 4]);
      p[j4*4+0] += qv * kk.x; p[j4*4+1] += qv * kk.y;
      p[j4*4+2] += qv * kk.z; p[j4*4+3] += qv * kk.w;
    }
  }
#pragma unroll
  for (int jj = 0; jj < 16; jj++){
    int j = g * 16 + jj;
    qp[l][j] = (j <= l) ? p[jj] : 0.f;                // Ps in qp
  }
  __syncthreads();

  float acc[16];
#pragma unroll
  for (int mm = 0; mm < 16; mm++){
    float a = 0.f;
#pragma unroll
    for (int d4 = 0; d4 < 16; d4++){
      float4 kv4 = *reinterpret_cast<const float4*>(&kvs[g * 16 + mm][d4 * 4]);
      a += qrow[d4*4+0]*kv4.x + qrow[d4*4+1]*kv4.y + qrow[d4*4+2]*kv4.z + qrow[d4*4+3]*kv4.w;
    }
    acc[mm] = a;
  }
  for (int j = 0; j < 64; j++){
    float pv = qp[l][j];
#pragma unroll
    for (int m4 = 0; m4 < 4; m4++){
      float4 vv = *reinterpret_cast<const float4*>(&vss[j][g * 16 + m4 * 4]);
      acc[m4*4+0] += pv * vv.x; acc[m4*4+1] += pv * vv.y;
      acc[m4*4+2] += pv * vv.z; acc[m4*4+3] += pv * vv.w;
    }
  }
  float sav = sa[(size_t)bh * LSEQ + c * 64 + l];
  u16* xo = x + ((size_t)(b * 1024 + c * 64 + l)) * 1024 + h * 64 + g * 16;
#pragma unroll
  for (int mm = 0; mm < 16; mm++) xo[mm] = f2bf(acc[mm] * sav);
}

// ---------------- fused layernorms ----------------
__global__ __launch_bounds__(256) void ln_fused2b(
    const float* __restrict__ p0, const float* __restrict__ p1,
    const float* __restrict__ resid, const float* __restrict__ bias,
    const float* __restrict__ g, const float* __restrict__ b,
    float* __restrict__ out, u16* __restrict__ outbf){
  int row = blockIdx.x; int tid = threadIdx.x;
  int lane = tid & 63, wave = tid >> 6;
  size_t off = (size_t)row * 1024 + tid * 4;
  float4 a0 = *reinterpret_cast<const float4*>(p0 + off);
  float4 a1 = *reinterpret_cast<const float4*>(p1 + off);
  float4 rr = *reinterpret_cast<const float4*>(resid + off);
  float4 bb = *reinterpret_cast<const float4*>(bias + tid * 4);
  float4 v = make_float4(a0.x + a1.x + rr.x + bb.x, a0.y + a1.y + rr.y + bb.y,
                         a0.z + a1.z + rr.z + bb.z, a0.w + a1.w + rr.w + bb.w);
  float s = v.x + v.y + v.z + v.w;
  float s2 = v.x*v.x + v.y*v.y + v.z*v.z + v.w*v.w;
  s = wred64(s); s2 = wred64(s2);
  __shared__ float red[2][4];
  if (lane == 0){ red[0][wave] = s; red[1][wave] = s2; }
  __syncthreads();
  float S = red[0][0] + red[0][1] + red[0][2] + red[0][3];
  float S2 = red[1][0] + red[1][1] + red[1][2] + red[1][3];
  float mean = S * (1.f / 1024.f);
  float var = S2 * (1.f / 1024.f) - mean * mean;
  float inv = rsqrtf(var + 1e-5f);
  float4 gv = *reinterpret_cast<const float4*>(g + tid * 4);
  float4 bv = *reinterpret_cast<const float4*>(b + tid * 4);
  float y0 = (v.x - mean) * inv * gv.x + bv.x;
  float y1 = (v.y - mean) * inv * gv.y + bv.y;
  float y2 = (v.z - mean) * inv * gv.z + bv.z;
  float y3 = (v.w - mean) * inv * gv.w + bv.w;
  *reinterpret_cast<float4*>(out + off) = make_float4(y0, y1, y2, y3);
  ushort4 o; o.x = f2bf(y0); o.y = f2bf(y1); o.z = f2bf(y2); o.w = f2bf(y3);
  *reinterpret_cast<ushort4*>(outbf + off) = o;
}

__global__ __launch_bounds__(256) void ln_fused4(
    const float* __restrict__ p0, const float* __restrict__ p1,
    const float* __restrict__ p2, const float* __restrict__ p3,
    const float* __restrict__ resid, const float* __restrict__ bias,
    const float* __restrict__ g, const float* __restrict__ b,
    float* __restrict__ out){
  int row = blockIdx.x; int tid = threadIdx.x;
  int lane = tid & 63, wave = tid >> 6;
  size_t off = (size_t)row * 1024 + tid * 4;
  float4 a0 = *reinterpret_cast<const float4*>(p0 + off);
  float4 a1 = *reinterpret_cast<const float4*>(p1 + off);
  float4 a2 = *reinterpret_cast<const float4*>(p2 + off);
  float4 a3 = *reinterpret_cast<const float4*>(p3 + off);
  float4 rr = *reinterpret_cast<const float4*>(resid + off);
  float4 bb = *reinterpret_cast<const float4*>(bias + tid * 4);
  float4 v = make_float4(a0.x + a1.x + a2.x + a3.x + rr.x + bb.x,
                         a0.y + a1.y + a2.y + a3.y + rr.y + bb.y,
                         a0.z + a1.z + a2.z + a3.z + rr.z + bb.z,
                         a0.w + a1.w + a2.w + a3.w + rr.w + bb.w);
  float s = v.x + v.y + v.z + v.w;
  float s2 = v.x*v.x + v.y*v.y + v.z*v.z + v.w*v.w;
  s = wred64(s); s2 = wred64(s2);
  __shared__ float red[2][4];
  if (lane == 0){ red[0][wave] = s; red[1][wave] = s2; }
  __syncthreads();
  float S = red[0][0] + red[0][1] + red[0][2] + red[0][3];
  float S2 = red[1][0] + red[1][1] + red[1][2] + red[1][3];
  float mean = S * (1.f / 1024.f);
  float var = S2 * (1.f / 1024.f) - mean * mean;
  float inv = rsqrtf(var + 1e-5f);
  float4 gv = *reinterpret_cast<const float4*>(g + tid * 4);
  float4 bv = *reinterpret_cast<const float4*>(b + tid * 4);
  float y0 = (v.x - mean) * inv * gv.x + bv.x;
  float y1 = (v.y - mean) * inv * gv.y + bv.y;
  float y2 = (v.z - mean) * inv * gv.z + bv.z;
  float y3 = (v.w - mean) * inv * gv.w + bv.w;
  *reinterpret_cast<float4*>(out + off) = make_float4(y0, y1, y2, y3);
}

// ---------------- launch ----------------
extern "C" void kernel_launch(void* const* d_in, const int* in_sizes, int n_in,
                              void* d_out, int out_size, void* d_ws, size_t ws_size,
                              hipStream_t stream){
  (void)in_sizes; (void)n_in; (void)out_size; (void)ws_size;
  const float* inputs = (const float*)d_in[0];
  const float* Wq = (const float*)d_in[2];  const float* bq = (const float*)d_in[3];
  const float* Wk = (const float*)d_in[4];  const float* bk = (const float*)d_in[5];
  const float* Wv = (const float*)d_in[6];  const float* bv = (const float*)d_in[7];
  const float* Wo = (const float*)d_in[8];  const float* bo = (const float*)d_in[9];
  const float* ln1g = (const float*)d_in[10]; const float* ln1b = (const float*)d_in[11];
  const float* W1 = (const float*)d_in[12]; const float* b1 = (const float*)d_in[13];
  const float* W2 = (const float*)d_in[14]; const float* b2 = (const float*)d_in[15];
  const float* ln2g = (const float*)d_in[16]; const float* ln2b = (const float*)d_in[17];
  float* out = (float*)d_out;

  char* wsp = (char*)d_ws; size_t off = 0;
  auto alloc = [&](size_t bytes) -> void* {
    off = (off + 255) & ~(size_t)255;
    void* p = wsp + off; off += bytes; return p;
  };
  const size_t MD = (size_t)2048 * 1024;
  u16* Xbf    = (u16*)alloc(MD * 2);
  u16* WqkvT  = (u16*)alloc((size_t)3 * 1024 * 1024 * 2);
  u16* WoT    = (u16*)alloc((size_t)1024 * 1024 * 2);
  u16* W1T    = (u16*)alloc((size_t)4096 * 1024 * 2);
  u16* W2T    = (u16*)alloc((size_t)4096 * 1024 * 2);
  float* bqkv = (float*)alloc(3072 * 4);
  float* qkvb = (float*)alloc(3 * MD * 4);
  float* qb = qkvb; float* kb = qkvb + MD; float* vb = qkvb + 2 * MD;
  float* quad = (float*)alloc(4 * MD * 4);
  float* Sbuf = quad;
  float* ckb  = (float*)alloc((size_t)512 * 64 * 4);
  float* cqb  = (float*)alloc((size_t)512 * 64 * 4);
  float* csob = (float*)alloc((size_t)512 * 64 * 4);
  float* cqsib= (float*)alloc((size_t)512 * 64 * 4);
  float* sink_in = (float*)alloc(NBH * LSEQ * 4);
  float* src_out = (float*)alloc(NBH * LSEQ * 4);
  float* sabuf   = (float*)alloc(NBH * LSEQ * 4);
  float* ebuf    = (float*)alloc(NBH * LSEQ * 4);
  float* scbuf   = (float*)alloc(NBH * LSEQ * 4);
  u16* xatt   = (u16*)alloc(MD * 2);
  u16* g1     = (u16*)alloc((size_t)2048 * 4096 * 2);
  float* part = quad;
  float* hbuf = vb;
  u16* hbf = (u16*)qb;

  // all prep in one launch: f2bf (2048) + 4x tr1024 (4096) + W1/W2 tr (8192) + bias (12)
  prep_all<<<14348, 256, 0, stream>>>(inputs, Xbf, Wq, Wk, Wv, Wo, WqkvT, WoT,
                                      W1, W2, W1T, W2T, bq, bk, bv, bqkv);

  // fused QKV projection: BM=128,BN=64, grid 16x48 = 768 blocks (3/CU, 48KB LDS)
  gemm_mfma<128, 64, 0, 1><<<dim3(16, 48), 256, 0, stream>>>(
      Xbf, WqkvT, bqkv, nullptr, qkvb, nullptr, 2048, 3072, 1024);

  // attention scalars (chunked Gram-tile pipeline)
  chunk_sums<<<512, 256, 0, stream>>>(kb, qb, ckb, cqb);
  sink_tile<<<512, 256, 0, stream>>>(qb, kb, ckb, cqb, sink_in, src_out, csob, cqsib);
  cons_tile<<<512, 256, 0, stream>>>(qb, kb, csob, cqsib, sink_in, src_out, sabuf, ebuf);
  srccomp_kernel<<<32, 64, 0, stream>>>(ebuf, scbuf);

  // chunked causal linear attention (scale fused; KV-prefix inlined in phaseC)
  phaseA<<<512, 256, 0, stream>>>(kb, vb, scbuf, Sbuf);
  phaseC<<<512, 256, 0, stream>>>(qb, kb, vb, Sbuf, sink_in, scbuf, sabuf, xatt);

  // output projection: BM=128,BN=64, split-K=2 (partials in quad slots 2,3)
  float* wopart = quad + 2 * MD;
  gemm_mfma<128, 64, 0, 4><<<dim3(16, 16, 2), 256, 0, stream>>>(
      xatt, WoT, nullptr, nullptr, wopart, nullptr, 2048, 1024, 1024);
  ln_fused2b<<<2048, 256, 0, stream>>>(wopart, wopart + MD, inputs, bo, ln1g, ln1b, hbuf, hbf);

  // FFN1: BM=128,BN=128 (fast gelu)
  gemm_mfma<128, 128, 2, 3><<<dim3(16, 32), 256, 0, stream>>>(
      hbf, W1T, b1, nullptr, nullptr, g1, 2048, 4096, 1024);
  // FFN2: BM=128,BN=128, split-K=4
  gemm_mfma<128, 128, 0, 4><<<dim3(16, 8, 4), 256, 0, stream>>>(
      g1, W2T, nullptr, nullptr, part, nullptr, 2048, 1024, 4096);
  ln_fused4<<<2048, 256, 0, stream>>>(part, part + MD, part + 2 * MD, part + 3 * MD,
                                      hbuf, b2, ln2g, ln2b, out);
}

// Round 15
// 195.570 us; speedup vs baseline: 1.4744x; 1.0170x over previous
//
#include <hip/hip_runtime.h>
#include <hip/hip_bf16.h>

// ---------------- constants ----------------
#define EPS 1e-6f
#define NBH 32      // B*H
#define LSEQ 1024
#define DHD 64

typedef unsigned short u16;
typedef __bf16 bf16x8 __attribute__((ext_vector_type(8)));
typedef float f32x4 __attribute__((ext_vector_type(4)));

__device__ inline u16 f2bf(float f){
  union { float f; unsigned u; } un; un.f = f;
  unsigned u = un.u;
  u += 0x7fffu + ((u >> 16) & 1u);
  return (u16)(u >> 16);
}

__device__ inline float bf2f(u16 v){
  union { unsigned u; float f; } un; un.u = ((unsigned)v) << 16; return un.f;
}

__device__ inline float wred64(float v){
#pragma unroll
  for (int off = 32; off > 0; off >>= 1) v += __shfl_xor(v, off, 64);
  return v;
}

__device__ inline float wscan64(float v, int lane){
  float run = v;
#pragma unroll
  for (int off = 1; off < 64; off <<= 1){
    float t = __shfl_up(run, off, 64);
    if (lane >= off) run += t;
  }
  return run;   // inclusive
}

__device__ inline float fast_sigmoid(float x){
  return 1.f / (1.f + __expf(-x));
}

__device__ inline void gload_lds16(const u16* g, u16* l){
  __builtin_amdgcn_global_load_lds(
      (const __attribute__((address_space(1))) unsigned int*)g,
      (__attribute__((address_space(3))) unsigned int*)l, 16, 0, 0);
}

// ---------------- mega prep kernel (f2bf + 6 transposes + bias + zero) -------
__device__ inline void tr_tile2(const float* in, u16* out, int R, int C, int r0, int c0){
  __shared__ float tile[32][33];
  int x = threadIdx.x & 31, y = threadIdx.x >> 5;
#pragma unroll
  for (int j = 0; j < 4; j++)
    tile[y + j*8][x] = in[(size_t)(r0 + y + j*8) * C + c0 + x];
  __syncthreads();
#pragma unroll
  for (int j = 0; j < 4; j++)
    out[(size_t)(c0 + y + j*8) * R + r0 + x] = f2bf(tile[x][y + j*8]);
}

// blocks: [0,2048) f2bf inputs; [2048,6144) Wq/Wk/Wv/Wo transposes;
// [6144,14336) W1/W2 transposes; [14336,14348) bias gather;
// [14348,14412) zero ckb||cqb (contiguous 256KB)
__global__ __launch_bounds__(256) void prep_all(
    const float* __restrict__ inputs, u16* __restrict__ Xbf,
    const float* __restrict__ Wq, const float* __restrict__ Wk,
    const float* __restrict__ Wv, const float* __restrict__ Wo,
    u16* __restrict__ dqkv, u16* __restrict__ dwo,
    const float* __restrict__ W1, const float* __restrict__ W2,
    u16* __restrict__ d1, u16* __restrict__ d2,
    const float* __restrict__ bq, const float* __restrict__ bk,
    const float* __restrict__ bv, float* __restrict__ bqkv,
    float* __restrict__ ckq_zero)
{
  int b = blockIdx.x;
  if (b < 2048){
    int i = b * 256 + threadIdx.x;
    float4 v = reinterpret_cast<const float4*>(inputs)[i];
    ushort4 o; o.x = f2bf(v.x); o.y = f2bf(v.y); o.z = f2bf(v.z); o.w = f2bf(v.w);
    reinterpret_cast<ushort4*>(Xbf)[i] = o;
  } else if (b < 6144){
    int t = b - 2048;
    int z = t >> 10, rem = t & 1023;
    int bx = rem & 31, by = rem >> 5;
    const float* in = (z == 0) ? Wq : (z == 1) ? Wk : (z == 2) ? Wv : Wo;
    u16* out = (z < 3) ? (dqkv + (size_t)z * 1024 * 1024) : dwo;
    tr_tile2(in, out, 1024, 1024, by * 32, bx * 32);
  } else if (b < 14336){
    int t = b - 6144;
    int z = t >> 12, rem = t & 4095;
    int bx = rem & 127, by = rem >> 7;
    if (z == 0) tr_tile2(W1, d1, 1024, 4096, by * 32, bx * 32);
    else        tr_tile2(W2, d2, 4096, 1024, bx * 32, by * 32);
  } else if (b < 14348){
    int i = (b - 14336) * 256 + threadIdx.x;
    if (i < 3072){
      float v = (i < 1024) ? bq[i] : (i < 2048) ? bk[i - 1024] : bv[i - 2048];
      bqkv[i] = v;
    }
  } else {
    int i = (b - 14348) * 256 + threadIdx.x;
    reinterpret_cast<float4*>(ckq_zero)[i] = make_float4(0.f, 0.f, 0.f, 0.f);
  }
}

// ---------------- bf16 MFMA GEMM (dbuf + counted vmcnt, T2 XOR-swizzled LDS) ----
// C[M,N] = act(A[M,K] @ Bt[N,K]^T + bias)
// LDS: BK=64 bf16 rows = 8 x 16B slots; slot s of row r at phys slot s^(r&7)
// (rule #21: linear gload_lds dest + pre-swizzled SOURCE + swizzled READ).
// Pipeline: STAGE(next) before compute(cur); counted vmcnt across the barrier.
// ACT: 0 none, 2 gelu  (OM==1 applies fast sigmoid for col<2048 internally)
// OM: 1 fused-QKV remap to 3x[B,H,L,DH] + fused chunk-sum atomics into cq/ck;
//     3 bf16 [M][N]; 4 raw f32 partial (slice z at outF + z*M*N);
//     5 bf16 partial (slice z at outB + z*M*N)
template<int BM, int BN, int ACT, int OM>
__global__ __launch_bounds__(256) void gemm_mfma(
    const u16* __restrict__ A, const u16* __restrict__ Bt,
    const float* __restrict__ bias, const float* __restrict__ resid,
    float* __restrict__ outF, u16* __restrict__ outB,
    float* __restrict__ cqA, float* __restrict__ ckA,
    int M, int N, int K)
{
  constexpr int BK = 64;
  constexpr int MI = BM / 32;
  constexpr int NJ = BN / 32;
  constexpr int RA = BM / 32;
  constexpr int RB = BN / 32;
  constexpr int NS = RA + RB;
  __shared__ u16 As[2][BM * BK];
  __shared__ u16 Bs[2][BN * BK];
  const int tid = threadIdx.x;
  const int lane = tid & 63, wave = tid >> 6;
  const int lrow = lane & 15, lg = lane >> 4;
  const int m0 = blockIdx.x * BM, n0 = blockIdx.y * BN;
  const int wm = (wave >> 1) * (BM / 2), wn = (wave & 1) * (BN / 2);

  const int ksz = K / gridDim.z;
  const int k_begin = blockIdx.z * ksz;
  const int k_end = k_begin + ksz;

  f32x4 acc[MI][NJ];
#pragma unroll
  for (int i = 0; i < MI; i++)
#pragma unroll
    for (int j = 0; j < NJ; j++) acc[i][j] = (f32x4){0.f, 0.f, 0.f, 0.f};

  const u16* Ab = A + (size_t)m0 * K;
  const u16* Bb = Bt + (size_t)n0 * K;

  const int s0 = ((0 * 4 + lg) ^ (lrow & 7)) * 8;
  const int s1 = ((1 * 4 + lg) ^ (lrow & 7)) * 8;

  auto STAGE = [&](int buf, int k0){
#pragma unroll
    for (int r = 0; r < RA; ++r){
      int c = r * 256 + tid;
      int row = c >> 3;
      int kk = ((c ^ row) & 7) << 3;
      gload_lds16(Ab + (size_t)row * K + k0 + kk, &As[buf][(r * 256 + wave * 64) * 8]);
    }
#pragma unroll
    for (int r = 0; r < RB; ++r){
      int c = r * 256 + tid;
      int row = c >> 3;
      int kk = ((c ^ row) & 7) << 3;
      gload_lds16(Bb + (size_t)row * K + k0 + kk, &Bs[buf][(r * 256 + wave * 64) * 8]);
    }
  };

  STAGE(0, k_begin);
  int cur = 0;
  for (int k0 = k_begin; k0 < k_end; k0 += BK){
    if (k0 + BK < k_end){
      STAGE(cur ^ 1, k0 + BK);
      if constexpr (NS == 8)      asm volatile("s_waitcnt vmcnt(8)" ::: "memory");
      else if constexpr (NS == 6) asm volatile("s_waitcnt vmcnt(6)" ::: "memory");
      else                        asm volatile("s_waitcnt vmcnt(0)" ::: "memory");
    } else {
      asm volatile("s_waitcnt vmcnt(0)" ::: "memory");
    }
    __builtin_amdgcn_s_barrier();
    __builtin_amdgcn_sched_barrier(0);
#pragma unroll
    for (int kh = 0; kh < 2; ++kh){
      const int ss = (kh == 0) ? s0 : s1;
      bf16x8 af[MI], bfv[NJ];
#pragma unroll
      for (int i = 0; i < MI; ++i)
        af[i] = *reinterpret_cast<const bf16x8*>(&As[cur][(wm + i * 16 + lrow) * BK + ss]);
#pragma unroll
      for (int j = 0; j < NJ; ++j)
        bfv[j] = *reinterpret_cast<const bf16x8*>(&Bs[cur][(wn + j * 16 + lrow) * BK + ss]);
#pragma unroll
      for (int i = 0; i < MI; ++i)
#pragma unroll
        for (int j = 0; j < NJ; ++j)
          acc[i][j] = __builtin_amdgcn_mfma_f32_16x16x32_bf16(af[i], bfv[j], acc[i][j], 0, 0, 0);
    }
    __builtin_amdgcn_s_barrier();
    cur ^= 1;
  }

  float csum[NJ];
#pragma unroll
  for (int j = 0; j < NJ; ++j) csum[j] = 0.f;

#pragma unroll
  for (int i = 0; i < MI; ++i){
#pragma unroll
    for (int j = 0; j < NJ; ++j){
      int col = n0 + wn + j * 16 + lrow;
      float bv = (OM < 4 && bias) ? bias[col] : 0.f;
#pragma unroll
      for (int r = 0; r < 4; ++r){
        int row = m0 + wm + i * 16 + lg * 4 + r;
        float x = acc[i][j][r] + bv;
        if (OM == 1){
          if (col < 2048){ x = fast_sigmoid(x); csum[j] += x; }
          int which = col >> 10, cc = col & 1023, h = cc >> 6, d = cc & 63;
          int b = row >> 10, l = row & 1023;
          outF[(size_t)which * (2048ull * 1024) +
               (((size_t)(b * 16 + h)) * 1024 + l) * 64 + d] = x;
        } else if (OM == 4){
          outF[((size_t)blockIdx.z * M + row) * N + col] = x;
        } else if (OM == 5){
          outB[((size_t)blockIdx.z * M + row) * N + col] = f2bf(x);
        } else {
          if (ACT == 2){
            float u = 0.7978845608f * (x + 0.044715f * x * x * x);
            float e = __expf(2.f * u);
            x = 0.5f * x * (2.f - 2.f / (e + 1.f));
          }
          outB[(size_t)row * N + col] = f2bf(x);
        }
      }
    }
  }
  // fused chunk-sums: 16 rows per thread (fixed chunk), one atomic per j-frag
  if (OM == 1){
#pragma unroll
    for (int j = 0; j < NJ; ++j){
      int col = n0 + wn + j * 16 + lrow;
      if (col < 2048){
        int which = col >> 10, cc = col & 1023, h = cc >> 6, d = cc & 63;
        int rowbase = m0 + wm;
        int bh = (rowbase >> 10) * 16 + h;
        int chunk = (rowbase & 1023) >> 6;
        float* dst = (which == 0) ? cqA : ckA;
        atomicAdd(&dst[((size_t)bh * 16 + chunk) * 64 + d], csum[j]);
      }
    }
  }
}

// ---------------- attention scalar pipeline (chunked Gram-tile form) ----------------
__global__ __launch_bounds__(256) void sink_tile(
    const float* __restrict__ q, const float* __restrict__ k,
    const float* __restrict__ ck, const float* __restrict__ cq,
    float* __restrict__ sink_in, float* __restrict__ src_out,
    float* __restrict__ cso, float* __restrict__ cqsi)
{
  int blk = blockIdx.x, bh = blk >> 4, c = blk & 15;
  int tid = threadIdx.x, lane = tid & 63, wave = tid >> 6;
  __shared__ float qT[64][65], kT[64][65], G[64][66];
  __shared__ float PK[64], PQ[64];
  __shared__ float rk[64], rq[64], crk[64], crq[64], siv[64], sov[64];
  __shared__ float rd[2][4][64];
  size_t base = ((size_t)bh * LSEQ + c * 64) * DHD;
  const float* qb = q + base; const float* kb = k + base;
  for (int c4 = tid; c4 < 1024; c4 += 256){
    int l = c4 >> 4, d0 = (c4 & 15) * 4;
    float4 qv = *reinterpret_cast<const float4*>(qb + c4 * 4);
    qT[d0+0][l] = qv.x; qT[d0+1][l] = qv.y; qT[d0+2][l] = qv.z; qT[d0+3][l] = qv.w;
    float4 kv = *reinterpret_cast<const float4*>(kb + c4 * 4);
    kT[d0+0][l] = kv.x; kT[d0+1][l] = kv.y; kT[d0+2][l] = kv.z; kT[d0+3][l] = kv.w;
  }
  if (tid < 64){
    float pk = 0.f, pq = 0.f;
    for (int cc = 0; cc < c; cc++){
      pk += ck[((size_t)bh * 16 + cc) * 64 + tid];
      pq += cq[((size_t)bh * 16 + cc) * 64 + tid];
    }
    PK[tid] = pk; PQ[tid] = pq;
  }
  __syncthreads();
  float sumPK = wred64(PK[lane]);
  float sumPQ = wred64(PQ[lane]);
  {
    int l = lane, g = wave;
    float qrow[64];
#pragma unroll
    for (int d = 0; d < 64; d++) qrow[d] = qT[d][l];
    float p[16] = {};
    for (int d = 0; d < 64; d++){
      float qv = qrow[d];
#pragma unroll
      for (int j4 = 0; j4 < 4; j4++){
        float4 kk = *reinterpret_cast<const float4*>(&kT[d][g * 16 + j4 * 4]);
        p[j4*4+0] += qv * kk.x; p[j4*4+1] += qv * kk.y;
        p[j4*4+2] += qv * kk.z; p[j4*4+3] += qv * kk.w;
      }
    }
#pragma unroll
    for (int jj = 0; jj < 16; jj++) G[l][g * 16 + jj] = p[jj];
  }
  {
    float pk_ = 0.f, pq_ = 0.f;
#pragma unroll
    for (int d = wave * 16; d < wave * 16 + 16; d++){
      pk_ += kT[d][lane]; pq_ += qT[d][lane];
    }
    rd[0][wave][lane] = pk_; rd[1][wave][lane] = pq_;
  }
  __syncthreads();
  if (tid < 64){
    rk[tid] = rd[0][0][tid] + rd[0][1][tid] + rd[0][2][tid] + rd[0][3][tid];
    rq[tid] = rd[1][0][tid] + rd[1][1][tid] + rd[1][2][tid] + rd[1][3][tid];
  }
  __syncthreads();
  if (wave == 0)      crk[lane] = wscan64(rk[lane], lane);
  else if (wave == 1) crq[lane] = wscan64(rq[lane], lane);
  __syncthreads();
  {
    int l = lane;
    float p1 = 0.f, p2 = 0.f;
#pragma unroll
    for (int j = wave * 16; j < wave * 16 + 16; j++){
      float g1 = (j <= l) ? G[l][j] : 0.f;
      p1 += g1 + qT[j][l] * PK[j];
      float g2 = (j <= l) ? G[j][l] : 0.f;
      p2 += g2 + kT[j][l] * PQ[j];
    }
    rd[0][wave][l] = p1; rd[1][wave][l] = p2;
  }
  __syncthreads();
  const float EPS2 = 64.f * EPS * EPS;
  if (tid < 64){
    int l = tid;
    float s1 = rd[0][0][l] + rd[0][1][l] + rd[0][2][l] + rd[0][3][l];
    float s2 = rd[1][0][l] + rd[1][1][l] + rd[1][2][l] + rd[1][3][l];
    int L = c * 64 + l; float nrm = (float)(L + 1);
    float den1 = s1 + EPS * rq[l] + EPS * (sumPK + crk[l]) + EPS2;
    float den2 = s2 + EPS * rk[l] + EPS * (sumPQ + crq[l]) + EPS2;
    float si_ = nrm / den1, so_ = nrm / den2;
    sink_in[(size_t)bh * LSEQ + L] = si_;
    src_out[(size_t)bh * LSEQ + L] = so_;
    siv[l] = si_; sov[l] = so_;
  }
  __syncthreads();
  float s1 = 0.f, s2 = 0.f;
  for (int l = wave * 16; l < wave * 16 + 16; l++){
    s1 += sov[l] * kT[lane][l];
    s2 += siv[l] * qT[lane][l];
  }
  rd[0][wave][lane] = s1; rd[1][wave][lane] = s2;
  __syncthreads();
  if (wave == 0){
    cso [(size_t)blk * 64 + lane] = rd[0][0][lane] + rd[0][1][lane] + rd[0][2][lane] + rd[0][3][lane];
    cqsi[(size_t)blk * 64 + lane] = rd[1][0][lane] + rd[1][1][lane] + rd[1][2][lane] + rd[1][3][lane];
  }
}

__global__ __launch_bounds__(256) void cons_tile(
    const float* __restrict__ q, const float* __restrict__ k,
    const float* __restrict__ cso, const float* __restrict__ cqsi,
    const float* __restrict__ sink_in, const float* __restrict__ src_out,
    float* __restrict__ sa, float* __restrict__ ebuf)
{
  int blk = blockIdx.x, bh = blk >> 4, c = blk & 15;
  int tid = threadIdx.x, lane = tid & 63, wave = tid >> 6;
  __shared__ float qT[64][65], kT[64][65], G[64][66];
  __shared__ float PKso[64], PQsi[64];
  __shared__ float rk[64], rq[64], cwrk[64], cwrq[64], siv[64], sov[64];
  __shared__ float rd[2][4][64];
  size_t base = ((size_t)bh * LSEQ + c * 64) * DHD;
  const float* qb = q + base; const float* kb = k + base;
  for (int c4 = tid; c4 < 1024; c4 += 256){
    int l = c4 >> 4, d0 = (c4 & 15) * 4;
    float4 qv = *reinterpret_cast<const float4*>(qb + c4 * 4);
    qT[d0+0][l] = qv.x; qT[d0+1][l] = qv.y; qT[d0+2][l] = qv.z; qT[d0+3][l] = qv.w;
    float4 kv = *reinterpret_cast<const float4*>(kb + c4 * 4);
    kT[d0+0][l] = kv.x; kT[d0+1][l] = kv.y; kT[d0+2][l] = kv.z; kT[d0+3][l] = kv.w;
  }
  if (tid < 64){
    float pk = 0.f, pq = 0.f;
    for (int cc = 0; cc < c; cc++){
      pk += cso [((size_t)bh * 16 + cc) * 64 + tid];
      pq += cqsi[((size_t)bh * 16 + cc) * 64 + tid];
    }
    PKso[tid] = pk; PQsi[tid] = pq;
  } else if (tid < 128){
    int l = tid - 64;
    sov[l] = src_out[(size_t)bh * LSEQ + c * 64 + l];
    siv[l] = sink_in[(size_t)bh * LSEQ + c * 64 + l];
  }
  __syncthreads();
  float sumPKso = wred64(PKso[lane]);
  float sumPQsi = wred64(PQsi[lane]);
  {
    int l = lane, g = wave;
    float qrow[64];
#pragma unroll
    for (int d = 0; d < 64; d++) qrow[d] = qT[d][l];
    float p[16] = {};
    for (int d = 0; d < 64; d++){
      float qv = qrow[d];
#pragma unroll
      for (int j4 = 0; j4 < 4; j4++){
        float4 kk = *reinterpret_cast<const float4*>(&kT[d][g * 16 + j4 * 4]);
        p[j4*4+0] += qv * kk.x; p[j4*4+1] += qv * kk.y;
        p[j4*4+2] += qv * kk.z; p[j4*4+3] += qv * kk.w;
      }
    }
#pragma unroll
    for (int jj = 0; jj < 16; jj++) G[l][g * 16 + jj] = p[jj];
  }
  {
    float pk_ = 0.f, pq_ = 0.f;
#pragma unroll
    for (int d = wave * 16; d < wave * 16 + 16; d++){
      pk_ += kT[d][lane]; pq_ += qT[d][lane];
    }
    rd[0][wave][lane] = pk_; rd[1][wave][lane] = pq_;
  }
  __syncthreads();
  if (tid < 64){
    rk[tid] = rd[0][0][tid] + rd[0][1][tid] + rd[0][2][tid] + rd[0][3][tid];
    rq[tid] = rd[1][0][tid] + rd[1][1][tid] + rd[1][2][tid] + rd[1][3][tid];
  }
  __syncthreads();
  if (wave == 0)      cwrk[lane] = wscan64(sov[lane] * rk[lane], lane);
  else if (wave == 1) cwrq[lane] = wscan64(siv[lane] * rq[lane], lane);
  __syncthreads();
  {
    int l = lane;
    float p3 = 0.f, p4 = 0.f;
#pragma unroll
    for (int j = wave * 16; j < wave * 16 + 16; j++){
      float g3 = (j <= l) ? sov[j] * G[l][j] : 0.f;
      p3 += g3 + qT[j][l] * PKso[j];
      float g4 = (j <= l) ? siv[j] * G[j][l] : 0.f;
      p4 += g4 + kT[j][l] * PQsi[j];
    }
    rd[0][wave][l] = p3; rd[1][wave][l] = p4;
  }
  __syncthreads();
  const float EPS2 = 64.f * EPS * EPS;
  if (tid < 64){
    int l = tid;
    float s3 = rd[0][0][l] + rd[0][1][l] + rd[0][2][l] + rd[0][3][l];
    float s4 = rd[1][0][l] + rd[1][1][l] + rd[1][2][l] + rd[1][3][l];
    int L = c * 64 + l; float nrm = (float)(L + 1);
    float cs = (s3 + EPS * rq[l] + EPS * (sumPKso + cwrk[l]) + EPS2) / nrm;
    sa[(size_t)bh * LSEQ + L] = fast_sigmoid(cs);
    float c2 = (s4 + EPS * rk[l] + EPS * (sumPQsi + cwrq[l]) + EPS2) / nrm;
    c2 = fminf(1.f, fmaxf(-1.f, c2));
    ebuf[(size_t)bh * LSEQ + L] = __expf(c2);
  }
}

// src_comp = e / cumsum(e) * (l+1)
__global__ __launch_bounds__(64) void srccomp_kernel(const float* __restrict__ ebuf, float* __restrict__ sc){
  int bh = blockIdx.x; int lane = threadIdx.x;
  const float* eb = ebuf + (size_t)bh * LSEQ;
  float loc[16]; float s = 0.f;
#pragma unroll
  for (int i = 0; i < 16; i++){ loc[i] = eb[lane * 16 + i]; s += loc[i]; }
  float run = wscan64(s, lane);
  float acc = run - s;
  float* scb = sc + (size_t)bh * LSEQ;
#pragma unroll
  for (int i = 0; i < 16; i++){
    acc += loc[i];
    scb[lane * 16 + i] = loc[i] / acc * (float)(lane * 16 + i + 1);
  }
}

// ---------------- chunked causal linear attention (scale fused in) ----------------
__global__ __launch_bounds__(256) void phaseA(const float* __restrict__ k, const float* __restrict__ v,
                                              const float* __restrict__ sc, float* __restrict__ S){
  int blk = blockIdx.x; int bh = blk >> 4, c = blk & 15;
  __shared__ float ks[64][68], vss[64][68];
  __shared__ float vc[64];
  int tid = threadIdx.x;
  size_t base = ((size_t)bh * LSEQ + c * 64) * DHD;
  const float* kb = k + base; const float* vb = v + base;
  if (tid < 64) vc[tid] = sc[(size_t)bh * LSEQ + c * 64 + tid];
  __syncthreads();
  for (int c4 = tid; c4 < 1024; c4 += 256){
    int l = c4 >> 4, d0 = (c4 & 15) * 4;
    *reinterpret_cast<float4*>(&ks[l][d0]) = *reinterpret_cast<const float4*>(kb + c4 * 4);
    float4 vv = *reinterpret_cast<const float4*>(vb + c4 * 4);
    float w = vc[l];
    vss[l][d0+0] = vv.x * w; vss[l][d0+1] = vv.y * w;
    vss[l][d0+2] = vv.z * w; vss[l][d0+3] = vv.w * w;
  }
  __syncthreads();
  int m = tid >> 2, dg = tid & 3;
  float acc[16] = {};
  for (int l = 0; l < 64; l++){
    float vm = vss[l][m];
#pragma unroll
    for (int d4 = 0; d4 < 4; d4++){
      float4 kk = *reinterpret_cast<const float4*>(&ks[l][dg * 16 + d4 * 4]);
      acc[d4*4+0] += vm * kk.x; acc[d4*4+1] += vm * kk.y;
      acc[d4*4+2] += vm * kk.z; acc[d4*4+3] += vm * kk.w;
    }
  }
  float* Sb = S + (size_t)blk * 4096 + m * 64 + dg * 16;
#pragma unroll
  for (int d4 = 0; d4 < 4; d4++)
    *reinterpret_cast<float4*>(Sb + d4 * 4) =
        make_float4(acc[d4*4], acc[d4*4+1], acc[d4*4+2], acc[d4*4+3]);
}

// phase C with inlined KV-prefix; Ps overlays qsT (qrow registers cached first)
__global__ __launch_bounds__(256) void phaseC(const float* __restrict__ q, const float* __restrict__ k,
                                              const float* __restrict__ v, const float* __restrict__ S,
                                              const float* __restrict__ sink_in, const float* __restrict__ sc,
                                              const float* __restrict__ sa, u16* __restrict__ x){
  int blk = blockIdx.x; int bh = blk >> 4, c = blk & 15;
  int b = bh >> 4, h = bh & 15;
  __shared__ float qp[64][66];      // qsT[d][l] first, then Ps[l][j]
  __shared__ float kT[64][68];
  __shared__ float vss[64][68];
  __shared__ float kvs[64][68];
  __shared__ float qc[64], vc[64];
  int tid = threadIdx.x;
  size_t base = ((size_t)bh * LSEQ + c * 64) * DHD;
  const float* qb = q + base; const float* kb = k + base; const float* vb = v + base;
  if (tid < 64){
    int L = c * 64 + tid;
    qc[tid] = sink_in[(size_t)bh * LSEQ + L] / (float)(L + 1);
    vc[tid] = sc[(size_t)bh * LSEQ + L];
  }
  {
    int off16 = tid * 16;
    float accp[16] = {};
    for (int cc = 0; cc < c; cc++){
      size_t idx = ((size_t)bh * 16 + cc) * 4096 + off16;
#pragma unroll
      for (int t4 = 0; t4 < 4; t4++){
        float4 sv = *reinterpret_cast<const float4*>(S + idx + t4 * 4);
        accp[t4*4+0] += sv.x; accp[t4*4+1] += sv.y;
        accp[t4*4+2] += sv.z; accp[t4*4+3] += sv.w;
      }
    }
#pragma unroll
    for (int e = 0; e < 16; e++){
      int j = off16 + e;
      kvs[j >> 6][j & 63] = accp[e];
    }
  }
  __syncthreads();
  for (int c4 = tid; c4 < 1024; c4 += 256){
    int l = c4 >> 4, d0 = (c4 & 15) * 4;
    float qw = qc[l], vw = vc[l];
    float4 qv = *reinterpret_cast<const float4*>(qb + c4 * 4);
    qp[d0+0][l] = qv.x * qw; qp[d0+1][l] = qv.y * qw;
    qp[d0+2][l] = qv.z * qw; qp[d0+3][l] = qv.w * qw;
    float4 kv4 = *reinterpret_cast<const float4*>(kb + c4 * 4);
    kT[d0+0][l] = kv4.x; kT[d0+1][l] = kv4.y; kT[d0+2][l] = kv4.z; kT[d0+3][l] = kv4.w;
    float4 vv = *reinterpret_cast<const float4*>(vb + c4 * 4);
    vss[l][d0+0] = vv.x * vw; vss[l][d0+1] = vv.y * vw;
    vss[l][d0+2] = vv.z * vw; vss[l][d0+3] = vv.w * vw;
  }
  __syncthreads();
  int l = tid & 63, g = tid >> 6;
  float qrow[64];
#pragma unroll
  for (int d = 0; d < 64; d++) qrow[d] = qp[d][l];
  __syncthreads();

  float p[16] = {};
  for (int d = 0; d < 64; d++){
    float qv = qrow[d];
#pragma unroll
    for (int j4 = 0; j4 < 4; j4++){
      float4 kk = *reinterpret_cast<const float4*>(&kT[d][g * 16 + j4 * 4]);
      p[j4*4+0] += qv * kk.x; p[j4*4+1] += qv * kk.y;
      p[j4*4+2] += qv * kk.z; p[j4*4+3] += qv * kk.w;
    }
  }
#pragma unroll
  for (int jj = 0; jj < 16; jj++){
    int j = g * 16 + jj;
    qp[l][j] = (j <= l) ? p[jj] : 0.f;
  }
  __syncthreads();

  float acc[16];
#pragma unroll
  for (int mm = 0; mm < 16; mm++){
    float a = 0.f;
#pragma unroll
    for (int d4 = 0; d4 < 16; d4++){
      float4 kv4 = *reinterpret_cast<const float4*>(&kvs[g * 16 + mm][d4 * 4]);
      a += qrow[d4*4+0]*kv4.x + qrow[d4*4+1]*kv4.y + qrow[d4*4+2]*kv4.z + qrow[d4*4+3]*kv4.w;
    }
    acc[mm] = a;
  }
  for (int j = 0; j < 64; j++){
    float pv = qp[l][j];
#pragma unroll
    for (int m4 = 0; m4 < 4; m4++){
      float4 vv = *reinterpret_cast<const float4*>(&vss[j][g * 16 + m4 * 4]);
      acc[m4*4+0] += pv * vv.x; acc[m4*4+1] += pv * vv.y;
      acc[m4*4+2] += pv * vv.z; acc[m4*4+3] += pv * vv.w;
    }
  }
  float sav = sa[(size_t)bh * LSEQ + c * 64 + l];
  u16* xo = x + ((size_t)(b * 1024 + c * 64 + l)) * 1024 + h * 64 + g * 16;
#pragma unroll
  for (int mm = 0; mm < 16; mm++) xo[mm] = f2bf(acc[mm] * sav);
}

// ---------------- fused layernorms ----------------
__global__ __launch_bounds__(256) void ln_fused2b(
    const float* __restrict__ p0, const float* __restrict__ p1,
    const float* __restrict__ resid, const float* __restrict__ bias,
    const float* __restrict__ g, const float* __restrict__ b,
    float* __restrict__ out, u16* __restrict__ outbf){
  int row = blockIdx.x; int tid = threadIdx.x;
  int lane = tid & 63, wave = tid >> 6;
  size_t off = (size_t)row * 1024 + tid * 4;
  float4 a0 = *reinterpret_cast<const float4*>(p0 + off);
  float4 a1 = *reinterpret_cast<const float4*>(p1 + off);
  float4 rr = *reinterpret_cast<const float4*>(resid + off);
  float4 bb = *reinterpret_cast<const float4*>(bias + tid * 4);
  float4 v = make_float4(a0.x + a1.x + rr.x + bb.x, a0.y + a1.y + rr.y + bb.y,
                         a0.z + a1.z + rr.z + bb.z, a0.w + a1.w + rr.w + bb.w);
  float s = v.x + v.y + v.z + v.w;
  float s2 = v.x*v.x + v.y*v.y + v.z*v.z + v.w*v.w;
  s = wred64(s); s2 = wred64(s2);
  __shared__ float red[2][4];
  if (lane == 0){ red[0][wave] = s; red[1][wave] = s2; }
  __syncthreads();
  float S = red[0][0] + red[0][1] + red[0][2] + red[0][3];
  float S2 = red[1][0] + red[1][1] + red[1][2] + red[1][3];
  float mean = S * (1.f / 1024.f);
  float var = S2 * (1.f / 1024.f) - mean * mean;
  float inv = rsqrtf(var + 1e-5f);
  float4 gv = *reinterpret_cast<const float4*>(g + tid * 4);
  float4 bv = *reinterpret_cast<const float4*>(b + tid * 4);
  float y0 = (v.x - mean) * inv * gv.x + bv.x;
  float y1 = (v.y - mean) * inv * gv.y + bv.y;
  float y2 = (v.z - mean) * inv * gv.z + bv.z;
  float y3 = (v.w - mean) * inv * gv.w + bv.w;
  *reinterpret_cast<float4*>(out + off) = make_float4(y0, y1, y2, y3);
  ushort4 o; o.x = f2bf(y0); o.y = f2bf(y1); o.z = f2bf(y2); o.w = f2bf(y3);
  *reinterpret_cast<ushort4*>(outbf + off) = o;
}

// LN over (bf16 p0..p3 + bias + resid) -> f32 out (FFN2 split-K4 combine + LN2)
__global__ __launch_bounds__(256) void ln_fused4b(
    const u16* __restrict__ p0, const u16* __restrict__ p1,
    const u16* __restrict__ p2, const u16* __restrict__ p3,
    const float* __restrict__ resid, const float* __restrict__ bias,
    const float* __restrict__ g, const float* __restrict__ b,
    float* __restrict__ out){
  int row = blockIdx.x; int tid = threadIdx.x;
  int lane = tid & 63, wave = tid >> 6;
  size_t off = (size_t)row * 1024 + tid * 4;
  ushort4 u0 = *reinterpret_cast<const ushort4*>(p0 + off);
  ushort4 u1 = *reinterpret_cast<const ushort4*>(p1 + off);
  ushort4 u2 = *reinterpret_cast<const ushort4*>(p2 + off);
  ushort4 u3 = *reinterpret_cast<const ushort4*>(p3 + off);
  float4 rr = *reinterpret_cast<const float4*>(resid + off);
  float4 bb = *reinterpret_cast<const float4*>(bias + tid * 4);
  float4 v = make_float4(
      bf2f(u0.x) + bf2f(u1.x) + bf2f(u2.x) + bf2f(u3.x) + rr.x + bb.x,
      bf2f(u0.y) + bf2f(u1.y) + bf2f(u2.y) + bf2f(u3.y) + rr.y + bb.y,
      bf2f(u0.z) + bf2f(u1.z) + bf2f(u2.z) + bf2f(u3.z) + rr.z + bb.z,
      bf2f(u0.w) + bf2f(u1.w) + bf2f(u2.w) + bf2f(u3.w) + rr.w + bb.w);
  float s = v.x + v.y + v.z + v.w;
  float s2 = v.x*v.x + v.y*v.y + v.z*v.z + v.w*v.w;
  s = wred64(s); s2 = wred64(s2);
  __shared__ float red[2][4];
  if (lane == 0){ red[0][wave] = s; red[1][wave] = s2; }
  __syncthreads();
  float S = red[0][0] + red[0][1] + red[0][2] + red[0][3];
  float S2 = red[1][0] + red[1][1] + red[1][2] + red[1][3];
  float mean = S * (1.f / 1024.f);
  float var = S2 * (1.f / 1024.f) - mean * mean;
  float inv = rsqrtf(var + 1e-5f);
  float4 gv = *reinterpret_cast<const float4*>(g + tid * 4);
  float4 bv = *reinterpret_cast<const float4*>(b + tid * 4);
  float y0 = (v.x - mean) * inv * gv.x + bv.x;
  float y1 = (v.y - mean) * inv * gv.y + bv.y;
  float y2 = (v.z - mean) * inv * gv.z + bv.z;
  float y3 = (v.w - mean) * inv * gv.w + bv.w;
  *reinterpret_cast<float4*>(out + off) = make_float4(y0, y1, y2, y3);
}

// ---------------- launch ----------------
extern "C" void kernel_launch(void* const* d_in, const int* in_sizes, int n_in,
                              void* d_out, int out_size, void* d_ws, size_t ws_size,
                              hipStream_t stream){
  (void)in_sizes; (void)n_in; (void)out_size; (void)ws_size;
  const float* inputs = (const float*)d_in[0];
  const float* Wq = (const float*)d_in[2];  const float* bq = (const float*)d_in[3];
  const float* Wk = (const float*)d_in[4];  const float* bk = (const float*)d_in[5];
  const float* Wv = (const float*)d_in[6];  const float* bv = (const float*)d_in[7];
  const float* Wo = (const float*)d_in[8];  const float* bo = (const float*)d_in[9];
  const float* ln1g = (const float*)d_in[10]; const float* ln1b = (const float*)d_in[11];
  const float* W1 = (const float*)d_in[12]; const float* b1 = (const float*)d_in[13];
  const float* W2 = (const float*)d_in[14]; const float* b2 = (const float*)d_in[15];
  const float* ln2g = (const float*)d_in[16]; const float* ln2b = (const float*)d_in[17];
  float* out = (float*)d_out;

  char* wsp = (char*)d_ws; size_t off = 0;
  auto alloc = [&](size_t bytes) -> void* {
    off = (off + 255) & ~(size_t)255;
    void* p = wsp + off; off += bytes; return p;
  };
  const size_t MD = (size_t)2048 * 1024;
  u16* Xbf    = (u16*)alloc(MD * 2);
  u16* WqkvT  = (u16*)alloc((size_t)3 * 1024 * 1024 * 2);
  u16* WoT    = (u16*)alloc((size_t)1024 * 1024 * 2);
  u16* W1T    = (u16*)alloc((size_t)4096 * 1024 * 2);
  u16* W2T    = (u16*)alloc((size_t)4096 * 1024 * 2);
  float* bqkv = (float*)alloc(3072 * 4);
  float* qkvb = (float*)alloc(3 * MD * 4);
  float* qb = qkvb; float* kb = qkvb + MD; float* vb = qkvb + 2 * MD;
  float* quad = (float*)alloc(4 * MD * 4);
  float* Sbuf = quad;
  float* ckb  = (float*)alloc((size_t)512 * 64 * 4);   // contiguous with cqb
  float* cqb  = (float*)alloc((size_t)512 * 64 * 4);
  float* csob = (float*)alloc((size_t)512 * 64 * 4);
  float* cqsib= (float*)alloc((size_t)512 * 64 * 4);
  float* sink_in = (float*)alloc(NBH * LSEQ * 4);
  float* src_out = (float*)alloc(NBH * LSEQ * 4);
  float* sabuf   = (float*)alloc(NBH * LSEQ * 4);
  float* ebuf    = (float*)alloc(NBH * LSEQ * 4);
  float* scbuf   = (float*)alloc(NBH * LSEQ * 4);
  u16* xatt   = (u16*)alloc(MD * 2);
  u16* g1     = (u16*)alloc((size_t)2048 * 4096 * 2);
  u16* partb  = (u16*)quad;        // FFN2 bf16 partials: 4 x MD x 2B = 16MB
  float* hbuf = vb;
  u16* hbf = (u16*)qb;

  // all prep in one launch (+64 blocks zeroing ckb||cqb)
  prep_all<<<14412, 256, 0, stream>>>(inputs, Xbf, Wq, Wk, Wv, Wo, WqkvT, WoT,
                                      W1, W2, W1T, W2T, bq, bk, bv, bqkv, ckb);

  // fused QKV projection + chunk-sum atomics: BM=128,BN=64, grid 16x48
  gemm_mfma<128, 64, 0, 1><<<dim3(16, 48), 256, 0, stream>>>(
      Xbf, WqkvT, bqkv, nullptr, qkvb, nullptr, cqb, ckb, 2048, 3072, 1024);

  // attention scalars (chunked Gram-tile pipeline)
  sink_tile<<<512, 256, 0, stream>>>(qb, kb, ckb, cqb, sink_in, src_out, csob, cqsib);
  cons_tile<<<512, 256, 0, stream>>>(qb, kb, csob, cqsib, sink_in, src_out, sabuf, ebuf);
  srccomp_kernel<<<32, 64, 0, stream>>>(ebuf, scbuf);

  // chunked causal linear attention (scale fused; KV-prefix inlined in phaseC)
  phaseA<<<512, 256, 0, stream>>>(kb, vb, scbuf, Sbuf);
  phaseC<<<512, 256, 0, stream>>>(qb, kb, vb, Sbuf, sink_in, scbuf, sabuf, xatt);

  // output projection: BM=128,BN=64, split-K=2 (f32 partials in quad slots 2,3)
  float* wopart = quad + 2 * MD;
  gemm_mfma<128, 64, 0, 4><<<dim3(16, 16, 2), 256, 0, stream>>>(
      xatt, WoT, nullptr, nullptr, wopart, nullptr, nullptr, nullptr, 2048, 1024, 1024);
  ln_fused2b<<<2048, 256, 0, stream>>>(wopart, wopart + MD, inputs, bo, ln1g, ln1b, hbuf, hbf);

  // FFN1: BM=128,BN=128 (fast gelu)
  gemm_mfma<128, 128, 2, 3><<<dim3(16, 32), 256, 0, stream>>>(
      hbf, W1T, b1, nullptr, nullptr, g1, nullptr, nullptr, 2048, 4096, 1024);
  // FFN2: BM=128,BN=128, split-K=4, bf16 partials (halved traffic)
  gemm_mfma<128, 128, 0, 5><<<dim3(16, 8, 4), 256, 0, stream>>>(
      g1, W2T, nullptr, nullptr, nullptr, partb, nullptr, nullptr, 2048, 1024, 4096);
  ln_fused4b<<<2048, 256, 0, stream>>>(partb, partb + MD, partb + 2 * MD, partb + 3 * MD,
                                       hbuf, b2, ln2g, ln2b, out);
}

// Round 16
// 191.271 us; speedup vs baseline: 1.5075x; 1.0225x over previous
//
#include <hip/hip_runtime.h>
#include <hip/hip_bf16.h>

// ---------------- constants ----------------
#define EPS 1e-6f
#define NBH 32      // B*H
#define LSEQ 1024
#define DHD 64

typedef unsigned short u16;
typedef __bf16 bf16x8 __attribute__((ext_vector_type(8)));
typedef float f32x4 __attribute__((ext_vector_type(4)));

__device__ inline u16 f2bf(float f){
  union { float f; unsigned u; } un; un.f = f;
  unsigned u = un.u;
  u += 0x7fffu + ((u >> 16) & 1u);
  return (u16)(u >> 16);
}

__device__ inline float bf2f(u16 v){
  union { unsigned u; float f; } un; un.u = ((unsigned)v) << 16; return un.f;
}

__device__ inline float wred64(float v){
#pragma unroll
  for (int off = 32; off > 0; off >>= 1) v += __shfl_xor(v, off, 64);
  return v;
}

__device__ inline float wscan64(float v, int lane){
  float run = v;
#pragma unroll
  for (int off = 1; off < 64; off <<= 1){
    float t = __shfl_up(run, off, 64);
    if (lane >= off) run += t;
  }
  return run;   // inclusive
}

__device__ inline float fast_sigmoid(float x){
  return 1.f / (1.f + __expf(-x));
}

__device__ inline void gload_lds16(const u16* g, u16* l){
  __builtin_amdgcn_global_load_lds(
      (const __attribute__((address_space(1))) unsigned int*)g,
      (__attribute__((address_space(3))) unsigned int*)l, 16, 0, 0);
}

// ---------------- mega prep kernel (f2bf + 6 transposes + bias + zero) -------
__device__ inline void tr_tile2(const float* in, u16* out, int R, int C, int r0, int c0){
  __shared__ float tile[32][33];
  int x = threadIdx.x & 31, y = threadIdx.x >> 5;
#pragma unroll
  for (int j = 0; j < 4; j++)
    tile[y + j*8][x] = in[(size_t)(r0 + y + j*8) * C + c0 + x];
  __syncthreads();
#pragma unroll
  for (int j = 0; j < 4; j++)
    out[(size_t)(c0 + y + j*8) * R + r0 + x] = f2bf(tile[x][y + j*8]);
}

// blocks: [0,2048) f2bf inputs; [2048,6144) Wq/Wk/Wv/Wo transposes;
// [6144,14336) W1/W2 transposes; [14336,14348) bias gather;
// [14348,14412) zero ckb||cqb (contiguous 256KB)
__global__ __launch_bounds__(256) void prep_all(
    const float* __restrict__ inputs, u16* __restrict__ Xbf,
    const float* __restrict__ Wq, const float* __restrict__ Wk,
    const float* __restrict__ Wv, const float* __restrict__ Wo,
    u16* __restrict__ dqkv, u16* __restrict__ dwo,
    const float* __restrict__ W1, const float* __restrict__ W2,
    u16* __restrict__ d1, u16* __restrict__ d2,
    const float* __restrict__ bq, const float* __restrict__ bk,
    const float* __restrict__ bv, float* __restrict__ bqkv,
    float* __restrict__ ckq_zero)
{
  int b = blockIdx.x;
  if (b < 2048){
    int i = b * 256 + threadIdx.x;
    float4 v = reinterpret_cast<const float4*>(inputs)[i];
    ushort4 o; o.x = f2bf(v.x); o.y = f2bf(v.y); o.z = f2bf(v.z); o.w = f2bf(v.w);
    reinterpret_cast<ushort4*>(Xbf)[i] = o;
  } else if (b < 6144){
    int t = b - 2048;
    int z = t >> 10, rem = t & 1023;
    int bx = rem & 31, by = rem >> 5;
    const float* in = (z == 0) ? Wq : (z == 1) ? Wk : (z == 2) ? Wv : Wo;
    u16* out = (z < 3) ? (dqkv + (size_t)z * 1024 * 1024) : dwo;
    tr_tile2(in, out, 1024, 1024, by * 32, bx * 32);
  } else if (b < 14336){
    int t = b - 6144;
    int z = t >> 12, rem = t & 4095;
    int bx = rem & 127, by = rem >> 7;
    if (z == 0) tr_tile2(W1, d1, 1024, 4096, by * 32, bx * 32);
    else        tr_tile2(W2, d2, 4096, 1024, bx * 32, by * 32);
  } else if (b < 14348){
    int i = (b - 14336) * 256 + threadIdx.x;
    if (i < 3072){
      float v = (i < 1024) ? bq[i] : (i < 2048) ? bk[i - 1024] : bv[i - 2048];
      bqkv[i] = v;
    }
  } else {
    int i = (b - 14348) * 256 + threadIdx.x;
    reinterpret_cast<float4*>(ckq_zero)[i] = make_float4(0.f, 0.f, 0.f, 0.f);
  }
}

// ---------------- bf16 MFMA GEMM (dbuf + counted vmcnt, T2 XOR-swizzled LDS) ----
// C[M,N] = act(A[M,K] @ Bt[N,K]^T + bias)
// LDS: BK=64 bf16 rows = 8 x 16B slots; slot s of row r at phys slot s^(r&7)
// (rule #21: linear gload_lds dest + pre-swizzled SOURCE + swizzled READ).
// Pipeline: STAGE(next) before compute(cur); counted vmcnt across the barrier.
// ACT: 0 none, 2 gelu  (OM==1 applies fast sigmoid for col<2048 internally)
// OM: 1 fused-QKV bf16 remap to 3x[B,H,L,DH] + chunk-sum atomics into cq/ck;
//     3 bf16 [M][N]; 4 raw f32 partial (slice z at outF + z*M*N);
//     5 bf16 partial (slice z at outB + z*M*N)
template<int BM, int BN, int ACT, int OM>
__global__ __launch_bounds__(256) void gemm_mfma(
    const u16* __restrict__ A, const u16* __restrict__ Bt,
    const float* __restrict__ bias, const float* __restrict__ resid,
    float* __restrict__ outF, u16* __restrict__ outB,
    float* __restrict__ cqA, float* __restrict__ ckA,
    int M, int N, int K)
{
  constexpr int BK = 64;
  constexpr int MI = BM / 32;
  constexpr int NJ = BN / 32;
  constexpr int RA = BM / 32;
  constexpr int RB = BN / 32;
  constexpr int NS = RA + RB;
  __shared__ u16 As[2][BM * BK];
  __shared__ u16 Bs[2][BN * BK];
  const int tid = threadIdx.x;
  const int lane = tid & 63, wave = tid >> 6;
  const int lrow = lane & 15, lg = lane >> 4;
  const int m0 = blockIdx.x * BM, n0 = blockIdx.y * BN;
  const int wm = (wave >> 1) * (BM / 2), wn = (wave & 1) * (BN / 2);

  const int ksz = K / gridDim.z;
  const int k_begin = blockIdx.z * ksz;
  const int k_end = k_begin + ksz;

  f32x4 acc[MI][NJ];
#pragma unroll
  for (int i = 0; i < MI; i++)
#pragma unroll
    for (int j = 0; j < NJ; j++) acc[i][j] = (f32x4){0.f, 0.f, 0.f, 0.f};

  const u16* Ab = A + (size_t)m0 * K;
  const u16* Bb = Bt + (size_t)n0 * K;

  const int s0 = ((0 * 4 + lg) ^ (lrow & 7)) * 8;
  const int s1 = ((1 * 4 + lg) ^ (lrow & 7)) * 8;

  auto STAGE = [&](int buf, int k0){
#pragma unroll
    for (int r = 0; r < RA; ++r){
      int c = r * 256 + tid;
      int row = c >> 3;
      int kk = ((c ^ row) & 7) << 3;
      gload_lds16(Ab + (size_t)row * K + k0 + kk, &As[buf][(r * 256 + wave * 64) * 8]);
    }
#pragma unroll
    for (int r = 0; r < RB; ++r){
      int c = r * 256 + tid;
      int row = c >> 3;
      int kk = ((c ^ row) & 7) << 3;
      gload_lds16(Bb + (size_t)row * K + k0 + kk, &Bs[buf][(r * 256 + wave * 64) * 8]);
    }
  };

  STAGE(0, k_begin);
  int cur = 0;
  for (int k0 = k_begin; k0 < k_end; k0 += BK){
    if (k0 + BK < k_end){
      STAGE(cur ^ 1, k0 + BK);
      if constexpr (NS == 8)      asm volatile("s_waitcnt vmcnt(8)" ::: "memory");
      else if constexpr (NS == 6) asm volatile("s_waitcnt vmcnt(6)" ::: "memory");
      else                        asm volatile("s_waitcnt vmcnt(0)" ::: "memory");
    } else {
      asm volatile("s_waitcnt vmcnt(0)" ::: "memory");
    }
    __builtin_amdgcn_s_barrier();
    __builtin_amdgcn_sched_barrier(0);
#pragma unroll
    for (int kh = 0; kh < 2; ++kh){
      const int ss = (kh == 0) ? s0 : s1;
      bf16x8 af[MI], bfv[NJ];
#pragma unroll
      for (int i = 0; i < MI; ++i)
        af[i] = *reinterpret_cast<const bf16x8*>(&As[cur][(wm + i * 16 + lrow) * BK + ss]);
#pragma unroll
      for (int j = 0; j < NJ; ++j)
        bfv[j] = *reinterpret_cast<const bf16x8*>(&Bs[cur][(wn + j * 16 + lrow) * BK + ss]);
#pragma unroll
      for (int i = 0; i < MI; ++i)
#pragma unroll
        for (int j = 0; j < NJ; ++j)
          acc[i][j] = __builtin_amdgcn_mfma_f32_16x16x32_bf16(af[i], bfv[j], acc[i][j], 0, 0, 0);
    }
    __builtin_amdgcn_s_barrier();
    cur ^= 1;
  }

  float csum[NJ];
#pragma unroll
  for (int j = 0; j < NJ; ++j) csum[j] = 0.f;

#pragma unroll
  for (int i = 0; i < MI; ++i){
#pragma unroll
    for (int j = 0; j < NJ; ++j){
      int col = n0 + wn + j * 16 + lrow;
      float bv = (OM < 4 && bias) ? bias[col] : 0.f;
#pragma unroll
      for (int r = 0; r < 4; ++r){
        int row = m0 + wm + i * 16 + lg * 4 + r;
        float x = acc[i][j][r] + bv;
        if (OM == 1){
          if (col < 2048){ x = fast_sigmoid(x); csum[j] += x; }
          int which = col >> 10, cc = col & 1023, h = cc >> 6, d = cc & 63;
          int b = row >> 10, l = row & 1023;
          outB[(size_t)which * (2048ull * 1024) +
               (((size_t)(b * 16 + h)) * 1024 + l) * 64 + d] = f2bf(x);
        } else if (OM == 4){
          outF[((size_t)blockIdx.z * M + row) * N + col] = x;
        } else if (OM == 5){
          outB[((size_t)blockIdx.z * M + row) * N + col] = f2bf(x);
        } else {
          if (ACT == 2){
            float u = 0.7978845608f * (x + 0.044715f * x * x * x);
            float e = __expf(2.f * u);
            x = 0.5f * x * (2.f - 2.f / (e + 1.f));
          }
          outB[(size_t)row * N + col] = f2bf(x);
        }
      }
    }
  }
  // fused chunk-sums: 16 rows per thread (fixed chunk), one atomic per j-frag
  if (OM == 1){
#pragma unroll
    for (int j = 0; j < NJ; ++j){
      int col = n0 + wn + j * 16 + lrow;
      if (col < 2048){
        int which = col >> 10, cc = col & 1023, h = cc >> 6, d = cc & 63;
        int rowbase = m0 + wm;
        int bh = (rowbase >> 10) * 16 + h;
        int chunk = (rowbase & 1023) >> 6;
        float* dst = (which == 0) ? cqA : ckA;
        atomicAdd(&dst[((size_t)bh * 16 + chunk) * 64 + d], csum[j]);
      }
    }
  }
}

// ---------------- attention scalar pipeline (chunked Gram-tile form, bf16 in) ----
__global__ __launch_bounds__(256) void sink_tile(
    const u16* __restrict__ q, const u16* __restrict__ k,
    const float* __restrict__ ck, const float* __restrict__ cq,
    float* __restrict__ sink_in, float* __restrict__ src_out,
    float* __restrict__ cso, float* __restrict__ cqsi)
{
  int blk = blockIdx.x, bh = blk >> 4, c = blk & 15;
  int tid = threadIdx.x, lane = tid & 63, wave = tid >> 6;
  __shared__ float qT[64][65], kT[64][65], G[64][66];
  __shared__ float PK[64], PQ[64];
  __shared__ float rk[64], rq[64], crk[64], crq[64], siv[64], sov[64];
  __shared__ float rd[2][4][64];
  size_t base = ((size_t)bh * LSEQ + c * 64) * DHD;
  const u16* qb = q + base; const u16* kb = k + base;
  for (int c4 = tid; c4 < 1024; c4 += 256){
    int l = c4 >> 4, d0 = (c4 & 15) * 4;
    ushort4 qv = *reinterpret_cast<const ushort4*>(qb + c4 * 4);
    qT[d0+0][l] = bf2f(qv.x); qT[d0+1][l] = bf2f(qv.y);
    qT[d0+2][l] = bf2f(qv.z); qT[d0+3][l] = bf2f(qv.w);
    ushort4 kv = *reinterpret_cast<const ushort4*>(kb + c4 * 4);
    kT[d0+0][l] = bf2f(kv.x); kT[d0+1][l] = bf2f(kv.y);
    kT[d0+2][l] = bf2f(kv.z); kT[d0+3][l] = bf2f(kv.w);
  }
  if (tid < 64){
    float pk = 0.f, pq = 0.f;
    for (int cc = 0; cc < c; cc++){
      pk += ck[((size_t)bh * 16 + cc) * 64 + tid];
      pq += cq[((size_t)bh * 16 + cc) * 64 + tid];
    }
    PK[tid] = pk; PQ[tid] = pq;
  }
  __syncthreads();
  float sumPK = wred64(PK[lane]);
  float sumPQ = wred64(PQ[lane]);
  {
    int l = lane, g = wave;
    float qrow[64];
#pragma unroll
    for (int d = 0; d < 64; d++) qrow[d] = qT[d][l];
    float p[16] = {};
    for (int d = 0; d < 64; d++){
      float qv = qrow[d];
#pragma unroll
      for (int j4 = 0; j4 < 4; j4++){
        float4 kk = *reinterpret_cast<const float4*>(&kT[d][g * 16 + j4 * 4]);
        p[j4*4+0] += qv * kk.x; p[j4*4+1] += qv * kk.y;
        p[j4*4+2] += qv * kk.z; p[j4*4+3] += qv * kk.w;
      }
    }
#pragma unroll
    for (int jj = 0; jj < 16; jj++) G[l][g * 16 + jj] = p[jj];
  }
  {
    float pk_ = 0.f, pq_ = 0.f;
#pragma unroll
    for (int d = wave * 16; d < wave * 16 + 16; d++){
      pk_ += kT[d][lane]; pq_ += qT[d][lane];
    }
    rd[0][wave][lane] = pk_; rd[1][wave][lane] = pq_;
  }
  __syncthreads();
  if (tid < 64){
    rk[tid] = rd[0][0][tid] + rd[0][1][tid] + rd[0][2][tid] + rd[0][3][tid];
    rq[tid] = rd[1][0][tid] + rd[1][1][tid] + rd[1][2][tid] + rd[1][3][tid];
  }
  __syncthreads();
  if (wave == 0)      crk[lane] = wscan64(rk[lane], lane);
  else if (wave == 1) crq[lane] = wscan64(rq[lane], lane);
  __syncthreads();
  {
    int l = lane;
    float p1 = 0.f, p2 = 0.f;
#pragma unroll
    for (int j = wave * 16; j < wave * 16 + 16; j++){
      float g1 = (j <= l) ? G[l][j] : 0.f;
      p1 += g1 + qT[j][l] * PK[j];
      float g2 = (j <= l) ? G[j][l] : 0.f;
      p2 += g2 + kT[j][l] * PQ[j];
    }
    rd[0][wave][l] = p1; rd[1][wave][l] = p2;
  }
  __syncthreads();
  const float EPS2 = 64.f * EPS * EPS;
  if (tid < 64){
    int l = tid;
    float s1 = rd[0][0][l] + rd[0][1][l] + rd[0][2][l] + rd[0][3][l];
    float s2 = rd[1][0][l] + rd[1][1][l] + rd[1][2][l] + rd[1][3][l];
    int L = c * 64 + l; float nrm = (float)(L + 1);
    float den1 = s1 + EPS * rq[l] + EPS * (sumPK + crk[l]) + EPS2;
    float den2 = s2 + EPS * rk[l] + EPS * (sumPQ + crq[l]) + EPS2;
    float si_ = nrm / den1, so_ = nrm / den2;
    sink_in[(size_t)bh * LSEQ + L] = si_;
    src_out[(size_t)bh * LSEQ + L] = so_;
    siv[l] = si_; sov[l] = so_;
  }
  __syncthreads();
  float s1 = 0.f, s2 = 0.f;
  for (int l = wave * 16; l < wave * 16 + 16; l++){
    s1 += sov[l] * kT[lane][l];
    s2 += siv[l] * qT[lane][l];
  }
  rd[0][wave][lane] = s1; rd[1][wave][lane] = s2;
  __syncthreads();
  if (wave == 0){
    cso [(size_t)blk * 64 + lane] = rd[0][0][lane] + rd[0][1][lane] + rd[0][2][lane] + rd[0][3][lane];
    cqsi[(size_t)blk * 64 + lane] = rd[1][0][lane] + rd[1][1][lane] + rd[1][2][lane] + rd[1][3][lane];
  }
}

__global__ __launch_bounds__(256) void cons_tile(
    const u16* __restrict__ q, const u16* __restrict__ k,
    const float* __restrict__ cso, const float* __restrict__ cqsi,
    const float* __restrict__ sink_in, const float* __restrict__ src_out,
    float* __restrict__ sa, float* __restrict__ ebuf)
{
  int blk = blockIdx.x, bh = blk >> 4, c = blk & 15;
  int tid = threadIdx.x, lane = tid & 63, wave = tid >> 6;
  __shared__ float qT[64][65], kT[64][65], G[64][66];
  __shared__ float PKso[64], PQsi[64];
  __shared__ float rk[64], rq[64], cwrk[64], cwrq[64], siv[64], sov[64];
  __shared__ float rd[2][4][64];
  size_t base = ((size_t)bh * LSEQ + c * 64) * DHD;
  const u16* qb = q + base; const u16* kb = k + base;
  for (int c4 = tid; c4 < 1024; c4 += 256){
    int l = c4 >> 4, d0 = (c4 & 15) * 4;
    ushort4 qv = *reinterpret_cast<const ushort4*>(qb + c4 * 4);
    qT[d0+0][l] = bf2f(qv.x); qT[d0+1][l] = bf2f(qv.y);
    qT[d0+2][l] = bf2f(qv.z); qT[d0+3][l] = bf2f(qv.w);
    ushort4 kv = *reinterpret_cast<const ushort4*>(kb + c4 * 4);
    kT[d0+0][l] = bf2f(kv.x); kT[d0+1][l] = bf2f(kv.y);
    kT[d0+2][l] = bf2f(kv.z); kT[d0+3][l] = bf2f(kv.w);
  }
  if (tid < 64){
    float pk = 0.f, pq = 0.f;
    for (int cc = 0; cc < c; cc++){
      pk += cso [((size_t)bh * 16 + cc) * 64 + tid];
      pq += cqsi[((size_t)bh * 16 + cc) * 64 + tid];
    }
    PKso[tid] = pk; PQsi[tid] = pq;
  } else if (tid < 128){
    int l = tid - 64;
    sov[l] = src_out[(size_t)bh * LSEQ + c * 64 + l];
    siv[l] = sink_in[(size_t)bh * LSEQ + c * 64 + l];
  }
  __syncthreads();
  float sumPKso = wred64(PKso[lane]);
  float sumPQsi = wred64(PQsi[lane]);
  {
    int l = lane, g = wave;
    float qrow[64];
#pragma unroll
    for (int d = 0; d < 64; d++) qrow[d] = qT[d][l];
    float p[16] = {};
    for (int d = 0; d < 64; d++){
      float qv = qrow[d];
#pragma unroll
      for (int j4 = 0; j4 < 4; j4++){
        float4 kk = *reinterpret_cast<const float4*>(&kT[d][g * 16 + j4 * 4]);
        p[j4*4+0] += qv * kk.x; p[j4*4+1] += qv * kk.y;
        p[j4*4+2] += qv * kk.z; p[j4*4+3] += qv * kk.w;
      }
    }
#pragma unroll
    for (int jj = 0; jj < 16; jj++) G[l][g * 16 + jj] = p[jj];
  }
  {
    float pk_ = 0.f, pq_ = 0.f;
#pragma unroll
    for (int d = wave * 16; d < wave * 16 + 16; d++){
      pk_ += kT[d][lane]; pq_ += qT[d][lane];
    }
    rd[0][wave][lane] = pk_; rd[1][wave][lane] = pq_;
  }
  __syncthreads();
  if (tid < 64){
    rk[tid] = rd[0][0][tid] + rd[0][1][tid] + rd[0][2][tid] + rd[0][3][tid];
    rq[tid] = rd[1][0][tid] + rd[1][1][tid] + rd[1][2][tid] + rd[1][3][tid];
  }
  __syncthreads();
  if (wave == 0)      cwrk[lane] = wscan64(sov[lane] * rk[lane], lane);
  else if (wave == 1) cwrq[lane] = wscan64(siv[lane] * rq[lane], lane);
  __syncthreads();
  {
    int l = lane;
    float p3 = 0.f, p4 = 0.f;
#pragma unroll
    for (int j = wave * 16; j < wave * 16 + 16; j++){
      float g3 = (j <= l) ? sov[j] * G[l][j] : 0.f;
      p3 += g3 + qT[j][l] * PKso[j];
      float g4 = (j <= l) ? siv[j] * G[j][l] : 0.f;
      p4 += g4 + kT[j][l] * PQsi[j];
    }
    rd[0][wave][l] = p3; rd[1][wave][l] = p4;
  }
  __syncthreads();
  const float EPS2 = 64.f * EPS * EPS;
  if (tid < 64){
    int l = tid;
    float s3 = rd[0][0][l] + rd[0][1][l] + rd[0][2][l] + rd[0][3][l];
    float s4 = rd[1][0][l] + rd[1][1][l] + rd[1][2][l] + rd[1][3][l];
    int L = c * 64 + l; float nrm = (float)(L + 1);
    float cs = (s3 + EPS * rq[l] + EPS * (sumPKso + cwrk[l]) + EPS2) / nrm;
    sa[(size_t)bh * LSEQ + L] = fast_sigmoid(cs);
    float c2 = (s4 + EPS * rk[l] + EPS * (sumPQsi + cwrq[l]) + EPS2) / nrm;
    c2 = fminf(1.f, fmaxf(-1.f, c2));
    ebuf[(size_t)bh * LSEQ + L] = __expf(c2);
  }
}

// src_comp = e / cumsum(e) * (l+1)
__global__ __launch_bounds__(64) void srccomp_kernel(const float* __restrict__ ebuf, float* __restrict__ sc){
  int bh = blockIdx.x; int lane = threadIdx.x;
  const float* eb = ebuf + (size_t)bh * LSEQ;
  float loc[16]; float s = 0.f;
#pragma unroll
  for (int i = 0; i < 16; i++){ loc[i] = eb[lane * 16 + i]; s += loc[i]; }
  float run = wscan64(s, lane);
  float acc = run - s;
  float* scb = sc + (size_t)bh * LSEQ;
#pragma unroll
  for (int i = 0; i < 16; i++){
    acc += loc[i];
    scb[lane * 16 + i] = loc[i] / acc * (float)(lane * 16 + i + 1);
  }
}

// ---------------- chunked causal linear attention (scale fused in, bf16 in) ------
__global__ __launch_bounds__(256) void phaseA(const u16* __restrict__ k, const u16* __restrict__ v,
                                              const float* __restrict__ sc, float* __restrict__ S){
  int blk = blockIdx.x; int bh = blk >> 4, c = blk & 15;
  __shared__ float ks[64][68], vss[64][68];
  __shared__ float vc[64];
  int tid = threadIdx.x;
  size_t base = ((size_t)bh * LSEQ + c * 64) * DHD;
  const u16* kb = k + base; const u16* vb = v + base;
  if (tid < 64) vc[tid] = sc[(size_t)bh * LSEQ + c * 64 + tid];
  __syncthreads();
  for (int c4 = tid; c4 < 1024; c4 += 256){
    int l = c4 >> 4, d0 = (c4 & 15) * 4;
    ushort4 kv = *reinterpret_cast<const ushort4*>(kb + c4 * 4);
    ks[l][d0+0] = bf2f(kv.x); ks[l][d0+1] = bf2f(kv.y);
    ks[l][d0+2] = bf2f(kv.z); ks[l][d0+3] = bf2f(kv.w);
    ushort4 vv = *reinterpret_cast<const ushort4*>(vb + c4 * 4);
    float w = vc[l];
    vss[l][d0+0] = bf2f(vv.x) * w; vss[l][d0+1] = bf2f(vv.y) * w;
    vss[l][d0+2] = bf2f(vv.z) * w; vss[l][d0+3] = bf2f(vv.w) * w;
  }
  __syncthreads();
  int m = tid >> 2, dg = tid & 3;
  float acc[16] = {};
  for (int l = 0; l < 64; l++){
    float vm = vss[l][m];
#pragma unroll
    for (int d4 = 0; d4 < 4; d4++){
      float4 kk = *reinterpret_cast<const float4*>(&ks[l][dg * 16 + d4 * 4]);
      acc[d4*4+0] += vm * kk.x; acc[d4*4+1] += vm * kk.y;
      acc[d4*4+2] += vm * kk.z; acc[d4*4+3] += vm * kk.w;
    }
  }
  float* Sb = S + (size_t)blk * 4096 + m * 64 + dg * 16;
#pragma unroll
  for (int d4 = 0; d4 < 4; d4++)
    *reinterpret_cast<float4*>(Sb + d4 * 4) =
        make_float4(acc[d4*4], acc[d4*4+1], acc[d4*4+2], acc[d4*4+3]);
}

// phase C with inlined KV-prefix; Ps overlays qsT (qrow registers cached first)
__global__ __launch_bounds__(256) void phaseC(const u16* __restrict__ q, const u16* __restrict__ k,
                                              const u16* __restrict__ v, const float* __restrict__ S,
                                              const float* __restrict__ sink_in, const float* __restrict__ sc,
                                              const float* __restrict__ sa, u16* __restrict__ x){
  int blk = blockIdx.x; int bh = blk >> 4, c = blk & 15;
  int b = bh >> 4, h = bh & 15;
  __shared__ float qp[64][66];      // qsT[d][l] first, then Ps[l][j]
  __shared__ float kT[64][68];
  __shared__ float vss[64][68];
  __shared__ float kvs[64][68];
  __shared__ float qc[64], vc[64];
  int tid = threadIdx.x;
  size_t base = ((size_t)bh * LSEQ + c * 64) * DHD;
  const u16* qb = q + base; const u16* kb = k + base; const u16* vb = v + base;
  if (tid < 64){
    int L = c * 64 + tid;
    qc[tid] = sink_in[(size_t)bh * LSEQ + L] / (float)(L + 1);
    vc[tid] = sc[(size_t)bh * LSEQ + L];
  }
  {
    int off16 = tid * 16;
    float accp[16] = {};
    for (int cc = 0; cc < c; cc++){
      size_t idx = ((size_t)bh * 16 + cc) * 4096 + off16;
#pragma unroll
      for (int t4 = 0; t4 < 4; t4++){
        float4 sv = *reinterpret_cast<const float4*>(S + idx + t4 * 4);
        accp[t4*4+0] += sv.x; accp[t4*4+1] += sv.y;
        accp[t4*4+2] += sv.z; accp[t4*4+3] += sv.w;
      }
    }
#pragma unroll
    for (int e = 0; e < 16; e++){
      int j = off16 + e;
      kvs[j >> 6][j & 63] = accp[e];
    }
  }
  __syncthreads();
  for (int c4 = tid; c4 < 1024; c4 += 256){
    int l = c4 >> 4, d0 = (c4 & 15) * 4;
    float qw = qc[l], vw = vc[l];
    ushort4 qv = *reinterpret_cast<const ushort4*>(qb + c4 * 4);
    qp[d0+0][l] = bf2f(qv.x) * qw; qp[d0+1][l] = bf2f(qv.y) * qw;
    qp[d0+2][l] = bf2f(qv.z) * qw; qp[d0+3][l] = bf2f(qv.w) * qw;
    ushort4 kv4 = *reinterpret_cast<const ushort4*>(kb + c4 * 4);
    kT[d0+0][l] = bf2f(kv4.x); kT[d0+1][l] = bf2f(kv4.y);
    kT[d0+2][l] = bf2f(kv4.z); kT[d0+3][l] = bf2f(kv4.w);
    ushort4 vv = *reinterpret_cast<const ushort4*>(vb + c4 * 4);
    vss[l][d0+0] = bf2f(vv.x) * vw; vss[l][d0+1] = bf2f(vv.y) * vw;
    vss[l][d0+2] = bf2f(vv.z) * vw; vss[l][d0+3] = bf2f(vv.w) * vw;
  }
  __syncthreads();
  int l = tid & 63, g = tid >> 6;
  float qrow[64];
#pragma unroll
  for (int d = 0; d < 64; d++) qrow[d] = qp[d][l];
  __syncthreads();

  float p[16] = {};
  for (int d = 0; d < 64; d++){
    float qv = qrow[d];
#pragma unroll
    for (int j4 = 0; j4 < 4; j4++){
      float4 kk = *reinterpret_cast<const float4*>(&kT[d][g * 16 + j4 * 4]);
      p[j4*4+0] += qv * kk.x; p[j4*4+1] += qv * kk.y;
      p[j4*4+2] += qv * kk.z; p[j4*4+3] += qv * kk.w;
    }
  }
#pragma unroll
  for (int jj = 0; jj < 16; jj++){
    int j = g * 16 + jj;
    qp[l][j] = (j <= l) ? p[jj] : 0.f;
  }
  __syncthreads();

  float acc[16];
#pragma unroll
  for (int mm = 0; mm < 16; mm++){
    float a = 0.f;
#pragma unroll
    for (int d4 = 0; d4 < 16; d4++){
      float4 kv4 = *reinterpret_cast<const float4*>(&kvs[g * 16 + mm][d4 * 4]);
      a += qrow[d4*4+0]*kv4.x + qrow[d4*4+1]*kv4.y + qrow[d4*4+2]*kv4.z + qrow[d4*4+3]*kv4.w;
    }
    acc[mm] = a;
  }
  for (int j = 0; j < 64; j++){
    float pv = qp[l][j];
#pragma unroll
    for (int m4 = 0; m4 < 4; m4++){
      float4 vv = *reinterpret_cast<const float4*>(&vss[j][g * 16 + m4 * 4]);
      acc[m4*4+0] += pv * vv.x; acc[m4*4+1] += pv * vv.y;
      acc[m4*4+2] += pv * vv.z; acc[m4*4+3] += pv * vv.w;
    }
  }
  float sav = sa[(size_t)bh * LSEQ + c * 64 + l];
  u16* xo = x + ((size_t)(b * 1024 + c * 64 + l)) * 1024 + h * 64 + g * 16;
#pragma unroll
  for (int mm = 0; mm < 16; mm++) xo[mm] = f2bf(acc[mm] * sav);
}

// ---------------- fused layernorms ----------------
// LN over (bf16 p0+p1 + bias + resid); emits f32 + bf16 (Wo split-K + LN1)
__global__ __launch_bounds__(256) void ln_fused2b(
    const u16* __restrict__ p0, const u16* __restrict__ p1,
    const float* __restrict__ resid, const float* __restrict__ bias,
    const float* __restrict__ g, const float* __restrict__ b,
    float* __restrict__ out, u16* __restrict__ outbf){
  int row = blockIdx.x; int tid = threadIdx.x;
  int lane = tid & 63, wave = tid >> 6;
  size_t off = (size_t)row * 1024 + tid * 4;
  ushort4 a0 = *reinterpret_cast<const ushort4*>(p0 + off);
  ushort4 a1 = *reinterpret_cast<const ushort4*>(p1 + off);
  float4 rr = *reinterpret_cast<const float4*>(resid + off);
  float4 bb = *reinterpret_cast<const float4*>(bias + tid * 4);
  float4 v = make_float4(bf2f(a0.x) + bf2f(a1.x) + rr.x + bb.x,
                         bf2f(a0.y) + bf2f(a1.y) + rr.y + bb.y,
                         bf2f(a0.z) + bf2f(a1.z) + rr.z + bb.z,
                         bf2f(a0.w) + bf2f(a1.w) + rr.w + bb.w);
  float s = v.x + v.y + v.z + v.w;
  float s2 = v.x*v.x + v.y*v.y + v.z*v.z + v.w*v.w;
  s = wred64(s); s2 = wred64(s2);
  __shared__ float red[2][4];
  if (lane == 0){ red[0][wave] = s; red[1][wave] = s2; }
  __syncthreads();
  float S = red[0][0] + red[0][1] + red[0][2] + red[0][3];
  float S2 = red[1][0] + red[1][1] + red[1][2] + red[1][3];
  float mean = S * (1.f / 1024.f);
  float var = S2 * (1.f / 1024.f) - mean * mean;
  float inv = rsqrtf(var + 1e-5f);
  float4 gv = *reinterpret_cast<const float4*>(g + tid * 4);
  float4 bv = *reinterpret_cast<const float4*>(b + tid * 4);
  float y0 = (v.x - mean) * inv * gv.x + bv.x;
  float y1 = (v.y - mean) * inv * gv.y + bv.y;
  float y2 = (v.z - mean) * inv * gv.z + bv.z;
  float y3 = (v.w - mean) * inv * gv.w + bv.w;
  *reinterpret_cast<float4*>(out + off) = make_float4(y0, y1, y2, y3);
  ushort4 o; o.x = f2bf(y0); o.y = f2bf(y1); o.z = f2bf(y2); o.w = f2bf(y3);
  *reinterpret_cast<ushort4*>(outbf + off) = o;
}

// LN over (bf16 p0..p3 + bias + resid) -> f32 out (FFN2 split-K4 combine + LN2)
__global__ __launch_bounds__(256) void ln_fused4b(
    const u16* __restrict__ p0, const u16* __restrict__ p1,
    const u16* __restrict__ p2, const u16* __restrict__ p3,
    const float* __restrict__ resid, const float* __restrict__ bias,
    const float* __restrict__ g, const float* __restrict__ b,
    float* __restrict__ out){
  int row = blockIdx.x; int tid = threadIdx.x;
  int lane = tid & 63, wave = tid >> 6;
  size_t off = (size_t)row * 1024 + tid * 4;
  ushort4 u0 = *reinterpret_cast<const ushort4*>(p0 + off);
  ushort4 u1 = *reinterpret_cast<const ushort4*>(p1 + off);
  ushort4 u2 = *reinterpret_cast<const ushort4*>(p2 + off);
  ushort4 u3 = *reinterpret_cast<const ushort4*>(p3 + off);
  float4 rr = *reinterpret_cast<const float4*>(resid + off);
  float4 bb = *reinterpret_cast<const float4*>(bias + tid * 4);
  float4 v = make_float4(
      bf2f(u0.x) + bf2f(u1.x) + bf2f(u2.x) + bf2f(u3.x) + rr.x + bb.x,
      bf2f(u0.y) + bf2f(u1.y) + bf2f(u2.y) + bf2f(u3.y) + rr.y + bb.y,
      bf2f(u0.z) + bf2f(u1.z) + bf2f(u2.z) + bf2f(u3.z) + rr.z + bb.z,
      bf2f(u0.w) + bf2f(u1.w) + bf2f(u2.w) + bf2f(u3.w) + rr.w + bb.w);
  float s = v.x + v.y + v.z + v.w;
  float s2 = v.x*v.x + v.y*v.y + v.z*v.z + v.w*v.w;
  s = wred64(s); s2 = wred64(s2);
  __shared__ float red[2][4];
  if (lane == 0){ red[0][wave] = s; red[1][wave] = s2; }
  __syncthreads();
  float S = red[0][0] + red[0][1] + red[0][2] + red[0][3];
  float S2 = red[1][0] + red[1][1] + red[1][2] + red[1][3];
  float mean = S * (1.f / 1024.f);
  float var = S2 * (1.f / 1024.f) - mean * mean;
  float inv = rsqrtf(var + 1e-5f);
  float4 gv = *reinterpret_cast<const float4*>(g + tid * 4);
  float4 bv = *reinterpret_cast<const float4*>(b + tid * 4);
  float y0 = (v.x - mean) * inv * gv.x + bv.x;
  float y1 = (v.y - mean) * inv * gv.y + bv.y;
  float y2 = (v.z - mean) * inv * gv.z + bv.z;
  float y3 = (v.w - mean) * inv * gv.w + bv.w;
  *reinterpret_cast<float4*>(out + off) = make_float4(y0, y1, y2, y3);
}

// ---------------- launch ----------------
extern "C" void kernel_launch(void* const* d_in, const int* in_sizes, int n_in,
                              void* d_out, int out_size, void* d_ws, size_t ws_size,
                              hipStream_t stream){
  (void)in_sizes; (void)n_in; (void)out_size; (void)ws_size;
  const float* inputs = (const float*)d_in[0];
  const float* Wq = (const float*)d_in[2];  const float* bq = (const float*)d_in[3];
  const float* Wk = (const float*)d_in[4];  const float* bk = (const float*)d_in[5];
  const float* Wv = (const float*)d_in[6];  const float* bv = (const float*)d_in[7];
  const float* Wo = (const float*)d_in[8];  const float* bo = (const float*)d_in[9];
  const float* ln1g = (const float*)d_in[10]; const float* ln1b = (const float*)d_in[11];
  const float* W1 = (const float*)d_in[12]; const float* b1 = (const float*)d_in[13];
  const float* W2 = (const float*)d_in[14]; const float* b2 = (const float*)d_in[15];
  const float* ln2g = (const float*)d_in[16]; const float* ln2b = (const float*)d_in[17];
  float* out = (float*)d_out;

  char* wsp = (char*)d_ws; size_t off = 0;
  auto alloc = [&](size_t bytes) -> void* {
    off = (off + 255) & ~(size_t)255;
    void* p = wsp + off; off += bytes; return p;
  };
  const size_t MD = (size_t)2048 * 1024;
  u16* Xbf    = (u16*)alloc(MD * 2);
  u16* WqkvT  = (u16*)alloc((size_t)3 * 1024 * 1024 * 2);
  u16* WoT    = (u16*)alloc((size_t)1024 * 1024 * 2);
  u16* W1T    = (u16*)alloc((size_t)4096 * 1024 * 2);
  u16* W2T    = (u16*)alloc((size_t)4096 * 1024 * 2);
  float* bqkv = (float*)alloc(3072 * 4);
  u16* qkvb   = (u16*)alloc(3 * MD * 2);     // bf16 q|k|v in [B,H,L,DH]
  u16* qb = qkvb; u16* kb = qkvb + MD; u16* vb = qkvb + 2 * MD;
  float* quad = (float*)alloc(4 * MD * 4);
  float* Sbuf = quad;
  float* ckb  = (float*)alloc((size_t)512 * 64 * 4);   // contiguous with cqb
  float* cqb  = (float*)alloc((size_t)512 * 64 * 4);
  float* csob = (float*)alloc((size_t)512 * 64 * 4);
  float* cqsib= (float*)alloc((size_t)512 * 64 * 4);
  float* sink_in = (float*)alloc(NBH * LSEQ * 4);
  float* src_out = (float*)alloc(NBH * LSEQ * 4);
  float* sabuf   = (float*)alloc(NBH * LSEQ * 4);
  float* ebuf    = (float*)alloc(NBH * LSEQ * 4);
  float* scbuf   = (float*)alloc(NBH * LSEQ * 4);
  u16* xatt   = (u16*)alloc(MD * 2);
  u16* g1     = (u16*)alloc((size_t)2048 * 4096 * 2);
  // quad reuse: slot0 Sbuf -> hbuf (f32 LN1 out); slot1 hbf (bf16 LN1 out);
  // slot2 wopart (bf16 x2 = 8MB); slots2-3 FFN2 bf16 partials (16MB)
  float* hbuf  = quad;
  u16* hbf     = (u16*)(quad + MD);
  u16* wopart  = (u16*)(quad + 2 * MD);
  u16* partb   = (u16*)(quad + 2 * MD);

  // all prep in one launch (+64 blocks zeroing ckb||cqb)
  prep_all<<<14412, 256, 0, stream>>>(inputs, Xbf, Wq, Wk, Wv, Wo, WqkvT, WoT,
                                      W1, W2, W1T, W2T, bq, bk, bv, bqkv, ckb);

  // fused QKV projection (bf16 out) + chunk-sum atomics: BM=128,BN=64, grid 16x48
  gemm_mfma<128, 64, 0, 1><<<dim3(16, 48), 256, 0, stream>>>(
      Xbf, WqkvT, bqkv, nullptr, nullptr, qkvb, cqb, ckb, 2048, 3072, 1024);

  // attention scalars (chunked Gram-tile pipeline, bf16 inputs)
  sink_tile<<<512, 256, 0, stream>>>(qb, kb, ckb, cqb, sink_in, src_out, csob, cqsib);
  cons_tile<<<512, 256, 0, stream>>>(qb, kb, csob, cqsib, sink_in, src_out, sabuf, ebuf);
  srccomp_kernel<<<32, 64, 0, stream>>>(ebuf, scbuf);

  // chunked causal linear attention (scale fused; KV-prefix inlined in phaseC)
  phaseA<<<512, 256, 0, stream>>>(kb, vb, scbuf, Sbuf);
  phaseC<<<512, 256, 0, stream>>>(qb, kb, vb, Sbuf, sink_in, scbuf, sabuf, xatt);

  // output projection: BM=128,BN=64, split-K=2, bf16 partials
  gemm_mfma<128, 64, 0, 5><<<dim3(16, 16, 2), 256, 0, stream>>>(
      xatt, WoT, nullptr, nullptr, nullptr, wopart, nullptr, nullptr, 2048, 1024, 1024);
  ln_fused2b<<<2048, 256, 0, stream>>>(wopart, wopart + MD, inputs, bo, ln1g, ln1b, hbuf, hbf);

  // FFN1: BM=128,BN=128 (fast gelu)
  gemm_mfma<128, 128, 2, 3><<<dim3(16, 32), 256, 0, stream>>>(
      hbf, W1T, b1, nullptr, nullptr, g1, nullptr, nullptr, 2048, 4096, 1024);
  // FFN2: BM=128,BN=128, split-K=4, bf16 partials
  gemm_mfma<128, 128, 0, 5><<<dim3(16, 8, 4), 256, 0, stream>>>(
      g1, W2T, nullptr, nullptr, nullptr, partb, nullptr, nullptr, 2048, 1024, 4096);
  ln_fused4b<<<2048, 256, 0, stream>>>(partb, partb + MD, partb + 2 * MD, partb + 3 * MD,
                                       hbuf, b2, ln2g, ln2b, out);
}

// Round 17
// 187.829 us; speedup vs baseline: 1.5351x; 1.0183x over previous
//
#include <hip/hip_runtime.h>
#include <hip/hip_bf16.h>

// ---------------- constants ----------------
#define EPS 1e-6f
#define NBH 32      // B*H
#define LSEQ 1024
#define DHD 64

typedef unsigned short u16;
typedef __bf16 bf16x8 __attribute__((ext_vector_type(8)));
typedef float f32x4 __attribute__((ext_vector_type(4)));

__device__ inline u16 f2bf(float f){
  union { float f; unsigned u; } un; un.f = f;
  unsigned u = un.u;
  u += 0x7fffu + ((u >> 16) & 1u);
  return (u16)(u >> 16);
}

__device__ inline float bf2f(u16 v){
  union { unsigned u; float f; } un; un.u = ((unsigned)v) << 16; return un.f;
}

__device__ inline float wred64(float v){
#pragma unroll
  for (int off = 32; off > 0; off >>= 1) v += __shfl_xor(v, off, 64);
  return v;
}

__device__ inline float wscan64(float v, int lane){
  float run = v;
#pragma unroll
  for (int off = 1; off < 64; off <<= 1){
    float t = __shfl_up(run, off, 64);
    if (lane >= off) run += t;
  }
  return run;   // inclusive
}

__device__ inline float fast_sigmoid(float x){
  return 1.f / (1.f + __expf(-x));
}

__device__ inline void gload_lds16(const u16* g, u16* l){
  __builtin_amdgcn_global_load_lds(
      (const __attribute__((address_space(1))) unsigned int*)g,
      (__attribute__((address_space(3))) unsigned int*)l, 16, 0, 0);
}

// ---------------- mega prep kernel (f2bf + 6 transposes + bias + zero) -------
__device__ inline void tr_tile2(const float* in, u16* out, int R, int C, int r0, int c0){
  __shared__ float tile[32][33];
  int x = threadIdx.x & 31, y = threadIdx.x >> 5;
#pragma unroll
  for (int j = 0; j < 4; j++)
    tile[y + j*8][x] = in[(size_t)(r0 + y + j*8) * C + c0 + x];
  __syncthreads();
#pragma unroll
  for (int j = 0; j < 4; j++)
    out[(size_t)(c0 + y + j*8) * R + r0 + x] = f2bf(tile[x][y + j*8]);
}

// blocks: [0,2048) f2bf inputs; [2048,6144) Wq/Wk/Wv/Wo transposes;
// [6144,14336) W1/W2 transposes; [14336,14348) bias gather;
// [14348,14412) zero ckb||cqb (contiguous 256KB)
__global__ __launch_bounds__(256) void prep_all(
    const float* __restrict__ inputs, u16* __restrict__ Xbf,
    const float* __restrict__ Wq, const float* __restrict__ Wk,
    const float* __restrict__ Wv, const float* __restrict__ Wo,
    u16* __restrict__ dqkv, u16* __restrict__ dwo,
    const float* __restrict__ W1, const float* __restrict__ W2,
    u16* __restrict__ d1, u16* __restrict__ d2,
    const float* __restrict__ bq, const float* __restrict__ bk,
    const float* __restrict__ bv, float* __restrict__ bqkv,
    float* __restrict__ ckq_zero)
{
  int b = blockIdx.x;
  if (b < 2048){
    int i = b * 256 + threadIdx.x;
    float4 v = reinterpret_cast<const float4*>(inputs)[i];
    ushort4 o; o.x = f2bf(v.x); o.y = f2bf(v.y); o.z = f2bf(v.z); o.w = f2bf(v.w);
    reinterpret_cast<ushort4*>(Xbf)[i] = o;
  } else if (b < 6144){
    int t = b - 2048;
    int z = t >> 10, rem = t & 1023;
    int bx = rem & 31, by = rem >> 5;
    const float* in = (z == 0) ? Wq : (z == 1) ? Wk : (z == 2) ? Wv : Wo;
    u16* out = (z < 3) ? (dqkv + (size_t)z * 1024 * 1024) : dwo;
    tr_tile2(in, out, 1024, 1024, by * 32, bx * 32);
  } else if (b < 14336){
    int t = b - 6144;
    int z = t >> 12, rem = t & 4095;
    int bx = rem & 127, by = rem >> 7;
    if (z == 0) tr_tile2(W1, d1, 1024, 4096, by * 32, bx * 32);
    else        tr_tile2(W2, d2, 4096, 1024, bx * 32, by * 32);
  } else if (b < 14348){
    int i = (b - 14336) * 256 + threadIdx.x;
    if (i < 3072){
      float v = (i < 1024) ? bq[i] : (i < 2048) ? bk[i - 1024] : bv[i - 2048];
      bqkv[i] = v;
    }
  } else {
    int i = (b - 14348) * 256 + threadIdx.x;
    reinterpret_cast<float4*>(ckq_zero)[i] = make_float4(0.f, 0.f, 0.f, 0.f);
  }
}

// ---------------- bf16 MFMA GEMM (dbuf + counted vmcnt, T2 XOR-swizzled LDS) ----
// C[M,N] = act(A[M,K] @ Bt[N,K]^T + bias)
// LDS: BK=64 bf16 rows = 8 x 16B slots; slot s of row r at phys slot s^(r&7)
// (rule #21: linear gload_lds dest + pre-swizzled SOURCE + swizzled READ).
// Pipeline: STAGE(next) before compute(cur); counted vmcnt across the barrier.
// ACT: 0 none, 2 gelu  (OM==1 applies fast sigmoid for col<2048 internally)
// OM: 1 fused-QKV bf16 remap to 3x[B,H,L,DH] + chunk-sum atomics into cq/ck;
//     3 bf16 [M][N]; 4 raw f32 partial (slice z at outF + z*M*N);
//     5 bf16 partial (slice z at outB + z*M*N)
template<int BM, int BN, int ACT, int OM>
__global__ __launch_bounds__(256) void gemm_mfma(
    const u16* __restrict__ A, const u16* __restrict__ Bt,
    const float* __restrict__ bias, const float* __restrict__ resid,
    float* __restrict__ outF, u16* __restrict__ outB,
    float* __restrict__ cqA, float* __restrict__ ckA,
    int M, int N, int K)
{
  constexpr int BK = 64;
  constexpr int MI = BM / 32;
  constexpr int NJ = BN / 32;
  constexpr int RA = BM / 32;
  constexpr int RB = BN / 32;
  constexpr int NS = RA + RB;
  __shared__ u16 As[2][BM * BK];
  __shared__ u16 Bs[2][BN * BK];
  const int tid = threadIdx.x;
  const int lane = tid & 63, wave = tid >> 6;
  const int lrow = lane & 15, lg = lane >> 4;
  const int m0 = blockIdx.x * BM, n0 = blockIdx.y * BN;
  const int wm = (wave >> 1) * (BM / 2), wn = (wave & 1) * (BN / 2);

  const int ksz = K / gridDim.z;
  const int k_begin = blockIdx.z * ksz;
  const int k_end = k_begin + ksz;

  f32x4 acc[MI][NJ];
#pragma unroll
  for (int i = 0; i < MI; i++)
#pragma unroll
    for (int j = 0; j < NJ; j++) acc[i][j] = (f32x4){0.f, 0.f, 0.f, 0.f};

  const u16* Ab = A + (size_t)m0 * K;
  const u16* Bb = Bt + (size_t)n0 * K;

  const int s0 = ((0 * 4 + lg) ^ (lrow & 7)) * 8;
  const int s1 = ((1 * 4 + lg) ^ (lrow & 7)) * 8;

  auto STAGE = [&](int buf, int k0){
#pragma unroll
    for (int r = 0; r < RA; ++r){
      int c = r * 256 + tid;
      int row = c >> 3;
      int kk = ((c ^ row) & 7) << 3;
      gload_lds16(Ab + (size_t)row * K + k0 + kk, &As[buf][(r * 256 + wave * 64) * 8]);
    }
#pragma unroll
    for (int r = 0; r < RB; ++r){
      int c = r * 256 + tid;
      int row = c >> 3;
      int kk = ((c ^ row) & 7) << 3;
      gload_lds16(Bb + (size_t)row * K + k0 + kk, &Bs[buf][(r * 256 + wave * 64) * 8]);
    }
  };

  STAGE(0, k_begin);
  int cur = 0;
  for (int k0 = k_begin; k0 < k_end; k0 += BK){
    if (k0 + BK < k_end){
      STAGE(cur ^ 1, k0 + BK);
      if constexpr (NS == 8)      asm volatile("s_waitcnt vmcnt(8)" ::: "memory");
      else if constexpr (NS == 6) asm volatile("s_waitcnt vmcnt(6)" ::: "memory");
      else                        asm volatile("s_waitcnt vmcnt(0)" ::: "memory");
    } else {
      asm volatile("s_waitcnt vmcnt(0)" ::: "memory");
    }
    __builtin_amdgcn_s_barrier();
    __builtin_amdgcn_sched_barrier(0);
#pragma unroll
    for (int kh = 0; kh < 2; ++kh){
      const int ss = (kh == 0) ? s0 : s1;
      bf16x8 af[MI], bfv[NJ];
#pragma unroll
      for (int i = 0; i < MI; ++i)
        af[i] = *reinterpret_cast<const bf16x8*>(&As[cur][(wm + i * 16 + lrow) * BK + ss]);
#pragma unroll
      for (int j = 0; j < NJ; ++j)
        bfv[j] = *reinterpret_cast<const bf16x8*>(&Bs[cur][(wn + j * 16 + lrow) * BK + ss]);
#pragma unroll
      for (int i = 0; i < MI; ++i)
#pragma unroll
        for (int j = 0; j < NJ; ++j)
          acc[i][j] = __builtin_amdgcn_mfma_f32_16x16x32_bf16(af[i], bfv[j], acc[i][j], 0, 0, 0);
    }
    __builtin_amdgcn_s_barrier();
    cur ^= 1;
  }

  float csum[NJ];
#pragma unroll
  for (int j = 0; j < NJ; ++j) csum[j] = 0.f;

#pragma unroll
  for (int i = 0; i < MI; ++i){
#pragma unroll
    for (int j = 0; j < NJ; ++j){
      int col = n0 + wn + j * 16 + lrow;
      float bv = (OM < 4 && bias) ? bias[col] : 0.f;
#pragma unroll
      for (int r = 0; r < 4; ++r){
        int row = m0 + wm + i * 16 + lg * 4 + r;
        float x = acc[i][j][r] + bv;
        if (OM == 1){
          if (col < 2048){ x = fast_sigmoid(x); csum[j] += x; }
          int which = col >> 10, cc = col & 1023, h = cc >> 6, d = cc & 63;
          int b = row >> 10, l = row & 1023;
          outB[(size_t)which * (2048ull * 1024) +
               (((size_t)(b * 16 + h)) * 1024 + l) * 64 + d] = f2bf(x);
        } else if (OM == 4){
          outF[((size_t)blockIdx.z * M + row) * N + col] = x;
        } else if (OM == 5){
          outB[((size_t)blockIdx.z * M + row) * N + col] = f2bf(x);
        } else {
          if (ACT == 2){
            float u = 0.7978845608f * (x + 0.044715f * x * x * x);
            float e = __expf(2.f * u);
            x = 0.5f * x * (2.f - 2.f / (e + 1.f));
          }
          outB[(size_t)row * N + col] = f2bf(x);
        }
      }
    }
  }
  // fused chunk-sums: 16 rows per thread (fixed chunk), one atomic per j-frag
  if (OM == 1){
#pragma unroll
    for (int j = 0; j < NJ; ++j){
      int col = n0 + wn + j * 16 + lrow;
      if (col < 2048){
        int which = col >> 10, cc = col & 1023, h = cc >> 6, d = cc & 63;
        int rowbase = m0 + wm;
        int bh = (rowbase >> 10) * 16 + h;
        int chunk = (rowbase & 1023) >> 6;
        float* dst = (which == 0) ? cqA : ckA;
        atomicAdd(&dst[((size_t)bh * 16 + chunk) * 64 + d], csum[j]);
      }
    }
  }
}

// ---------------- attention scalar pipeline (chunked Gram-tile form, bf16 in) ----
__global__ __launch_bounds__(256) void sink_tile(
    const u16* __restrict__ q, const u16* __restrict__ k,
    const float* __restrict__ ck, const float* __restrict__ cq,
    float* __restrict__ sink_in, float* __restrict__ src_out,
    float* __restrict__ cso, float* __restrict__ cqsi)
{
  int blk = blockIdx.x, bh = blk >> 4, c = blk & 15;
  int tid = threadIdx.x, lane = tid & 63, wave = tid >> 6;
  __shared__ float qT[64][65], kT[64][65], G[64][66];
  __shared__ float PK[64], PQ[64];
  __shared__ float rk[64], rq[64], crk[64], crq[64], siv[64], sov[64];
  __shared__ float rd[2][4][64];
  size_t base = ((size_t)bh * LSEQ + c * 64) * DHD;
  const u16* qb = q + base; const u16* kb = k + base;
  for (int c4 = tid; c4 < 1024; c4 += 256){
    int l = c4 >> 4, d0 = (c4 & 15) * 4;
    ushort4 qv = *reinterpret_cast<const ushort4*>(qb + c4 * 4);
    qT[d0+0][l] = bf2f(qv.x); qT[d0+1][l] = bf2f(qv.y);
    qT[d0+2][l] = bf2f(qv.z); qT[d0+3][l] = bf2f(qv.w);
    ushort4 kv = *reinterpret_cast<const ushort4*>(kb + c4 * 4);
    kT[d0+0][l] = bf2f(kv.x); kT[d0+1][l] = bf2f(kv.y);
    kT[d0+2][l] = bf2f(kv.z); kT[d0+3][l] = bf2f(kv.w);
  }
  if (tid < 64){
    float pk = 0.f, pq = 0.f;
    for (int cc = 0; cc < c; cc++){
      pk += ck[((size_t)bh * 16 + cc) * 64 + tid];
      pq += cq[((size_t)bh * 16 + cc) * 64 + tid];
    }
    PK[tid] = pk; PQ[tid] = pq;
  }
  __syncthreads();
  float sumPK = wred64(PK[lane]);
  float sumPQ = wred64(PQ[lane]);
  {
    int l = lane, g = wave;
    float qrow[64];
#pragma unroll
    for (int d = 0; d < 64; d++) qrow[d] = qT[d][l];
    float p[16] = {};
    for (int d = 0; d < 64; d++){
      float qv = qrow[d];
#pragma unroll
      for (int j4 = 0; j4 < 4; j4++){
        float4 kk = *reinterpret_cast<const float4*>(&kT[d][g * 16 + j4 * 4]);
        p[j4*4+0] += qv * kk.x; p[j4*4+1] += qv * kk.y;
        p[j4*4+2] += qv * kk.z; p[j4*4+3] += qv * kk.w;
      }
    }
#pragma unroll
    for (int jj = 0; jj < 16; jj++) G[l][g * 16 + jj] = p[jj];
  }
  {
    float pk_ = 0.f, pq_ = 0.f;
#pragma unroll
    for (int d = wave * 16; d < wave * 16 + 16; d++){
      pk_ += kT[d][lane]; pq_ += qT[d][lane];
    }
    rd[0][wave][lane] = pk_; rd[1][wave][lane] = pq_;
  }
  __syncthreads();
  if (tid < 64){
    rk[tid] = rd[0][0][tid] + rd[0][1][tid] + rd[0][2][tid] + rd[0][3][tid];
    rq[tid] = rd[1][0][tid] + rd[1][1][tid] + rd[1][2][tid] + rd[1][3][tid];
  }
  __syncthreads();
  if (wave == 0)      crk[lane] = wscan64(rk[lane], lane);
  else if (wave == 1) crq[lane] = wscan64(rq[lane], lane);
  __syncthreads();
  {
    int l = lane;
    float p1 = 0.f, p2 = 0.f;
#pragma unroll
    for (int j = wave * 16; j < wave * 16 + 16; j++){
      float g1 = (j <= l) ? G[l][j] : 0.f;
      p1 += g1 + qT[j][l] * PK[j];
      float g2 = (j <= l) ? G[j][l] : 0.f;
      p2 += g2 + kT[j][l] * PQ[j];
    }
    rd[0][wave][l] = p1; rd[1][wave][l] = p2;
  }
  __syncthreads();
  const float EPS2 = 64.f * EPS * EPS;
  if (tid < 64){
    int l = tid;
    float s1 = rd[0][0][l] + rd[0][1][l] + rd[0][2][l] + rd[0][3][l];
    float s2 = rd[1][0][l] + rd[1][1][l] + rd[1][2][l] + rd[1][3][l];
    int L = c * 64 + l; float nrm = (float)(L + 1);
    float den1 = s1 + EPS * rq[l] + EPS * (sumPK + crk[l]) + EPS2;
    float den2 = s2 + EPS * rk[l] + EPS * (sumPQ + crq[l]) + EPS2;
    float si_ = nrm / den1, so_ = nrm / den2;
    sink_in[(size_t)bh * LSEQ + L] = si_;
    src_out[(size_t)bh * LSEQ + L] = so_;
    siv[l] = si_; sov[l] = so_;
  }
  __syncthreads();
  float s1 = 0.f, s2 = 0.f;
  for (int l = wave * 16; l < wave * 16 + 16; l++){
    s1 += sov[l] * kT[lane][l];
    s2 += siv[l] * qT[lane][l];
  }
  rd[0][wave][lane] = s1; rd[1][wave][lane] = s2;
  __syncthreads();
  if (wave == 0){
    cso [(size_t)blk * 64 + lane] = rd[0][0][lane] + rd[0][1][lane] + rd[0][2][lane] + rd[0][3][lane];
    cqsi[(size_t)blk * 64 + lane] = rd[1][0][lane] + rd[1][1][lane] + rd[1][2][lane] + rd[1][3][lane];
  }
}

__global__ __launch_bounds__(256) void cons_tile(
    const u16* __restrict__ q, const u16* __restrict__ k,
    const float* __restrict__ cso, const float* __restrict__ cqsi,
    const float* __restrict__ sink_in, const float* __restrict__ src_out,
    float* __restrict__ sa, float* __restrict__ ebuf)
{
  int blk = blockIdx.x, bh = blk >> 4, c = blk & 15;
  int tid = threadIdx.x, lane = tid & 63, wave = tid >> 6;
  __shared__ float qT[64][65], kT[64][65], G[64][66];
  __shared__ float PKso[64], PQsi[64];
  __shared__ float rk[64], rq[64], cwrk[64], cwrq[64], siv[64], sov[64];
  __shared__ float rd[2][4][64];
  size_t base = ((size_t)bh * LSEQ + c * 64) * DHD;
  const u16* qb = q + base; const u16* kb = k + base;
  for (int c4 = tid; c4 < 1024; c4 += 256){
    int l = c4 >> 4, d0 = (c4 & 15) * 4;
    ushort4 qv = *reinterpret_cast<const ushort4*>(qb + c4 * 4);
    qT[d0+0][l] = bf2f(qv.x); qT[d0+1][l] = bf2f(qv.y);
    qT[d0+2][l] = bf2f(qv.z); qT[d0+3][l] = bf2f(qv.w);
    ushort4 kv = *reinterpret_cast<const ushort4*>(kb + c4 * 4);
    kT[d0+0][l] = bf2f(kv.x); kT[d0+1][l] = bf2f(kv.y);
    kT[d0+2][l] = bf2f(kv.z); kT[d0+3][l] = bf2f(kv.w);
  }
  if (tid < 64){
    float pk = 0.f, pq = 0.f;
    for (int cc = 0; cc < c; cc++){
      pk += cso [((size_t)bh * 16 + cc) * 64 + tid];
      pq += cqsi[((size_t)bh * 16 + cc) * 64 + tid];
    }
    PKso[tid] = pk; PQsi[tid] = pq;
  } else if (tid < 128){
    int l = tid - 64;
    sov[l] = src_out[(size_t)bh * LSEQ + c * 64 + l];
    siv[l] = sink_in[(size_t)bh * LSEQ + c * 64 + l];
  }
  __syncthreads();
  float sumPKso = wred64(PKso[lane]);
  float sumPQsi = wred64(PQsi[lane]);
  {
    int l = lane, g = wave;
    float qrow[64];
#pragma unroll
    for (int d = 0; d < 64; d++) qrow[d] = qT[d][l];
    float p[16] = {};
    for (int d = 0; d < 64; d++){
      float qv = qrow[d];
#pragma unroll
      for (int j4 = 0; j4 < 4; j4++){
        float4 kk = *reinterpret_cast<const float4*>(&kT[d][g * 16 + j4 * 4]);
        p[j4*4+0] += qv * kk.x; p[j4*4+1] += qv * kk.y;
        p[j4*4+2] += qv * kk.z; p[j4*4+3] += qv * kk.w;
      }
    }
#pragma unroll
    for (int jj = 0; jj < 16; jj++) G[l][g * 16 + jj] = p[jj];
  }
  {
    float pk_ = 0.f, pq_ = 0.f;
#pragma unroll
    for (int d = wave * 16; d < wave * 16 + 16; d++){
      pk_ += kT[d][lane]; pq_ += qT[d][lane];
    }
    rd[0][wave][lane] = pk_; rd[1][wave][lane] = pq_;
  }
  __syncthreads();
  if (tid < 64){
    rk[tid] = rd[0][0][tid] + rd[0][1][tid] + rd[0][2][tid] + rd[0][3][tid];
    rq[tid] = rd[1][0][tid] + rd[1][1][tid] + rd[1][2][tid] + rd[1][3][tid];
  }
  __syncthreads();
  if (wave == 0)      cwrk[lane] = wscan64(sov[lane] * rk[lane], lane);
  else if (wave == 1) cwrq[lane] = wscan64(siv[lane] * rq[lane], lane);
  __syncthreads();
  {
    int l = lane;
    float p3 = 0.f, p4 = 0.f;
#pragma unroll
    for (int j = wave * 16; j < wave * 16 + 16; j++){
      float g3 = (j <= l) ? sov[j] * G[l][j] : 0.f;
      p3 += g3 + qT[j][l] * PKso[j];
      float g4 = (j <= l) ? siv[j] * G[j][l] : 0.f;
      p4 += g4 + kT[j][l] * PQsi[j];
    }
    rd[0][wave][l] = p3; rd[1][wave][l] = p4;
  }
  __syncthreads();
  const float EPS2 = 64.f * EPS * EPS;
  if (tid < 64){
    int l = tid;
    float s3 = rd[0][0][l] + rd[0][1][l] + rd[0][2][l] + rd[0][3][l];
    float s4 = rd[1][0][l] + rd[1][1][l] + rd[1][2][l] + rd[1][3][l];
    int L = c * 64 + l; float nrm = (float)(L + 1);
    float cs = (s3 + EPS * rq[l] + EPS * (sumPKso + cwrk[l]) + EPS2) / nrm;
    sa[(size_t)bh * LSEQ + L] = fast_sigmoid(cs);
    float c2 = (s4 + EPS * rk[l] + EPS * (sumPQsi + cwrq[l]) + EPS2) / nrm;
    c2 = fminf(1.f, fmaxf(-1.f, c2));
    ebuf[(size_t)bh * LSEQ + L] = __expf(c2);
  }
}

// src_comp = e / cumsum(e) * (l+1)
__global__ __launch_bounds__(64) void srccomp_kernel(const float* __restrict__ ebuf, float* __restrict__ sc){
  int bh = blockIdx.x; int lane = threadIdx.x;
  const float* eb = ebuf + (size_t)bh * LSEQ;
  float loc[16]; float s = 0.f;
#pragma unroll
  for (int i = 0; i < 16; i++){ loc[i] = eb[lane * 16 + i]; s += loc[i]; }
  float run = wscan64(s, lane);
  float acc = run - s;
  float* scb = sc + (size_t)bh * LSEQ;
#pragma unroll
  for (int i = 0; i < 16; i++){
    acc += loc[i];
    scb[lane * 16 + i] = loc[i] / acc * (float)(lane * 16 + i + 1);
  }
}

// ---------------- chunked causal linear attention (scale fused in, bf16 S) ------
__global__ __launch_bounds__(256) void phaseA(const u16* __restrict__ k, const u16* __restrict__ v,
                                              const float* __restrict__ sc, u16* __restrict__ S){
  int blk = blockIdx.x; int bh = blk >> 4, c = blk & 15;
  __shared__ float ks[64][68], vss[64][68];
  __shared__ float vc[64];
  int tid = threadIdx.x;
  size_t base = ((size_t)bh * LSEQ + c * 64) * DHD;
  const u16* kb = k + base; const u16* vb = v + base;
  if (tid < 64) vc[tid] = sc[(size_t)bh * LSEQ + c * 64 + tid];
  __syncthreads();
  for (int c4 = tid; c4 < 1024; c4 += 256){
    int l = c4 >> 4, d0 = (c4 & 15) * 4;
    ushort4 kv = *reinterpret_cast<const ushort4*>(kb + c4 * 4);
    ks[l][d0+0] = bf2f(kv.x); ks[l][d0+1] = bf2f(kv.y);
    ks[l][d0+2] = bf2f(kv.z); ks[l][d0+3] = bf2f(kv.w);
    ushort4 vv = *reinterpret_cast<const ushort4*>(vb + c4 * 4);
    float w = vc[l];
    vss[l][d0+0] = bf2f(vv.x) * w; vss[l][d0+1] = bf2f(vv.y) * w;
    vss[l][d0+2] = bf2f(vv.z) * w; vss[l][d0+3] = bf2f(vv.w) * w;
  }
  __syncthreads();
  if (c == 15) return;                 // chunk 15's S is never read
  int m = tid >> 2, dg = tid & 3;
  float acc[16] = {};
  for (int l = 0; l < 64; l++){
    float vm = vss[l][m];
#pragma unroll
    for (int d4 = 0; d4 < 4; d4++){
      float4 kk = *reinterpret_cast<const float4*>(&ks[l][dg * 16 + d4 * 4]);
      acc[d4*4+0] += vm * kk.x; acc[d4*4+1] += vm * kk.y;
      acc[d4*4+2] += vm * kk.z; acc[d4*4+3] += vm * kk.w;
    }
  }
  u16* Sb = S + (size_t)blk * 4096 + m * 64 + dg * 16;
#pragma unroll
  for (int d4 = 0; d4 < 4; d4++){
    ushort4 o;
    o.x = f2bf(acc[d4*4+0]); o.y = f2bf(acc[d4*4+1]);
    o.z = f2bf(acc[d4*4+2]); o.w = f2bf(acc[d4*4+3]);
    *reinterpret_cast<ushort4*>(Sb + d4 * 4) = o;
  }
}

// phase C with inlined KV-prefix (bf16 S); Ps overlays qsT (qrow cached first)
__global__ __launch_bounds__(256) void phaseC(const u16* __restrict__ q, const u16* __restrict__ k,
                                              const u16* __restrict__ v, const u16* __restrict__ S,
                                              const float* __restrict__ sink_in, const float* __restrict__ sc,
                                              const float* __restrict__ sa, u16* __restrict__ x){
  int blk = blockIdx.x; int bh = blk >> 4, c = blk & 15;
  int b = bh >> 4, h = bh & 15;
  __shared__ float qp[64][66];      // qsT[d][l] first, then Ps[l][j]
  __shared__ float kT[64][68];
  __shared__ float vss[64][68];
  __shared__ float kvs[64][68];
  __shared__ float qc[64], vc[64];
  int tid = threadIdx.x;
  size_t base = ((size_t)bh * LSEQ + c * 64) * DHD;
  const u16* qb = q + base; const u16* kb = k + base; const u16* vb = v + base;
  if (tid < 64){
    int L = c * 64 + tid;
    qc[tid] = sink_in[(size_t)bh * LSEQ + L] / (float)(L + 1);
    vc[tid] = sc[(size_t)bh * LSEQ + L];
  }
  // KV prefix: accumulate 16 bf16 elements per thread over chunks 0..c-1
  {
    int off16 = tid * 16;
    float accp[16] = {};
    for (int cc = 0; cc < c; cc++){
      size_t idx = ((size_t)bh * 16 + cc) * 4096 + off16;
#pragma unroll
      for (int t4 = 0; t4 < 4; t4++){
        ushort4 sv = *reinterpret_cast<const ushort4*>(S + idx + t4 * 4);
        accp[t4*4+0] += bf2f(sv.x); accp[t4*4+1] += bf2f(sv.y);
        accp[t4*4+2] += bf2f(sv.z); accp[t4*4+3] += bf2f(sv.w);
      }
    }
#pragma unroll
    for (int e = 0; e < 16; e++){
      int j = off16 + e;
      kvs[j >> 6][j & 63] = accp[e];
    }
  }
  __syncthreads();
  for (int c4 = tid; c4 < 1024; c4 += 256){
    int l = c4 >> 4, d0 = (c4 & 15) * 4;
    float qw = qc[l], vw = vc[l];
    ushort4 qv = *reinterpret_cast<const ushort4*>(qb + c4 * 4);
    qp[d0+0][l] = bf2f(qv.x) * qw; qp[d0+1][l] = bf2f(qv.y) * qw;
    qp[d0+2][l] = bf2f(qv.z) * qw; qp[d0+3][l] = bf2f(qv.w) * qw;
    ushort4 kv4 = *reinterpret_cast<const ushort4*>(kb + c4 * 4);
    kT[d0+0][l] = bf2f(kv4.x); kT[d0+1][l] = bf2f(kv4.y);
    kT[d0+2][l] = bf2f(kv4.z); kT[d0+3][l] = bf2f(kv4.w);
    ushort4 vv = *reinterpret_cast<const ushort4*>(vb + c4 * 4);
    vss[l][d0+0] = bf2f(vv.x) * vw; vss[l][d0+1] = bf2f(vv.y) * vw;
    vss[l][d0+2] = bf2f(vv.z) * vw; vss[l][d0+3] = bf2f(vv.w) * vw;
  }
  __syncthreads();
  int l = tid & 63, g = tid >> 6;
  float qrow[64];
#pragma unroll
  for (int d = 0; d < 64; d++) qrow[d] = qp[d][l];
  __syncthreads();

  float p[16] = {};
  for (int d = 0; d < 64; d++){
    float qv = qrow[d];
#pragma unroll
    for (int j4 = 0; j4 < 4; j4++){
      float4 kk = *reinterpret_cast<const float4*>(&kT[d][g * 16 + j4 * 4]);
      p[j4*4+0] += qv * kk.x; p[j4*4+1] += qv * kk.y;
      p[j4*4+2] += qv * kk.z; p[j4*4+3] += qv * kk.w;
    }
  }
#pragma unroll
  for (int jj = 0; jj < 16; jj++){
    int j = g * 16 + jj;
    qp[l][j] = (j <= l) ? p[jj] : 0.f;
  }
  __syncthreads();

  float acc[16];
#pragma unroll
  for (int mm = 0; mm < 16; mm++){
    float a = 0.f;
#pragma unroll
    for (int d4 = 0; d4 < 16; d4++){
      float4 kv4 = *reinterpret_cast<const float4*>(&kvs[g * 16 + mm][d4 * 4]);
      a += qrow[d4*4+0]*kv4.x + qrow[d4*4+1]*kv4.y + qrow[d4*4+2]*kv4.z + qrow[d4*4+3]*kv4.w;
    }
    acc[mm] = a;
  }
  for (int j = 0; j < 64; j++){
    float pv = qp[l][j];
#pragma unroll
    for (int m4 = 0; m4 < 4; m4++){
      float4 vv = *reinterpret_cast<const float4*>(&vss[j][g * 16 + m4 * 4]);
      acc[m4*4+0] += pv * vv.x; acc[m4*4+1] += pv * vv.y;
      acc[m4*4+2] += pv * vv.z; acc[m4*4+3] += pv * vv.w;
    }
  }
  float sav = sa[(size_t)bh * LSEQ + c * 64 + l];
  u16* xo = x + ((size_t)(b * 1024 + c * 64 + l)) * 1024 + h * 64 + g * 16;
#pragma unroll
  for (int mm = 0; mm < 16; mm++) xo[mm] = f2bf(acc[mm] * sav);
}

// ---------------- fused layernorms ----------------
// LN over (bf16 p0+p1 + bias + resid); emits f32 + bf16 (Wo split-K + LN1)
__global__ __launch_bounds__(256) void ln_fused2b(
    const u16* __restrict__ p0, const u16* __restrict__ p1,
    const float* __restrict__ resid, const float* __restrict__ bias,
    const float* __restrict__ g, const float* __restrict__ b,
    float* __restrict__ out, u16* __restrict__ outbf){
  int row = blockIdx.x; int tid = threadIdx.x;
  int lane = tid & 63, wave = tid >> 6;
  size_t off = (size_t)row * 1024 + tid * 4;
  ushort4 a0 = *reinterpret_cast<const ushort4*>(p0 + off);
  ushort4 a1 = *reinterpret_cast<const ushort4*>(p1 + off);
  float4 rr = *reinterpret_cast<const float4*>(resid + off);
  float4 bb = *reinterpret_cast<const float4*>(bias + tid * 4);
  float4 v = make_float4(bf2f(a0.x) + bf2f(a1.x) + rr.x + bb.x,
                         bf2f(a0.y) + bf2f(a1.y) + rr.y + bb.y,
                         bf2f(a0.z) + bf2f(a1.z) + rr.z + bb.z,
                         bf2f(a0.w) + bf2f(a1.w) + rr.w + bb.w);
  float s = v.x + v.y + v.z + v.w;
  float s2 = v.x*v.x + v.y*v.y + v.z*v.z + v.w*v.w;
  s = wred64(s); s2 = wred64(s2);
  __shared__ float red[2][4];
  if (lane == 0){ red[0][wave] = s; red[1][wave] = s2; }
  __syncthreads();
  float S = red[0][0] + red[0][1] + red[0][2] + red[0][3];
  float S2 = red[1][0] + red[1][1] + red[1][2] + red[1][3];
  float mean = S * (1.f / 1024.f);
  float var = S2 * (1.f / 1024.f) - mean * mean;
  float inv = rsqrtf(var + 1e-5f);
  float4 gv = *reinterpret_cast<const float4*>(g + tid * 4);
  float4 bv = *reinterpret_cast<const float4*>(b + tid * 4);
  float y0 = (v.x - mean) * inv * gv.x + bv.x;
  float y1 = (v.y - mean) * inv * gv.y + bv.y;
  float y2 = (v.z - mean) * inv * gv.z + bv.z;
  float y3 = (v.w - mean) * inv * gv.w + bv.w;
  *reinterpret_cast<float4*>(out + off) = make_float4(y0, y1, y2, y3);
  ushort4 o; o.x = f2bf(y0); o.y = f2bf(y1); o.z = f2bf(y2); o.w = f2bf(y3);
  *reinterpret_cast<ushort4*>(outbf + off) = o;
}

// LN over (bf16 p0..p3 + bias + resid) -> f32 out (FFN2 split-K4 combine + LN2)
__global__ __launch_bounds__(256) void ln_fused4b(
    const u16* __restrict__ p0, const u16* __restrict__ p1,
    const u16* __restrict__ p2, const u16* __restrict__ p3,
    const float* __restrict__ resid, const float* __restrict__ bias,
    const float* __restrict__ g, const float* __restrict__ b,
    float* __restrict__ out){
  int row = blockIdx.x; int tid = threadIdx.x;
  int lane = tid & 63, wave = tid >> 6;
  size_t off = (size_t)row * 1024 + tid * 4;
  ushort4 u0 = *reinterpret_cast<const ushort4*>(p0 + off);
  ushort4 u1 = *reinterpret_cast<const ushort4*>(p1 + off);
  ushort4 u2 = *reinterpret_cast<const ushort4*>(p2 + off);
  ushort4 u3 = *reinterpret_cast<const ushort4*>(p3 + off);
  float4 rr = *reinterpret_cast<const float4*>(resid + off);
  float4 bb = *reinterpret_cast<const float4*>(bias + tid * 4);
  float4 v = make_float4(
      bf2f(u0.x) + bf2f(u1.x) + bf2f(u2.x) + bf2f(u3.x) + rr.x + bb.x,
      bf2f(u0.y) + bf2f(u1.y) + bf2f(u2.y) + bf2f(u3.y) + rr.y + bb.y,
      bf2f(u0.z) + bf2f(u1.z) + bf2f(u2.z) + bf2f(u3.z) + rr.z + bb.z,
      bf2f(u0.w) + bf2f(u1.w) + bf2f(u2.w) + bf2f(u3.w) + rr.w + bb.w);
  float s = v.x + v.y + v.z + v.w;
  float s2 = v.x*v.x + v.y*v.y + v.z*v.z + v.w*v.w;
  s = wred64(s); s2 = wred64(s2);
  __shared__ float red[2][4];
  if (lane == 0){ red[0][wave] = s; red[1][wave] = s2; }
  __syncthreads();
  float S = red[0][0] + red[0][1] + red[0][2] + red[0][3];
  float S2 = red[1][0] + red[1][1] + red[1][2] + red[1][3];
  float mean = S * (1.f / 1024.f);
  float var = S2 * (1.f / 1024.f) - mean * mean;
  float inv = rsqrtf(var + 1e-5f);
  float4 gv = *reinterpret_cast<const float4*>(g + tid * 4);
  float4 bv = *reinterpret_cast<const float4*>(b + tid * 4);
  float y0 = (v.x - mean) * inv * gv.x + bv.x;
  float y1 = (v.y - mean) * inv * gv.y + bv.y;
  float y2 = (v.z - mean) * inv * gv.z + bv.z;
  float y3 = (v.w - mean) * inv * gv.w + bv.w;
  *reinterpret_cast<float4*>(out + off) = make_float4(y0, y1, y2, y3);
}

// ---------------- launch ----------------
extern "C" void kernel_launch(void* const* d_in, const int* in_sizes, int n_in,
                              void* d_out, int out_size, void* d_ws, size_t ws_size,
                              hipStream_t stream){
  (void)in_sizes; (void)n_in; (void)out_size; (void)ws_size;
  const float* inputs = (const float*)d_in[0];
  const float* Wq = (const float*)d_in[2];  const float* bq = (const float*)d_in[3];
  const float* Wk = (const float*)d_in[4];  const float* bk = (const float*)d_in[5];
  const float* Wv = (const float*)d_in[6];  const float* bv = (const float*)d_in[7];
  const float* Wo = (const float*)d_in[8];  const float* bo = (const float*)d_in[9];
  const float* ln1g = (const float*)d_in[10]; const float* ln1b = (const float*)d_in[11];
  const float* W1 = (const float*)d_in[12]; const float* b1 = (const float*)d_in[13];
  const float* W2 = (const float*)d_in[14]; const float* b2 = (const float*)d_in[15];
  const float* ln2g = (const float*)d_in[16]; const float* ln2b = (const float*)d_in[17];
  float* out = (float*)d_out;

  char* wsp = (char*)d_ws; size_t off = 0;
  auto alloc = [&](size_t bytes) -> void* {
    off = (off + 255) & ~(size_t)255;
    void* p = wsp + off; off += bytes; return p;
  };
  const size_t MD = (size_t)2048 * 1024;
  u16* Xbf    = (u16*)alloc(MD * 2);
  u16* WqkvT  = (u16*)alloc((size_t)3 * 1024 * 1024 * 2);
  u16* WoT    = (u16*)alloc((size_t)1024 * 1024 * 2);
  u16* W1T    = (u16*)alloc((size_t)4096 * 1024 * 2);
  u16* W2T    = (u16*)alloc((size_t)4096 * 1024 * 2);
  float* bqkv = (float*)alloc(3072 * 4);
  u16* qkvb   = (u16*)alloc(3 * MD * 2);     // bf16 q|k|v in [B,H,L,DH]
  u16* qb = qkvb; u16* kb = qkvb + MD; u16* vb = qkvb + 2 * MD;
  float* quad = (float*)alloc(4 * MD * 4);
  u16* Sbuf   = (u16*)quad;                  // bf16 S: 512 x 4096 x 2B = 4MB (slot 0 half)
  float* ckb  = (float*)alloc((size_t)512 * 64 * 4);   // contiguous with cqb
  float* cqb  = (float*)alloc((size_t)512 * 64 * 4);
  float* csob = (float*)alloc((size_t)512 * 64 * 4);
  float* cqsib= (float*)alloc((size_t)512 * 64 * 4);
  float* sink_in = (float*)alloc(NBH * LSEQ * 4);
  float* src_out = (float*)alloc(NBH * LSEQ * 4);
  float* sabuf   = (float*)alloc(NBH * LSEQ * 4);
  float* ebuf    = (float*)alloc(NBH * LSEQ * 4);
  float* scbuf   = (float*)alloc(NBH * LSEQ * 4);
  u16* xatt   = (u16*)alloc(MD * 2);
  u16* g1     = (u16*)alloc((size_t)2048 * 4096 * 2);
  // quad reuse: slot0 Sbuf(bf16,4MB) -> hbuf (f32 LN1 out, 8MB); slot1 hbf (bf16);
  // slots2-3: Wo bf16 partials (8MB) then FFN2 bf16 partials (16MB)
  float* hbuf  = quad;
  u16* hbf     = (u16*)(quad + MD);
  u16* wopart  = (u16*)(quad + 2 * MD);
  u16* partb   = (u16*)(quad + 2 * MD);

  // all prep in one launch (+64 blocks zeroing ckb||cqb)
  prep_all<<<14412, 256, 0, stream>>>(inputs, Xbf, Wq, Wk, Wv, Wo, WqkvT, WoT,
                                      W1, W2, W1T, W2T, bq, bk, bv, bqkv, ckb);

  // fused QKV projection (bf16 out) + chunk-sum atomics: BM=128,BN=64, grid 16x48
  gemm_mfma<128, 64, 0, 1><<<dim3(16, 48), 256, 0, stream>>>(
      Xbf, WqkvT, bqkv, nullptr, nullptr, qkvb, cqb, ckb, 2048, 3072, 1024);

  // attention scalars (chunked Gram-tile pipeline, bf16 inputs)
  sink_tile<<<512, 256, 0, stream>>>(qb, kb, ckb, cqb, sink_in, src_out, csob, cqsib);
  cons_tile<<<512, 256, 0, stream>>>(qb, kb, csob, cqsib, sink_in, src_out, sabuf, ebuf);
  srccomp_kernel<<<32, 64, 0, stream>>>(ebuf, scbuf);

  // chunked causal linear attention (scale fused; bf16 S; KV-prefix in phaseC)
  phaseA<<<512, 256, 0, stream>>>(kb, vb, scbuf, Sbuf);
  phaseC<<<512, 256, 0, stream>>>(qb, kb, vb, Sbuf, sink_in, scbuf, sabuf, xatt);

  // output projection: BM=128,BN=64, split-K=2, bf16 partials
  gemm_mfma<128, 64, 0, 5><<<dim3(16, 16, 2), 256, 0, stream>>>(
      xatt, WoT, nullptr, nullptr, nullptr, wopart, nullptr, nullptr, 2048, 1024, 1024);
  ln_fused2b<<<2048, 256, 0, stream>>>(wopart, wopart + MD, inputs, bo, ln1g, ln1b, hbuf, hbf);

  // FFN1: BM=128,BN=128 (fast gelu)
  gemm_mfma<128, 128, 2, 3><<<dim3(16, 32), 256, 0, stream>>>(
      hbf, W1T, b1, nullptr, nullptr, g1, nullptr, nullptr, 2048, 4096, 1024);
  // FFN2: BM=128,BN=128, split-K=4, bf16 partials
  gemm_mfma<128, 128, 0, 5><<<dim3(16, 8, 4), 256, 0, stream>>>(
      g1, W2T, nullptr, nullptr, nullptr, partb, nullptr, nullptr, 2048, 1024, 4096);
  ln_fused4b<<<2048, 256, 0, stream>>>(partb, partb + MD, partb + 2 * MD, partb + 3 * MD,
                                       hbuf, b2, ln2g, ln2b, out);
}